// Round 10
// baseline (1175.694 us; speedup 1.0000x reference)
//
#include <hip/hip_runtime.h>
#include <math.h>

// ---------------------------------------------------------------------------
// Round 9->10: revert to round-7 dataflow (striped sexp -> P, single PV,
// fold+p2cl), with attention GEMMs ported to MX-fp8 (e4m3, scale=1.0,
// mfma_scale_f32_16x16x128_f8f6f4, 2x MFMA rate, half staging bytes).
// P stored full as fp8 (85 MB) -> PV is ONE dispatch, K=9216.
// Convs unchanged (bf16 MFMA). Workspace peak ~169.6 MB (< 180.5 safe).
// ---------------------------------------------------------------------------

typedef unsigned short u16;
typedef unsigned char u8;
typedef short short4v __attribute__((ext_vector_type(4)));
typedef short short8v __attribute__((ext_vector_type(8)));
typedef float f32x4 __attribute__((ext_vector_type(4)));
typedef int i32x4 __attribute__((ext_vector_type(4)));
typedef int i32x8 __attribute__((ext_vector_type(8)));

__device__ __forceinline__ u16 f2bf(float f) {
    unsigned u = __float_as_uint(f);
    return (u16)((u + 0x7FFF + ((u >> 16) & 1)) >> 16);
}
__device__ __forceinline__ float bf2f(u16 h) {
    return __uint_as_float(((unsigned)h) << 16);
}
// f32 -> fp8 e4m3fn (OCP), RNE, saturate to ±448
__device__ __forceinline__ u8 f2e4m3(float f) {
    unsigned u = __float_as_uint(f);
    unsigned s = (u >> 24) & 0x80u;
    unsigned a = u & 0x7FFFFFFFu;
    if (a >= 0x43E00000u) return (u8)(s | 0x7Eu);        // >=448 or NaN
    int e = (int)(a >> 23) - 127;
    if (e >= -6) {
        unsigned keep = (a >> 20) & 7u;
        unsigned rem  = a & 0xFFFFFu;
        keep += (rem > 0x80000u) || (rem == 0x80000u && (keep & 1u));
        unsigned e4 = (unsigned)(e + 7);
        if (keep == 8u) { keep = 0u; ++e4; }
        if (e4 >= 15u && keep >= 7u) return (u8)(s | 0x7Eu);
        return (u8)(s | (e4 << 3) | keep);
    }
    float q = __uint_as_float(a) * 512.f;                 // denormal: units 2^-9
    int m = (int)rintf(q);
    if (m >= 8) return (u8)(s | 0x08u);
    return (u8)(s | (unsigned)m);
}

#define GLOAD16(g, l) __builtin_amdgcn_global_load_lds(                      \
    (const __attribute__((address_space(1))) void*)(g),                      \
    (__attribute__((address_space(3))) void*)(l), 16, 0, 0)

#define MFMA_MX(a, b, c) __builtin_amdgcn_mfma_scale_f32_16x16x128_f8f6f4(   \
    (a), (b), (c), 0, 0, 0, 127, 0, 127)

// frag read: 32 contiguous k-bytes of row, via two XOR-swizzled 16B chunks
__device__ __forceinline__ i32x8 ld_frag8(const u8* base, int row, int kg) {
    int sw = (row & 7) << 4;
    const char* p = (const char*)base + row * 128;
    i32x4 lo = *(const i32x4*)(p + ((kg * 32)      ^ sw));
    i32x4 hi = *(const i32x4*)(p + ((kg * 32 + 16) ^ sw));
    i32x8 r;
    r[0] = lo[0]; r[1] = lo[1]; r[2] = lo[2]; r[3] = lo[3];
    r[4] = hi[0]; r[5] = hi[1]; r[6] = hi[2]; r[7] = hi[3];
    return r;
}

// ---------------- x -> channels-last bf16 ic4 (for conv1 MFMA) --------------
__global__ void x4cl_kernel(const float* __restrict__ x, u16* __restrict__ out)
{
    int i = blockIdx.x * 256 + threadIdx.x;
    if (i >= 589824) return;
    u16 v[4];
    v[0] = f2bf(x[i]);
    v[1] = f2bf(x[589824 + i]);
    v[2] = f2bf(x[1179648 + i]);
    v[3] = 0;
    *(short4v*)(out + (size_t)i * 4) = *(short4v*)v;
}

__global__ void pack_w1_kernel(const float* __restrict__ w, u16* __restrict__ wp)
{
    int i = blockIdx.x * 256 + threadIdx.x;
    if (i >= 4096) return;
    int oc = i >> 7, k = i & 127;
    int tap = k >> 2, ic = k & 3;
    u16 v = 0;
    if (tap < 25 && ic < 3) v = f2bf(w[oc * 75 + ic * 25 + tap]);
    wp[i] = v;
}

// ---------------- conv1 MFMA: 3->32, 5x5, s1, reflect pad2, ELU -------------
__global__ __launch_bounds__(256)
void conv1_mfma_kernel(const u16* __restrict__ x4, const u16* __restrict__ wp1,
                       const float* __restrict__ bias, u16* __restrict__ out)
{
    __shared__ __align__(16) u16 sIn[12 * 20 * 4];
    const int tid = threadIdx.x;
    const int lane = tid & 63;
    const int w = tid >> 6;
    const int lm = lane & 15;
    const int lk = lane >> 4;
    const int oy0 = blockIdx.y * 8, ox0 = blockIdx.x * 16;

    for (int u = tid; u < 240; u += 256) {
        int yt = u / 20, xt = u - yt * 20;
        int gy = oy0 - 2 + yt; gy = gy < 0 ? -gy : (gy >= 768 ? 1534 - gy : gy);
        int gx = ox0 - 2 + xt; gx = gx < 0 ? -gx : (gx >= 768 ? 1534 - gx : gx);
        *(short4v*)(sIn + u * 4) = *(const short4v*)(x4 + ((size_t)gy * 768 + gx) * 4);
    }
    int aoff[4][2];
#pragma unroll
    for (int ks = 0; ks < 4; ++ks) {
        int t0 = ks * 8 + lk * 2;
        int t1 = t0 + 1;
        if (t0 > 24) t0 = 24;
        if (t1 > 24) t1 = 24;
        int dy0 = t0 / 5, dx0 = t0 - 5 * dy0;
        int dy1 = t1 / 5, dx1 = t1 - 5 * dy1;
        aoff[ks][0] = (dy0 * 20 + dx0 + lm) * 4;
        aoff[ks][1] = (dy1 * 20 + dx1 + lm) * 4;
    }
    __syncthreads();

    f32x4 acc[2][2];
#pragma unroll
    for (int i = 0; i < 2; ++i)
#pragma unroll
        for (int j = 0; j < 2; ++j) acc[i][j] = (f32x4){0.f, 0.f, 0.f, 0.f};

#pragma unroll
    for (int ks = 0; ks < 4; ++ks) {
        short8v a[2], b[2];
#pragma unroll
        for (int fm = 0; fm < 2; ++fm) {
            int base = (w * 2 + fm) * 80;
            short4v lo = *(const short4v*)(sIn + base + aoff[ks][0]);
            short4v hi = *(const short4v*)(sIn + base + aoff[ks][1]);
            short8v av;
            av[0] = lo[0]; av[1] = lo[1]; av[2] = lo[2]; av[3] = lo[3];
            av[4] = hi[0]; av[5] = hi[1]; av[6] = hi[2]; av[7] = hi[3];
            a[fm] = av;
        }
#pragma unroll
        for (int fn = 0; fn < 2; ++fn)
            b[fn] = *(const short8v*)(wp1 + (size_t)(fn * 16 + lm) * 128 + ks * 32 + lk * 8);
#pragma unroll
        for (int fm = 0; fm < 2; ++fm)
#pragma unroll
            for (int fn = 0; fn < 2; ++fn)
                acc[fm][fn] = __builtin_amdgcn_mfma_f32_16x16x32_bf16(
                    a[fm], b[fn], acc[fm][fn], 0, 0, 0);
    }

#pragma unroll
    for (int fm = 0; fm < 2; ++fm) {
        int gy = oy0 + w * 2 + fm;
#pragma unroll
        for (int fn = 0; fn < 2; ++fn) {
            int oc = fn * 16 + lm;
            float bv = bias[oc];
#pragma unroll
            for (int i = 0; i < 4; ++i) {
                int xx = lk * 4 + i;
                float v = acc[fm][fn][i] + bv;
                v = v > 0.f ? v : expm1f(v);
                out[((size_t)gy * 768 + ox0 + xx) * 32 + oc] = f2bf(v);
            }
        }
    }
}

// ---------------- weight prepack ----------------
__global__ void pack_w_kernel(const float* __restrict__ w, u16* __restrict__ wp,
                              int OC, int IC)
{
    int idx = blockIdx.x * 256 + threadIdx.x;
    if (idx >= OC * 9 * IC) return;
    int oc = idx / (9 * IC);
    int r  = idx - oc * 9 * IC;
    int tap = r / IC;
    int ic  = r - tap * IC;
    wp[idx] = f2bf(w[((size_t)oc * IC + ic) * 9 + tap]);
}

// ---------------- MFMA implicit-GEMM conv (3x3, reflect pad 1) --------------
template<int FM, int FN, int NWM, int NWN, int S, int IC, int ICC, int ACT, int OUTF32>
__global__ __launch_bounds__(256)
void mfma_conv_kernel(const u16* __restrict__ in, const u16* __restrict__ wgtP,
                      const float* __restrict__ bias, void* __restrict__ out,
                      int H, int W, int Ho, int Wo, int OC)
{
    constexpr int TY = 7 * S + 3;
    constexpr int TX = 15 * S + 3;
    constexpr int NSLOT = ICC / 8;
    constexpr int SWMSK = NSLOT - 1;
    constexpr int KTOT = 9 * IC;
    __shared__ __align__(16) u16 sIn[TY * TX * ICC];

    const int tid  = threadIdx.x;
    const int lane = tid & 63;
    const int wid  = tid >> 6;
    const int wmi  = wid / NWN;
    const int wni  = wid % NWN;
    const int lm   = lane & 15;
    const int lk   = lane >> 4;
    const int noff = blockIdx.z * (NWN * FN * 16);

    f32x4 acc[FM][FN];
#pragma unroll
    for (int i = 0; i < FM; ++i)
#pragma unroll
        for (int j = 0; j < FN; ++j) acc[i][j] = (f32x4){0.f, 0.f, 0.f, 0.f};

    const int iy0 = blockIdx.y * 8 * S - 1;
    const int ix0 = blockIdx.x * 16 * S - 1;

    for (int c0 = 0; c0 < IC; c0 += ICC) {
        if (c0) __syncthreads();
        for (int u = tid; u < TY * TX * NSLOT; u += 256) {
            int yt = u / (TX * NSLOT);
            int r  = u - yt * (TX * NSLOT);
            int xt = r / NSLOT;
            int sl = r - xt * NSLOT;
            int gy = iy0 + yt; gy = gy < 0 ? -gy : (gy >= H ? 2 * H - 2 - gy : gy);
            int gx = ix0 + xt; gx = gx < 0 ? -gx : (gx >= W ? 2 * W - 2 - gx : gx);
            *(short8v*)((char*)sIn + (size_t)((yt * TX + xt) * NSLOT + (sl ^ (xt & SWMSK))) * 16) =
                *(const short8v*)(in + ((size_t)gy * W + gx) * IC + c0 + sl * 8);
        }
        __syncthreads();
#pragma unroll
        for (int tap = 0; tap < 9; ++tap) {
            const int dy = tap / 3, dx = tap % 3;
#pragma unroll
            for (int icw = 0; icw < ICC / 32; ++icw) {
                short8v a[FM], b[FN];
#pragma unroll
                for (int fm = 0; fm < FM; ++fm) {
                    int yt = (wmi * FM + fm) * S + dy;
                    int xt = lm * S + dx;
                    a[fm] = *(const short8v*)((const char*)sIn +
                        (size_t)((yt * TX + xt) * NSLOT + ((icw * 4 + lk) ^ (xt & SWMSK))) * 16);
                }
#pragma unroll
                for (int fn = 0; fn < FN; ++fn) {
                    int n = noff + wni * FN * 16 + fn * 16 + lm;
                    b[fn] = *(const short8v*)(wgtP + (size_t)n * KTOT + tap * IC + c0 + icw * 32 + lk * 8);
                }
#pragma unroll
                for (int fm = 0; fm < FM; ++fm)
#pragma unroll
                    for (int fn = 0; fn < FN; ++fn)
                        acc[fm][fn] = __builtin_amdgcn_mfma_f32_16x16x32_bf16(
                            a[fm], b[fn], acc[fm][fn], 0, 0, 0);
            }
        }
    }

#pragma unroll
    for (int fm = 0; fm < FM; ++fm) {
        int y = blockIdx.y * 8 + wmi * FM + fm;
#pragma unroll
        for (int fn = 0; fn < FN; ++fn) {
            int oc = noff + wni * FN * 16 + fn * 16 + lm;
            float bv = bias[oc];
#pragma unroll
            for (int i = 0; i < 4; ++i) {
                int x = blockIdx.x * 16 + lk * 4 + i;
                float v = acc[fm][fn][i] + bv;
                if (ACT == 0) v = v > 0.f ? v : 0.f;
                else          v = v > 0.f ? v : expm1f(v);
                size_t o = ((size_t)y * Wo + x) * OC + oc;
                if (OUTF32) ((float*)out)[o] = v;
                else        ((u16*)out)[o]   = f2bf(v);
            }
        }
    }
}

// channels-last f32 [36864][128] -> planar f32 [128][36864]
__global__ __launch_bounds__(256)
void cl2p_kernel(const float* __restrict__ in, float* __restrict__ out)
{
    __shared__ float t[32][130];
    const int tid = threadIdx.x;
    const int p0 = blockIdx.x * 32;
#pragma unroll
    for (int j = 0; j < 16; ++j) {
        int idx = j * 256 + tid;
        int px = idx >> 7, c = idx & 127;
        t[px][c] = in[(size_t)(p0 + px) * 128 + c];
    }
    __syncthreads();
#pragma unroll
    for (int j = 0; j < 16; ++j) {
        int c = j * 8 + (tid >> 5);
        int px = tid & 31;
        out[(size_t)c * 36864 + p0 + px] = t[px][c];
    }
}

// planar f32 [128][36864] -> channels-last bf16 [36864][128]
__global__ __launch_bounds__(256)
void p2cl_kernel(const float* __restrict__ in, u16* __restrict__ out)
{
    __shared__ float t[32][130];
    const int tid = threadIdx.x;
    const int p0 = blockIdx.x * 32;
#pragma unroll
    for (int j = 0; j < 16; ++j) {
        int c = j * 8 + (tid >> 5);
        int px = tid & 31;
        t[px][c] = in[(size_t)c * 36864 + p0 + px];
    }
    __syncthreads();
#pragma unroll
    for (int j = 0; j < 16; ++j) {
        int idx = j * 256 + tid;
        int px = idx >> 7, c = idx & 127;
        out[(size_t)(p0 + px) * 128 + c] = f2bf(t[px][c]);
    }
}

// ---------------- patch builders: write fp8 e4m3 ----------------------------
__global__ void build_patches_T8(const u16* __restrict__ h6, const float* __restrict__ mask,
                                 u8* __restrict__ fgpT, u8* __restrict__ bgpT)
{
    int idx = blockIdx.x * 256 + threadIdx.x;   // p*1152 + k
    if (idx >= 9216 * 1152) return;
    int p = idx / 1152, k = idx - p * 1152;
    int y = p / 96, x = p - y * 96;
    int c = k / 9, t = k - c * 9;
    int dy = t / 3, dx = t - dy * 3;
    int sy = y + dy - 1, sx = x + dx - 1;
    float v = 0.f, vm = 0.f;
    if (sy >= 0 && sy < 96 && sx >= 0 && sx < 96) {
        v  = bf2f(h6[((size_t)(2 * sy) * 192 + 2 * sx) * 128 + c]);
        vm = v * mask[(size_t)(2 * sy) * 192 + 2 * sx];
    }
    bgpT[idx] = f2e4m3(v);
    fgpT[idx] = f2e4m3(vm);
}

__global__ void build_patches_K8(const u16* __restrict__ h6, const float* __restrict__ mask,
                                 u8* __restrict__ fgpK, u8* __restrict__ bgpK)
{
    int idx = blockIdx.x * 256 + threadIdx.x;   // k*9216 + q
    if (idx >= 9216 * 1152) return;
    int k = idx / 9216, q = idx - k * 9216;
    int y = q / 96, x = q - y * 96;
    int c = k / 9, t = k - c * 9;
    int dy = t / 3, dx = t - dy * 3;
    int sy = y + dy - 1, sx = x + dx - 1;
    float v = 0.f, vm = 0.f;
    if (sy >= 0 && sy < 96 && sx >= 0 && sx < 96) {
        v  = bf2f(h6[((size_t)(2 * sy) * 192 + 2 * sx) * 128 + c]);
        vm = v * mask[(size_t)(2 * sy) * 192 + 2 * sx];
    }
    bgpK[idx] = f2e4m3(v);
    fgpK[idx] = f2e4m3(vm);
}

// ---------------- sexp MX: S-tile (K=1152 fp8) -> exp -> fp8 P + rowsums ----
__global__ __launch_bounds__(256)
void sexp_mx_kernel(const u8* __restrict__ A, const u8* __restrict__ B,
                    u8* __restrict__ P8, int qs,
                    const float* __restrict__ scale_p,
                    float* __restrict__ rsP, int rcol0)
{
    __shared__ __align__(16) u8 As[128 * 128];
    __shared__ __align__(16) u8 Bs[128 * 128];
    const int tid  = threadIdx.x;
    const int wid  = tid >> 6;
    const int lane = tid & 63;
    const int wm = (wid >> 1) * 64;
    const int wn = (wid & 1) * 64;
    const size_t bm = (size_t)blockIdx.y * 128;
    const size_t bn = (size_t)blockIdx.x * 128;

    f32x4 acc[4][4];
#pragma unroll
    for (int i = 0; i < 4; ++i)
#pragma unroll
        for (int j = 0; j < 4; ++j)
            acc[i][j] = (f32x4){0.f, 0.f, 0.f, 0.f};

    const int lrow = lane >> 3;
    const int lcb  = ((lane & 7) << 4) ^ ((lrow & 7) << 4);
    const u8* gA = A + (bm + wid * 32 + lrow) * (size_t)1152 + lcb;
    const u8* gB = B + (bn + wid * 32 + lrow) * (size_t)1152 + lcb;
    u8* lA = As + (size_t)(wid * 32) * 128;
    u8* lB = Bs + (size_t)(wid * 32) * 128;
    const size_t rstep = (size_t)1152 * 8;
    const int lm = lane & 15, lk = lane >> 4;

    for (int k0 = 0; k0 < 1152; k0 += 128) {
        __syncthreads();
#pragma unroll
        for (int j = 0; j < 4; ++j) {
            GLOAD16(gA + j * rstep + k0, lA + j * 1024);
            GLOAD16(gB + j * rstep + k0, lB + j * 1024);
        }
        __syncthreads();
        i32x8 a[4], b[4];
#pragma unroll
        for (int f = 0; f < 4; ++f) {
            a[f] = ld_frag8(As, wm + f * 16 + lm, lk);
            b[f] = ld_frag8(Bs, wn + f * 16 + lm, lk);
        }
#pragma unroll
        for (int fm = 0; fm < 4; ++fm)
#pragma unroll
            for (int fn = 0; fn < 4; ++fn)
                acc[fm][fn] = MFMA_MX(a[fm], b[fn], acc[fm][fn]);
    }

    const float scale = *scale_p;
    float rloc[4][4];
#pragma unroll
    for (int fm = 0; fm < 4; ++fm)
#pragma unroll
        for (int i = 0; i < 4; ++i) rloc[fm][i] = 0.f;
#pragma unroll
    for (int fm = 0; fm < 4; ++fm)
#pragma unroll
        for (int fn = 0; fn < 4; ++fn)
#pragma unroll
            for (int i = 0; i < 4; ++i) {
                int r = wm + fm * 16 + ((lane >> 4) * 4) + i;
                int c = wn + fn * 16 + (lane & 15);
                float e = __expf(scale * acc[fm][fn][i]);
                P8[(bm + r) * (size_t)9216 + qs + bn + c] = f2e4m3(e);
                rloc[fm][i] += e;
            }
#pragma unroll
    for (int fm = 0; fm < 4; ++fm)
#pragma unroll
        for (int i = 0; i < 4; ++i) {
            float s = rloc[fm][i];
            s += __shfl_xor(s, 8, 64);
            s += __shfl_xor(s, 4, 64);
            s += __shfl_xor(s, 2, 64);
            s += __shfl_xor(s, 1, 64);
            if ((lane & 15) == 0)
                rsP[(bm + wm + fm * 16 + ((lane >> 4) * 4) + i) * 144 +
                    rcol0 + blockIdx.x * 2 + (wid & 1)] = s;
        }
}

// ---------------- PV MX: R2[c9][p] = sum_q bgpK8[c9][q] * P8[p][q] ----------
// 64x128 tile, single dispatch, K=9216. grid (72, 18).
__global__ __launch_bounds__(256)
void pv_mx_kernel(const u8* __restrict__ A, const u8* __restrict__ B,
                  float* __restrict__ outF)
{
    __shared__ __align__(16) u8 As[64 * 128];
    __shared__ __align__(16) u8 Bs[128 * 128];
    const int tid  = threadIdx.x;
    const int wid  = tid >> 6;
    const int lane = tid & 63;
    const int wm = (wid >> 1) * 32;
    const int wn = (wid & 1) * 64;
    const size_t bm = (size_t)blockIdx.y * 64;
    const size_t bn = (size_t)blockIdx.x * 128;

    f32x4 acc[2][4];
#pragma unroll
    for (int i = 0; i < 2; ++i)
#pragma unroll
        for (int j = 0; j < 4; ++j)
            acc[i][j] = (f32x4){0.f, 0.f, 0.f, 0.f};

    const int lrow = lane >> 3;
    const int lcb  = ((lane & 7) << 4) ^ ((lrow & 7) << 4);
    const u8* gA = A + (bm + wid * 16 + lrow) * (size_t)9216 + lcb;
    const u8* gB = B + (bn + wid * 32 + lrow) * (size_t)9216 + lcb;
    u8* lA = As + (size_t)(wid * 16) * 128;
    u8* lB = Bs + (size_t)(wid * 32) * 128;
    const size_t rstep = (size_t)9216 * 8;
    const int lm = lane & 15, lk = lane >> 4;

    for (int k0 = 0; k0 < 9216; k0 += 128) {
        __syncthreads();
#pragma unroll
        for (int j = 0; j < 2; ++j)
            GLOAD16(gA + j * rstep + k0, lA + j * 1024);
#pragma unroll
        for (int j = 0; j < 4; ++j)
            GLOAD16(gB + j * rstep + k0, lB + j * 1024);
        __syncthreads();
        i32x8 a[2], b[4];
#pragma unroll
        for (int f = 0; f < 2; ++f)
            a[f] = ld_frag8(As, wm + f * 16 + lm, lk);
#pragma unroll
        for (int f = 0; f < 4; ++f)
            b[f] = ld_frag8(Bs, wn + f * 16 + lm, lk);
#pragma unroll
        for (int fm = 0; fm < 2; ++fm)
#pragma unroll
            for (int fn = 0; fn < 4; ++fn)
                acc[fm][fn] = MFMA_MX(a[fm], b[fn], acc[fm][fn]);
    }

#pragma unroll
    for (int fm = 0; fm < 2; ++fm)
#pragma unroll
        for (int fn = 0; fn < 4; ++fn)
#pragma unroll
            for (int i = 0; i < 4; ++i) {
                int r = wm + fm * 16 + ((lane >> 4) * 4) + i;
                int c = wn + fn * 16 + (lane & 15);
                outF[(bm + r) * (size_t)9216 + bn + c] = acc[fm][fn][i];
            }
}

// ---------------- Gram MX: grid (9,9,8); z = pair*4 + splitK ----------------
__global__ __launch_bounds__(256)
void gram_mx_kernel(const u8* __restrict__ F, const u8* __restrict__ Bg,
                    float* __restrict__ GP)
{
    const u8* A = (blockIdx.z >> 2) ? Bg : F;
    const int split = blockIdx.z & 3;
    __shared__ __align__(16) u8 As[128 * 128];
    __shared__ __align__(16) u8 Bs[128 * 128];
    const int tid  = threadIdx.x;
    const int wid  = tid >> 6;
    const int lane = tid & 63;
    const int wm = (wid >> 1) * 64;
    const int wn = (wid & 1) * 64;
    const size_t bm = (size_t)blockIdx.y * 128;
    const size_t bn = (size_t)blockIdx.x * 128;

    f32x4 acc[4][4];
#pragma unroll
    for (int i = 0; i < 4; ++i)
#pragma unroll
        for (int j = 0; j < 4; ++j)
            acc[i][j] = (f32x4){0.f, 0.f, 0.f, 0.f};

    const int lrow = lane >> 3;
    const int lcb  = ((lane & 7) << 4) ^ ((lrow & 7) << 4);
    const u8* gR = A + (bm + wid * 32 + lrow) * (size_t)9216 + lcb;
    const u8* gC = A + (bn + wid * 32 + lrow) * (size_t)9216 + lcb;
    u8* lA = As + (size_t)(wid * 32) * 128;
    u8* lB = Bs + (size_t)(wid * 32) * 128;
    const size_t rstep = (size_t)9216 * 8;
    const int kbeg = split * 2304;
    const int lm = lane & 15, lk = lane >> 4;

    for (int k0 = kbeg; k0 < kbeg + 2304; k0 += 128) {
        __syncthreads();
#pragma unroll
        for (int j = 0; j < 4; ++j) {
            GLOAD16(gR + j * rstep + k0, lA + j * 1024);
            GLOAD16(gC + j * rstep + k0, lB + j * 1024);
        }
        __syncthreads();
        i32x8 a[4], b[4];
#pragma unroll
        for (int f = 0; f < 4; ++f) {
            a[f] = ld_frag8(As, wm + f * 16 + lm, lk);
            b[f] = ld_frag8(Bs, wn + f * 16 + lm, lk);
        }
#pragma unroll
        for (int fm = 0; fm < 4; ++fm)
#pragma unroll
            for (int fn = 0; fn < 4; ++fn)
                acc[fm][fn] = MFMA_MX(a[fm], b[fn], acc[fm][fn]);
    }

    float* out = GP + (size_t)blockIdx.z * 1327104;
#pragma unroll
    for (int fm = 0; fm < 4; ++fm)
#pragma unroll
        for (int fn = 0; fn < 4; ++fn)
#pragma unroll
            for (int i = 0; i < 4; ++i) {
                int r = wm + fm * 16 + ((lane >> 4) * 4) + i;
                int c = wn + fn * 16 + (lane & 15);
                out[(bm + r) * 1152 + bn + c] = acc[fm][fn][i];
            }
}

__global__ void dot_gram_stage1(const float* __restrict__ GP, double* __restrict__ partial)
{
    const size_t n = 1327104;
    size_t i = (size_t)blockIdx.x * 256 + threadIdx.x;
    size_t stride = (size_t)gridDim.x * 256;
    double s = 0.0;
    for (; i < n; i += stride) {
        float gf = GP[i] + GP[n + i] + GP[2 * n + i] + GP[3 * n + i];
        float gb = GP[4 * n + i] + GP[5 * n + i] + GP[6 * n + i] + GP[7 * n + i];
        s += (double)gf * (double)gb;
    }
    for (int off = 32; off; off >>= 1) s += __shfl_down(s, off, 64);
    __shared__ double wsum[4];
    int lane = threadIdx.x & 63, wid = threadIdx.x >> 6;
    if (lane == 0) wsum[wid] = s;
    __syncthreads();
    if (threadIdx.x == 0) partial[blockIdx.x] = wsum[0] + wsum[1] + wsum[2] + wsum[3];
}

__global__ void sumsq_stage2(const double* __restrict__ partial, int nblocks, float* __restrict__ scale)
{
    double s = 0.0;
    for (int i = threadIdx.x; i < nblocks; i += 256) s += partial[i];
    for (int off = 32; off; off >>= 1) s += __shfl_down(s, off, 64);
    __shared__ double wsum[4];
    int lane = threadIdx.x & 63, wid = threadIdx.x >> 6;
    if (lane == 0) wsum[wid] = s;
    __syncthreads();
    if (threadIdx.x == 0) {
        double nrm = sqrt(wsum[0] + wsum[1] + wsum[2] + wsum[3]);
        if (nrm < 1e-12) nrm = 1e-12;
        *scale = (float)(10.0 / nrm);
    }
}

__global__ void inv_kernel(const float* __restrict__ rsP, float* __restrict__ inv)
{
    int i = blockIdx.x * 256 + threadIdx.x;
    if (i >= 9216) return;
    const float4* rp = (const float4*)(rsP + (size_t)i * 144);
    float s = 0.f;
#pragma unroll
    for (int j = 0; j < 36; ++j) {
        float4 v = rp[j];
        s += v.x + v.y + v.z + v.w;
    }
    inv[i] = 1.f / s;
}

// ---------------- fold + mask + upsample (planar fp32 out) ------------------
__global__ void fold_mask_up_kernel(const float* __restrict__ R2,
                                    const float* __restrict__ inv,
                                    const float* __restrict__ mask,
                                    float* __restrict__ up)
{
    int idx = blockIdx.x * 256 + threadIdx.x; // 128*96*96
    if (idx >= 128 * 96 * 96) return;
    int x = idx % 96;
    int y = (idx / 96) % 96;
    int c = idx / (96 * 96);
    float s = 0.f;
#pragma unroll
    for (int dy = 0; dy < 3; ++dy) {
        int yy = y + 1 - dy;
        if (yy < 0 || yy >= 96) continue;
#pragma unroll
        for (int dx = 0; dx < 3; ++dx) {
            int xx = x + 1 - dx;
            if (xx < 0 || xx >= 96) continue;
            int pp = yy * 96 + xx;
            s += R2[(size_t)(c * 9 + dy * 3 + dx) * 9216 + pp] * inv[pp];
        }
    }
    s *= mask[(size_t)(2 * y) * 192 + 2 * x];
    size_t base = (size_t)c * 192 * 192;
    up[base + (size_t)(2 * y) * 192 + 2 * x]         = s;
    up[base + (size_t)(2 * y) * 192 + 2 * x + 1]     = s;
    up[base + (size_t)(2 * y + 1) * 192 + 2 * x]     = s;
    up[base + (size_t)(2 * y + 1) * 192 + 2 * x + 1] = s;
}

// ---------------------------------------------------------------------------
extern "C" void kernel_launch(void* const* d_in, const int* in_sizes, int n_in,
                              void* d_out, int out_size, void* d_ws, size_t ws_size,
                              hipStream_t stream)
{
    const float* x    = (const float*)d_in[0];
    const float* mask = (const float*)d_in[1];
    const float* w[8];
    const float* b[8];
    for (int i = 0; i < 8; ++i) {
        w[i] = (const float*)d_in[2 + 2 * i];
        b[i] = (const float*)d_in[3 + 2 * i];
    }
    char* ws = (char*)d_ws;
    dim3 blk(256);

    // byte offsets (liveness-audited; peak ~169.6 MB)
    const size_t U_H1CL  = 0;            // 37,748,736 (convs)
    const size_t U_H2    = 37748736;
    const size_t U_H3    = 47185920;
    const size_t U_H4    = 66060288;
    const size_t U_H5    = 75497472;
    const size_t U_H6    = 84934656;     // ends 94,371,840
    const size_t U_X4    = 94371840;     // ends 99,090,432 (conv1 only)
    const size_t B_FGPT  = 0;            // u8 10,616,832 (over dead h1cl)
    const size_t B_BGPT  = 10616832;     // ends 21,233,664
    const size_t B_FGPK  = 21233664;     // ends 31,850,496
    const size_t B_BGPK  = 157556736;    // ends 168,173,568 (high; lives to PV)
    const size_t F_GP    = 99090432;     // 42,467,328 -> 141,557,760 (x4/h6 dead)
    const size_t B_P8    = 42467328;     // 84,934,656 -> 127,401,984 (GP overlap ok: GP dead)
    const size_t F_RSP   = 141557760;    // 5,308,416 -> 146,866,176
    const size_t F_INV   = 146866176;    // 36,864 -> 146,903,040
    const size_t F_R2    = 0;            // 42,467,328 (patch-T/K low arrays dead)
    const size_t F_UP    = 42467328;     // 18,874,368 -> 61,341,696 (P8 dead)
    const size_t U_UPCL  = 61341696;     // 9,437,184 -> 70,778,880
    const size_t U_H7    = 70778880;     // 9,437,184 -> 80,216,064
    const size_t F_H8    = 80216064;     // 18,874,368 -> 99,090,432
    const size_t U_WP1   = 168173568;    // 8,192
    const size_t U_WP2   = 168181760;    // 18,432
    const size_t U_WP3   = 168200192;    // 36,864
    const size_t U_WP4   = 168237056;    // 147,456
    const size_t U_WP5   = 168384512;    // 294,912
    const size_t U_WP6   = 168679424;
    const size_t U_WP7   = 168974336;
    const size_t U_WP8   = 169269248;    // -> 169,564,160
    const size_t D_RED   = 169564160;    // 4,096
    const size_t F_SCALE = 169568256;    // peak ~169,568,512

    u16* h1cl   = (u16*)(ws + U_H1CL);
    u16* h2     = (u16*)(ws + U_H2);
    u16* h3     = (u16*)(ws + U_H3);
    u16* h4     = (u16*)(ws + U_H4);
    u16* h5     = (u16*)(ws + U_H5);
    u16* h6     = (u16*)(ws + U_H6);
    u16* x4     = (u16*)(ws + U_X4);
    u8*  fgpT   = (u8*)(ws + B_FGPT);
    u8*  bgpT   = (u8*)(ws + B_BGPT);
    u8*  fgpK   = (u8*)(ws + B_FGPK);
    u8*  bgpK   = (u8*)(ws + B_BGPK);
    float* GP   = (float*)(ws + F_GP);
    u8*  P8     = (u8*)(ws + B_P8);
    float* rsP  = (float*)(ws + F_RSP);
    float* inv  = (float*)(ws + F_INV);
    float* R2   = (float*)(ws + F_R2);
    float* upP  = (float*)(ws + F_UP);
    u16* upCL   = (u16*)(ws + U_UPCL);
    u16* h7     = (u16*)(ws + U_H7);
    float* h8   = (float*)(ws + F_H8);
    u16* wp1    = (u16*)(ws + U_WP1);
    u16* wp2    = (u16*)(ws + U_WP2);
    u16* wp3    = (u16*)(ws + U_WP3);
    u16* wp4    = (u16*)(ws + U_WP4);
    u16* wp5    = (u16*)(ws + U_WP5);
    u16* wp6    = (u16*)(ws + U_WP6);
    u16* wp7    = (u16*)(ws + U_WP7);
    u16* wp8    = (u16*)(ws + U_WP8);
    double* red = (double*)(ws + D_RED);
    float* scale= (float*)(ws + F_SCALE);

    // ---- prepack ----
    pack_w1_kernel<<<dim3(16), blk, 0, stream>>>(w[0], wp1);
    pack_w_kernel<<<dim3(36),  blk, 0, stream>>>(w[1], wp2, 32, 32);
    pack_w_kernel<<<dim3(72),  blk, 0, stream>>>(w[2], wp3, 64, 32);
    pack_w_kernel<<<dim3(288), blk, 0, stream>>>(w[3], wp4, 128, 64);
    pack_w_kernel<<<dim3(576), blk, 0, stream>>>(w[4], wp5, 128, 128);
    pack_w_kernel<<<dim3(576), blk, 0, stream>>>(w[5], wp6, 128, 128);
    pack_w_kernel<<<dim3(576), blk, 0, stream>>>(w[6], wp7, 128, 128);
    pack_w_kernel<<<dim3(576), blk, 0, stream>>>(w[7], wp8, 128, 128);
    x4cl_kernel<<<dim3(2304), blk, 0, stream>>>(x, x4);

    // ---- conv front-end (bf16 MFMA, unchanged) ----
    conv1_mfma_kernel<<<dim3(48, 96), blk, 0, stream>>>(x4, wp1, b[0], h1cl);
    mfma_conv_kernel<4, 1, 2, 2, 2, 32, 32, 1, 0><<<dim3(24, 48), blk, 0, stream>>>(
        h1cl, wp2, b[1], h2, 768, 768, 384, 384, 32);
    mfma_conv_kernel<4, 2, 2, 2, 1, 32, 32, 1, 0><<<dim3(24, 48), blk, 0, stream>>>(
        h2, wp3, b[2], h3, 384, 384, 384, 384, 64);
    mfma_conv_kernel<4, 2, 2, 2, 2, 64, 32, 1, 0><<<dim3(12, 24, 2), blk, 0, stream>>>(
        h3, wp4, b[3], h4, 384, 384, 192, 192, 128);
    mfma_conv_kernel<4, 2, 2, 2, 1, 128, 128, 1, 0><<<dim3(12, 24, 2), blk, 0, stream>>>(
        h4, wp5, b[4], h5, 192, 192, 192, 192, 128);
    mfma_conv_kernel<4, 2, 2, 2, 1, 128, 128, 0, 0><<<dim3(12, 24, 2), blk, 0, stream>>>(
        h5, wp6, b[5], h6, 192, 192, 192, 192, 128);

    // ---- patch matrices (fp8 e4m3) ----
    build_patches_T8<<<dim3(41472), blk, 0, stream>>>(h6, mask, fgpT, bgpT);
    build_patches_K8<<<dim3(41472), blk, 0, stream>>>(h6, mask, fgpK, bgpK);

    // ---- norm scale via Gram trick (MX fp8) ----
    gram_mx_kernel<<<dim3(9, 9, 8), blk, 0, stream>>>(fgpK, bgpK, GP);
    dot_gram_stage1<<<dim3(512), blk, 0, stream>>>(GP, red);
    sumsq_stage2<<<dim3(1), blk, 0, stream>>>(red, 512, scale);

    // ---- 3 q-stripes: S-exp (MX) -> full fp8 P + fused rowsums ----
    for (int s = 0; s < 3; ++s) {
        sexp_mx_kernel<<<dim3(24, 72), blk, 0, stream>>>(
            fgpT, bgpT + (size_t)s * 3072 * 1152, P8, s * 3072, scale, rsP, s * 48);
    }
    inv_kernel<<<dim3(36), blk, 0, stream>>>(rsP, inv);

    // ---- PV (MX): single dispatch, K=9216 ----
    pv_mx_kernel<<<dim3(72, 18), blk, 0, stream>>>(bgpK, P8, R2);

    // ---- fold + mask + upsample, then to channels-last bf16 ----
    fold_mask_up_kernel<<<dim3(4608), blk, 0, stream>>>(R2, inv, mask, upP);
    p2cl_kernel<<<dim3(1152), blk, 0, stream>>>(upP, upCL);

    // ---- back-end convs ----
    mfma_conv_kernel<4, 2, 2, 2, 1, 128, 128, 1, 0><<<dim3(12, 24, 2), blk, 0, stream>>>(
        upCL, wp7, b[6], h7, 192, 192, 192, 192, 128);
    mfma_conv_kernel<4, 2, 2, 2, 1, 128, 128, 1, 1><<<dim3(12, 24, 2), blk, 0, stream>>>(
        h7, wp8, b[7], h8, 192, 192, 192, 192, 128);
    cl2p_kernel<<<dim3(1152), blk, 0, stream>>>(h8, (float*)d_out);
}

// Round 11
// 987.157 us; speedup vs baseline: 1.1910x; 1.1910x over previous
//
#include <hip/hip_runtime.h>
#include <math.h>

// ---------------------------------------------------------------------------
// Round 10->11: consolidation to best-known config. Round-7 dataflow
// (bf16 MFMA attention, 3 stripes of 3072) + round-8's pv64 (64x128,
// 1296 blocks) + gram 8-way split (round-7 form). MX-fp8 attempt reverted
// (VGPR spill: 256 regs, 229MB scratch writes). Peak ws ~171.3 MB.
// ---------------------------------------------------------------------------

typedef unsigned short u16;
typedef short short4v __attribute__((ext_vector_type(4)));
typedef short short8v __attribute__((ext_vector_type(8)));
typedef float f32x4 __attribute__((ext_vector_type(4)));

__device__ __forceinline__ u16 f2bf(float f) {
    unsigned u = __float_as_uint(f);
    return (u16)((u + 0x7FFF + ((u >> 16) & 1)) >> 16);
}
__device__ __forceinline__ float bf2f(u16 h) {
    return __uint_as_float(((unsigned)h) << 16);
}

#define GLOAD16(g, l) __builtin_amdgcn_global_load_lds(                      \
    (const __attribute__((address_space(1))) void*)(g),                      \
    (__attribute__((address_space(3))) void*)(l), 16, 0, 0)

// ---------------- x -> channels-last bf16 ic4 (for conv1 MFMA) --------------
__global__ void x4cl_kernel(const float* __restrict__ x, u16* __restrict__ out)
{
    int i = blockIdx.x * 256 + threadIdx.x;   // 589824 pixels
    if (i >= 589824) return;
    u16 v[4];
    v[0] = f2bf(x[i]);
    v[1] = f2bf(x[589824 + i]);
    v[2] = f2bf(x[1179648 + i]);
    v[3] = 0;
    *(short4v*)(out + (size_t)i * 4) = *(short4v*)v;
}

// w1 [32][3][5][5] f32 -> wp1 [32][128] bf16, k = tap*4+ic (pad zeros)
__global__ void pack_w1_kernel(const float* __restrict__ w, u16* __restrict__ wp)
{
    int i = blockIdx.x * 256 + threadIdx.x;   // 4096
    if (i >= 4096) return;
    int oc = i >> 7, k = i & 127;
    int tap = k >> 2, ic = k & 3;
    u16 v = 0;
    if (tap < 25 && ic < 3) v = f2bf(w[oc * 75 + ic * 25 + tap]);
    wp[i] = v;
}

// ---------------- conv1 MFMA: 3->32, 5x5, s1, reflect pad2, ELU -------------
__global__ __launch_bounds__(256)
void conv1_mfma_kernel(const u16* __restrict__ x4, const u16* __restrict__ wp1,
                       const float* __restrict__ bias, u16* __restrict__ out)
{
    __shared__ __align__(16) u16 sIn[12 * 20 * 4];
    const int tid = threadIdx.x;
    const int lane = tid & 63;
    const int w = tid >> 6;
    const int lm = lane & 15;
    const int lk = lane >> 4;
    const int oy0 = blockIdx.y * 8, ox0 = blockIdx.x * 16;

    for (int u = tid; u < 240; u += 256) {
        int yt = u / 20, xt = u - yt * 20;
        int gy = oy0 - 2 + yt; gy = gy < 0 ? -gy : (gy >= 768 ? 1534 - gy : gy);
        int gx = ox0 - 2 + xt; gx = gx < 0 ? -gx : (gx >= 768 ? 1534 - gx : gx);
        *(short4v*)(sIn + u * 4) = *(const short4v*)(x4 + ((size_t)gy * 768 + gx) * 4);
    }
    int aoff[4][2];
#pragma unroll
    for (int ks = 0; ks < 4; ++ks) {
        int t0 = ks * 8 + lk * 2;
        int t1 = t0 + 1;
        if (t0 > 24) t0 = 24;
        if (t1 > 24) t1 = 24;
        int dy0 = t0 / 5, dx0 = t0 - 5 * dy0;
        int dy1 = t1 / 5, dx1 = t1 - 5 * dy1;
        aoff[ks][0] = (dy0 * 20 + dx0 + lm) * 4;
        aoff[ks][1] = (dy1 * 20 + dx1 + lm) * 4;
    }
    __syncthreads();

    f32x4 acc[2][2];
#pragma unroll
    for (int i = 0; i < 2; ++i)
#pragma unroll
        for (int j = 0; j < 2; ++j) acc[i][j] = (f32x4){0.f, 0.f, 0.f, 0.f};

#pragma unroll
    for (int ks = 0; ks < 4; ++ks) {
        short8v a[2], b[2];
#pragma unroll
        for (int fm = 0; fm < 2; ++fm) {
            int base = (w * 2 + fm) * 80;
            short4v lo = *(const short4v*)(sIn + base + aoff[ks][0]);
            short4v hi = *(const short4v*)(sIn + base + aoff[ks][1]);
            short8v av;
            av[0] = lo[0]; av[1] = lo[1]; av[2] = lo[2]; av[3] = lo[3];
            av[4] = hi[0]; av[5] = hi[1]; av[6] = hi[2]; av[7] = hi[3];
            a[fm] = av;
        }
#pragma unroll
        for (int fn = 0; fn < 2; ++fn)
            b[fn] = *(const short8v*)(wp1 + (size_t)(fn * 16 + lm) * 128 + ks * 32 + lk * 8);
#pragma unroll
        for (int fm = 0; fm < 2; ++fm)
#pragma unroll
            for (int fn = 0; fn < 2; ++fn)
                acc[fm][fn] = __builtin_amdgcn_mfma_f32_16x16x32_bf16(
                    a[fm], b[fn], acc[fm][fn], 0, 0, 0);
    }

#pragma unroll
    for (int fm = 0; fm < 2; ++fm) {
        int gy = oy0 + w * 2 + fm;
#pragma unroll
        for (int fn = 0; fn < 2; ++fn) {
            int oc = fn * 16 + lm;
            float bv = bias[oc];
#pragma unroll
            for (int i = 0; i < 4; ++i) {
                int xx = lk * 4 + i;
                float v = acc[fm][fn][i] + bv;
                v = v > 0.f ? v : expm1f(v);
                out[((size_t)gy * 768 + ox0 + xx) * 32 + oc] = f2bf(v);
            }
        }
    }
}

// ---------------- weight prepack: [oc][ic][3][3] f32 -> [oc][tap][ic] bf16 --
__global__ void pack_w_kernel(const float* __restrict__ w, u16* __restrict__ wp,
                              int OC, int IC)
{
    int idx = blockIdx.x * 256 + threadIdx.x;
    if (idx >= OC * 9 * IC) return;
    int oc = idx / (9 * IC);
    int r  = idx - oc * 9 * IC;
    int tap = r / IC;
    int ic  = r - tap * IC;
    wp[idx] = f2bf(w[((size_t)oc * IC + ic) * 9 + tap]);
}

// ---------------- MFMA implicit-GEMM conv (3x3, reflect pad 1) --------------
template<int FM, int FN, int NWM, int NWN, int S, int IC, int ICC, int ACT, int OUTF32>
__global__ __launch_bounds__(256)
void mfma_conv_kernel(const u16* __restrict__ in, const u16* __restrict__ wgtP,
                      const float* __restrict__ bias, void* __restrict__ out,
                      int H, int W, int Ho, int Wo, int OC)
{
    constexpr int TY = 7 * S + 3;
    constexpr int TX = 15 * S + 3;
    constexpr int NSLOT = ICC / 8;
    constexpr int SWMSK = NSLOT - 1;
    constexpr int KTOT = 9 * IC;
    __shared__ __align__(16) u16 sIn[TY * TX * ICC];

    const int tid  = threadIdx.x;
    const int lane = tid & 63;
    const int wid  = tid >> 6;
    const int wmi  = wid / NWN;
    const int wni  = wid % NWN;
    const int lm   = lane & 15;
    const int lk   = lane >> 4;
    const int noff = blockIdx.z * (NWN * FN * 16);

    f32x4 acc[FM][FN];
#pragma unroll
    for (int i = 0; i < FM; ++i)
#pragma unroll
        for (int j = 0; j < FN; ++j) acc[i][j] = (f32x4){0.f, 0.f, 0.f, 0.f};

    const int iy0 = blockIdx.y * 8 * S - 1;
    const int ix0 = blockIdx.x * 16 * S - 1;

    for (int c0 = 0; c0 < IC; c0 += ICC) {
        if (c0) __syncthreads();
        for (int u = tid; u < TY * TX * NSLOT; u += 256) {
            int yt = u / (TX * NSLOT);
            int r  = u - yt * (TX * NSLOT);
            int xt = r / NSLOT;
            int sl = r - xt * NSLOT;
            int gy = iy0 + yt; gy = gy < 0 ? -gy : (gy >= H ? 2 * H - 2 - gy : gy);
            int gx = ix0 + xt; gx = gx < 0 ? -gx : (gx >= W ? 2 * W - 2 - gx : gx);
            *(short8v*)((char*)sIn + (size_t)((yt * TX + xt) * NSLOT + (sl ^ (xt & SWMSK))) * 16) =
                *(const short8v*)(in + ((size_t)gy * W + gx) * IC + c0 + sl * 8);
        }
        __syncthreads();
#pragma unroll
        for (int tap = 0; tap < 9; ++tap) {
            const int dy = tap / 3, dx = tap % 3;
#pragma unroll
            for (int icw = 0; icw < ICC / 32; ++icw) {
                short8v a[FM], b[FN];
#pragma unroll
                for (int fm = 0; fm < FM; ++fm) {
                    int yt = (wmi * FM + fm) * S + dy;
                    int xt = lm * S + dx;
                    a[fm] = *(const short8v*)((const char*)sIn +
                        (size_t)((yt * TX + xt) * NSLOT + ((icw * 4 + lk) ^ (xt & SWMSK))) * 16);
                }
#pragma unroll
                for (int fn = 0; fn < FN; ++fn) {
                    int n = noff + wni * FN * 16 + fn * 16 + lm;
                    b[fn] = *(const short8v*)(wgtP + (size_t)n * KTOT + tap * IC + c0 + icw * 32 + lk * 8);
                }
#pragma unroll
                for (int fm = 0; fm < FM; ++fm)
#pragma unroll
                    for (int fn = 0; fn < FN; ++fn)
                        acc[fm][fn] = __builtin_amdgcn_mfma_f32_16x16x32_bf16(
                            a[fm], b[fn], acc[fm][fn], 0, 0, 0);
            }
        }
    }

#pragma unroll
    for (int fm = 0; fm < FM; ++fm) {
        int y = blockIdx.y * 8 + wmi * FM + fm;
#pragma unroll
        for (int fn = 0; fn < FN; ++fn) {
            int oc = noff + wni * FN * 16 + fn * 16 + lm;
            float bv = bias[oc];
#pragma unroll
            for (int i = 0; i < 4; ++i) {
                int x = blockIdx.x * 16 + lk * 4 + i;
                float v = acc[fm][fn][i] + bv;
                if (ACT == 0) v = v > 0.f ? v : 0.f;
                else          v = v > 0.f ? v : expm1f(v);
                size_t o = ((size_t)y * Wo + x) * OC + oc;
                if (OUTF32) ((float*)out)[o] = v;
                else        ((u16*)out)[o]   = f2bf(v);
            }
        }
    }
}

// channels-last f32 [36864][128] -> planar f32 [128][36864]
__global__ __launch_bounds__(256)
void cl2p_kernel(const float* __restrict__ in, float* __restrict__ out)
{
    __shared__ float t[32][130];
    const int tid = threadIdx.x;
    const int p0 = blockIdx.x * 32;
#pragma unroll
    for (int j = 0; j < 16; ++j) {
        int idx = j * 256 + tid;
        int px = idx >> 7, c = idx & 127;
        t[px][c] = in[(size_t)(p0 + px) * 128 + c];
    }
    __syncthreads();
#pragma unroll
    for (int j = 0; j < 16; ++j) {
        int c = j * 8 + (tid >> 5);
        int px = tid & 31;
        out[(size_t)c * 36864 + p0 + px] = t[px][c];
    }
}

// planar f32 [128][36864] -> channels-last bf16 [36864][128]
__global__ __launch_bounds__(256)
void p2cl_kernel(const float* __restrict__ in, u16* __restrict__ out)
{
    __shared__ float t[32][130];
    const int tid = threadIdx.x;
    const int p0 = blockIdx.x * 32;
#pragma unroll
    for (int j = 0; j < 16; ++j) {
        int c = j * 8 + (tid >> 5);
        int px = tid & 31;
        t[px][c] = in[(size_t)c * 36864 + p0 + px];
    }
    __syncthreads();
#pragma unroll
    for (int j = 0; j < 16; ++j) {
        int idx = j * 256 + tid;
        int px = idx >> 7, c = idx & 127;
        out[(size_t)(p0 + px) * 128 + c] = f2bf(t[px][c]);
    }
}

// ---------------- patch builders (h6 is channels-last bf16) -----------------
__global__ void build_patches_T(const u16* __restrict__ h6, const float* __restrict__ mask,
                                u16* __restrict__ fgpT, u16* __restrict__ bgpT)
{
    int idx = blockIdx.x * 256 + threadIdx.x;   // p*1152 + k
    if (idx >= 9216 * 1152) return;
    int p = idx / 1152, k = idx - p * 1152;
    int y = p / 96, x = p - y * 96;
    int c = k / 9, t = k - c * 9;
    int dy = t / 3, dx = t - dy * 3;
    int sy = y + dy - 1, sx = x + dx - 1;
    float v = 0.f, vm = 0.f;
    if (sy >= 0 && sy < 96 && sx >= 0 && sx < 96) {
        v  = bf2f(h6[((size_t)(2 * sy) * 192 + 2 * sx) * 128 + c]);
        vm = v * mask[(size_t)(2 * sy) * 192 + 2 * sx];
    }
    bgpT[idx] = f2bf(v);
    fgpT[idx] = f2bf(vm);
}

__global__ void build_patches_K(const u16* __restrict__ h6, const float* __restrict__ mask,
                                u16* __restrict__ fgpK, u16* __restrict__ bgpK)
{
    int idx = blockIdx.x * 256 + threadIdx.x;   // k*9216 + q
    if (idx >= 9216 * 1152) return;
    int k = idx / 9216, q = idx - k * 9216;
    int y = q / 96, x = q - y * 96;
    int c = k / 9, t = k - c * 9;
    int dy = t / 3, dx = t - dy * 3;
    int sy = y + dy - 1, sx = x + dx - 1;
    float v = 0.f, vm = 0.f;
    if (sy >= 0 && sy < 96 && sx >= 0 && sx < 96) {
        v  = bf2f(h6[((size_t)(2 * sy) * 192 + 2 * sx) * 128 + c]);
        vm = v * mask[(size_t)(2 * sy) * 192 + 2 * sx];
    }
    bgpK[idx] = f2bf(v);
    fgpK[idx] = f2bf(vm);
}

// ---------------- sexp: bf16 NT MFMA GEMM, 128x128, exp epilogue ------------
__global__ __launch_bounds__(256)
void mfma_nt_sexp_kernel(const u16* __restrict__ A, const u16* __restrict__ B,
                         int lda, int ldb, int K,
                         u16* __restrict__ outH, int ldo,
                         const float* __restrict__ scale_p,
                         float* __restrict__ rsP, int rcol0)
{
    __shared__ __align__(16) u16 As[128 * 64];
    __shared__ __align__(16) u16 Bs[128 * 64];
    const int tid  = threadIdx.x;
    const int wid  = tid >> 6;
    const int lane = tid & 63;
    const int wm = (wid >> 1) * 64;
    const int wn = (wid & 1) * 64;
    const size_t bm = (size_t)blockIdx.y * 128;
    const size_t bn = (size_t)blockIdx.x * 128;

    f32x4 acc[4][4];
#pragma unroll
    for (int i = 0; i < 4; ++i)
#pragma unroll
        for (int j = 0; j < 4; ++j)
            acc[i][j] = (f32x4){0.f, 0.f, 0.f, 0.f};

    const int lrow = lane >> 3;
    const int lcb  = ((lane & 7) << 4) ^ ((lrow & 7) << 4);
    const char* gA = (const char*)A + ((bm + wid * 32 + lrow) * (size_t)lda) * 2 + lcb;
    const char* gB = (const char*)B + ((bn + wid * 32 + lrow) * (size_t)ldb) * 2 + lcb;
    char* lA = (char*)As + (size_t)(wid * 32) * 128;
    char* lB = (char*)Bs + (size_t)(wid * 32) * 128;
    const size_t rsA = (size_t)lda * 16;
    const size_t rsB = (size_t)ldb * 16;

    for (int k0 = 0; k0 < K; k0 += 64) {
        __syncthreads();
#pragma unroll
        for (int j = 0; j < 4; ++j) {
            GLOAD16(gA + j * rsA + (size_t)k0 * 2, lA + j * 1024);
            GLOAD16(gB + j * rsB + (size_t)k0 * 2, lB + j * 1024);
        }
        __syncthreads();
#pragma unroll
        for (int ks = 0; ks < 2; ++ks) {
            short8v a[4], b[4];
#pragma unroll
            for (int f = 0; f < 4; ++f) {
                int ma = wm + f * 16 + (lane & 15);
                int kba = (ks * 64 + ((lane >> 4) * 16)) ^ ((ma & 7) << 4);
                a[f] = *(const short8v*)((const char*)As + ma * 128 + kba);
                int nb = wn + f * 16 + (lane & 15);
                int kbb = (ks * 64 + ((lane >> 4) * 16)) ^ ((nb & 7) << 4);
                b[f] = *(const short8v*)((const char*)Bs + nb * 128 + kbb);
            }
#pragma unroll
            for (int fm = 0; fm < 4; ++fm)
#pragma unroll
                for (int fn = 0; fn < 4; ++fn)
                    acc[fm][fn] = __builtin_amdgcn_mfma_f32_16x16x32_bf16(
                        a[fm], b[fn], acc[fm][fn], 0, 0, 0);
        }
    }

    const float scale = *scale_p;
    float rloc[4][4];
#pragma unroll
    for (int fm = 0; fm < 4; ++fm)
#pragma unroll
        for (int i = 0; i < 4; ++i) rloc[fm][i] = 0.f;
#pragma unroll
    for (int fm = 0; fm < 4; ++fm)
#pragma unroll
        for (int fn = 0; fn < 4; ++fn)
#pragma unroll
            for (int i = 0; i < 4; ++i) {
                int r = wm + fm * 16 + ((lane >> 4) * 4) + i;
                int c = wn + fn * 16 + (lane & 15);
                float e = __expf(scale * acc[fm][fn][i]);
                outH[(bm + r) * (size_t)ldo + bn + c] = f2bf(e);
                rloc[fm][i] += e;
            }
#pragma unroll
    for (int fm = 0; fm < 4; ++fm)
#pragma unroll
        for (int i = 0; i < 4; ++i) {
            float s = rloc[fm][i];
            s += __shfl_xor(s, 8, 64);
            s += __shfl_xor(s, 4, 64);
            s += __shfl_xor(s, 2, 64);
            s += __shfl_xor(s, 1, 64);
            if ((lane & 15) == 0)
                rsP[(bm + wm + fm * 16 + ((lane >> 4) * 4) + i) * 144 +
                    rcol0 + blockIdx.x * 2 + (wid & 1)] = s;
        }
}

// ---------------- PV: 64x128 tile, 4 waves (2x2, each 32x64) ----------------
template<int ACCUM>
__global__ __launch_bounds__(256)
void pv64_kernel(const u16* __restrict__ A, const u16* __restrict__ B,
                 int lda, int ldb, int K, float* __restrict__ outF, int ldo)
{
    __shared__ __align__(16) u16 As[64 * 64];
    __shared__ __align__(16) u16 Bs[128 * 64];
    const int tid  = threadIdx.x;
    const int wid  = tid >> 6;
    const int lane = tid & 63;
    const int wm = (wid >> 1) * 32;
    const int wn = (wid & 1) * 64;
    const size_t bm = (size_t)blockIdx.y * 64;
    const size_t bn = (size_t)blockIdx.x * 128;

    f32x4 acc[2][4];
#pragma unroll
    for (int i = 0; i < 2; ++i)
#pragma unroll
        for (int j = 0; j < 4; ++j)
            acc[i][j] = (f32x4){0.f, 0.f, 0.f, 0.f};

    const int lrow = lane >> 3;
    const int lcb  = ((lane & 7) << 4) ^ ((lrow & 7) << 4);
    const char* gA = (const char*)A + ((bm + wid * 16 + lrow) * (size_t)lda) * 2 + lcb;
    const char* gB = (const char*)B + ((bn + wid * 32 + lrow) * (size_t)ldb) * 2 + lcb;
    char* lA = (char*)As + (size_t)(wid * 16) * 128;
    char* lB = (char*)Bs + (size_t)(wid * 32) * 128;
    const size_t rsA = (size_t)lda * 16;
    const size_t rsB = (size_t)ldb * 16;

    for (int k0 = 0; k0 < K; k0 += 64) {
        __syncthreads();
#pragma unroll
        for (int j = 0; j < 2; ++j)
            GLOAD16(gA + j * rsA + (size_t)k0 * 2, lA + j * 1024);
#pragma unroll
        for (int j = 0; j < 4; ++j)
            GLOAD16(gB + j * rsB + (size_t)k0 * 2, lB + j * 1024);
        __syncthreads();
#pragma unroll
        for (int ks = 0; ks < 2; ++ks) {
            short8v a[2], b[4];
#pragma unroll
            for (int f = 0; f < 2; ++f) {
                int ma = wm + f * 16 + (lane & 15);
                int kba = (ks * 64 + ((lane >> 4) * 16)) ^ ((ma & 7) << 4);
                a[f] = *(const short8v*)((const char*)As + ma * 128 + kba);
            }
#pragma unroll
            for (int f = 0; f < 4; ++f) {
                int nb = wn + f * 16 + (lane & 15);
                int kbb = (ks * 64 + ((lane >> 4) * 16)) ^ ((nb & 7) << 4);
                b[f] = *(const short8v*)((const char*)Bs + nb * 128 + kbb);
            }
#pragma unroll
            for (int fm = 0; fm < 2; ++fm)
#pragma unroll
                for (int fn = 0; fn < 4; ++fn)
                    acc[fm][fn] = __builtin_amdgcn_mfma_f32_16x16x32_bf16(
                        a[fm], b[fn], acc[fm][fn], 0, 0, 0);
        }
    }

#pragma unroll
    for (int fm = 0; fm < 2; ++fm)
#pragma unroll
        for (int fn = 0; fn < 4; ++fn)
#pragma unroll
            for (int i = 0; i < 4; ++i) {
                int r = wm + fm * 16 + ((lane >> 4) * 4) + i;
                int c = wn + fn * 16 + (lane & 15);
                float v = acc[fm][fn][i];
                if (ACCUM) outF[(bm + r) * (size_t)ldo + bn + c] += v;
                else       outF[(bm + r) * (size_t)ldo + bn + c]  = v;
            }
}

// ---------------- Gram kernel: grid (9,9,8); z = pair*4 + splitK ------------
__global__ __launch_bounds__(256)
void gram_kernel(const u16* __restrict__ F, const u16* __restrict__ Bg,
                 float* __restrict__ GP)
{
    const u16* A = (blockIdx.z >> 2) ? Bg : F;
    const int split = blockIdx.z & 3;
    __shared__ __align__(16) u16 As[128 * 64];
    __shared__ __align__(16) u16 Bs[128 * 64];
    const int tid  = threadIdx.x;
    const int wid  = tid >> 6;
    const int lane = tid & 63;
    const int wm = (wid >> 1) * 64;
    const int wn = (wid & 1) * 64;
    const size_t bm = (size_t)blockIdx.y * 128;
    const size_t bn = (size_t)blockIdx.x * 128;

    f32x4 acc[4][4];
#pragma unroll
    for (int i = 0; i < 4; ++i)
#pragma unroll
        for (int j = 0; j < 4; ++j)
            acc[i][j] = (f32x4){0.f, 0.f, 0.f, 0.f};

    const int lrow = lane >> 3;
    const int lcb  = ((lane & 7) << 4) ^ ((lrow & 7) << 4);
    const char* gR = (const char*)A + ((bm + wid * 32 + lrow) * (size_t)9216) * 2 + lcb;
    const char* gC = (const char*)A + ((bn + wid * 32 + lrow) * (size_t)9216) * 2 + lcb;
    char* lA = (char*)As + (size_t)(wid * 32) * 128;
    char* lB = (char*)Bs + (size_t)(wid * 32) * 128;
    const size_t rs8 = (size_t)9216 * 16;
    const int kbeg = split * 2304;

    for (int k0 = kbeg; k0 < kbeg + 2304; k0 += 64) {
        __syncthreads();
#pragma unroll
        for (int j = 0; j < 4; ++j) {
            GLOAD16(gR + j * rs8 + (size_t)k0 * 2, lA + j * 1024);
            GLOAD16(gC + j * rs8 + (size_t)k0 * 2, lB + j * 1024);
        }
        __syncthreads();
#pragma unroll
        for (int ks = 0; ks < 2; ++ks) {
            short8v a[4], b[4];
#pragma unroll
            for (int f = 0; f < 4; ++f) {
                int ma = wm + f * 16 + (lane & 15);
                int kba = (ks * 64 + ((lane >> 4) * 16)) ^ ((ma & 7) << 4);
                a[f] = *(const short8v*)((const char*)As + ma * 128 + kba);
                int nb = wn + f * 16 + (lane & 15);
                int kbb = (ks * 64 + ((lane >> 4) * 16)) ^ ((nb & 7) << 4);
                b[f] = *(const short8v*)((const char*)Bs + nb * 128 + kbb);
            }
#pragma unroll
            for (int fm = 0; fm < 4; ++fm)
#pragma unroll
                for (int fn = 0; fn < 4; ++fn)
                    acc[fm][fn] = __builtin_amdgcn_mfma_f32_16x16x32_bf16(
                        a[fm], b[fn], acc[fm][fn], 0, 0, 0);
        }
    }

    float* out = GP + (size_t)blockIdx.z * 1327104;
#pragma unroll
    for (int fm = 0; fm < 4; ++fm)
#pragma unroll
        for (int fn = 0; fn < 4; ++fn)
#pragma unroll
            for (int i = 0; i < 4; ++i) {
                int r = wm + fm * 16 + ((lane >> 4) * 4) + i;
                int c = wn + fn * 16 + (lane & 15);
                out[(bm + r) * 1152 + bn + c] = acc[fm][fn][i];
            }
}

// dot over summed split-K partials (4 fg + 4 bg, fixed order)
__global__ void dot_gram_stage1(const float* __restrict__ GP, double* __restrict__ partial)
{
    const size_t n = 1327104;
    size_t i = (size_t)blockIdx.x * 256 + threadIdx.x;
    size_t stride = (size_t)gridDim.x * 256;
    double s = 0.0;
    for (; i < n; i += stride) {
        float gf = GP[i] + GP[n + i] + GP[2 * n + i] + GP[3 * n + i];
        float gb = GP[4 * n + i] + GP[5 * n + i] + GP[6 * n + i] + GP[7 * n + i];
        s += (double)gf * (double)gb;
    }
    for (int off = 32; off; off >>= 1) s += __shfl_down(s, off, 64);
    __shared__ double wsum[4];
    int lane = threadIdx.x & 63, wid = threadIdx.x >> 6;
    if (lane == 0) wsum[wid] = s;
    __syncthreads();
    if (threadIdx.x == 0) partial[blockIdx.x] = wsum[0] + wsum[1] + wsum[2] + wsum[3];
}

__global__ void sumsq_stage2(const double* __restrict__ partial, int nblocks, float* __restrict__ scale)
{
    double s = 0.0;
    for (int i = threadIdx.x; i < nblocks; i += 256) s += partial[i];
    for (int off = 32; off; off >>= 1) s += __shfl_down(s, off, 64);
    __shared__ double wsum[4];
    int lane = threadIdx.x & 63, wid = threadIdx.x >> 6;
    if (lane == 0) wsum[wid] = s;
    __syncthreads();
    if (threadIdx.x == 0) {
        double nrm = sqrt(wsum[0] + wsum[1] + wsum[2] + wsum[3]);
        if (nrm < 1e-12) nrm = 1e-12;
        *scale = (float)(10.0 / nrm);
    }
}

__global__ void inv_kernel(const float* __restrict__ rsP, float* __restrict__ inv)
{
    int i = blockIdx.x * 256 + threadIdx.x;
    if (i >= 9216) return;
    const float4* rp = (const float4*)(rsP + (size_t)i * 144);
    float s = 0.f;
#pragma unroll
    for (int j = 0; j < 36; ++j) {
        float4 v = rp[j];
        s += v.x + v.y + v.z + v.w;
    }
    inv[i] = 1.f / s;
}

// ---------------- fold + mask + upsample (planar fp32 out) ------------------
__global__ void fold_mask_up_kernel(const float* __restrict__ R2,
                                    const float* __restrict__ inv,
                                    const float* __restrict__ mask,
                                    float* __restrict__ up)
{
    int idx = blockIdx.x * 256 + threadIdx.x; // 128*96*96
    if (idx >= 128 * 96 * 96) return;
    int x = idx % 96;
    int y = (idx / 96) % 96;
    int c = idx / (96 * 96);
    float s = 0.f;
#pragma unroll
    for (int dy = 0; dy < 3; ++dy) {
        int yy = y + 1 - dy;
        if (yy < 0 || yy >= 96) continue;
#pragma unroll
        for (int dx = 0; dx < 3; ++dx) {
            int xx = x + 1 - dx;
            if (xx < 0 || xx >= 96) continue;
            int pp = yy * 96 + xx;
            s += R2[(size_t)(c * 9 + dy * 3 + dx) * 9216 + pp] * inv[pp];
        }
    }
    s *= mask[(size_t)(2 * y) * 192 + 2 * x];
    size_t base = (size_t)c * 192 * 192;
    up[base + (size_t)(2 * y) * 192 + 2 * x]         = s;
    up[base + (size_t)(2 * y) * 192 + 2 * x + 1]     = s;
    up[base + (size_t)(2 * y + 1) * 192 + 2 * x]     = s;
    up[base + (size_t)(2 * y + 1) * 192 + 2 * x + 1] = s;
}

// ---------------------------------------------------------------------------
extern "C" void kernel_launch(void* const* d_in, const int* in_sizes, int n_in,
                              void* d_out, int out_size, void* d_ws, size_t ws_size,
                              hipStream_t stream)
{
    const float* x    = (const float*)d_in[0];
    const float* mask = (const float*)d_in[1];
    const float* w[8];
    const float* b[8];
    for (int i = 0; i < 8; ++i) {
        w[i] = (const float*)d_in[2 + 2 * i];
        b[i] = (const float*)d_in[3 + 2 * i];
    }
    char* ws = (char*)d_ws;
    dim3 blk(256);

    // byte offsets (liveness-audited; peak 171.3 MB)
    const size_t U_H1CL = 0;            // cl bf16 768^2 x32  (37,748,736)
    const size_t U_H2   = 37748736;     // ( 9,437,184)
    const size_t U_H3   = 47185920;     // (18,874,368)
    const size_t U_H4   = 66060288;     // ( 9,437,184)
    const size_t U_H5   = 75497472;
    const size_t U_H6   = 84934656;     // ends 94,371,840
    const size_t U_X4   = 94371840;     // ( 4,718,592) conv1 only
    const size_t U_FGPT = 0;            // (21,233,664) [h1cl/h2 dead]
    const size_t U_BGPT = 21233664;
    const size_t U_BGPK = 42467328;
    const size_t U_FGPK = 63700992;     // ends 84,934,656
    const size_t F_GP   = 94371840;     // 8 x 5,308,416 = 42,467,328; ends 136,839,168 [h6/x4 dead]
    const size_t U_P    = 63700992;     // (56,623,104) ends 120,324,096 [fgpK, GP dead]
    const size_t F_R2   = 120324096;    // (42,467,328) ends 162,791,424 [GP dead]
    const size_t F_RSP  = 162791424;    // ( 5,308,416) ends 168,099,840
    const size_t F_INV  = 168099840;    // (36,864) ends 168,136,704
    const size_t U_WP1  = 168136704;    // ( 8,192)
    const size_t U_WP2  = 168144896;    // (18,432)
    const size_t U_WP3  = 168163328;    // (36,864)
    const size_t U_WP4  = 168200192;    // (147,456)
    const size_t U_WP5  = 168347648;    // (294,912)
    const size_t U_WP6  = 168642560;
    const size_t U_WP7  = 168937472;
    const size_t U_WP8  = 169232384;    // ends 169,527,296
    const size_t D_RED  = 169527296;    // (4,096)
    const size_t F_SCALE= 169531392;    // (256)
    const size_t F_UP   = 0;            // (18,874,368) [fgpT dead]
    const size_t U_UPCL = 18874368;     // ( 9,437,184)
    const size_t U_H7   = 28311552;
    const size_t F_H8   = 37748736;     // (18,874,368) ends 56,623,104 [bgpT/bgpK dead]

    u16* h1cl   = (u16*)(ws + U_H1CL);
    u16* h2     = (u16*)(ws + U_H2);
    u16* h3     = (u16*)(ws + U_H3);
    u16* h4     = (u16*)(ws + U_H4);
    u16* h5     = (u16*)(ws + U_H5);
    u16* h6     = (u16*)(ws + U_H6);
    u16* x4     = (u16*)(ws + U_X4);
    u16* fgpT   = (u16*)(ws + U_FGPT);
    u16* bgpT   = (u16*)(ws + U_BGPT);
    u16* bgpK   = (u16*)(ws + U_BGPK);
    u16* fgpK   = (u16*)(ws + U_FGPK);
    float* GP   = (float*)(ws + F_GP);
    u16* P      = (u16*)(ws + U_P);
    float* R2   = (float*)(ws + F_R2);
    float* rsP  = (float*)(ws + F_RSP);
    float* inv  = (float*)(ws + F_INV);
    u16* wp1    = (u16*)(ws + U_WP1);
    u16* wp2    = (u16*)(ws + U_WP2);
    u16* wp3    = (u16*)(ws + U_WP3);
    u16* wp4    = (u16*)(ws + U_WP4);
    u16* wp5    = (u16*)(ws + U_WP5);
    u16* wp6    = (u16*)(ws + U_WP6);
    u16* wp7    = (u16*)(ws + U_WP7);
    u16* wp8    = (u16*)(ws + U_WP8);
    double* red = (double*)(ws + D_RED);
    float* scale= (float*)(ws + F_SCALE);
    float* upP  = (float*)(ws + F_UP);
    u16* upCL   = (u16*)(ws + U_UPCL);
    u16* h7     = (u16*)(ws + U_H7);
    float* h8   = (float*)(ws + F_H8);

    // ---- prepack ----
    pack_w1_kernel<<<dim3(16), blk, 0, stream>>>(w[0], wp1);
    pack_w_kernel<<<dim3(36),  blk, 0, stream>>>(w[1], wp2, 32, 32);
    pack_w_kernel<<<dim3(72),  blk, 0, stream>>>(w[2], wp3, 64, 32);
    pack_w_kernel<<<dim3(288), blk, 0, stream>>>(w[3], wp4, 128, 64);
    pack_w_kernel<<<dim3(576), blk, 0, stream>>>(w[4], wp5, 128, 128);
    pack_w_kernel<<<dim3(576), blk, 0, stream>>>(w[5], wp6, 128, 128);
    pack_w_kernel<<<dim3(576), blk, 0, stream>>>(w[6], wp7, 128, 128);
    pack_w_kernel<<<dim3(576), blk, 0, stream>>>(w[7], wp8, 128, 128);
    x4cl_kernel<<<dim3(2304), blk, 0, stream>>>(x, x4);

    // ---- conv front-end ----
    conv1_mfma_kernel<<<dim3(48, 96), blk, 0, stream>>>(x4, wp1, b[0], h1cl);
    mfma_conv_kernel<4, 1, 2, 2, 2, 32, 32, 1, 0><<<dim3(24, 48), blk, 0, stream>>>(
        h1cl, wp2, b[1], h2, 768, 768, 384, 384, 32);
    mfma_conv_kernel<4, 2, 2, 2, 1, 32, 32, 1, 0><<<dim3(24, 48), blk, 0, stream>>>(
        h2, wp3, b[2], h3, 384, 384, 384, 384, 64);
    mfma_conv_kernel<4, 2, 2, 2, 2, 64, 32, 1, 0><<<dim3(12, 24, 2), blk, 0, stream>>>(
        h3, wp4, b[3], h4, 384, 384, 192, 192, 128);
    mfma_conv_kernel<4, 2, 2, 2, 1, 128, 128, 1, 0><<<dim3(12, 24, 2), blk, 0, stream>>>(
        h4, wp5, b[4], h5, 192, 192, 192, 192, 128);
    mfma_conv_kernel<4, 2, 2, 2, 1, 128, 128, 0, 0><<<dim3(12, 24, 2), blk, 0, stream>>>(
        h5, wp6, b[5], h6, 192, 192, 192, 192, 128);

    // ---- patch matrices ----
    build_patches_T<<<dim3(41472), blk, 0, stream>>>(h6, mask, fgpT, bgpT);
    build_patches_K<<<dim3(41472), blk, 0, stream>>>(h6, mask, fgpK, bgpK);

    // ---- norm scale via Gram trick (8-way split, 648 blocks) ----
    gram_kernel<<<dim3(9, 9, 8), blk, 0, stream>>>(fgpK, bgpK, GP);
    dot_gram_stage1<<<dim3(512), blk, 0, stream>>>(GP, red);
    sumsq_stage2<<<dim3(1), blk, 0, stream>>>(red, 512, scale);

    // ---- 3 q-stripes of 3072: S-exp -> P (fused row-partials), PV 64x128 ----
    for (int s = 0; s < 3; ++s) {
        size_t qs = (size_t)s * 3072;
        mfma_nt_sexp_kernel<<<dim3(24, 72), blk, 0, stream>>>(
            fgpT, bgpT + qs * 1152, 1152, 1152, 1152, P, 3072, scale, rsP, s * 48);
        if (s == 0)
            pv64_kernel<0><<<dim3(72, 18), blk, 0, stream>>>(
                bgpK + qs, P, 9216, 3072, 3072, R2, 9216);
        else
            pv64_kernel<1><<<dim3(72, 18), blk, 0, stream>>>(
                bgpK + qs, P, 9216, 3072, 3072, R2, 9216);
    }
    inv_kernel<<<dim3(36), blk, 0, stream>>>(rsP, inv);
    fold_mask_up_kernel<<<dim3(4608), blk, 0, stream>>>(R2, inv, mask, upP);

    // ---- back-end convs ----
    p2cl_kernel<<<dim3(1152), blk, 0, stream>>>(upP, upCL);
    mfma_conv_kernel<4, 2, 2, 2, 1, 128, 128, 1, 0><<<dim3(12, 24, 2), blk, 0, stream>>>(
        upCL, wp7, b[6], h7, 192, 192, 192, 192, 128);
    mfma_conv_kernel<4, 2, 2, 2, 1, 128, 128, 1, 1><<<dim3(12, 24, 2), blk, 0, stream>>>(
        h7, wp8, b[7], h8, 192, 192, 192, 192, 128);
    cl2p_kernel<<<dim3(1152), blk, 0, stream>>>(h8, (float*)d_out);
}

// Round 12
// 772.799 us; speedup vs baseline: 1.5213x; 1.2774x over previous
//
#include <hip/hip_runtime.h>
#include <hip/hip_fp16.h>
#include <math.h>

// ---------------------------------------------------------------------------
// Round 11->12: S via G-stencil factorization (EXACT identity):
//   S[p][q] = sum_t valid(t,p,q) * G[p+e_t][q+e_t],  G[a][b]=sum_c fg[c][a]bg[c][b]
// G: K=128 GEMM (21.7 GF, e5m2, x1/8 range headroom) -> stencil pass
// (S8 e5m2 + Frobenius partials) -> elementwise exp pass (in-place, rowsums
// from quantized P) -> PV in non-scaled fp8 MFMA (single dispatch, K=9216).
// Removes fgpT/bgpT/fgpK builders + gram + sexp GEMMs.
// Workspace peak 187.0 MB (ws >= 206.8 MB proven by round-2 Path C pass).
// ---------------------------------------------------------------------------

typedef unsigned short u16;
typedef unsigned char u8;
typedef short short4v __attribute__((ext_vector_type(4)));
typedef short short8v __attribute__((ext_vector_type(8)));
typedef float f32x4 __attribute__((ext_vector_type(4)));

__device__ __forceinline__ u16 f2bf(float f) {
    unsigned u = __float_as_uint(f);
    return (u16)((u + 0x7FFF + ((u >> 16) & 1)) >> 16);
}
__device__ __forceinline__ float bf2f(u16 h) {
    return __uint_as_float(((unsigned)h) << 16);
}
// f32 -> fp8 e5m2 (RNE via fp16 truncation; field-validated round 9)
__device__ __forceinline__ u8 f2e5m2(float f) {
    unsigned short hb = __half_as_ushort(__float2half(f));
    unsigned rem = hb & 0xFF;
    unsigned b = hb >> 8;
    b += (rem > 0x80u) || (rem == 0x80u && (b & 1u));
    return (u8)b;
}
// e5m2 -> f32 (e5m2 is truncated fp16)
__device__ __forceinline__ float e5m2f(unsigned b) {
    return __half2float(__ushort_as_half((unsigned short)(b << 8)));
}
// f32 -> fp8 e4m3fn (OCP), RNE, saturate (field-validated round 10)
__device__ __forceinline__ u8 f2e4m3(float f) {
    unsigned u = __float_as_uint(f);
    unsigned s = (u >> 24) & 0x80u;
    unsigned a = u & 0x7FFFFFFFu;
    if (a >= 0x43E00000u) return (u8)(s | 0x7Eu);
    int e = (int)(a >> 23) - 127;
    if (e >= -6) {
        unsigned keep = (a >> 20) & 7u;
        unsigned rem  = a & 0xFFFFFu;
        keep += (rem > 0x80000u) || (rem == 0x80000u && (keep & 1u));
        unsigned e4 = (unsigned)(e + 7);
        if (keep == 8u) { keep = 0u; ++e4; }
        if (e4 >= 15u && keep >= 7u) return (u8)(s | 0x7Eu);
        return (u8)(s | (e4 << 3) | keep);
    }
    float q = __uint_as_float(a) * 512.f;
    int m = (int)rintf(q);
    if (m >= 8) return (u8)(s | 0x08u);
    return (u8)(s | (unsigned)m);
}

#define GLOAD16(g, l) __builtin_amdgcn_global_load_lds(                      \
    (const __attribute__((address_space(1))) void*)(g),                      \
    (__attribute__((address_space(3))) void*)(l), 16, 0, 0)

// ---------------- x -> channels-last bf16 ic4 (for conv1 MFMA) --------------
__global__ void x4cl_kernel(const float* __restrict__ x, u16* __restrict__ out)
{
    int i = blockIdx.x * 256 + threadIdx.x;
    if (i >= 589824) return;
    u16 v[4];
    v[0] = f2bf(x[i]);
    v[1] = f2bf(x[589824 + i]);
    v[2] = f2bf(x[1179648 + i]);
    v[3] = 0;
    *(short4v*)(out + (size_t)i * 4) = *(short4v*)v;
}

__global__ void pack_w1_kernel(const float* __restrict__ w, u16* __restrict__ wp)
{
    int i = blockIdx.x * 256 + threadIdx.x;
    if (i >= 4096) return;
    int oc = i >> 7, k = i & 127;
    int tap = k >> 2, ic = k & 3;
    u16 v = 0;
    if (tap < 25 && ic < 3) v = f2bf(w[oc * 75 + ic * 25 + tap]);
    wp[i] = v;
}

// ---------------- conv1 MFMA: 3->32, 5x5, s1, reflect pad2, ELU -------------
__global__ __launch_bounds__(256)
void conv1_mfma_kernel(const u16* __restrict__ x4, const u16* __restrict__ wp1,
                       const float* __restrict__ bias, u16* __restrict__ out)
{
    __shared__ __align__(16) u16 sIn[12 * 20 * 4];
    const int tid = threadIdx.x;
    const int lane = tid & 63;
    const int w = tid >> 6;
    const int lm = lane & 15;
    const int lk = lane >> 4;
    const int oy0 = blockIdx.y * 8, ox0 = blockIdx.x * 16;

    for (int u = tid; u < 240; u += 256) {
        int yt = u / 20, xt = u - yt * 20;
        int gy = oy0 - 2 + yt; gy = gy < 0 ? -gy : (gy >= 768 ? 1534 - gy : gy);
        int gx = ox0 - 2 + xt; gx = gx < 0 ? -gx : (gx >= 768 ? 1534 - gx : gx);
        *(short4v*)(sIn + u * 4) = *(const short4v*)(x4 + ((size_t)gy * 768 + gx) * 4);
    }
    int aoff[4][2];
#pragma unroll
    for (int ks = 0; ks < 4; ++ks) {
        int t0 = ks * 8 + lk * 2;
        int t1 = t0 + 1;
        if (t0 > 24) t0 = 24;
        if (t1 > 24) t1 = 24;
        int dy0 = t0 / 5, dx0 = t0 - 5 * dy0;
        int dy1 = t1 / 5, dx1 = t1 - 5 * dy1;
        aoff[ks][0] = (dy0 * 20 + dx0 + lm) * 4;
        aoff[ks][1] = (dy1 * 20 + dx1 + lm) * 4;
    }
    __syncthreads();

    f32x4 acc[2][2];
#pragma unroll
    for (int i = 0; i < 2; ++i)
#pragma unroll
        for (int j = 0; j < 2; ++j) acc[i][j] = (f32x4){0.f, 0.f, 0.f, 0.f};

#pragma unroll
    for (int ks = 0; ks < 4; ++ks) {
        short8v a[2], b[2];
#pragma unroll
        for (int fm = 0; fm < 2; ++fm) {
            int base = (w * 2 + fm) * 80;
            short4v lo = *(const short4v*)(sIn + base + aoff[ks][0]);
            short4v hi = *(const short4v*)(sIn + base + aoff[ks][1]);
            short8v av;
            av[0] = lo[0]; av[1] = lo[1]; av[2] = lo[2]; av[3] = lo[3];
            av[4] = hi[0]; av[5] = hi[1]; av[6] = hi[2]; av[7] = hi[3];
            a[fm] = av;
        }
#pragma unroll
        for (int fn = 0; fn < 2; ++fn)
            b[fn] = *(const short8v*)(wp1 + (size_t)(fn * 16 + lm) * 128 + ks * 32 + lk * 8);
#pragma unroll
        for (int fm = 0; fm < 2; ++fm)
#pragma unroll
            for (int fn = 0; fn < 2; ++fn)
                acc[fm][fn] = __builtin_amdgcn_mfma_f32_16x16x32_bf16(
                    a[fm], b[fn], acc[fm][fn], 0, 0, 0);
    }

#pragma unroll
    for (int fm = 0; fm < 2; ++fm) {
        int gy = oy0 + w * 2 + fm;
#pragma unroll
        for (int fn = 0; fn < 2; ++fn) {
            int oc = fn * 16 + lm;
            float bv = bias[oc];
#pragma unroll
            for (int i = 0; i < 4; ++i) {
                int xx = lk * 4 + i;
                float v = acc[fm][fn][i] + bv;
                v = v > 0.f ? v : expm1f(v);
                out[((size_t)gy * 768 + ox0 + xx) * 32 + oc] = f2bf(v);
            }
        }
    }
}

// ---------------- weight prepack ----------------
__global__ void pack_w_kernel(const float* __restrict__ w, u16* __restrict__ wp,
                              int OC, int IC)
{
    int idx = blockIdx.x * 256 + threadIdx.x;
    if (idx >= OC * 9 * IC) return;
    int oc = idx / (9 * IC);
    int r  = idx - oc * 9 * IC;
    int tap = r / IC;
    int ic  = r - tap * IC;
    wp[idx] = f2bf(w[((size_t)oc * IC + ic) * 9 + tap]);
}

// ---------------- MFMA implicit-GEMM conv (3x3, reflect pad 1) --------------
template<int FM, int FN, int NWM, int NWN, int S, int IC, int ICC, int ACT, int OUTF32>
__global__ __launch_bounds__(256)
void mfma_conv_kernel(const u16* __restrict__ in, const u16* __restrict__ wgtP,
                      const float* __restrict__ bias, void* __restrict__ out,
                      int H, int W, int Ho, int Wo, int OC)
{
    constexpr int TY = 7 * S + 3;
    constexpr int TX = 15 * S + 3;
    constexpr int NSLOT = ICC / 8;
    constexpr int SWMSK = NSLOT - 1;
    constexpr int KTOT = 9 * IC;
    __shared__ __align__(16) u16 sIn[TY * TX * ICC];

    const int tid  = threadIdx.x;
    const int lane = tid & 63;
    const int wid  = tid >> 6;
    const int wmi  = wid / NWN;
    const int wni  = wid % NWN;
    const int lm   = lane & 15;
    const int lk   = lane >> 4;
    const int noff = blockIdx.z * (NWN * FN * 16);

    f32x4 acc[FM][FN];
#pragma unroll
    for (int i = 0; i < FM; ++i)
#pragma unroll
        for (int j = 0; j < FN; ++j) acc[i][j] = (f32x4){0.f, 0.f, 0.f, 0.f};

    const int iy0 = blockIdx.y * 8 * S - 1;
    const int ix0 = blockIdx.x * 16 * S - 1;

    for (int c0 = 0; c0 < IC; c0 += ICC) {
        if (c0) __syncthreads();
        for (int u = tid; u < TY * TX * NSLOT; u += 256) {
            int yt = u / (TX * NSLOT);
            int r  = u - yt * (TX * NSLOT);
            int xt = r / NSLOT;
            int sl = r - xt * NSLOT;
            int gy = iy0 + yt; gy = gy < 0 ? -gy : (gy >= H ? 2 * H - 2 - gy : gy);
            int gx = ix0 + xt; gx = gx < 0 ? -gx : (gx >= W ? 2 * W - 2 - gx : gx);
            *(short8v*)((char*)sIn + (size_t)((yt * TX + xt) * NSLOT + (sl ^ (xt & SWMSK))) * 16) =
                *(const short8v*)(in + ((size_t)gy * W + gx) * IC + c0 + sl * 8);
        }
        __syncthreads();
#pragma unroll
        for (int tap = 0; tap < 9; ++tap) {
            const int dy = tap / 3, dx = tap % 3;
#pragma unroll
            for (int icw = 0; icw < ICC / 32; ++icw) {
                short8v a[FM], b[FN];
#pragma unroll
                for (int fm = 0; fm < FM; ++fm) {
                    int yt = (wmi * FM + fm) * S + dy;
                    int xt = lm * S + dx;
                    a[fm] = *(const short8v*)((const char*)sIn +
                        (size_t)((yt * TX + xt) * NSLOT + ((icw * 4 + lk) ^ (xt & SWMSK))) * 16);
                }
#pragma unroll
                for (int fn = 0; fn < FN; ++fn) {
                    int n = noff + wni * FN * 16 + fn * 16 + lm;
                    b[fn] = *(const short8v*)(wgtP + (size_t)n * KTOT + tap * IC + c0 + icw * 32 + lk * 8);
                }
#pragma unroll
                for (int fm = 0; fm < FM; ++fm)
#pragma unroll
                    for (int fn = 0; fn < FN; ++fn)
                        acc[fm][fn] = __builtin_amdgcn_mfma_f32_16x16x32_bf16(
                            a[fm], b[fn], acc[fm][fn], 0, 0, 0);
            }
        }
    }

#pragma unroll
    for (int fm = 0; fm < FM; ++fm) {
        int y = blockIdx.y * 8 + wmi * FM + fm;
#pragma unroll
        for (int fn = 0; fn < FN; ++fn) {
            int oc = noff + wni * FN * 16 + fn * 16 + lm;
            float bv = bias[oc];
#pragma unroll
            for (int i = 0; i < 4; ++i) {
                int x = blockIdx.x * 16 + lk * 4 + i;
                float v = acc[fm][fn][i] + bv;
                if (ACT == 0) v = v > 0.f ? v : 0.f;
                else          v = v > 0.f ? v : expm1f(v);
                size_t o = ((size_t)y * Wo + x) * OC + oc;
                if (OUTF32) ((float*)out)[o] = v;
                else        ((u16*)out)[o]   = f2bf(v);
            }
        }
    }
}

// channels-last f32 [36864][128] -> planar f32 [128][36864]
__global__ __launch_bounds__(256)
void cl2p_kernel(const float* __restrict__ in, float* __restrict__ out)
{
    __shared__ float t[32][130];
    const int tid = threadIdx.x;
    const int p0 = blockIdx.x * 32;
#pragma unroll
    for (int j = 0; j < 16; ++j) {
        int idx = j * 256 + tid;
        int px = idx >> 7, c = idx & 127;
        t[px][c] = in[(size_t)(p0 + px) * 128 + c];
    }
    __syncthreads();
#pragma unroll
    for (int j = 0; j < 16; ++j) {
        int c = j * 8 + (tid >> 5);
        int px = tid & 31;
        out[(size_t)c * 36864 + p0 + px] = t[px][c];
    }
}

// planar f32 [128][36864] -> channels-last bf16 [36864][128]
__global__ __launch_bounds__(256)
void p2cl_kernel(const float* __restrict__ in, u16* __restrict__ out)
{
    __shared__ float t[32][130];
    const int tid = threadIdx.x;
    const int p0 = blockIdx.x * 32;
#pragma unroll
    for (int j = 0; j < 16; ++j) {
        int c = j * 8 + (tid >> 5);
        int px = tid & 31;
        t[px][c] = in[(size_t)c * 36864 + p0 + px];
    }
    __syncthreads();
#pragma unroll
    for (int j = 0; j < 16; ++j) {
        int idx = j * 256 + tid;
        int px = idx >> 7, c = idx & 127;
        out[(size_t)(p0 + px) * 128 + c] = f2bf(t[px][c]);
    }
}

// ---------------- half-res channel-last images: fgC (masked), bgC -----------
__global__ void build_fgbgc_kernel(const u16* __restrict__ h6, const float* __restrict__ mask,
                                   u16* __restrict__ fgC, u16* __restrict__ bgC)
{
    int idx = blockIdx.x * 256 + threadIdx.x;   // 9216*16
    if (idx >= 147456) return;
    int q = idx >> 4, cs = (idx & 15) * 8;
    int qy = q / 96, qx = q - qy * 96;
    const u16* src = h6 + ((size_t)(2 * qy) * 192 + 2 * qx) * 128 + cs;
    float m = mask[(size_t)(2 * qy) * 192 + 2 * qx];
    short8v v = *(const short8v*)src;
    u16 fo[8];
#pragma unroll
    for (int j = 0; j < 8; ++j) fo[j] = f2bf(bf2f((u16)v[j]) * m);
    *(short8v*)(bgC + (size_t)q * 128 + cs) = v;
    *(short8v*)(fgC + (size_t)q * 128 + cs) = *(short8v*)fo;
}

// ---------------- bgpK8: e4m3 patch matrix [1152][9216] (unmasked) ----------
__global__ void build_bgpk8_kernel(const u16* __restrict__ h6, u8* __restrict__ bgpK)
{
    int idx = blockIdx.x * 256 + threadIdx.x;   // 1152*9216
    if (idx >= 1152 * 9216) return;
    int k = idx / 9216, q = idx - k * 9216;
    int y = q / 96, x = q - y * 96;
    int c = k / 9, t = k - c * 9;
    int dy = t / 3, dx = t - dy * 3;
    int sy = y + dy - 1, sx = x + dx - 1;
    float v = 0.f;
    if (sy >= 0 && sy < 96 && sx >= 0 && sx < 96)
        v = bf2f(h6[((size_t)(2 * sy) * 192 + 2 * sx) * 128 + c]);
    bgpK[idx] = f2e4m3(v);
}

// ---------------- G-GEMM: G[a][b] = 1/8 * sum_c fgC[a][c]*bgC[b][c] ---------
// bf16 NT, K=128, 128x128 tile, e5m2 output. grid (72,72).
__global__ __launch_bounds__(256)
void g_gemm_kernel(const u16* __restrict__ A, const u16* __restrict__ B,
                   u8* __restrict__ G)
{
    __shared__ __align__(16) u16 As[128 * 64];
    __shared__ __align__(16) u16 Bs[128 * 64];
    const int tid  = threadIdx.x;
    const int wid  = tid >> 6;
    const int lane = tid & 63;
    const int wm = (wid >> 1) * 64;
    const int wn = (wid & 1) * 64;
    const size_t bm = (size_t)blockIdx.y * 128;
    const size_t bn = (size_t)blockIdx.x * 128;

    f32x4 acc[4][4];
#pragma unroll
    for (int i = 0; i < 4; ++i)
#pragma unroll
        for (int j = 0; j < 4; ++j)
            acc[i][j] = (f32x4){0.f, 0.f, 0.f, 0.f};

    const int lrow = lane >> 3;
    const int lcb  = ((lane & 7) << 4) ^ ((lrow & 7) << 4);
    const char* gA = (const char*)A + ((bm + wid * 32 + lrow) * (size_t)128) * 2 + lcb;
    const char* gB = (const char*)B + ((bn + wid * 32 + lrow) * (size_t)128) * 2 + lcb;
    char* lA = (char*)As + (size_t)(wid * 32) * 128;
    char* lB = (char*)Bs + (size_t)(wid * 32) * 128;
    const size_t rs8 = (size_t)128 * 16;   // 8 rows * 256 B

    for (int k0 = 0; k0 < 128; k0 += 64) {
        __syncthreads();
#pragma unroll
        for (int j = 0; j < 4; ++j) {
            GLOAD16(gA + j * rs8 + (size_t)k0 * 2, lA + j * 1024);
            GLOAD16(gB + j * rs8 + (size_t)k0 * 2, lB + j * 1024);
        }
        __syncthreads();
#pragma unroll
        for (int ks = 0; ks < 2; ++ks) {
            short8v a[4], b[4];
#pragma unroll
            for (int f = 0; f < 4; ++f) {
                int ma = wm + f * 16 + (lane & 15);
                int kba = (ks * 64 + ((lane >> 4) * 16)) ^ ((ma & 7) << 4);
                a[f] = *(const short8v*)((const char*)As + ma * 128 + kba);
                int nb = wn + f * 16 + (lane & 15);
                int kbb = (ks * 64 + ((lane >> 4) * 16)) ^ ((nb & 7) << 4);
                b[f] = *(const short8v*)((const char*)Bs + nb * 128 + kbb);
            }
#pragma unroll
            for (int fm = 0; fm < 4; ++fm)
#pragma unroll
                for (int fn = 0; fn < 4; ++fn)
                    acc[fm][fn] = __builtin_amdgcn_mfma_f32_16x16x32_bf16(
                        a[fm], b[fn], acc[fm][fn], 0, 0, 0);
        }
    }

#pragma unroll
    for (int fm = 0; fm < 4; ++fm)
#pragma unroll
        for (int fn = 0; fn < 4; ++fn)
#pragma unroll
            for (int i = 0; i < 4; ++i) {
                int r = wm + fm * 16 + ((lane >> 4) * 4) + i;
                int c = wn + fn * 16 + (lane & 15);
                G[(bm + r) * (size_t)9216 + bn + c] = f2e5m2(0.125f * acc[fm][fn][i]);
            }
}

// ---------------- stencil pass: S8 = stencil(G), partial = sum S^2 ----------
// grid (18, 2304): wave per p-row, 512 q per wave, 8 q per lane.
__global__ __launch_bounds__(256)
void sstencil_kernel(const u8* __restrict__ G, u8* __restrict__ S8,
                     double* __restrict__ partial)
{
    const int wid  = threadIdx.x >> 6;
    const int lane = threadIdx.x & 63;
    const int p = blockIdx.y * 4 + wid;
    const int py = p / 96, px = p - py * 96;
    const int q0 = blockIdx.x * 512 + lane * 8;
    const int qy = q0 / 96, qx0 = q0 - qy * 96;

    float acc[8];
#pragma unroll
    for (int j = 0; j < 8; ++j) acc[j] = 0.f;

#pragma unroll
    for (int ey = -1; ey <= 1; ++ey) {
#pragma unroll
        for (int ex = -1; ex <= 1; ++ex) {
            if ((unsigned)(py + ey) >= 96u || (unsigned)(px + ex) >= 96u) continue;
            if ((unsigned)(qy + ey) >= 96u) continue;
            const int e = ey * 96 + ex;
            const u8* rp = G + (size_t)(p + e) * 9216;
            const int cc = q0 + e;
            unsigned long long v8;
            if (ex == 0) {
                v8 = *(const unsigned long long*)(rp + cc);
            } else {
                int base = cc & ~7;
                int sh = (cc & 7) * 8;
                unsigned long long lo = *(const unsigned long long*)(rp + base);
                unsigned long long hi = *(const unsigned long long*)(rp + base + 8);
                v8 = (lo >> sh) | (hi << (64 - sh));
            }
#pragma unroll
            for (int j = 0; j < 8; ++j) {
                if ((unsigned)(qx0 + j + ex) >= 96u) continue;
                acc[j] += e5m2f((unsigned)(v8 >> (8 * j)) & 0xFFu);
            }
        }
    }

    unsigned long long ow = 0;
    double s2 = 0.0;
#pragma unroll
    for (int j = 0; j < 8; ++j) {
        ow |= (unsigned long long)f2e5m2(acc[j]) << (8 * j);
        s2 += (double)acc[j] * (double)acc[j];
    }
    *(unsigned long long*)(S8 + (size_t)p * 9216 + q0) = ow;

    for (int off = 32; off; off >>= 1) s2 += __shfl_down(s2, off, 64);
    __shared__ double wsum[4];
    if (lane == 0) wsum[wid] = s2;
    __syncthreads();
    if (threadIdx.x == 0)
        partial[(size_t)blockIdx.y * 18 + blockIdx.x] = wsum[0] + wsum[1] + wsum[2] + wsum[3];
}

__global__ void sumsq_stage2(const double* __restrict__ partial, int nblocks, float* __restrict__ scale)
{
    double s = 0.0;
    for (int i = threadIdx.x; i < nblocks; i += 256) s += partial[i];
    for (int off = 32; off; off >>= 1) s += __shfl_down(s, off, 64);
    __shared__ double wsum[4];
    int lane = threadIdx.x & 63, wid = threadIdx.x >> 6;
    if (lane == 0) wsum[wid] = s;
    __syncthreads();
    if (threadIdx.x == 0) {
        double nrm = sqrt(wsum[0] + wsum[1] + wsum[2] + wsum[3]);
        if (nrm < 1e-12) nrm = 1e-12;
        *scale = (float)(10.0 / nrm);
    }
}

// ---------------- exp pass: P8 = e5m2(exp(scale*S8)) in-place + rowsums -----
__global__ __launch_bounds__(256)
void exp_rows_kernel(u8* __restrict__ P8, const float* __restrict__ scale_p,
                     float* __restrict__ rs)
{
    const int wid = threadIdx.x >> 6, lane = threadIdx.x & 63;
    const int p = blockIdx.x * 4 + wid;   // grid 2304
    u8* rp = P8 + (size_t)p * 9216;
    const float scale = *scale_p;
    float s = 0.f;
#pragma unroll
    for (int it = 0; it < 18; ++it) {
        unsigned long long v8 = *(unsigned long long*)(rp + it * 512 + lane * 8);
        unsigned long long ow = 0;
#pragma unroll
        for (int j = 0; j < 8; ++j) {
            float sv = e5m2f((unsigned)(v8 >> (8 * j)) & 0xFFu);
            u8 e8 = f2e5m2(__expf(scale * sv));
            ow |= (unsigned long long)e8 << (8 * j);
            s += e5m2f(e8);   // sum of QUANTIZED P -> normalization cancels bias
        }
        *(unsigned long long*)(rp + it * 512 + lane * 8) = ow;
    }
    for (int off = 32; off; off >>= 1) s += __shfl_down(s, off, 64);
    if (lane == 0) rs[p] = s;
}

__global__ void inv_kernel(const float* __restrict__ rs, float* __restrict__ inv)
{
    int i = blockIdx.x * 256 + threadIdx.x;
    if (i < 9216) inv[i] = 1.f / rs[i];
}

// ---------------- PV fp8: R2[c9][p] = sum_q bgpK8[c9][q] * P8[p][q] ---------
// A e4m3 (fp8), B e5m2 (bf8); 64x128 tile, BK=128, K=9216; grid (72,18).
__global__ __launch_bounds__(256)
void pv_fp8_kernel(const u8* __restrict__ A, const u8* __restrict__ B,
                   float* __restrict__ outF)
{
    __shared__ __align__(16) u8 As[64 * 128];
    __shared__ __align__(16) u8 Bs[128 * 128];
    const int tid  = threadIdx.x;
    const int wid  = tid >> 6;
    const int lane = tid & 63;
    const int wm = (wid >> 1) * 32;
    const int wn = (wid & 1) * 64;
    const size_t bm = (size_t)blockIdx.y * 64;
    const size_t bn = (size_t)blockIdx.x * 128;

    f32x4 acc[2][4];
#pragma unroll
    for (int i = 0; i < 2; ++i)
#pragma unroll
        for (int j = 0; j < 4; ++j)
            acc[i][j] = (f32x4){0.f, 0.f, 0.f, 0.f};

    const int lrow = lane >> 3;
    const int lcb  = ((lane & 7) << 4) ^ ((lrow & 7) << 4);
    const u8* gA = A + (bm + wid * 16 + lrow) * (size_t)9216 + lcb;
    const u8* gB = B + (bn + wid * 32 + lrow) * (size_t)9216 + lcb;
    u8* lA = As + (size_t)(wid * 16) * 128;
    u8* lB = Bs + (size_t)(wid * 32) * 128;
    const size_t rstep = (size_t)9216 * 8;
    const int lm = lane & 15, lk = lane >> 4;

    for (int k0 = 0; k0 < 9216; k0 += 128) {
        __syncthreads();
#pragma unroll
        for (int j = 0; j < 2; ++j)
            GLOAD16(gA + j * rstep + k0, lA + j * 1024);
#pragma unroll
        for (int j = 0; j < 4; ++j)
            GLOAD16(gB + j * rstep + k0, lB + j * 1024);
        __syncthreads();
#pragma unroll
        for (int ks = 0; ks < 4; ++ks) {
            const int koff = ks * 32 + lk * 8;
            long a[2], b[4];
#pragma unroll
            for (int f = 0; f < 2; ++f) {
                int ma = wm + f * 16 + lm;
                a[f] = *(const long*)(As + ma * 128 + (koff ^ ((ma & 7) << 4)));
            }
#pragma unroll
            for (int f = 0; f < 4; ++f) {
                int nb = wn + f * 16 + lm;
                b[f] = *(const long*)(Bs + nb * 128 + (koff ^ ((nb & 7) << 4)));
            }
#pragma unroll
            for (int fm = 0; fm < 2; ++fm)
#pragma unroll
                for (int fn = 0; fn < 4; ++fn)
                    acc[fm][fn] = __builtin_amdgcn_mfma_f32_16x16x32_fp8_bf8(
                        a[fm], b[fn], acc[fm][fn], 0, 0, 0);
        }
    }

#pragma unroll
    for (int fm = 0; fm < 2; ++fm)
#pragma unroll
        for (int fn = 0; fn < 4; ++fn)
#pragma unroll
            for (int i = 0; i < 4; ++i) {
                int r = wm + fm * 16 + ((lane >> 4) * 4) + i;
                int c = wn + fn * 16 + (lane & 15);
                outF[(bm + r) * (size_t)9216 + bn + c] = acc[fm][fn][i];
            }
}

// ---------------- fold + mask + upsample (planar fp32 out) ------------------
__global__ void fold_mask_up_kernel(const float* __restrict__ R2,
                                    const float* __restrict__ inv,
                                    const float* __restrict__ mask,
                                    float* __restrict__ up)
{
    int idx = blockIdx.x * 256 + threadIdx.x; // 128*96*96
    if (idx >= 128 * 96 * 96) return;
    int x = idx % 96;
    int y = (idx / 96) % 96;
    int c = idx / (96 * 96);
    float s = 0.f;
#pragma unroll
    for (int dy = 0; dy < 3; ++dy) {
        int yy = y + 1 - dy;
        if (yy < 0 || yy >= 96) continue;
#pragma unroll
        for (int dx = 0; dx < 3; ++dx) {
            int xx = x + 1 - dx;
            if (xx < 0 || xx >= 96) continue;
            int pp = yy * 96 + xx;
            s += R2[(size_t)(c * 9 + dy * 3 + dx) * 9216 + pp] * inv[pp];
        }
    }
    s *= mask[(size_t)(2 * y) * 192 + 2 * x];
    size_t base = (size_t)c * 192 * 192;
    up[base + (size_t)(2 * y) * 192 + 2 * x]         = s;
    up[base + (size_t)(2 * y) * 192 + 2 * x + 1]     = s;
    up[base + (size_t)(2 * y + 1) * 192 + 2 * x]     = s;
    up[base + (size_t)(2 * y + 1) * 192 + 2 * x + 1] = s;
}

// ---------------------------------------------------------------------------
extern "C" void kernel_launch(void* const* d_in, const int* in_sizes, int n_in,
                              void* d_out, int out_size, void* d_ws, size_t ws_size,
                              hipStream_t stream)
{
    const float* x    = (const float*)d_in[0];
    const float* mask = (const float*)d_in[1];
    const float* w[8];
    const float* b[8];
    for (int i = 0; i < 8; ++i) {
        w[i] = (const float*)d_in[2 + 2 * i];
        b[i] = (const float*)d_in[3 + 2 * i];
    }
    char* ws = (char*)d_ws;
    dim3 blk(256);

    // byte offsets (liveness-audited; peak 187.0 MB; ws >= 206.8 MB proven)
    const size_t U_H1CL = 0;            // 37,748,736
    const size_t U_H2   = 37748736;
    const size_t U_H3   = 47185920;
    const size_t U_H4   = 66060288;
    const size_t U_H5   = 75497472;
    const size_t U_H6   = 84934656;     // ends 94,371,840
    const size_t U_X4   = 94371840;     // ends 99,090,432
    const size_t U_FGC  = 0;            // 2,359,296  [h1cl dead]
    const size_t U_BGC  = 2359296;      // -> 4,718,592
    const size_t B_BGPK = 4718592;      // -> 15,335,424
    const size_t B_G    = 15335424;     // 84,934,656 -> 100,270,080 [h2..x4 dead]
    const size_t B_P8   = 100270080;    // 84,934,656 -> 185,204,736
    const size_t F_R2   = 15335424;     // 42,467,328 -> 57,802,752 [G dead after exp]
    const size_t F_UP   = 57802752;     // 18,874,368 -> 76,677,120
    const size_t U_UPCL = 76677120;     // -> 86,114,304
    const size_t U_H7   = 86114304;     // -> 95,551,488
    const size_t F_H8   = 95551488;     // 18,874,368 -> 114,425,856 [P8 dead]
    const size_t U_WP1  = 185204736;    // 8,192
    const size_t U_WP2  = 185212928;    // 18,432
    const size_t U_WP3  = 185231360;    // 36,864
    const size_t U_WP4  = 185268224;    // 147,456
    const size_t U_WP5  = 185415680;    // 294,912
    const size_t U_WP6  = 185710592;
    const size_t U_WP7  = 186005504;
    const size_t U_WP8  = 186300416;    // -> 186,595,328
    const size_t D_RED  = 186595328;    // 41472 doubles = 331,776 -> 186,927,104
    const size_t F_SCALE= 186927104;    // -> 186,927,360
    const size_t F_RS   = 186927360;    // 36,864 -> 186,964,224
    const size_t F_INV  = 186964224;    // -> 187,001,088 (peak)

    u16* h1cl   = (u16*)(ws + U_H1CL);
    u16* h2     = (u16*)(ws + U_H2);
    u16* h3     = (u16*)(ws + U_H3);
    u16* h4     = (u16*)(ws + U_H4);
    u16* h5     = (u16*)(ws + U_H5);
    u16* h6     = (u16*)(ws + U_H6);
    u16* x4     = (u16*)(ws + U_X4);
    u16* fgC    = (u16*)(ws + U_FGC);
    u16* bgC    = (u16*)(ws + U_BGC);
    u8*  bgpK   = (u8*)(ws + B_BGPK);
    u8*  G      = (u8*)(ws + B_G);
    u8*  P8     = (u8*)(ws + B_P8);
    float* R2   = (float*)(ws + F_R2);
    float* upP  = (float*)(ws + F_UP);
    u16* upCL   = (u16*)(ws + U_UPCL);
    u16* h7     = (u16*)(ws + U_H7);
    float* h8   = (float*)(ws + F_H8);
    u16* wp1    = (u16*)(ws + U_WP1);
    u16* wp2    = (u16*)(ws + U_WP2);
    u16* wp3    = (u16*)(ws + U_WP3);
    u16* wp4    = (u16*)(ws + U_WP4);
    u16* wp5    = (u16*)(ws + U_WP5);
    u16* wp6    = (u16*)(ws + U_WP6);
    u16* wp7    = (u16*)(ws + U_WP7);
    u16* wp8    = (u16*)(ws + U_WP8);
    double* red = (double*)(ws + D_RED);
    float* scale= (float*)(ws + F_SCALE);
    float* rs   = (float*)(ws + F_RS);
    float* inv  = (float*)(ws + F_INV);

    // ---- prepack ----
    pack_w1_kernel<<<dim3(16), blk, 0, stream>>>(w[0], wp1);
    pack_w_kernel<<<dim3(36),  blk, 0, stream>>>(w[1], wp2, 32, 32);
    pack_w_kernel<<<dim3(72),  blk, 0, stream>>>(w[2], wp3, 64, 32);
    pack_w_kernel<<<dim3(288), blk, 0, stream>>>(w[3], wp4, 128, 64);
    pack_w_kernel<<<dim3(576), blk, 0, stream>>>(w[4], wp5, 128, 128);
    pack_w_kernel<<<dim3(576), blk, 0, stream>>>(w[5], wp6, 128, 128);
    pack_w_kernel<<<dim3(576), blk, 0, stream>>>(w[6], wp7, 128, 128);
    pack_w_kernel<<<dim3(576), blk, 0, stream>>>(w[7], wp8, 128, 128);
    x4cl_kernel<<<dim3(2304), blk, 0, stream>>>(x, x4);

    // ---- conv front-end ----
    conv1_mfma_kernel<<<dim3(48, 96), blk, 0, stream>>>(x4, wp1, b[0], h1cl);
    mfma_conv_kernel<4, 1, 2, 2, 2, 32, 32, 1, 0><<<dim3(24, 48), blk, 0, stream>>>(
        h1cl, wp2, b[1], h2, 768, 768, 384, 384, 32);
    mfma_conv_kernel<4, 2, 2, 2, 1, 32, 32, 1, 0><<<dim3(24, 48), blk, 0, stream>>>(
        h2, wp3, b[2], h3, 384, 384, 384, 384, 64);
    mfma_conv_kernel<4, 2, 2, 2, 2, 64, 32, 1, 0><<<dim3(12, 24, 2), blk, 0, stream>>>(
        h3, wp4, b[3], h4, 384, 384, 192, 192, 128);
    mfma_conv_kernel<4, 2, 2, 2, 1, 128, 128, 1, 0><<<dim3(12, 24, 2), blk, 0, stream>>>(
        h4, wp5, b[4], h5, 192, 192, 192, 192, 128);
    mfma_conv_kernel<4, 2, 2, 2, 1, 128, 128, 0, 0><<<dim3(12, 24, 2), blk, 0, stream>>>(
        h5, wp6, b[5], h6, 192, 192, 192, 192, 128);

    // ---- attention inputs ----
    build_fgbgc_kernel<<<dim3(576), blk, 0, stream>>>(h6, mask, fgC, bgC);
    build_bgpk8_kernel<<<dim3(41472), blk, 0, stream>>>(h6, bgpK);

    // ---- G (K=128 Gram, e5m2, x1/8) ----
    g_gemm_kernel<<<dim3(72, 72), blk, 0, stream>>>(fgC, bgC, G);

    // ---- stencil: S8 + Frobenius partials -> scale ----
    sstencil_kernel<<<dim3(18, 2304), blk, 0, stream>>>(G, P8, red);
    sumsq_stage2<<<dim3(1), blk, 0, stream>>>(red, 41472, scale);

    // ---- exp in-place + rowsums -> inv ----
    exp_rows_kernel<<<dim3(2304), blk, 0, stream>>>(P8, scale, rs);
    inv_kernel<<<dim3(36), blk, 0, stream>>>(rs, inv);

    // ---- PV (fp8, single dispatch, K=9216) ----
    pv_fp8_kernel<<<dim3(72, 18), blk, 0, stream>>>(bgpK, P8, R2);

    // ---- fold + mask + upsample ----
    fold_mask_up_kernel<<<dim3(4608), blk, 0, stream>>>(R2, inv, mask, upP);
    p2cl_kernel<<<dim3(1152), blk, 0, stream>>>(upP, upCL);

    // ---- back-end convs ----
    mfma_conv_kernel<4, 2, 2, 2, 1, 128, 128, 1, 0><<<dim3(12, 24, 2), blk, 0, stream>>>(
        upCL, wp7, b[6], h7, 192, 192, 192, 192, 128);
    mfma_conv_kernel<4, 2, 2, 2, 1, 128, 128, 1, 1><<<dim3(12, 24, 2), blk, 0, stream>>>(
        h7, wp8, b[7], h8, 192, 192, 192, 192, 128);
    cl2p_kernel<<<dim3(1152), blk, 0, stream>>>(h8, (float*)d_out);
}

// Round 13
// 738.126 us; speedup vs baseline: 1.5928x; 1.0470x over previous
//
#include <hip/hip_runtime.h>
#include <hip/hip_fp16.h>
#include <math.h>

// ---------------------------------------------------------------------------
// Round 12->13: PV bank-conflict fix via k-permutation of fp8 operands.
// Within each 128B k-block, 8B chunks are stored transposed ((ks,lk)->(lk,ks))
// so each lane's 4 MFMA operands are 32 contiguous bytes -> 2x b128 reads
// (conflict-free 2-way) instead of 4x b64 (4-way). Permutation applied at
// build time (bgpk8 writes permuted; exp_rows writes P8 permuted in-place).
// Everything else identical to round 12 (772 us, absmax 0.078).
// ---------------------------------------------------------------------------

typedef unsigned short u16;
typedef unsigned char u8;
typedef short short4v __attribute__((ext_vector_type(4)));
typedef short short8v __attribute__((ext_vector_type(8)));
typedef float f32x4 __attribute__((ext_vector_type(4)));
typedef long long2v __attribute__((ext_vector_type(2)));

__device__ __forceinline__ u16 f2bf(float f) {
    unsigned u = __float_as_uint(f);
    return (u16)((u + 0x7FFF + ((u >> 16) & 1)) >> 16);
}
__device__ __forceinline__ float bf2f(u16 h) {
    return __uint_as_float(((unsigned)h) << 16);
}
// f32 -> fp8 e5m2 (RNE via fp16 truncation; field-validated)
__device__ __forceinline__ u8 f2e5m2(float f) {
    unsigned short hb = __half_as_ushort(__float2half(f));
    unsigned rem = hb & 0xFF;
    unsigned b = hb >> 8;
    b += (rem > 0x80u) || (rem == 0x80u && (b & 1u));
    return (u8)b;
}
__device__ __forceinline__ float e5m2f(unsigned b) {
    return __half2float(__ushort_as_half((unsigned short)(b << 8)));
}
// f32 -> fp8 e4m3fn (OCP), RNE, saturate (field-validated)
__device__ __forceinline__ u8 f2e4m3(float f) {
    unsigned u = __float_as_uint(f);
    unsigned s = (u >> 24) & 0x80u;
    unsigned a = u & 0x7FFFFFFFu;
    if (a >= 0x43E00000u) return (u8)(s | 0x7Eu);
    int e = (int)(a >> 23) - 127;
    if (e >= -6) {
        unsigned keep = (a >> 20) & 7u;
        unsigned rem  = a & 0xFFFFFu;
        keep += (rem > 0x80000u) || (rem == 0x80000u && (keep & 1u));
        unsigned e4 = (unsigned)(e + 7);
        if (keep == 8u) { keep = 0u; ++e4; }
        if (e4 >= 15u && keep >= 7u) return (u8)(s | 0x7Eu);
        return (u8)(s | (e4 << 3) | keep);
    }
    float q = __uint_as_float(a) * 512.f;
    int m = (int)rintf(q);
    if (m >= 8) return (u8)(s | 0x08u);
    return (u8)(s | (unsigned)m);
}
// 8B-chunk permutation within a 128B k-block: (ks,lk) -> (lk,ks)
__device__ __forceinline__ int perm8(int o8) { return ((o8 & 3) << 2) | (o8 >> 2); }

#define GLOAD16(g, l) __builtin_amdgcn_global_load_lds(                      \
    (const __attribute__((address_space(1))) void*)(g),                      \
    (__attribute__((address_space(3))) void*)(l), 16, 0, 0)

// ---------------- x -> channels-last bf16 ic4 (for conv1 MFMA) --------------
__global__ void x4cl_kernel(const float* __restrict__ x, u16* __restrict__ out)
{
    int i = blockIdx.x * 256 + threadIdx.x;
    if (i >= 589824) return;
    u16 v[4];
    v[0] = f2bf(x[i]);
    v[1] = f2bf(x[589824 + i]);
    v[2] = f2bf(x[1179648 + i]);
    v[3] = 0;
    *(short4v*)(out + (size_t)i * 4) = *(short4v*)v;
}

__global__ void pack_w1_kernel(const float* __restrict__ w, u16* __restrict__ wp)
{
    int i = blockIdx.x * 256 + threadIdx.x;
    if (i >= 4096) return;
    int oc = i >> 7, k = i & 127;
    int tap = k >> 2, ic = k & 3;
    u16 v = 0;
    if (tap < 25 && ic < 3) v = f2bf(w[oc * 75 + ic * 25 + tap]);
    wp[i] = v;
}

// ---------------- conv1 MFMA: 3->32, 5x5, s1, reflect pad2, ELU -------------
__global__ __launch_bounds__(256)
void conv1_mfma_kernel(const u16* __restrict__ x4, const u16* __restrict__ wp1,
                       const float* __restrict__ bias, u16* __restrict__ out)
{
    __shared__ __align__(16) u16 sIn[12 * 20 * 4];
    const int tid = threadIdx.x;
    const int lane = tid & 63;
    const int w = tid >> 6;
    const int lm = lane & 15;
    const int lk = lane >> 4;
    const int oy0 = blockIdx.y * 8, ox0 = blockIdx.x * 16;

    for (int u = tid; u < 240; u += 256) {
        int yt = u / 20, xt = u - yt * 20;
        int gy = oy0 - 2 + yt; gy = gy < 0 ? -gy : (gy >= 768 ? 1534 - gy : gy);
        int gx = ox0 - 2 + xt; gx = gx < 0 ? -gx : (gx >= 768 ? 1534 - gx : gx);
        *(short4v*)(sIn + u * 4) = *(const short4v*)(x4 + ((size_t)gy * 768 + gx) * 4);
    }
    int aoff[4][2];
#pragma unroll
    for (int ks = 0; ks < 4; ++ks) {
        int t0 = ks * 8 + lk * 2;
        int t1 = t0 + 1;
        if (t0 > 24) t0 = 24;
        if (t1 > 24) t1 = 24;
        int dy0 = t0 / 5, dx0 = t0 - 5 * dy0;
        int dy1 = t1 / 5, dx1 = t1 - 5 * dy1;
        aoff[ks][0] = (dy0 * 20 + dx0 + lm) * 4;
        aoff[ks][1] = (dy1 * 20 + dx1 + lm) * 4;
    }
    __syncthreads();

    f32x4 acc[2][2];
#pragma unroll
    for (int i = 0; i < 2; ++i)
#pragma unroll
        for (int j = 0; j < 2; ++j) acc[i][j] = (f32x4){0.f, 0.f, 0.f, 0.f};

#pragma unroll
    for (int ks = 0; ks < 4; ++ks) {
        short8v a[2], b[2];
#pragma unroll
        for (int fm = 0; fm < 2; ++fm) {
            int base = (w * 2 + fm) * 80;
            short4v lo = *(const short4v*)(sIn + base + aoff[ks][0]);
            short4v hi = *(const short4v*)(sIn + base + aoff[ks][1]);
            short8v av;
            av[0] = lo[0]; av[1] = lo[1]; av[2] = lo[2]; av[3] = lo[3];
            av[4] = hi[0]; av[5] = hi[1]; av[6] = hi[2]; av[7] = hi[3];
            a[fm] = av;
        }
#pragma unroll
        for (int fn = 0; fn < 2; ++fn)
            b[fn] = *(const short8v*)(wp1 + (size_t)(fn * 16 + lm) * 128 + ks * 32 + lk * 8);
#pragma unroll
        for (int fm = 0; fm < 2; ++fm)
#pragma unroll
            for (int fn = 0; fn < 2; ++fn)
                acc[fm][fn] = __builtin_amdgcn_mfma_f32_16x16x32_bf16(
                    a[fm], b[fn], acc[fm][fn], 0, 0, 0);
    }

#pragma unroll
    for (int fm = 0; fm < 2; ++fm) {
        int gy = oy0 + w * 2 + fm;
#pragma unroll
        for (int fn = 0; fn < 2; ++fn) {
            int oc = fn * 16 + lm;
            float bv = bias[oc];
#pragma unroll
            for (int i = 0; i < 4; ++i) {
                int xx = lk * 4 + i;
                float v = acc[fm][fn][i] + bv;
                v = v > 0.f ? v : expm1f(v);
                out[((size_t)gy * 768 + ox0 + xx) * 32 + oc] = f2bf(v);
            }
        }
    }
}

// ---------------- weight prepack ----------------
__global__ void pack_w_kernel(const float* __restrict__ w, u16* __restrict__ wp,
                              int OC, int IC)
{
    int idx = blockIdx.x * 256 + threadIdx.x;
    if (idx >= OC * 9 * IC) return;
    int oc = idx / (9 * IC);
    int r  = idx - oc * 9 * IC;
    int tap = r / IC;
    int ic  = r - tap * IC;
    wp[idx] = f2bf(w[((size_t)oc * IC + ic) * 9 + tap]);
}

// ---------------- MFMA implicit-GEMM conv (3x3, reflect pad 1) --------------
template<int FM, int FN, int NWM, int NWN, int S, int IC, int ICC, int ACT, int OUTF32>
__global__ __launch_bounds__(256)
void mfma_conv_kernel(const u16* __restrict__ in, const u16* __restrict__ wgtP,
                      const float* __restrict__ bias, void* __restrict__ out,
                      int H, int W, int Ho, int Wo, int OC)
{
    constexpr int TY = 7 * S + 3;
    constexpr int TX = 15 * S + 3;
    constexpr int NSLOT = ICC / 8;
    constexpr int SWMSK = NSLOT - 1;
    constexpr int KTOT = 9 * IC;
    __shared__ __align__(16) u16 sIn[TY * TX * ICC];

    const int tid  = threadIdx.x;
    const int lane = tid & 63;
    const int wid  = tid >> 6;
    const int wmi  = wid / NWN;
    const int wni  = wid % NWN;
    const int lm   = lane & 15;
    const int lk   = lane >> 4;
    const int noff = blockIdx.z * (NWN * FN * 16);

    f32x4 acc[FM][FN];
#pragma unroll
    for (int i = 0; i < FM; ++i)
#pragma unroll
        for (int j = 0; j < FN; ++j) acc[i][j] = (f32x4){0.f, 0.f, 0.f, 0.f};

    const int iy0 = blockIdx.y * 8 * S - 1;
    const int ix0 = blockIdx.x * 16 * S - 1;

    for (int c0 = 0; c0 < IC; c0 += ICC) {
        if (c0) __syncthreads();
        for (int u = tid; u < TY * TX * NSLOT; u += 256) {
            int yt = u / (TX * NSLOT);
            int r  = u - yt * (TX * NSLOT);
            int xt = r / NSLOT;
            int sl = r - xt * NSLOT;
            int gy = iy0 + yt; gy = gy < 0 ? -gy : (gy >= H ? 2 * H - 2 - gy : gy);
            int gx = ix0 + xt; gx = gx < 0 ? -gx : (gx >= W ? 2 * W - 2 - gx : gx);
            *(short8v*)((char*)sIn + (size_t)((yt * TX + xt) * NSLOT + (sl ^ (xt & SWMSK))) * 16) =
                *(const short8v*)(in + ((size_t)gy * W + gx) * IC + c0 + sl * 8);
        }
        __syncthreads();
#pragma unroll
        for (int tap = 0; tap < 9; ++tap) {
            const int dy = tap / 3, dx = tap % 3;
#pragma unroll
            for (int icw = 0; icw < ICC / 32; ++icw) {
                short8v a[FM], b[FN];
#pragma unroll
                for (int fm = 0; fm < FM; ++fm) {
                    int yt = (wmi * FM + fm) * S + dy;
                    int xt = lm * S + dx;
                    a[fm] = *(const short8v*)((const char*)sIn +
                        (size_t)((yt * TX + xt) * NSLOT + ((icw * 4 + lk) ^ (xt & SWMSK))) * 16);
                }
#pragma unroll
                for (int fn = 0; fn < FN; ++fn) {
                    int n = noff + wni * FN * 16 + fn * 16 + lm;
                    b[fn] = *(const short8v*)(wgtP + (size_t)n * KTOT + tap * IC + c0 + icw * 32 + lk * 8);
                }
#pragma unroll
                for (int fm = 0; fm < FM; ++fm)
#pragma unroll
                    for (int fn = 0; fn < FN; ++fn)
                        acc[fm][fn] = __builtin_amdgcn_mfma_f32_16x16x32_bf16(
                            a[fm], b[fn], acc[fm][fn], 0, 0, 0);
            }
        }
    }

#pragma unroll
    for (int fm = 0; fm < FM; ++fm) {
        int y = blockIdx.y * 8 + wmi * FM + fm;
#pragma unroll
        for (int fn = 0; fn < FN; ++fn) {
            int oc = noff + wni * FN * 16 + fn * 16 + lm;
            float bv = bias[oc];
#pragma unroll
            for (int i = 0; i < 4; ++i) {
                int x = blockIdx.x * 16 + lk * 4 + i;
                float v = acc[fm][fn][i] + bv;
                if (ACT == 0) v = v > 0.f ? v : 0.f;
                else          v = v > 0.f ? v : expm1f(v);
                size_t o = ((size_t)y * Wo + x) * OC + oc;
                if (OUTF32) ((float*)out)[o] = v;
                else        ((u16*)out)[o]   = f2bf(v);
            }
        }
    }
}

// channels-last f32 [36864][128] -> planar f32 [128][36864]
__global__ __launch_bounds__(256)
void cl2p_kernel(const float* __restrict__ in, float* __restrict__ out)
{
    __shared__ float t[32][130];
    const int tid = threadIdx.x;
    const int p0 = blockIdx.x * 32;
#pragma unroll
    for (int j = 0; j < 16; ++j) {
        int idx = j * 256 + tid;
        int px = idx >> 7, c = idx & 127;
        t[px][c] = in[(size_t)(p0 + px) * 128 + c];
    }
    __syncthreads();
#pragma unroll
    for (int j = 0; j < 16; ++j) {
        int c = j * 8 + (tid >> 5);
        int px = tid & 31;
        out[(size_t)c * 36864 + p0 + px] = t[px][c];
    }
}

// planar f32 [128][36864] -> channels-last bf16 [36864][128]
__global__ __launch_bounds__(256)
void p2cl_kernel(const float* __restrict__ in, u16* __restrict__ out)
{
    __shared__ float t[32][130];
    const int tid = threadIdx.x;
    const int p0 = blockIdx.x * 32;
#pragma unroll
    for (int j = 0; j < 16; ++j) {
        int c = j * 8 + (tid >> 5);
        int px = tid & 31;
        t[px][c] = in[(size_t)c * 36864 + p0 + px];
    }
    __syncthreads();
#pragma unroll
    for (int j = 0; j < 16; ++j) {
        int idx = j * 256 + tid;
        int px = idx >> 7, c = idx & 127;
        out[(size_t)(p0 + px) * 128 + c] = f2bf(t[px][c]);
    }
}

// ---------------- half-res channel-last images: fgC (masked), bgC -----------
__global__ void build_fgbgc_kernel(const u16* __restrict__ h6, const float* __restrict__ mask,
                                   u16* __restrict__ fgC, u16* __restrict__ bgC)
{
    int idx = blockIdx.x * 256 + threadIdx.x;   // 9216*16
    if (idx >= 147456) return;
    int q = idx >> 4, cs = (idx & 15) * 8;
    int qy = q / 96, qx = q - qy * 96;
    const u16* src = h6 + ((size_t)(2 * qy) * 192 + 2 * qx) * 128 + cs;
    float m = mask[(size_t)(2 * qy) * 192 + 2 * qx];
    short8v v = *(const short8v*)src;
    u16 fo[8];
#pragma unroll
    for (int j = 0; j < 8; ++j) fo[j] = f2bf(bf2f((u16)v[j]) * m);
    *(short8v*)(bgC + (size_t)q * 128 + cs) = v;
    *(short8v*)(fgC + (size_t)q * 128 + cs) = *(short8v*)fo;
}

// ---------------- bgpK8: e4m3 patch matrix [1152][9216], K-PERMUTED ---------
__global__ void build_bgpk8_kernel(const u16* __restrict__ h6, u8* __restrict__ bgpK)
{
    int idx = blockIdx.x * 256 + threadIdx.x;   // 1152*9216
    if (idx >= 1152 * 9216) return;
    int k = idx / 9216, q = idx - k * 9216;
    int y = q / 96, x = q - y * 96;
    int c = k / 9, t = k - c * 9;
    int dy = t / 3, dx = t - dy * 3;
    int sy = y + dy - 1, sx = x + dx - 1;
    float v = 0.f;
    if (sy >= 0 && sy < 96 && sx >= 0 && sx < 96)
        v = bf2f(h6[((size_t)(2 * sy) * 192 + 2 * sx) * 128 + c]);
    // permuted write position within the 128B k-block
    int qb = q >> 7, o = q & 127;
    int n = perm8(o >> 3) * 8 + (o & 7);
    bgpK[(size_t)k * 9216 + (qb << 7) + n] = f2e4m3(v);
}

// ---------------- G-GEMM: G[a][b] = 1/8 * sum_c fgC[a][c]*bgC[b][c] ---------
__global__ __launch_bounds__(256)
void g_gemm_kernel(const u16* __restrict__ A, const u16* __restrict__ B,
                   u8* __restrict__ G)
{
    __shared__ __align__(16) u16 As[128 * 64];
    __shared__ __align__(16) u16 Bs[128 * 64];
    const int tid  = threadIdx.x;
    const int wid  = tid >> 6;
    const int lane = tid & 63;
    const int wm = (wid >> 1) * 64;
    const int wn = (wid & 1) * 64;
    const size_t bm = (size_t)blockIdx.y * 128;
    const size_t bn = (size_t)blockIdx.x * 128;

    f32x4 acc[4][4];
#pragma unroll
    for (int i = 0; i < 4; ++i)
#pragma unroll
        for (int j = 0; j < 4; ++j)
            acc[i][j] = (f32x4){0.f, 0.f, 0.f, 0.f};

    const int lrow = lane >> 3;
    const int lcb  = ((lane & 7) << 4) ^ ((lrow & 7) << 4);
    const char* gA = (const char*)A + ((bm + wid * 32 + lrow) * (size_t)128) * 2 + lcb;
    const char* gB = (const char*)B + ((bn + wid * 32 + lrow) * (size_t)128) * 2 + lcb;
    char* lA = (char*)As + (size_t)(wid * 32) * 128;
    char* lB = (char*)Bs + (size_t)(wid * 32) * 128;
    const size_t rs8 = (size_t)128 * 16;

    for (int k0 = 0; k0 < 128; k0 += 64) {
        __syncthreads();
#pragma unroll
        for (int j = 0; j < 4; ++j) {
            GLOAD16(gA + j * rs8 + (size_t)k0 * 2, lA + j * 1024);
            GLOAD16(gB + j * rs8 + (size_t)k0 * 2, lB + j * 1024);
        }
        __syncthreads();
#pragma unroll
        for (int ks = 0; ks < 2; ++ks) {
            short8v a[4], b[4];
#pragma unroll
            for (int f = 0; f < 4; ++f) {
                int ma = wm + f * 16 + (lane & 15);
                int kba = (ks * 64 + ((lane >> 4) * 16)) ^ ((ma & 7) << 4);
                a[f] = *(const short8v*)((const char*)As + ma * 128 + kba);
                int nb = wn + f * 16 + (lane & 15);
                int kbb = (ks * 64 + ((lane >> 4) * 16)) ^ ((nb & 7) << 4);
                b[f] = *(const short8v*)((const char*)Bs + nb * 128 + kbb);
            }
#pragma unroll
            for (int fm = 0; fm < 4; ++fm)
#pragma unroll
                for (int fn = 0; fn < 4; ++fn)
                    acc[fm][fn] = __builtin_amdgcn_mfma_f32_16x16x32_bf16(
                        a[fm], b[fn], acc[fm][fn], 0, 0, 0);
        }
    }

#pragma unroll
    for (int fm = 0; fm < 4; ++fm)
#pragma unroll
        for (int fn = 0; fn < 4; ++fn)
#pragma unroll
            for (int i = 0; i < 4; ++i) {
                int r = wm + fm * 16 + ((lane >> 4) * 4) + i;
                int c = wn + fn * 16 + (lane & 15);
                G[(bm + r) * (size_t)9216 + bn + c] = f2e5m2(0.125f * acc[fm][fn][i]);
            }
}

// ---------------- stencil pass: S8 = stencil(G), partial = sum S^2 ----------
__global__ __launch_bounds__(256)
void sstencil_kernel(const u8* __restrict__ G, u8* __restrict__ S8,
                     double* __restrict__ partial)
{
    const int wid  = threadIdx.x >> 6;
    const int lane = threadIdx.x & 63;
    const int p = blockIdx.y * 4 + wid;
    const int py = p / 96, px = p - py * 96;
    const int q0 = blockIdx.x * 512 + lane * 8;
    const int qy = q0 / 96, qx0 = q0 - qy * 96;

    float acc[8];
#pragma unroll
    for (int j = 0; j < 8; ++j) acc[j] = 0.f;

#pragma unroll
    for (int ey = -1; ey <= 1; ++ey) {
#pragma unroll
        for (int ex = -1; ex <= 1; ++ex) {
            if ((unsigned)(py + ey) >= 96u || (unsigned)(px + ex) >= 96u) continue;
            if ((unsigned)(qy + ey) >= 96u) continue;
            const int e = ey * 96 + ex;
            const u8* rp = G + (size_t)(p + e) * 9216;
            const int cc = q0 + e;
            unsigned long long v8;
            if (ex == 0) {
                v8 = *(const unsigned long long*)(rp + cc);
            } else {
                int base = cc & ~7;
                int sh = (cc & 7) * 8;
                unsigned long long lo = *(const unsigned long long*)(rp + base);
                unsigned long long hi = *(const unsigned long long*)(rp + base + 8);
                v8 = (lo >> sh) | (hi << (64 - sh));
            }
#pragma unroll
            for (int j = 0; j < 8; ++j) {
                if ((unsigned)(qx0 + j + ex) >= 96u) continue;
                acc[j] += e5m2f((unsigned)(v8 >> (8 * j)) & 0xFFu);
            }
        }
    }

    unsigned long long ow = 0;
    double s2 = 0.0;
#pragma unroll
    for (int j = 0; j < 8; ++j) {
        ow |= (unsigned long long)f2e5m2(acc[j]) << (8 * j);
        s2 += (double)acc[j] * (double)acc[j];
    }
    *(unsigned long long*)(S8 + (size_t)p * 9216 + q0) = ow;

    for (int off = 32; off; off >>= 1) s2 += __shfl_down(s2, off, 64);
    __shared__ double wsum[4];
    if (lane == 0) wsum[wid] = s2;
    __syncthreads();
    if (threadIdx.x == 0)
        partial[(size_t)blockIdx.y * 18 + blockIdx.x] = wsum[0] + wsum[1] + wsum[2] + wsum[3];
}

__global__ void sumsq_stage2(const double* __restrict__ partial, int nblocks, float* __restrict__ scale)
{
    double s = 0.0;
    for (int i = threadIdx.x; i < nblocks; i += 256) s += partial[i];
    for (int off = 32; off; off >>= 1) s += __shfl_down(s, off, 64);
    __shared__ double wsum[4];
    int lane = threadIdx.x & 63, wid = threadIdx.x >> 6;
    if (lane == 0) wsum[wid] = s;
    __syncthreads();
    if (threadIdx.x == 0) {
        double nrm = sqrt(wsum[0] + wsum[1] + wsum[2] + wsum[3]);
        if (nrm < 1e-12) nrm = 1e-12;
        *scale = (float)(10.0 / nrm);
    }
}

// ---------------- exp pass: P8 = e5m2(exp(scale*S8)), K-PERMUTED in-place ---
// Reads S8 linear, writes permuted chunk within the same 128B block.
// Safe in-place: per unrolled iteration, the wave's loads complete before its
// stores issue; permutation stays within each iteration's 512B window.
__global__ __launch_bounds__(256)
void exp_rows_kernel(u8* __restrict__ P8, const float* __restrict__ scale_p,
                     float* __restrict__ rs)
{
    const int wid = threadIdx.x >> 6, lane = threadIdx.x & 63;
    const int p = blockIdx.x * 4 + wid;   // grid 2304
    u8* rp = P8 + (size_t)p * 9216;
    const float scale = *scale_p;
    const int rdo = lane * 8;                                  // linear read chunk
    const int wro = (lane >> 4) * 128 + perm8(lane & 15) * 8;  // permuted write chunk
    float s = 0.f;
#pragma unroll
    for (int it = 0; it < 18; ++it) {
        unsigned long long v8 = *(unsigned long long*)(rp + it * 512 + rdo);
        unsigned long long ow = 0;
#pragma unroll
        for (int j = 0; j < 8; ++j) {
            float sv = e5m2f((unsigned)(v8 >> (8 * j)) & 0xFFu);
            u8 e8 = f2e5m2(__expf(scale * sv));
            ow |= (unsigned long long)e8 << (8 * j);
            s += e5m2f(e8);
        }
        *(unsigned long long*)(rp + it * 512 + wro) = ow;
    }
    for (int off = 32; off; off >>= 1) s += __shfl_down(s, off, 64);
    if (lane == 0) rs[p] = s;
}

__global__ void inv_kernel(const float* __restrict__ rs, float* __restrict__ inv)
{
    int i = blockIdx.x * 256 + threadIdx.x;
    if (i < 9216) inv[i] = 1.f / rs[i];
}

// ---------------- PV fp8: R2[c9][p] = sum_q bgpK8[c9][q] * P8[p][q] ---------
// Operands stored K-PERMUTED: lane's 4 ks operands = 32 contiguous bytes
// -> 2x b128 reads per fragment (2-way bank, free). grid (72,18).
__global__ __launch_bounds__(256)
void pv_fp8_kernel(const u8* __restrict__ A, const u8* __restrict__ B,
                   float* __restrict__ outF)
{
    __shared__ __align__(16) u8 As[64 * 128];
    __shared__ __align__(16) u8 Bs[128 * 128];
    const int tid  = threadIdx.x;
    const int wid  = tid >> 6;
    const int lane = tid & 63;
    const int wm = (wid >> 1) * 32;
    const int wn = (wid & 1) * 64;
    const size_t bm = (size_t)blockIdx.y * 64;
    const size_t bn = (size_t)blockIdx.x * 128;

    f32x4 acc[2][4];
#pragma unroll
    for (int i = 0; i < 2; ++i)
#pragma unroll
        for (int j = 0; j < 4; ++j)
            acc[i][j] = (f32x4){0.f, 0.f, 0.f, 0.f};

    const int lrow = lane >> 3;
    const int lcb  = ((lane & 7) << 4) ^ ((lrow & 7) << 4);
    const u8* gA = A + (bm + wid * 16 + lrow) * (size_t)9216 + lcb;
    const u8* gB = B + (bn + wid * 32 + lrow) * (size_t)9216 + lcb;
    u8* lA = As + (size_t)(wid * 16) * 128;
    u8* lB = Bs + (size_t)(wid * 32) * 128;
    const size_t rstep = (size_t)9216 * 8;
    const int lm = lane & 15, lk = lane >> 4;

    for (int k0 = 0; k0 < 9216; k0 += 128) {
        __syncthreads();
#pragma unroll
        for (int j = 0; j < 2; ++j)
            GLOAD16(gA + j * rstep + k0, lA + j * 1024);
#pragma unroll
        for (int j = 0; j < 4; ++j)
            GLOAD16(gB + j * rstep + k0, lB + j * 1024);
        __syncthreads();

        long2v aop[2][2], bop[4][2];
#pragma unroll
        for (int f = 0; f < 2; ++f) {
            int ma = wm + f * 16 + lm;
            int sw = (ma & 7) << 4;
            const u8* pr = As + ma * 128;
            aop[f][0] = *(const long2v*)(pr + ((lk * 32) ^ sw));
            aop[f][1] = *(const long2v*)(pr + ((lk * 32 + 16) ^ sw));
        }
#pragma unroll
        for (int f = 0; f < 4; ++f) {
            int nb = wn + f * 16 + lm;
            int sw = (nb & 7) << 4;
            const u8* pr = Bs + nb * 128;
            bop[f][0] = *(const long2v*)(pr + ((lk * 32) ^ sw));
            bop[f][1] = *(const long2v*)(pr + ((lk * 32 + 16) ^ sw));
        }
#pragma unroll
        for (int ks = 0; ks < 4; ++ks)
#pragma unroll
            for (int fm = 0; fm < 2; ++fm)
#pragma unroll
                for (int fn = 0; fn < 4; ++fn)
                    acc[fm][fn] = __builtin_amdgcn_mfma_f32_16x16x32_fp8_bf8(
                        aop[fm][ks >> 1][ks & 1], bop[fn][ks >> 1][ks & 1],
                        acc[fm][fn], 0, 0, 0);
    }

#pragma unroll
    for (int fm = 0; fm < 2; ++fm)
#pragma unroll
        for (int fn = 0; fn < 4; ++fn)
#pragma unroll
            for (int i = 0; i < 4; ++i) {
                int r = wm + fm * 16 + ((lane >> 4) * 4) + i;
                int c = wn + fn * 16 + (lane & 15);
                outF[(bm + r) * (size_t)9216 + bn + c] = acc[fm][fn][i];
            }
}

// ---------------- fold + mask + upsample (planar fp32 out) ------------------
__global__ void fold_mask_up_kernel(const float* __restrict__ R2,
                                    const float* __restrict__ inv,
                                    const float* __restrict__ mask,
                                    float* __restrict__ up)
{
    int idx = blockIdx.x * 256 + threadIdx.x; // 128*96*96
    if (idx >= 128 * 96 * 96) return;
    int x = idx % 96;
    int y = (idx / 96) % 96;
    int c = idx / (96 * 96);
    float s = 0.f;
#pragma unroll
    for (int dy = 0; dy < 3; ++dy) {
        int yy = y + 1 - dy;
        if (yy < 0 || yy >= 96) continue;
#pragma unroll
        for (int dx = 0; dx < 3; ++dx) {
            int xx = x + 1 - dx;
            if (xx < 0 || xx >= 96) continue;
            int pp = yy * 96 + xx;
            s += R2[(size_t)(c * 9 + dy * 3 + dx) * 9216 + pp] * inv[pp];
        }
    }
    s *= mask[(size_t)(2 * y) * 192 + 2 * x];
    size_t base = (size_t)c * 192 * 192;
    up[base + (size_t)(2 * y) * 192 + 2 * x]         = s;
    up[base + (size_t)(2 * y) * 192 + 2 * x + 1]     = s;
    up[base + (size_t)(2 * y + 1) * 192 + 2 * x]     = s;
    up[base + (size_t)(2 * y + 1) * 192 + 2 * x + 1] = s;
}

// ---------------------------------------------------------------------------
extern "C" void kernel_launch(void* const* d_in, const int* in_sizes, int n_in,
                              void* d_out, int out_size, void* d_ws, size_t ws_size,
                              hipStream_t stream)
{
    const float* x    = (const float*)d_in[0];
    const float* mask = (const float*)d_in[1];
    const float* w[8];
    const float* b[8];
    for (int i = 0; i < 8; ++i) {
        w[i] = (const float*)d_in[2 + 2 * i];
        b[i] = (const float*)d_in[3 + 2 * i];
    }
    char* ws = (char*)d_ws;
    dim3 blk(256);

    // byte offsets (identical to round 12; peak 187.0 MB, proven safe)
    const size_t U_H1CL = 0;
    const size_t U_H2   = 37748736;
    const size_t U_H3   = 47185920;
    const size_t U_H4   = 66060288;
    const size_t U_H5   = 75497472;
    const size_t U_H6   = 84934656;
    const size_t U_X4   = 94371840;
    const size_t U_FGC  = 0;
    const size_t U_BGC  = 2359296;
    const size_t B_BGPK = 4718592;
    const size_t B_G    = 15335424;
    const size_t B_P8   = 100270080;
    const size_t F_R2   = 15335424;
    const size_t F_UP   = 57802752;
    const size_t U_UPCL = 76677120;
    const size_t U_H7   = 86114304;
    const size_t F_H8   = 95551488;
    const size_t U_WP1  = 185204736;
    const size_t U_WP2  = 185212928;
    const size_t U_WP3  = 185231360;
    const size_t U_WP4  = 185268224;
    const size_t U_WP5  = 185415680;
    const size_t U_WP6  = 185710592;
    const size_t U_WP7  = 186005504;
    const size_t U_WP8  = 186300416;
    const size_t D_RED  = 186595328;
    const size_t F_SCALE= 186927104;
    const size_t F_RS   = 186927360;
    const size_t F_INV  = 186964224;

    u16* h1cl   = (u16*)(ws + U_H1CL);
    u16* h2     = (u16*)(ws + U_H2);
    u16* h3     = (u16*)(ws + U_H3);
    u16* h4     = (u16*)(ws + U_H4);
    u16* h5     = (u16*)(ws + U_H5);
    u16* h6     = (u16*)(ws + U_H6);
    u16* x4     = (u16*)(ws + U_X4);
    u16* fgC    = (u16*)(ws + U_FGC);
    u16* bgC    = (u16*)(ws + U_BGC);
    u8*  bgpK   = (u8*)(ws + B_BGPK);
    u8*  G      = (u8*)(ws + B_G);
    u8*  P8     = (u8*)(ws + B_P8);
    float* R2   = (float*)(ws + F_R2);
    float* upP  = (float*)(ws + F_UP);
    u16* upCL   = (u16*)(ws + U_UPCL);
    u16* h7     = (u16*)(ws + U_H7);
    float* h8   = (float*)(ws + F_H8);
    u16* wp1    = (u16*)(ws + U_WP1);
    u16* wp2    = (u16*)(ws + U_WP2);
    u16* wp3    = (u16*)(ws + U_WP3);
    u16* wp4    = (u16*)(ws + U_WP4);
    u16* wp5    = (u16*)(ws + U_WP5);
    u16* wp6    = (u16*)(ws + U_WP6);
    u16* wp7    = (u16*)(ws + U_WP7);
    u16* wp8    = (u16*)(ws + U_WP8);
    double* red = (double*)(ws + D_RED);
    float* scale= (float*)(ws + F_SCALE);
    float* rs   = (float*)(ws + F_RS);
    float* inv  = (float*)(ws + F_INV);

    // ---- prepack ----
    pack_w1_kernel<<<dim3(16), blk, 0, stream>>>(w[0], wp1);
    pack_w_kernel<<<dim3(36),  blk, 0, stream>>>(w[1], wp2, 32, 32);
    pack_w_kernel<<<dim3(72),  blk, 0, stream>>>(w[2], wp3, 64, 32);
    pack_w_kernel<<<dim3(288), blk, 0, stream>>>(w[3], wp4, 128, 64);
    pack_w_kernel<<<dim3(576), blk, 0, stream>>>(w[4], wp5, 128, 128);
    pack_w_kernel<<<dim3(576), blk, 0, stream>>>(w[5], wp6, 128, 128);
    pack_w_kernel<<<dim3(576), blk, 0, stream>>>(w[6], wp7, 128, 128);
    pack_w_kernel<<<dim3(576), blk, 0, stream>>>(w[7], wp8, 128, 128);
    x4cl_kernel<<<dim3(2304), blk, 0, stream>>>(x, x4);

    // ---- conv front-end ----
    conv1_mfma_kernel<<<dim3(48, 96), blk, 0, stream>>>(x4, wp1, b[0], h1cl);
    mfma_conv_kernel<4, 1, 2, 2, 2, 32, 32, 1, 0><<<dim3(24, 48), blk, 0, stream>>>(
        h1cl, wp2, b[1], h2, 768, 768, 384, 384, 32);
    mfma_conv_kernel<4, 2, 2, 2, 1, 32, 32, 1, 0><<<dim3(24, 48), blk, 0, stream>>>(
        h2, wp3, b[2], h3, 384, 384, 384, 384, 64);
    mfma_conv_kernel<4, 2, 2, 2, 2, 64, 32, 1, 0><<<dim3(12, 24, 2), blk, 0, stream>>>(
        h3, wp4, b[3], h4, 384, 384, 192, 192, 128);
    mfma_conv_kernel<4, 2, 2, 2, 1, 128, 128, 1, 0><<<dim3(12, 24, 2), blk, 0, stream>>>(
        h4, wp5, b[4], h5, 192, 192, 192, 192, 128);
    mfma_conv_kernel<4, 2, 2, 2, 1, 128, 128, 0, 0><<<dim3(12, 24, 2), blk, 0, stream>>>(
        h5, wp6, b[5], h6, 192, 192, 192, 192, 128);

    // ---- attention inputs ----
    build_fgbgc_kernel<<<dim3(576), blk, 0, stream>>>(h6, mask, fgC, bgC);
    build_bgpk8_kernel<<<dim3(41472), blk, 0, stream>>>(h6, bgpK);

    // ---- G (K=128 Gram, e5m2, x1/8) ----
    g_gemm_kernel<<<dim3(72, 72), blk, 0, stream>>>(fgC, bgC, G);

    // ---- stencil: S8 + Frobenius partials -> scale ----
    sstencil_kernel<<<dim3(18, 2304), blk, 0, stream>>>(G, P8, red);
    sumsq_stage2<<<dim3(1), blk, 0, stream>>>(red, 41472, scale);

    // ---- exp in-place (writes k-permuted P8) + rowsums -> inv ----
    exp_rows_kernel<<<dim3(2304), blk, 0, stream>>>(P8, scale, rs);
    inv_kernel<<<dim3(36), blk, 0, stream>>>(rs, inv);

    // ---- PV (fp8, single dispatch, K=9216, permuted operands) ----
    pv_fp8_kernel<<<dim3(72, 18), blk, 0, stream>>>(bgpK, P8, R2);

    // ---- fold + mask + upsample ----
    fold_mask_up_kernel<<<dim3(4608), blk, 0, stream>>>(R2, inv, mask, upP);
    p2cl_kernel<<<dim3(1152), blk, 0, stream>>>(upP, upCL);

    // ---- back-end convs ----
    mfma_conv_kernel<4, 2, 2, 2, 1, 128, 128, 1, 0><<<dim3(12, 24, 2), blk, 0, stream>>>(
        upCL, wp7, b[6], h7, 192, 192, 192, 192, 128);
    mfma_conv_kernel<4, 2, 2, 2, 1, 128, 128, 1, 1><<<dim3(12, 24, 2), blk, 0, stream>>>(
        h7, wp8, b[7], h8, 192, 192, 192, 192, 128);
    cl2p_kernel<<<dim3(1152), blk, 0, stream>>>(h8, (float*)d_out);
}

// Round 14
// 727.315 us; speedup vs baseline: 1.6165x; 1.0149x over previous
//
#include <hip/hip_runtime.h>
#include <hip/hip_fp16.h>
#include <math.h>

// ---------------------------------------------------------------------------
// Round 13->14: fp16-packed stencil accumulation (v_pk_add_f16, ~2x VALU cut)
// + vectorized bgpK8 builder (8 q per thread). Everything else identical to
// round 13 (738 us, absmax 0.078): G-stencil attention, k-permuted fp8 PV.
// ---------------------------------------------------------------------------

typedef unsigned short u16;
typedef unsigned char u8;
typedef short short4v __attribute__((ext_vector_type(4)));
typedef short short8v __attribute__((ext_vector_type(8)));
typedef float f32x4 __attribute__((ext_vector_type(4)));
typedef long long2v __attribute__((ext_vector_type(2)));

__device__ __forceinline__ u16 f2bf(float f) {
    unsigned u = __float_as_uint(f);
    return (u16)((u + 0x7FFF + ((u >> 16) & 1)) >> 16);
}
__device__ __forceinline__ float bf2f(u16 h) {
    return __uint_as_float(((unsigned)h) << 16);
}
// f32 -> fp8 e5m2 (RNE via fp16 truncation; field-validated)
__device__ __forceinline__ u8 f2e5m2(float f) {
    unsigned short hb = __half_as_ushort(__float2half(f));
    unsigned rem = hb & 0xFF;
    unsigned b = hb >> 8;
    b += (rem > 0x80u) || (rem == 0x80u && (b & 1u));
    return (u8)b;
}
__device__ __forceinline__ float e5m2f(unsigned b) {
    return __half2float(__ushort_as_half((unsigned short)(b << 8)));
}
// f32 -> fp8 e4m3fn (OCP), RNE, saturate (field-validated)
__device__ __forceinline__ u8 f2e4m3(float f) {
    unsigned u = __float_as_uint(f);
    unsigned s = (u >> 24) & 0x80u;
    unsigned a = u & 0x7FFFFFFFu;
    if (a >= 0x43E00000u) return (u8)(s | 0x7Eu);
    int e = (int)(a >> 23) - 127;
    if (e >= -6) {
        unsigned keep = (a >> 20) & 7u;
        unsigned rem  = a & 0xFFFFFu;
        keep += (rem > 0x80000u) || (rem == 0x80000u && (keep & 1u));
        unsigned e4 = (unsigned)(e + 7);
        if (keep == 8u) { keep = 0u; ++e4; }
        if (e4 >= 15u && keep >= 7u) return (u8)(s | 0x7Eu);
        return (u8)(s | (e4 << 3) | keep);
    }
    float q = __uint_as_float(a) * 512.f;
    int m = (int)rintf(q);
    if (m >= 8) return (u8)(s | 0x08u);
    return (u8)(s | (unsigned)m);
}
// 8B-chunk permutation within a 128B k-block: (ks,lk) -> (lk,ks)
__device__ __forceinline__ int perm8(int o8) { return ((o8 & 3) << 2) | (o8 >> 2); }

#define GLOAD16(g, l) __builtin_amdgcn_global_load_lds(                      \
    (const __attribute__((address_space(1))) void*)(g),                      \
    (__attribute__((address_space(3))) void*)(l), 16, 0, 0)

// ---------------- x -> channels-last bf16 ic4 (for conv1 MFMA) --------------
__global__ void x4cl_kernel(const float* __restrict__ x, u16* __restrict__ out)
{
    int i = blockIdx.x * 256 + threadIdx.x;
    if (i >= 589824) return;
    u16 v[4];
    v[0] = f2bf(x[i]);
    v[1] = f2bf(x[589824 + i]);
    v[2] = f2bf(x[1179648 + i]);
    v[3] = 0;
    *(short4v*)(out + (size_t)i * 4) = *(short4v*)v;
}

__global__ void pack_w1_kernel(const float* __restrict__ w, u16* __restrict__ wp)
{
    int i = blockIdx.x * 256 + threadIdx.x;
    if (i >= 4096) return;
    int oc = i >> 7, k = i & 127;
    int tap = k >> 2, ic = k & 3;
    u16 v = 0;
    if (tap < 25 && ic < 3) v = f2bf(w[oc * 75 + ic * 25 + tap]);
    wp[i] = v;
}

// ---------------- conv1 MFMA: 3->32, 5x5, s1, reflect pad2, ELU -------------
__global__ __launch_bounds__(256)
void conv1_mfma_kernel(const u16* __restrict__ x4, const u16* __restrict__ wp1,
                       const float* __restrict__ bias, u16* __restrict__ out)
{
    __shared__ __align__(16) u16 sIn[12 * 20 * 4];
    const int tid = threadIdx.x;
    const int lane = tid & 63;
    const int w = tid >> 6;
    const int lm = lane & 15;
    const int lk = lane >> 4;
    const int oy0 = blockIdx.y * 8, ox0 = blockIdx.x * 16;

    for (int u = tid; u < 240; u += 256) {
        int yt = u / 20, xt = u - yt * 20;
        int gy = oy0 - 2 + yt; gy = gy < 0 ? -gy : (gy >= 768 ? 1534 - gy : gy);
        int gx = ox0 - 2 + xt; gx = gx < 0 ? -gx : (gx >= 768 ? 1534 - gx : gx);
        *(short4v*)(sIn + u * 4) = *(const short4v*)(x4 + ((size_t)gy * 768 + gx) * 4);
    }
    int aoff[4][2];
#pragma unroll
    for (int ks = 0; ks < 4; ++ks) {
        int t0 = ks * 8 + lk * 2;
        int t1 = t0 + 1;
        if (t0 > 24) t0 = 24;
        if (t1 > 24) t1 = 24;
        int dy0 = t0 / 5, dx0 = t0 - 5 * dy0;
        int dy1 = t1 / 5, dx1 = t1 - 5 * dy1;
        aoff[ks][0] = (dy0 * 20 + dx0 + lm) * 4;
        aoff[ks][1] = (dy1 * 20 + dx1 + lm) * 4;
    }
    __syncthreads();

    f32x4 acc[2][2];
#pragma unroll
    for (int i = 0; i < 2; ++i)
#pragma unroll
        for (int j = 0; j < 2; ++j) acc[i][j] = (f32x4){0.f, 0.f, 0.f, 0.f};

#pragma unroll
    for (int ks = 0; ks < 4; ++ks) {
        short8v a[2], b[2];
#pragma unroll
        for (int fm = 0; fm < 2; ++fm) {
            int base = (w * 2 + fm) * 80;
            short4v lo = *(const short4v*)(sIn + base + aoff[ks][0]);
            short4v hi = *(const short4v*)(sIn + base + aoff[ks][1]);
            short8v av;
            av[0] = lo[0]; av[1] = lo[1]; av[2] = lo[2]; av[3] = lo[3];
            av[4] = hi[0]; av[5] = hi[1]; av[6] = hi[2]; av[7] = hi[3];
            a[fm] = av;
        }
#pragma unroll
        for (int fn = 0; fn < 2; ++fn)
            b[fn] = *(const short8v*)(wp1 + (size_t)(fn * 16 + lm) * 128 + ks * 32 + lk * 8);
#pragma unroll
        for (int fm = 0; fm < 2; ++fm)
#pragma unroll
            for (int fn = 0; fn < 2; ++fn)
                acc[fm][fn] = __builtin_amdgcn_mfma_f32_16x16x32_bf16(
                    a[fm], b[fn], acc[fm][fn], 0, 0, 0);
    }

#pragma unroll
    for (int fm = 0; fm < 2; ++fm) {
        int gy = oy0 + w * 2 + fm;
#pragma unroll
        for (int fn = 0; fn < 2; ++fn) {
            int oc = fn * 16 + lm;
            float bv = bias[oc];
#pragma unroll
            for (int i = 0; i < 4; ++i) {
                int xx = lk * 4 + i;
                float v = acc[fm][fn][i] + bv;
                v = v > 0.f ? v : expm1f(v);
                out[((size_t)gy * 768 + ox0 + xx) * 32 + oc] = f2bf(v);
            }
        }
    }
}

// ---------------- weight prepack ----------------
__global__ void pack_w_kernel(const float* __restrict__ w, u16* __restrict__ wp,
                              int OC, int IC)
{
    int idx = blockIdx.x * 256 + threadIdx.x;
    if (idx >= OC * 9 * IC) return;
    int oc = idx / (9 * IC);
    int r  = idx - oc * 9 * IC;
    int tap = r / IC;
    int ic  = r - tap * IC;
    wp[idx] = f2bf(w[((size_t)oc * IC + ic) * 9 + tap]);
}

// ---------------- MFMA implicit-GEMM conv (3x3, reflect pad 1) --------------
template<int FM, int FN, int NWM, int NWN, int S, int IC, int ICC, int ACT, int OUTF32>
__global__ __launch_bounds__(256)
void mfma_conv_kernel(const u16* __restrict__ in, const u16* __restrict__ wgtP,
                      const float* __restrict__ bias, void* __restrict__ out,
                      int H, int W, int Ho, int Wo, int OC)
{
    constexpr int TY = 7 * S + 3;
    constexpr int TX = 15 * S + 3;
    constexpr int NSLOT = ICC / 8;
    constexpr int SWMSK = NSLOT - 1;
    constexpr int KTOT = 9 * IC;
    __shared__ __align__(16) u16 sIn[TY * TX * ICC];

    const int tid  = threadIdx.x;
    const int lane = tid & 63;
    const int wid  = tid >> 6;
    const int wmi  = wid / NWN;
    const int wni  = wid % NWN;
    const int lm   = lane & 15;
    const int lk   = lane >> 4;
    const int noff = blockIdx.z * (NWN * FN * 16);

    f32x4 acc[FM][FN];
#pragma unroll
    for (int i = 0; i < FM; ++i)
#pragma unroll
        for (int j = 0; j < FN; ++j) acc[i][j] = (f32x4){0.f, 0.f, 0.f, 0.f};

    const int iy0 = blockIdx.y * 8 * S - 1;
    const int ix0 = blockIdx.x * 16 * S - 1;

    for (int c0 = 0; c0 < IC; c0 += ICC) {
        if (c0) __syncthreads();
        for (int u = tid; u < TY * TX * NSLOT; u += 256) {
            int yt = u / (TX * NSLOT);
            int r  = u - yt * (TX * NSLOT);
            int xt = r / NSLOT;
            int sl = r - xt * NSLOT;
            int gy = iy0 + yt; gy = gy < 0 ? -gy : (gy >= H ? 2 * H - 2 - gy : gy);
            int gx = ix0 + xt; gx = gx < 0 ? -gx : (gx >= W ? 2 * W - 2 - gx : gx);
            *(short8v*)((char*)sIn + (size_t)((yt * TX + xt) * NSLOT + (sl ^ (xt & SWMSK))) * 16) =
                *(const short8v*)(in + ((size_t)gy * W + gx) * IC + c0 + sl * 8);
        }
        __syncthreads();
#pragma unroll
        for (int tap = 0; tap < 9; ++tap) {
            const int dy = tap / 3, dx = tap % 3;
#pragma unroll
            for (int icw = 0; icw < ICC / 32; ++icw) {
                short8v a[FM], b[FN];
#pragma unroll
                for (int fm = 0; fm < FM; ++fm) {
                    int yt = (wmi * FM + fm) * S + dy;
                    int xt = lm * S + dx;
                    a[fm] = *(const short8v*)((const char*)sIn +
                        (size_t)((yt * TX + xt) * NSLOT + ((icw * 4 + lk) ^ (xt & SWMSK))) * 16);
                }
#pragma unroll
                for (int fn = 0; fn < FN; ++fn) {
                    int n = noff + wni * FN * 16 + fn * 16 + lm;
                    b[fn] = *(const short8v*)(wgtP + (size_t)n * KTOT + tap * IC + c0 + icw * 32 + lk * 8);
                }
#pragma unroll
                for (int fm = 0; fm < FM; ++fm)
#pragma unroll
                    for (int fn = 0; fn < FN; ++fn)
                        acc[fm][fn] = __builtin_amdgcn_mfma_f32_16x16x32_bf16(
                            a[fm], b[fn], acc[fm][fn], 0, 0, 0);
            }
        }
    }

#pragma unroll
    for (int fm = 0; fm < FM; ++fm) {
        int y = blockIdx.y * 8 + wmi * FM + fm;
#pragma unroll
        for (int fn = 0; fn < FN; ++fn) {
            int oc = noff + wni * FN * 16 + fn * 16 + lm;
            float bv = bias[oc];
#pragma unroll
            for (int i = 0; i < 4; ++i) {
                int x = blockIdx.x * 16 + lk * 4 + i;
                float v = acc[fm][fn][i] + bv;
                if (ACT == 0) v = v > 0.f ? v : 0.f;
                else          v = v > 0.f ? v : expm1f(v);
                size_t o = ((size_t)y * Wo + x) * OC + oc;
                if (OUTF32) ((float*)out)[o] = v;
                else        ((u16*)out)[o]   = f2bf(v);
            }
        }
    }
}

// channels-last f32 [36864][128] -> planar f32 [128][36864]
__global__ __launch_bounds__(256)
void cl2p_kernel(const float* __restrict__ in, float* __restrict__ out)
{
    __shared__ float t[32][130];
    const int tid = threadIdx.x;
    const int p0 = blockIdx.x * 32;
#pragma unroll
    for (int j = 0; j < 16; ++j) {
        int idx = j * 256 + tid;
        int px = idx >> 7, c = idx & 127;
        t[px][c] = in[(size_t)(p0 + px) * 128 + c];
    }
    __syncthreads();
#pragma unroll
    for (int j = 0; j < 16; ++j) {
        int c = j * 8 + (tid >> 5);
        int px = tid & 31;
        out[(size_t)c * 36864 + p0 + px] = t[px][c];
    }
}

// planar f32 [128][36864] -> channels-last bf16 [36864][128]
__global__ __launch_bounds__(256)
void p2cl_kernel(const float* __restrict__ in, u16* __restrict__ out)
{
    __shared__ float t[32][130];
    const int tid = threadIdx.x;
    const int p0 = blockIdx.x * 32;
#pragma unroll
    for (int j = 0; j < 16; ++j) {
        int c = j * 8 + (tid >> 5);
        int px = tid & 31;
        t[px][c] = in[(size_t)c * 36864 + p0 + px];
    }
    __syncthreads();
#pragma unroll
    for (int j = 0; j < 16; ++j) {
        int idx = j * 256 + tid;
        int px = idx >> 7, c = idx & 127;
        out[(size_t)(p0 + px) * 128 + c] = f2bf(t[px][c]);
    }
}

// ---------------- half-res channel-last images: fgC (masked), bgC -----------
__global__ void build_fgbgc_kernel(const u16* __restrict__ h6, const float* __restrict__ mask,
                                   u16* __restrict__ fgC, u16* __restrict__ bgC)
{
    int idx = blockIdx.x * 256 + threadIdx.x;   // 9216*16
    if (idx >= 147456) return;
    int q = idx >> 4, cs = (idx & 15) * 8;
    int qy = q / 96, qx = q - qy * 96;
    const u16* src = h6 + ((size_t)(2 * qy) * 192 + 2 * qx) * 128 + cs;
    float m = mask[(size_t)(2 * qy) * 192 + 2 * qx];
    short8v v = *(const short8v*)src;
    u16 fo[8];
#pragma unroll
    for (int j = 0; j < 8; ++j) fo[j] = f2bf(bf2f((u16)v[j]) * m);
    *(short8v*)(bgC + (size_t)q * 128 + cs) = v;
    *(short8v*)(fgC + (size_t)q * 128 + cs) = *(short8v*)fo;
}

// ---------------- bgpK8: e4m3 patch matrix [1152][9216], K-PERMUTED ---------
// Vectorized: one thread per 8-q chunk (address math amortized, 8B store).
__global__ void build_bgpk8_kernel(const u16* __restrict__ h6, u8* __restrict__ bgpK)
{
    int idx = blockIdx.x * 256 + threadIdx.x;   // 1152 * 1152 chunks
    if (idx >= 1152 * 1152) return;
    int k = idx / 1152, qc = idx - k * 1152;
    int q0 = qc << 3;
    int c = k / 9, t = k - c * 9;
    int dy = t / 3, dx = t - dy * 3;
    int y = q0 / 96, x0 = q0 - y * 96;   // 96 % 8 == 0: all 8 share y
    int sy = y + dy - 1;
    unsigned long long ow = 0;
    if ((unsigned)sy < 96u) {
        const u16* row = h6 + (size_t)(2 * sy) * 192 * 128 + c;
#pragma unroll
        for (int j = 0; j < 8; ++j) {
            int sx = x0 + j + dx - 1;
            float v = ((unsigned)sx < 96u) ? bf2f(row[(size_t)(2 * sx) * 128]) : 0.f;
            ow |= (unsigned long long)f2e4m3(v) << (8 * j);
        }
    }
    int qb = q0 >> 7, o8 = (q0 & 127) >> 3;
    *(unsigned long long*)(bgpK + (size_t)k * 9216 + (qb << 7) + perm8(o8) * 8) = ow;
}

// ---------------- G-GEMM: G[a][b] = 1/8 * sum_c fgC[a][c]*bgC[b][c] ---------
__global__ __launch_bounds__(256)
void g_gemm_kernel(const u16* __restrict__ A, const u16* __restrict__ B,
                   u8* __restrict__ G)
{
    __shared__ __align__(16) u16 As[128 * 64];
    __shared__ __align__(16) u16 Bs[128 * 64];
    const int tid  = threadIdx.x;
    const int wid  = tid >> 6;
    const int lane = tid & 63;
    const int wm = (wid >> 1) * 64;
    const int wn = (wid & 1) * 64;
    const size_t bm = (size_t)blockIdx.y * 128;
    const size_t bn = (size_t)blockIdx.x * 128;

    f32x4 acc[4][4];
#pragma unroll
    for (int i = 0; i < 4; ++i)
#pragma unroll
        for (int j = 0; j < 4; ++j)
            acc[i][j] = (f32x4){0.f, 0.f, 0.f, 0.f};

    const int lrow = lane >> 3;
    const int lcb  = ((lane & 7) << 4) ^ ((lrow & 7) << 4);
    const char* gA = (const char*)A + ((bm + wid * 32 + lrow) * (size_t)128) * 2 + lcb;
    const char* gB = (const char*)B + ((bn + wid * 32 + lrow) * (size_t)128) * 2 + lcb;
    char* lA = (char*)As + (size_t)(wid * 32) * 128;
    char* lB = (char*)Bs + (size_t)(wid * 32) * 128;
    const size_t rs8 = (size_t)128 * 16;

    for (int k0 = 0; k0 < 128; k0 += 64) {
        __syncthreads();
#pragma unroll
        for (int j = 0; j < 4; ++j) {
            GLOAD16(gA + j * rs8 + (size_t)k0 * 2, lA + j * 1024);
            GLOAD16(gB + j * rs8 + (size_t)k0 * 2, lB + j * 1024);
        }
        __syncthreads();
#pragma unroll
        for (int ks = 0; ks < 2; ++ks) {
            short8v a[4], b[4];
#pragma unroll
            for (int f = 0; f < 4; ++f) {
                int ma = wm + f * 16 + (lane & 15);
                int kba = (ks * 64 + ((lane >> 4) * 16)) ^ ((ma & 7) << 4);
                a[f] = *(const short8v*)((const char*)As + ma * 128 + kba);
                int nb = wn + f * 16 + (lane & 15);
                int kbb = (ks * 64 + ((lane >> 4) * 16)) ^ ((nb & 7) << 4);
                b[f] = *(const short8v*)((const char*)Bs + nb * 128 + kbb);
            }
#pragma unroll
            for (int fm = 0; fm < 4; ++fm)
#pragma unroll
                for (int fn = 0; fn < 4; ++fn)
                    acc[fm][fn] = __builtin_amdgcn_mfma_f32_16x16x32_bf16(
                        a[fm], b[fn], acc[fm][fn], 0, 0, 0);
        }
    }

#pragma unroll
    for (int fm = 0; fm < 4; ++fm)
#pragma unroll
        for (int fn = 0; fn < 4; ++fn)
#pragma unroll
            for (int i = 0; i < 4; ++i) {
                int r = wm + fm * 16 + ((lane >> 4) * 4) + i;
                int c = wn + fn * 16 + (lane & 15);
                G[(bm + r) * (size_t)9216 + bn + c] = f2e5m2(0.125f * acc[fm][fn][i]);
            }
}

// ---------------- stencil pass: S8 = stencil(G), partial = sum S^2 ----------
// fp16-packed accumulation: e5m2->fp16 is exact (byte<<8); 4x v_pk_add_f16
// per tap instead of 8 f32 cvt+add. Boundary elements handled by byte masks.
__global__ __launch_bounds__(256)
void sstencil_kernel(const u8* __restrict__ G, u8* __restrict__ S8,
                     double* __restrict__ partial)
{
    const int wid  = threadIdx.x >> 6;
    const int lane = threadIdx.x & 63;
    const int p = blockIdx.y * 4 + wid;
    const int py = p / 96, px = p - py * 96;
    const int q0 = blockIdx.x * 512 + lane * 8;
    const int qy = q0 / 96, qx0 = q0 - qy * 96;

    __half2 hz = __floats2half2_rn(0.f, 0.f);
    __half2 hacc[4] = {hz, hz, hz, hz};

#pragma unroll
    for (int ey = -1; ey <= 1; ++ey) {
#pragma unroll
        for (int ex = -1; ex <= 1; ++ex) {
            if ((unsigned)(py + ey) >= 96u || (unsigned)(px + ex) >= 96u) continue;
            if ((unsigned)(qy + ey) >= 96u) continue;
            const int e = ey * 96 + ex;
            const u8* rp = G + (size_t)(p + e) * 9216;
            const int cc = q0 + e;
            unsigned long long v8;
            if (ex == 0) {
                v8 = *(const unsigned long long*)(rp + cc);
            } else {
                int base = cc & ~7;
                int sh = (cc & 7) * 8;
                unsigned long long lo = *(const unsigned long long*)(rp + base);
                unsigned long long hi = *(const unsigned long long*)(rp + base + 8);
                v8 = (lo >> sh) | (hi << (64 - sh));
            }
            // x-boundary masks (only possible at qx0==88 for ex=+1, qx0==0 for ex=-1)
            if (ex == 1 && qx0 == 88) v8 &= 0x00FFFFFFFFFFFFFFull;
            if (ex == -1 && qx0 == 0) v8 &= 0xFFFFFFFFFFFFFF00ull;

            unsigned lo32 = (unsigned)v8, hi32 = (unsigned)(v8 >> 32);
            unsigned pk[4];
            pk[0] = ((lo32 & 0x000000FFu) << 8) | ((lo32 & 0x0000FF00u) << 16);
            pk[1] = ((lo32 & 0x00FF0000u) >> 8) | (lo32 & 0xFF000000u);
            pk[2] = ((hi32 & 0x000000FFu) << 8) | ((hi32 & 0x0000FF00u) << 16);
            pk[3] = ((hi32 & 0x00FF0000u) >> 8) | (hi32 & 0xFF000000u);
#pragma unroll
            for (int i = 0; i < 4; ++i)
                hacc[i] = __hadd2(hacc[i], *(__half2*)&pk[i]);
        }
    }

    unsigned long long ow = 0;
    double s2 = 0.0;
#pragma unroll
    for (int i = 0; i < 4; ++i) {
        float2 f2 = __half22float2(hacc[i]);
        ow |= (unsigned long long)f2e5m2(f2.x) << (16 * i);
        ow |= (unsigned long long)f2e5m2(f2.y) << (16 * i + 8);
        s2 += (double)f2.x * f2.x + (double)f2.y * f2.y;
    }
    *(unsigned long long*)(S8 + (size_t)p * 9216 + q0) = ow;

    for (int off = 32; off; off >>= 1) s2 += __shfl_down(s2, off, 64);
    __shared__ double wsum[4];
    if (lane == 0) wsum[wid] = s2;
    __syncthreads();
    if (threadIdx.x == 0)
        partial[(size_t)blockIdx.y * 18 + blockIdx.x] = wsum[0] + wsum[1] + wsum[2] + wsum[3];
}

__global__ void sumsq_stage2(const double* __restrict__ partial, int nblocks, float* __restrict__ scale)
{
    double s = 0.0;
    for (int i = threadIdx.x; i < nblocks; i += 256) s += partial[i];
    for (int off = 32; off; off >>= 1) s += __shfl_down(s, off, 64);
    __shared__ double wsum[4];
    int lane = threadIdx.x & 63, wid = threadIdx.x >> 6;
    if (lane == 0) wsum[wid] = s;
    __syncthreads();
    if (threadIdx.x == 0) {
        double nrm = sqrt(wsum[0] + wsum[1] + wsum[2] + wsum[3]);
        if (nrm < 1e-12) nrm = 1e-12;
        *scale = (float)(10.0 / nrm);
    }
}

// ---------------- exp pass: P8 = e5m2(exp(scale*S8)), K-PERMUTED in-place ---
__global__ __launch_bounds__(256)
void exp_rows_kernel(u8* __restrict__ P8, const float* __restrict__ scale_p,
                     float* __restrict__ rs)
{
    const int wid = threadIdx.x >> 6, lane = threadIdx.x & 63;
    const int p = blockIdx.x * 4 + wid;   // grid 2304
    u8* rp = P8 + (size_t)p * 9216;
    const float scale = *scale_p;
    const int rdo = lane * 8;
    const int wro = (lane >> 4) * 128 + perm8(lane & 15) * 8;
    float s = 0.f;
#pragma unroll
    for (int it = 0; it < 18; ++it) {
        unsigned long long v8 = *(unsigned long long*)(rp + it * 512 + rdo);
        unsigned long long ow = 0;
#pragma unroll
        for (int j = 0; j < 8; ++j) {
            float sv = e5m2f((unsigned)(v8 >> (8 * j)) & 0xFFu);
            u8 e8 = f2e5m2(__expf(scale * sv));
            ow |= (unsigned long long)e8 << (8 * j);
            s += e5m2f(e8);
        }
        *(unsigned long long*)(rp + it * 512 + wro) = ow;
    }
    for (int off = 32; off; off >>= 1) s += __shfl_down(s, off, 64);
    if (lane == 0) rs[p] = s;
}

__global__ void inv_kernel(const float* __restrict__ rs, float* __restrict__ inv)
{
    int i = blockIdx.x * 256 + threadIdx.x;
    if (i < 9216) inv[i] = 1.f / rs[i];
}

// ---------------- PV fp8: R2[c9][p] = sum_q bgpK8[c9][q] * P8[p][q] ---------
__global__ __launch_bounds__(256)
void pv_fp8_kernel(const u8* __restrict__ A, const u8* __restrict__ B,
                   float* __restrict__ outF)
{
    __shared__ __align__(16) u8 As[64 * 128];
    __shared__ __align__(16) u8 Bs[128 * 128];
    const int tid  = threadIdx.x;
    const int wid  = tid >> 6;
    const int lane = tid & 63;
    const int wm = (wid >> 1) * 32;
    const int wn = (wid & 1) * 64;
    const size_t bm = (size_t)blockIdx.y * 64;
    const size_t bn = (size_t)blockIdx.x * 128;

    f32x4 acc[2][4];
#pragma unroll
    for (int i = 0; i < 2; ++i)
#pragma unroll
        for (int j = 0; j < 4; ++j)
            acc[i][j] = (f32x4){0.f, 0.f, 0.f, 0.f};

    const int lrow = lane >> 3;
    const int lcb  = ((lane & 7) << 4) ^ ((lrow & 7) << 4);
    const u8* gA = A + (bm + wid * 16 + lrow) * (size_t)9216 + lcb;
    const u8* gB = B + (bn + wid * 32 + lrow) * (size_t)9216 + lcb;
    u8* lA = As + (size_t)(wid * 16) * 128;
    u8* lB = Bs + (size_t)(wid * 32) * 128;
    const size_t rstep = (size_t)9216 * 8;
    const int lm = lane & 15, lk = lane >> 4;

    for (int k0 = 0; k0 < 9216; k0 += 128) {
        __syncthreads();
#pragma unroll
        for (int j = 0; j < 2; ++j)
            GLOAD16(gA + j * rstep + k0, lA + j * 1024);
#pragma unroll
        for (int j = 0; j < 4; ++j)
            GLOAD16(gB + j * rstep + k0, lB + j * 1024);
        __syncthreads();

        long2v aop[2][2], bop[4][2];
#pragma unroll
        for (int f = 0; f < 2; ++f) {
            int ma = wm + f * 16 + lm;
            int sw = (ma & 7) << 4;
            const u8* pr = As + ma * 128;
            aop[f][0] = *(const long2v*)(pr + ((lk * 32) ^ sw));
            aop[f][1] = *(const long2v*)(pr + ((lk * 32 + 16) ^ sw));
        }
#pragma unroll
        for (int f = 0; f < 4; ++f) {
            int nb = wn + f * 16 + lm;
            int sw = (nb & 7) << 4;
            const u8* pr = Bs + nb * 128;
            bop[f][0] = *(const long2v*)(pr + ((lk * 32) ^ sw));
            bop[f][1] = *(const long2v*)(pr + ((lk * 32 + 16) ^ sw));
        }
#pragma unroll
        for (int ks = 0; ks < 4; ++ks)
#pragma unroll
            for (int fm = 0; fm < 2; ++fm)
#pragma unroll
                for (int fn = 0; fn < 4; ++fn)
                    acc[fm][fn] = __builtin_amdgcn_mfma_f32_16x16x32_fp8_bf8(
                        aop[fm][ks >> 1][ks & 1], bop[fn][ks >> 1][ks & 1],
                        acc[fm][fn], 0, 0, 0);
    }

#pragma unroll
    for (int fm = 0; fm < 2; ++fm)
#pragma unroll
        for (int fn = 0; fn < 4; ++fn)
#pragma unroll
            for (int i = 0; i < 4; ++i) {
                int r = wm + fm * 16 + ((lane >> 4) * 4) + i;
                int c = wn + fn * 16 + (lane & 15);
                outF[(bm + r) * (size_t)9216 + bn + c] = acc[fm][fn][i];
            }
}

// ---------------- fold + mask + upsample (planar fp32 out) ------------------
__global__ void fold_mask_up_kernel(const float* __restrict__ R2,
                                    const float* __restrict__ inv,
                                    const float* __restrict__ mask,
                                    float* __restrict__ up)
{
    int idx = blockIdx.x * 256 + threadIdx.x; // 128*96*96
    if (idx >= 128 * 96 * 96) return;
    int x = idx % 96;
    int y = (idx / 96) % 96;
    int c = idx / (96 * 96);
    float s = 0.f;
#pragma unroll
    for (int dy = 0; dy < 3; ++dy) {
        int yy = y + 1 - dy;
        if (yy < 0 || yy >= 96) continue;
#pragma unroll
        for (int dx = 0; dx < 3; ++dx) {
            int xx = x + 1 - dx;
            if (xx < 0 || xx >= 96) continue;
            int pp = yy * 96 + xx;
            s += R2[(size_t)(c * 9 + dy * 3 + dx) * 9216 + pp] * inv[pp];
        }
    }
    s *= mask[(size_t)(2 * y) * 192 + 2 * x];
    size_t base = (size_t)c * 192 * 192;
    up[base + (size_t)(2 * y) * 192 + 2 * x]         = s;
    up[base + (size_t)(2 * y) * 192 + 2 * x + 1]     = s;
    up[base + (size_t)(2 * y + 1) * 192 + 2 * x]     = s;
    up[base + (size_t)(2 * y + 1) * 192 + 2 * x + 1] = s;
}

// ---------------------------------------------------------------------------
extern "C" void kernel_launch(void* const* d_in, const int* in_sizes, int n_in,
                              void* d_out, int out_size, void* d_ws, size_t ws_size,
                              hipStream_t stream)
{
    const float* x    = (const float*)d_in[0];
    const float* mask = (const float*)d_in[1];
    const float* w[8];
    const float* b[8];
    for (int i = 0; i < 8; ++i) {
        w[i] = (const float*)d_in[2 + 2 * i];
        b[i] = (const float*)d_in[3 + 2 * i];
    }
    char* ws = (char*)d_ws;
    dim3 blk(256);

    // byte offsets (identical to round 12/13; peak 187.0 MB, proven safe)
    const size_t U_H1CL = 0;
    const size_t U_H2   = 37748736;
    const size_t U_H3   = 47185920;
    const size_t U_H4   = 66060288;
    const size_t U_H5   = 75497472;
    const size_t U_H6   = 84934656;
    const size_t U_X4   = 94371840;
    const size_t U_FGC  = 0;
    const size_t U_BGC  = 2359296;
    const size_t B_BGPK = 4718592;
    const size_t B_G    = 15335424;
    const size_t B_P8   = 100270080;
    const size_t F_R2   = 15335424;
    const size_t F_UP   = 57802752;
    const size_t U_UPCL = 76677120;
    const size_t U_H7   = 86114304;
    const size_t F_H8   = 95551488;
    const size_t U_WP1  = 185204736;
    const size_t U_WP2  = 185212928;
    const size_t U_WP3  = 185231360;
    const size_t U_WP4  = 185268224;
    const size_t U_WP5  = 185415680;
    const size_t U_WP6  = 185710592;
    const size_t U_WP7  = 186005504;
    const size_t U_WP8  = 186300416;
    const size_t D_RED  = 186595328;
    const size_t F_SCALE= 186927104;
    const size_t F_RS   = 186927360;
    const size_t F_INV  = 186964224;

    u16* h1cl   = (u16*)(ws + U_H1CL);
    u16* h2     = (u16*)(ws + U_H2);
    u16* h3     = (u16*)(ws + U_H3);
    u16* h4     = (u16*)(ws + U_H4);
    u16* h5     = (u16*)(ws + U_H5);
    u16* h6     = (u16*)(ws + U_H6);
    u16* x4     = (u16*)(ws + U_X4);
    u16* fgC    = (u16*)(ws + U_FGC);
    u16* bgC    = (u16*)(ws + U_BGC);
    u8*  bgpK   = (u8*)(ws + B_BGPK);
    u8*  G      = (u8*)(ws + B_G);
    u8*  P8     = (u8*)(ws + B_P8);
    float* R2   = (float*)(ws + F_R2);
    float* upP  = (float*)(ws + F_UP);
    u16* upCL   = (u16*)(ws + U_UPCL);
    u16* h7     = (u16*)(ws + U_H7);
    float* h8   = (float*)(ws + F_H8);
    u16* wp1    = (u16*)(ws + U_WP1);
    u16* wp2    = (u16*)(ws + U_WP2);
    u16* wp3    = (u16*)(ws + U_WP3);
    u16* wp4    = (u16*)(ws + U_WP4);
    u16* wp5    = (u16*)(ws + U_WP5);
    u16* wp6    = (u16*)(ws + U_WP6);
    u16* wp7    = (u16*)(ws + U_WP7);
    u16* wp8    = (u16*)(ws + U_WP8);
    double* red = (double*)(ws + D_RED);
    float* scale= (float*)(ws + F_SCALE);
    float* rs   = (float*)(ws + F_RS);
    float* inv  = (float*)(ws + F_INV);

    // ---- prepack ----
    pack_w1_kernel<<<dim3(16), blk, 0, stream>>>(w[0], wp1);
    pack_w_kernel<<<dim3(36),  blk, 0, stream>>>(w[1], wp2, 32, 32);
    pack_w_kernel<<<dim3(72),  blk, 0, stream>>>(w[2], wp3, 64, 32);
    pack_w_kernel<<<dim3(288), blk, 0, stream>>>(w[3], wp4, 128, 64);
    pack_w_kernel<<<dim3(576), blk, 0, stream>>>(w[4], wp5, 128, 128);
    pack_w_kernel<<<dim3(576), blk, 0, stream>>>(w[5], wp6, 128, 128);
    pack_w_kernel<<<dim3(576), blk, 0, stream>>>(w[6], wp7, 128, 128);
    pack_w_kernel<<<dim3(576), blk, 0, stream>>>(w[7], wp8, 128, 128);
    x4cl_kernel<<<dim3(2304), blk, 0, stream>>>(x, x4);

    // ---- conv front-end ----
    conv1_mfma_kernel<<<dim3(48, 96), blk, 0, stream>>>(x4, wp1, b[0], h1cl);
    mfma_conv_kernel<4, 1, 2, 2, 2, 32, 32, 1, 0><<<dim3(24, 48), blk, 0, stream>>>(
        h1cl, wp2, b[1], h2, 768, 768, 384, 384, 32);
    mfma_conv_kernel<4, 2, 2, 2, 1, 32, 32, 1, 0><<<dim3(24, 48), blk, 0, stream>>>(
        h2, wp3, b[2], h3, 384, 384, 384, 384, 64);
    mfma_conv_kernel<4, 2, 2, 2, 2, 64, 32, 1, 0><<<dim3(12, 24, 2), blk, 0, stream>>>(
        h3, wp4, b[3], h4, 384, 384, 192, 192, 128);
    mfma_conv_kernel<4, 2, 2, 2, 1, 128, 128, 1, 0><<<dim3(12, 24, 2), blk, 0, stream>>>(
        h4, wp5, b[4], h5, 192, 192, 192, 192, 128);
    mfma_conv_kernel<4, 2, 2, 2, 1, 128, 128, 0, 0><<<dim3(12, 24, 2), blk, 0, stream>>>(
        h5, wp6, b[5], h6, 192, 192, 192, 192, 128);

    // ---- attention inputs ----
    build_fgbgc_kernel<<<dim3(576), blk, 0, stream>>>(h6, mask, fgC, bgC);
    build_bgpk8_kernel<<<dim3(5184), blk, 0, stream>>>(h6, bgpK);

    // ---- G (K=128 Gram, e5m2, x1/8) ----
    g_gemm_kernel<<<dim3(72, 72), blk, 0, stream>>>(fgC, bgC, G);

    // ---- stencil: S8 + Frobenius partials -> scale ----
    sstencil_kernel<<<dim3(18, 2304), blk, 0, stream>>>(G, P8, red);
    sumsq_stage2<<<dim3(1), blk, 0, stream>>>(red, 41472, scale);

    // ---- exp in-place (writes k-permuted P8) + rowsums -> inv ----
    exp_rows_kernel<<<dim3(2304), blk, 0, stream>>>(P8, scale, rs);
    inv_kernel<<<dim3(36), blk, 0, stream>>>(rs, inv);

    // ---- PV (fp8, single dispatch, K=9216, permuted operands) ----
    pv_fp8_kernel<<<dim3(72, 18), blk, 0, stream>>>(bgpK, P8, R2);

    // ---- fold + mask + upsample ----
    fold_mask_up_kernel<<<dim3(4608), blk, 0, stream>>>(R2, inv, mask, upP);
    p2cl_kernel<<<dim3(1152), blk, 0, stream>>>(upP, upCL);

    // ---- back-end convs ----
    mfma_conv_kernel<4, 2, 2, 2, 1, 128, 128, 1, 0><<<dim3(12, 24, 2), blk, 0, stream>>>(
        upCL, wp7, b[6], h7, 192, 192, 192, 192, 128);
    mfma_conv_kernel<4, 2, 2, 2, 1, 128, 128, 1, 1><<<dim3(12, 24, 2), blk, 0, stream>>>(
        h7, wp8, b[7], h8, 192, 192, 192, 192, 128);
    cl2p_kernel<<<dim3(1152), blk, 0, stream>>>(h8, (float*)d_out);
}

// Round 16
// 682.476 us; speedup vs baseline: 1.7227x; 1.0657x over previous
//
#include <hip/hip_runtime.h>
#include <hip/hip_fp16.h>
#include <math.h>

// ---------------------------------------------------------------------------
// Round 15->16: W-factorization with per-row quantization-ratio correction.
//   W[p][q] = sum_t inv[p+e]*P[p+e][q+e]  (fp16 stencil, e5m2 store, k-perm)
//   ratio[p] = sum(W_fp16)/sum(W_e5m2)    (cancels correlated quant error)
//   out[p][c] = ratio[p] * sum_q W8[p][q]*bg8[c][q]   (bf8 x fp8, split-K 8)
// bg stored e4m3 (PV-validated). Peak ws 188.4 MB (< 206.8 proven).
// ---------------------------------------------------------------------------

typedef unsigned short u16;
typedef unsigned char u8;
typedef short short4v __attribute__((ext_vector_type(4)));
typedef short short8v __attribute__((ext_vector_type(8)));
typedef float f32x4 __attribute__((ext_vector_type(4)));
typedef long long2v __attribute__((ext_vector_type(2)));

__device__ __forceinline__ u16 f2bf(float f) {
    unsigned u = __float_as_uint(f);
    return (u16)((u + 0x7FFF + ((u >> 16) & 1)) >> 16);
}
__device__ __forceinline__ float bf2f(u16 h) {
    return __uint_as_float(((unsigned)h) << 16);
}
// f32 -> fp8 e5m2 (RNE via fp16 truncation; field-validated)
__device__ __forceinline__ u8 f2e5m2(float f) {
    unsigned short hb = __half_as_ushort(__float2half(f));
    unsigned rem = hb & 0xFF;
    unsigned b = hb >> 8;
    b += (rem > 0x80u) || (rem == 0x80u && (b & 1u));
    return (u8)b;
}
__device__ __forceinline__ float e5m2f(unsigned b) {
    return __half2float(__ushort_as_half((unsigned short)(b << 8)));
}
// f32 -> fp8 e4m3fn (OCP), RNE, saturate (field-validated)
__device__ __forceinline__ u8 f2e4m3(float f) {
    unsigned u = __float_as_uint(f);
    unsigned s = (u >> 24) & 0x80u;
    unsigned a = u & 0x7FFFFFFFu;
    if (a >= 0x43E00000u) return (u8)(s | 0x7Eu);
    int e = (int)(a >> 23) - 127;
    if (e >= -6) {
        unsigned keep = (a >> 20) & 7u;
        unsigned rem  = a & 0xFFFFFu;
        keep += (rem > 0x80000u) || (rem == 0x80000u && (keep & 1u));
        unsigned e4 = (unsigned)(e + 7);
        if (keep == 8u) { keep = 0u; ++e4; }
        if (e4 >= 15u && keep >= 7u) return (u8)(s | 0x7Eu);
        return (u8)(s | (e4 << 3) | keep);
    }
    float q = __uint_as_float(a) * 512.f;
    int m = (int)rintf(q);
    if (m >= 8) return (u8)(s | 0x08u);
    return (u8)(s | (unsigned)m);
}
// 8B-chunk permutation within a 128B k-block: (ks,lk) -> (lk,ks)
__device__ __forceinline__ int perm8(int o8) { return ((o8 & 3) << 2) | (o8 >> 2); }

#define GLOAD16(g, l) __builtin_amdgcn_global_load_lds(                      \
    (const __attribute__((address_space(1))) void*)(g),                      \
    (__attribute__((address_space(3))) void*)(l), 16, 0, 0)

// ---------------- x -> channels-last bf16 ic4 (for conv1 MFMA) --------------
__global__ void x4cl_kernel(const float* __restrict__ x, u16* __restrict__ out)
{
    int i = blockIdx.x * 256 + threadIdx.x;
    if (i >= 589824) return;
    u16 v[4];
    v[0] = f2bf(x[i]);
    v[1] = f2bf(x[589824 + i]);
    v[2] = f2bf(x[1179648 + i]);
    v[3] = 0;
    *(short4v*)(out + (size_t)i * 4) = *(short4v*)v;
}

__global__ void pack_w1_kernel(const float* __restrict__ w, u16* __restrict__ wp)
{
    int i = blockIdx.x * 256 + threadIdx.x;
    if (i >= 4096) return;
    int oc = i >> 7, k = i & 127;
    int tap = k >> 2, ic = k & 3;
    u16 v = 0;
    if (tap < 25 && ic < 3) v = f2bf(w[oc * 75 + ic * 25 + tap]);
    wp[i] = v;
}

// ---------------- conv1 MFMA: 3->32, 5x5, s1, reflect pad2, ELU -------------
__global__ __launch_bounds__(256)
void conv1_mfma_kernel(const u16* __restrict__ x4, const u16* __restrict__ wp1,
                       const float* __restrict__ bias, u16* __restrict__ out)
{
    __shared__ __align__(16) u16 sIn[12 * 20 * 4];
    const int tid = threadIdx.x;
    const int lane = tid & 63;
    const int w = tid >> 6;
    const int lm = lane & 15;
    const int lk = lane >> 4;
    const int oy0 = blockIdx.y * 8, ox0 = blockIdx.x * 16;

    for (int u = tid; u < 240; u += 256) {
        int yt = u / 20, xt = u - yt * 20;
        int gy = oy0 - 2 + yt; gy = gy < 0 ? -gy : (gy >= 768 ? 1534 - gy : gy);
        int gx = ox0 - 2 + xt; gx = gx < 0 ? -gx : (gx >= 768 ? 1534 - gx : gx);
        *(short4v*)(sIn + u * 4) = *(const short4v*)(x4 + ((size_t)gy * 768 + gx) * 4);
    }
    int aoff[4][2];
#pragma unroll
    for (int ks = 0; ks < 4; ++ks) {
        int t0 = ks * 8 + lk * 2;
        int t1 = t0 + 1;
        if (t0 > 24) t0 = 24;
        if (t1 > 24) t1 = 24;
        int dy0 = t0 / 5, dx0 = t0 - 5 * dy0;
        int dy1 = t1 / 5, dx1 = t1 - 5 * dy1;
        aoff[ks][0] = (dy0 * 20 + dx0 + lm) * 4;
        aoff[ks][1] = (dy1 * 20 + dx1 + lm) * 4;
    }
    __syncthreads();

    f32x4 acc[2][2];
#pragma unroll
    for (int i = 0; i < 2; ++i)
#pragma unroll
        for (int j = 0; j < 2; ++j) acc[i][j] = (f32x4){0.f, 0.f, 0.f, 0.f};

#pragma unroll
    for (int ks = 0; ks < 4; ++ks) {
        short8v a[2], b[2];
#pragma unroll
        for (int fm = 0; fm < 2; ++fm) {
            int base = (w * 2 + fm) * 80;
            short4v lo = *(const short4v*)(sIn + base + aoff[ks][0]);
            short4v hi = *(const short4v*)(sIn + base + aoff[ks][1]);
            short8v av;
            av[0] = lo[0]; av[1] = lo[1]; av[2] = lo[2]; av[3] = lo[3];
            av[4] = hi[0]; av[5] = hi[1]; av[6] = hi[2]; av[7] = hi[3];
            a[fm] = av;
        }
#pragma unroll
        for (int fn = 0; fn < 2; ++fn)
            b[fn] = *(const short8v*)(wp1 + (size_t)(fn * 16 + lm) * 128 + ks * 32 + lk * 8);
#pragma unroll
        for (int fm = 0; fm < 2; ++fm)
#pragma unroll
            for (int fn = 0; fn < 2; ++fn)
                acc[fm][fn] = __builtin_amdgcn_mfma_f32_16x16x32_bf16(
                    a[fm], b[fn], acc[fm][fn], 0, 0, 0);
    }

#pragma unroll
    for (int fm = 0; fm < 2; ++fm) {
        int gy = oy0 + w * 2 + fm;
#pragma unroll
        for (int fn = 0; fn < 2; ++fn) {
            int oc = fn * 16 + lm;
            float bv = bias[oc];
#pragma unroll
            for (int i = 0; i < 4; ++i) {
                int xx = lk * 4 + i;
                float v = acc[fm][fn][i] + bv;
                v = v > 0.f ? v : expm1f(v);
                out[((size_t)gy * 768 + ox0 + xx) * 32 + oc] = f2bf(v);
            }
        }
    }
}

// ---------------- weight prepack ----------------
__global__ void pack_w_kernel(const float* __restrict__ w, u16* __restrict__ wp,
                              int OC, int IC)
{
    int idx = blockIdx.x * 256 + threadIdx.x;
    if (idx >= OC * 9 * IC) return;
    int oc = idx / (9 * IC);
    int r  = idx - oc * 9 * IC;
    int tap = r / IC;
    int ic  = r - tap * IC;
    wp[idx] = f2bf(w[((size_t)oc * IC + ic) * 9 + tap]);
}

// ---------------- MFMA implicit-GEMM conv (3x3, reflect pad 1) --------------
template<int FM, int FN, int NWM, int NWN, int S, int IC, int ICC, int ACT, int OUTF32>
__global__ __launch_bounds__(256)
void mfma_conv_kernel(const u16* __restrict__ in, const u16* __restrict__ wgtP,
                      const float* __restrict__ bias, void* __restrict__ out,
                      int H, int W, int Ho, int Wo, int OC)
{
    constexpr int TY = 7 * S + 3;
    constexpr int TX = 15 * S + 3;
    constexpr int NSLOT = ICC / 8;
    constexpr int SWMSK = NSLOT - 1;
    constexpr int KTOT = 9 * IC;
    __shared__ __align__(16) u16 sIn[TY * TX * ICC];

    const int tid  = threadIdx.x;
    const int lane = tid & 63;
    const int wid  = tid >> 6;
    const int wmi  = wid / NWN;
    const int wni  = wid % NWN;
    const int lm   = lane & 15;
    const int lk   = lane >> 4;
    const int noff = blockIdx.z * (NWN * FN * 16);

    f32x4 acc[FM][FN];
#pragma unroll
    for (int i = 0; i < FM; ++i)
#pragma unroll
        for (int j = 0; j < FN; ++j) acc[i][j] = (f32x4){0.f, 0.f, 0.f, 0.f};

    const int iy0 = blockIdx.y * 8 * S - 1;
    const int ix0 = blockIdx.x * 16 * S - 1;

    for (int c0 = 0; c0 < IC; c0 += ICC) {
        if (c0) __syncthreads();
        for (int u = tid; u < TY * TX * NSLOT; u += 256) {
            int yt = u / (TX * NSLOT);
            int r  = u - yt * (TX * NSLOT);
            int xt = r / NSLOT;
            int sl = r - xt * NSLOT;
            int gy = iy0 + yt; gy = gy < 0 ? -gy : (gy >= H ? 2 * H - 2 - gy : gy);
            int gx = ix0 + xt; gx = gx < 0 ? -gx : (gx >= W ? 2 * W - 2 - gx : gx);
            *(short8v*)((char*)sIn + (size_t)((yt * TX + xt) * NSLOT + (sl ^ (xt & SWMSK))) * 16) =
                *(const short8v*)(in + ((size_t)gy * W + gx) * IC + c0 + sl * 8);
        }
        __syncthreads();
#pragma unroll
        for (int tap = 0; tap < 9; ++tap) {
            const int dy = tap / 3, dx = tap % 3;
#pragma unroll
            for (int icw = 0; icw < ICC / 32; ++icw) {
                short8v a[FM], b[FN];
#pragma unroll
                for (int fm = 0; fm < FM; ++fm) {
                    int yt = (wmi * FM + fm) * S + dy;
                    int xt = lm * S + dx;
                    a[fm] = *(const short8v*)((const char*)sIn +
                        (size_t)((yt * TX + xt) * NSLOT + ((icw * 4 + lk) ^ (xt & SWMSK))) * 16);
                }
#pragma unroll
                for (int fn = 0; fn < FN; ++fn) {
                    int n = noff + wni * FN * 16 + fn * 16 + lm;
                    b[fn] = *(const short8v*)(wgtP + (size_t)n * KTOT + tap * IC + c0 + icw * 32 + lk * 8);
                }
#pragma unroll
                for (int fm = 0; fm < FM; ++fm)
#pragma unroll
                    for (int fn = 0; fn < FN; ++fn)
                        acc[fm][fn] = __builtin_amdgcn_mfma_f32_16x16x32_bf16(
                            a[fm], b[fn], acc[fm][fn], 0, 0, 0);
            }
        }
    }

#pragma unroll
    for (int fm = 0; fm < FM; ++fm) {
        int y = blockIdx.y * 8 + wmi * FM + fm;
#pragma unroll
        for (int fn = 0; fn < FN; ++fn) {
            int oc = noff + wni * FN * 16 + fn * 16 + lm;
            float bv = bias[oc];
#pragma unroll
            for (int i = 0; i < 4; ++i) {
                int x = blockIdx.x * 16 + lk * 4 + i;
                float v = acc[fm][fn][i] + bv;
                if (ACT == 0) v = v > 0.f ? v : 0.f;
                else          v = v > 0.f ? v : expm1f(v);
                size_t o = ((size_t)y * Wo + x) * OC + oc;
                if (OUTF32) ((float*)out)[o] = v;
                else        ((u16*)out)[o]   = f2bf(v);
            }
        }
    }
}

// channels-last f32 [36864][128] -> planar f32 [128][36864]
__global__ __launch_bounds__(256)
void cl2p_kernel(const float* __restrict__ in, float* __restrict__ out)
{
    __shared__ float t[32][130];
    const int tid = threadIdx.x;
    const int p0 = blockIdx.x * 32;
#pragma unroll
    for (int j = 0; j < 16; ++j) {
        int idx = j * 256 + tid;
        int px = idx >> 7, c = idx & 127;
        t[px][c] = in[(size_t)(p0 + px) * 128 + c];
    }
    __syncthreads();
#pragma unroll
    for (int j = 0; j < 16; ++j) {
        int c = j * 8 + (tid >> 5);
        int px = tid & 31;
        out[(size_t)c * 36864 + p0 + px] = t[px][c];
    }
}

// ---------------- half-res channel-last images: fgC (masked), bgC -----------
__global__ void build_fgbgc_kernel(const u16* __restrict__ h6, const float* __restrict__ mask,
                                   u16* __restrict__ fgC, u16* __restrict__ bgC)
{
    int idx = blockIdx.x * 256 + threadIdx.x;   // 9216*16
    if (idx >= 147456) return;
    int q = idx >> 4, cs = (idx & 15) * 8;
    int qy = q / 96, qx = q - qy * 96;
    const u16* src = h6 + ((size_t)(2 * qy) * 192 + 2 * qx) * 128 + cs;
    float m = mask[(size_t)(2 * qy) * 192 + 2 * qx];
    short8v v = *(const short8v*)src;
    u16 fo[8];
#pragma unroll
    for (int j = 0; j < 8; ++j) fo[j] = f2bf(bf2f((u16)v[j]) * m);
    *(short8v*)(bgC + (size_t)q * 128 + cs) = v;
    *(short8v*)(fgC + (size_t)q * 128 + cs) = *(short8v*)fo;
}

// ---------------- bgC8: e4m3 [128][9216] (unmasked bg, c-major), K-PERMUTED -
__global__ void build_bgc8_kernel(const u16* __restrict__ h6, u8* __restrict__ bgC8)
{
    int idx = blockIdx.x * 256 + threadIdx.x;   // 128 * 1152 chunks
    if (idx >= 128 * 1152) return;
    int c = idx / 1152, qc = idx - c * 1152;
    int q0 = qc << 3;
    int qy = q0 / 96, qx0 = q0 - qy * 96;   // 96 % 8 == 0: shared qy
    const u16* row = h6 + (size_t)(2 * qy) * 192 * 128 + c;
    unsigned long long ow = 0;
#pragma unroll
    for (int j = 0; j < 8; ++j) {
        float v = bf2f(row[(size_t)(2 * (qx0 + j)) * 128]);
        ow |= (unsigned long long)f2e4m3(v) << (8 * j);
    }
    *(unsigned long long*)(bgC8 + (size_t)c * 9216 + (q0 & ~127) + perm8(qc & 15) * 8) = ow;
}

// ---------------- G-GEMM: G[a][b] = 1/8 * sum_c fgC[a][c]*bgC[b][c] ---------
__global__ __launch_bounds__(256)
void g_gemm_kernel(const u16* __restrict__ A, const u16* __restrict__ B,
                   u8* __restrict__ G)
{
    __shared__ __align__(16) u16 As[128 * 64];
    __shared__ __align__(16) u16 Bs[128 * 64];
    const int tid  = threadIdx.x;
    const int wid  = tid >> 6;
    const int lane = tid & 63;
    const int wm = (wid >> 1) * 64;
    const int wn = (wid & 1) * 64;
    const size_t bm = (size_t)blockIdx.y * 128;
    const size_t bn = (size_t)blockIdx.x * 128;

    f32x4 acc[4][4];
#pragma unroll
    for (int i = 0; i < 4; ++i)
#pragma unroll
        for (int j = 0; j < 4; ++j)
            acc[i][j] = (f32x4){0.f, 0.f, 0.f, 0.f};

    const int lrow = lane >> 3;
    const int lcb  = ((lane & 7) << 4) ^ ((lrow & 7) << 4);
    const char* gA = (const char*)A + ((bm + wid * 32 + lrow) * (size_t)128) * 2 + lcb;
    const char* gB = (const char*)B + ((bn + wid * 32 + lrow) * (size_t)128) * 2 + lcb;
    char* lA = (char*)As + (size_t)(wid * 32) * 128;
    char* lB = (char*)Bs + (size_t)(wid * 32) * 128;
    const size_t rs8 = (size_t)128 * 16;

    for (int k0 = 0; k0 < 128; k0 += 64) {
        __syncthreads();
#pragma unroll
        for (int j = 0; j < 4; ++j) {
            GLOAD16(gA + j * rs8 + (size_t)k0 * 2, lA + j * 1024);
            GLOAD16(gB + j * rs8 + (size_t)k0 * 2, lB + j * 1024);
        }
        __syncthreads();
#pragma unroll
        for (int ks = 0; ks < 2; ++ks) {
            short8v a[4], b[4];
#pragma unroll
            for (int f = 0; f < 4; ++f) {
                int ma = wm + f * 16 + (lane & 15);
                int kba = (ks * 64 + ((lane >> 4) * 16)) ^ ((ma & 7) << 4);
                a[f] = *(const short8v*)((const char*)As + ma * 128 + kba);
                int nb = wn + f * 16 + (lane & 15);
                int kbb = (ks * 64 + ((lane >> 4) * 16)) ^ ((nb & 7) << 4);
                b[f] = *(const short8v*)((const char*)Bs + nb * 128 + kbb);
            }
#pragma unroll
            for (int fm = 0; fm < 4; ++fm)
#pragma unroll
                for (int fn = 0; fn < 4; ++fn)
                    acc[fm][fn] = __builtin_amdgcn_mfma_f32_16x16x32_bf16(
                        a[fm], b[fn], acc[fm][fn], 0, 0, 0);
        }
    }

#pragma unroll
    for (int fm = 0; fm < 4; ++fm)
#pragma unroll
        for (int fn = 0; fn < 4; ++fn)
#pragma unroll
            for (int i = 0; i < 4; ++i) {
                int r = wm + fm * 16 + ((lane >> 4) * 4) + i;
                int c = wn + fn * 16 + (lane & 15);
                G[(bm + r) * (size_t)9216 + bn + c] = f2e5m2(0.125f * acc[fm][fn][i]);
            }
}

// ---------------- stencil 1: S8 = stencil(G), partial = sum S^2 (fp16) ------
__global__ __launch_bounds__(256)
void sstencil_kernel(const u8* __restrict__ G, u8* __restrict__ S8,
                     double* __restrict__ partial)
{
    const int wid  = threadIdx.x >> 6;
    const int lane = threadIdx.x & 63;
    const int p = blockIdx.y * 4 + wid;
    const int py = p / 96, px = p - py * 96;
    const int q0 = blockIdx.x * 512 + lane * 8;
    const int qy = q0 / 96, qx0 = q0 - qy * 96;

    __half2 hz = __floats2half2_rn(0.f, 0.f);
    __half2 hacc[4] = {hz, hz, hz, hz};

#pragma unroll
    for (int ey = -1; ey <= 1; ++ey) {
#pragma unroll
        for (int ex = -1; ex <= 1; ++ex) {
            if ((unsigned)(py + ey) >= 96u || (unsigned)(px + ex) >= 96u) continue;
            if ((unsigned)(qy + ey) >= 96u) continue;
            const int e = ey * 96 + ex;
            const u8* rp = G + (size_t)(p + e) * 9216;
            const int cc = q0 + e;
            unsigned long long v8;
            if (ex == 0) {
                v8 = *(const unsigned long long*)(rp + cc);
            } else {
                int base = cc & ~7;
                int sh = (cc & 7) * 8;
                unsigned long long lo = *(const unsigned long long*)(rp + base);
                unsigned long long hi = *(const unsigned long long*)(rp + base + 8);
                v8 = (lo >> sh) | (hi << (64 - sh));
            }
            if (ex == 1 && qx0 == 88) v8 &= 0x00FFFFFFFFFFFFFFull;
            if (ex == -1 && qx0 == 0) v8 &= 0xFFFFFFFFFFFFFF00ull;

            unsigned lo32 = (unsigned)v8, hi32 = (unsigned)(v8 >> 32);
            unsigned pk[4];
            pk[0] = ((lo32 & 0x000000FFu) << 8) | ((lo32 & 0x0000FF00u) << 16);
            pk[1] = ((lo32 & 0x00FF0000u) >> 8) | (lo32 & 0xFF000000u);
            pk[2] = ((hi32 & 0x000000FFu) << 8) | ((hi32 & 0x0000FF00u) << 16);
            pk[3] = ((hi32 & 0x00FF0000u) >> 8) | (hi32 & 0xFF000000u);
#pragma unroll
            for (int i = 0; i < 4; ++i)
                hacc[i] = __hadd2(hacc[i], *(__half2*)&pk[i]);
        }
    }

    unsigned long long ow = 0;
    double s2 = 0.0;
#pragma unroll
    for (int i = 0; i < 4; ++i) {
        float2 f2 = __half22float2(hacc[i]);
        ow |= (unsigned long long)f2e5m2(f2.x) << (16 * i);
        ow |= (unsigned long long)f2e5m2(f2.y) << (16 * i + 8);
        s2 += (double)f2.x * f2.x + (double)f2.y * f2.y;
    }
    *(unsigned long long*)(S8 + (size_t)p * 9216 + q0) = ow;

    for (int off = 32; off; off >>= 1) s2 += __shfl_down(s2, off, 64);
    __shared__ double wsum[4];
    if (lane == 0) wsum[wid] = s2;
    __syncthreads();
    if (threadIdx.x == 0)
        partial[(size_t)blockIdx.y * 18 + blockIdx.x] = wsum[0] + wsum[1] + wsum[2] + wsum[3];
}

__global__ void sumsq_stage2(const double* __restrict__ partial, int nblocks, float* __restrict__ scale)
{
    double s = 0.0;
    for (int i = threadIdx.x; i < nblocks; i += 256) s += partial[i];
    for (int off = 32; off; off >>= 1) s += __shfl_down(s, off, 64);
    __shared__ double wsum[4];
    int lane = threadIdx.x & 63, wid = threadIdx.x >> 6;
    if (lane == 0) wsum[wid] = s;
    __syncthreads();
    if (threadIdx.x == 0) {
        double nrm = sqrt(wsum[0] + wsum[1] + wsum[2] + wsum[3]);
        if (nrm < 1e-12) nrm = 1e-12;
        *scale = (float)(10.0 / nrm);
    }
}

// ---------------- exp pass: P8 = e5m2(exp(scale*S8)) in-place (linear) ------
__global__ __launch_bounds__(256)
void exp_rows_kernel(u8* __restrict__ P8, const float* __restrict__ scale_p,
                     float* __restrict__ rs)
{
    const int wid = threadIdx.x >> 6, lane = threadIdx.x & 63;
    const int p = blockIdx.x * 4 + wid;   // grid 2304
    u8* rp = P8 + (size_t)p * 9216;
    const float scale = *scale_p;
    float s = 0.f;
#pragma unroll
    for (int it = 0; it < 18; ++it) {
        unsigned long long v8 = *(unsigned long long*)(rp + it * 512 + lane * 8);
        unsigned long long ow = 0;
#pragma unroll
        for (int j = 0; j < 8; ++j) {
            float sv = e5m2f((unsigned)(v8 >> (8 * j)) & 0xFFu);
            u8 e8 = f2e5m2(__expf(scale * sv));
            ow |= (unsigned long long)e8 << (8 * j);
            s += e5m2f(e8);
        }
        *(unsigned long long*)(rp + it * 512 + lane * 8) = ow;
    }
    for (int off = 32; off; off >>= 1) s += __shfl_down(s, off, 64);
    if (lane == 0) rs[p] = s;
}

__global__ void inv_kernel(const float* __restrict__ rs, float* __restrict__ inv)
{
    int i = blockIdx.x * 256 + threadIdx.x;
    if (i < 9216) inv[i] = 1.f / rs[i];
}

// ---------------- stencil 2: W = sum_t inv[p+e]*P[p+e][q+e], e5m2 K-PERM ----
// Also emits per-(p, qblock) sums of fp16-W (true) and e5m2-W (quantized)
// for the row-ratio correction.
__global__ __launch_bounds__(256)
void wstencil2_kernel(const u8* __restrict__ P8, const float* __restrict__ inv,
                      u8* __restrict__ W, float* __restrict__ wt,
                      float* __restrict__ wq)
{
    const int wid  = threadIdx.x >> 6;
    const int lane = threadIdx.x & 63;
    const int p = blockIdx.y * 4 + wid;
    const int py = p / 96, px = p - py * 96;
    const int q0 = blockIdx.x * 512 + lane * 8;
    const int qy = q0 / 96, qx0 = q0 - qy * 96;

    __half2 hz = __floats2half2_rn(0.f, 0.f);
    __half2 hacc[4] = {hz, hz, hz, hz};

#pragma unroll
    for (int ey = -1; ey <= 1; ++ey) {
#pragma unroll
        for (int ex = -1; ex <= 1; ++ex) {
            if ((unsigned)(py + ey) >= 96u || (unsigned)(px + ex) >= 96u) continue;
            if ((unsigned)(qy + ey) >= 96u) continue;
            const int e = ey * 96 + ex;
            const u8* rp = P8 + (size_t)(p + e) * 9216;
            const int cc = q0 + e;
            unsigned long long v8;
            if (ex == 0) {
                v8 = *(const unsigned long long*)(rp + cc);
            } else {
                int base = cc & ~7;
                int sh = (cc & 7) * 8;
                unsigned long long lo = *(const unsigned long long*)(rp + base);
                unsigned long long hi = *(const unsigned long long*)(rp + base + 8);
                v8 = (lo >> sh) | (hi << (64 - sh));
            }
            if (ex == 1 && qx0 == 88) v8 &= 0x00FFFFFFFFFFFFFFull;
            if (ex == -1 && qx0 == 0) v8 &= 0xFFFFFFFFFFFFFF00ull;

            float iv = inv[p + e];
            __half2 iv2 = __floats2half2_rn(iv, iv);
            unsigned lo32 = (unsigned)v8, hi32 = (unsigned)(v8 >> 32);
            unsigned pk[4];
            pk[0] = ((lo32 & 0x000000FFu) << 8) | ((lo32 & 0x0000FF00u) << 16);
            pk[1] = ((lo32 & 0x00FF0000u) >> 8) | (lo32 & 0xFF000000u);
            pk[2] = ((hi32 & 0x000000FFu) << 8) | ((hi32 & 0x0000FF00u) << 16);
            pk[3] = ((hi32 & 0x00FF0000u) >> 8) | (hi32 & 0xFF000000u);
#pragma unroll
            for (int i = 0; i < 4; ++i)
                hacc[i] = __hfma2(*(__half2*)&pk[i], iv2, hacc[i]);
        }
    }

    unsigned long long ow = 0;
    float st = 0.f, sq = 0.f;
#pragma unroll
    for (int i = 0; i < 4; ++i) {
        float fx = __half2float(__low2half(hacc[i]));
        float fy = __half2float(__high2half(hacc[i]));
        u8 bx = f2e5m2(fx), by = f2e5m2(fy);
        ow |= (unsigned long long)bx << (16 * i);
        ow |= (unsigned long long)by << (16 * i + 8);
        st += fx + fy;
        sq += e5m2f(bx) + e5m2f(by);
    }
    *(unsigned long long*)(W + (size_t)p * 9216 + (q0 & ~127) + perm8(lane & 15) * 8) = ow;

    for (int off = 32; off; off >>= 1) {
        st += __shfl_down(st, off, 64);
        sq += __shfl_down(sq, off, 64);
    }
    if (lane == 0) {
        wt[(size_t)p * 18 + blockIdx.x] = st;
        wq[(size_t)p * 18 + blockIdx.x] = sq;
    }
}

// ratio[p] = sum(wt) / sum(wq), fixed order
__global__ void ratio_kernel(const float* __restrict__ wt, const float* __restrict__ wq,
                             float* __restrict__ ratio)
{
    int i = blockIdx.x * 256 + threadIdx.x;
    if (i >= 9216) return;
    float st = 0.f, sq = 0.f;
#pragma unroll
    for (int j = 0; j < 18; ++j) {
        st += wt[(size_t)i * 18 + j];
        sq += wq[(size_t)i * 18 + j];
    }
    ratio[i] = (sq > 0.f) ? st / sq : 0.f;
}

// ---------------- out-GEMM: R3s[z][p][c] = sum_{q chunk} W[p][q]*bg[c][q] ---
// A = W (bf8 e5m2), B = bg (fp8 e4m3); 64x128 tile, split-K 8. grid (144, 8).
__global__ __launch_bounds__(256)
void og_kernel(const u8* __restrict__ Wm, const u8* __restrict__ Bc,
               float* __restrict__ R3s)
{
    __shared__ __align__(16) u8 As[64 * 128];
    __shared__ __align__(16) u8 Bs[128 * 128];
    const int tid  = threadIdx.x;
    const int wid  = tid >> 6;
    const int lane = tid & 63;
    const int wm = (wid >> 1) * 32;
    const int wn = (wid & 1) * 64;
    const size_t bm = (size_t)blockIdx.x * 64;
    const int kbeg = blockIdx.y * 1152;

    f32x4 acc[2][4];
#pragma unroll
    for (int i = 0; i < 2; ++i)
#pragma unroll
        for (int j = 0; j < 4; ++j)
            acc[i][j] = (f32x4){0.f, 0.f, 0.f, 0.f};

    const int lrow = lane >> 3;
    const int lcb  = ((lane & 7) << 4) ^ ((lrow & 7) << 4);
    const u8* gA = Wm + (bm + wid * 16 + lrow) * (size_t)9216 + lcb;
    const u8* gB = Bc + (wid * 32 + lrow) * (size_t)9216 + lcb;
    u8* lA = As + (size_t)(wid * 16) * 128;
    u8* lB = Bs + (size_t)(wid * 32) * 128;
    const size_t rstep = (size_t)9216 * 8;
    const int lm = lane & 15, lk = lane >> 4;

    for (int k0 = kbeg; k0 < kbeg + 1152; k0 += 128) {
        __syncthreads();
#pragma unroll
        for (int j = 0; j < 2; ++j)
            GLOAD16(gA + j * rstep + k0, lA + j * 1024);
#pragma unroll
        for (int j = 0; j < 4; ++j)
            GLOAD16(gB + j * rstep + k0, lB + j * 1024);
        __syncthreads();

        long2v aop[2][2], bop[4][2];
#pragma unroll
        for (int f = 0; f < 2; ++f) {
            int ma = wm + f * 16 + lm;
            int sw = (ma & 7) << 4;
            const u8* pr = As + ma * 128;
            aop[f][0] = *(const long2v*)(pr + ((lk * 32) ^ sw));
            aop[f][1] = *(const long2v*)(pr + ((lk * 32 + 16) ^ sw));
        }
#pragma unroll
        for (int f = 0; f < 4; ++f) {
            int nb = wn + f * 16 + lm;
            int sw = (nb & 7) << 4;
            const u8* pr = Bs + nb * 128;
            bop[f][0] = *(const long2v*)(pr + ((lk * 32) ^ sw));
            bop[f][1] = *(const long2v*)(pr + ((lk * 32 + 16) ^ sw));
        }
#pragma unroll
        for (int ks = 0; ks < 4; ++ks)
#pragma unroll
            for (int fm = 0; fm < 2; ++fm)
#pragma unroll
                for (int fn = 0; fn < 4; ++fn)
                    acc[fm][fn] = __builtin_amdgcn_mfma_f32_16x16x32_bf8_fp8(
                        aop[fm][ks >> 1][ks & 1], bop[fn][ks >> 1][ks & 1],
                        acc[fm][fn], 0, 0, 0);
    }

    float* out = R3s + (size_t)blockIdx.y * 9216 * 128;
#pragma unroll
    for (int fm = 0; fm < 2; ++fm)
#pragma unroll
        for (int fn = 0; fn < 4; ++fn)
#pragma unroll
            for (int i = 0; i < 4; ++i) {
                int r = wm + fm * 16 + ((lane >> 4) * 4) + i;
                int c = wn + fn * 16 + (lane & 15);
                out[(bm + r) * (size_t)128 + c] = acc[fm][fn][i];
            }
}

// ---------------- sum partials * ratio + mask + 2x upsample -> cl bf16 ------
__global__ void up_sum_kernel(const float* __restrict__ R3s, const float* __restrict__ ratio,
                              const float* __restrict__ mask, u16* __restrict__ upCL)
{
    int idx = blockIdx.x * 256 + threadIdx.x;   // 9216 * 16
    if (idx >= 147456) return;
    int p = idx >> 4, cs = (idx & 15) * 8;
    int y = p / 96, x = p - y * 96;
    float m = mask[(size_t)(2 * y) * 192 + 2 * x] * ratio[p];
    float acc[8];
#pragma unroll
    for (int j = 0; j < 8; ++j) acc[j] = 0.f;
#pragma unroll
    for (int z = 0; z < 8; ++z) {
        const float* rp = R3s + (size_t)z * 9216 * 128 + (size_t)p * 128 + cs;
        float4 a = *(const float4*)rp;
        float4 b = *(const float4*)(rp + 4);
        acc[0] += a.x; acc[1] += a.y; acc[2] += a.z; acc[3] += a.w;
        acc[4] += b.x; acc[5] += b.y; acc[6] += b.z; acc[7] += b.w;
    }
    u16 ov[8];
#pragma unroll
    for (int j = 0; j < 8; ++j) ov[j] = f2bf(acc[j] * m);
    short8v v = *(short8v*)ov;
    size_t r0 = ((size_t)(2 * y) * 192 + 2 * x) * 128 + cs;
    size_t r1 = ((size_t)(2 * y + 1) * 192 + 2 * x) * 128 + cs;
    *(short8v*)(upCL + r0)        = v;
    *(short8v*)(upCL + r0 + 128)  = v;
    *(short8v*)(upCL + r1)        = v;
    *(short8v*)(upCL + r1 + 128)  = v;
}

// ---------------------------------------------------------------------------
extern "C" void kernel_launch(void* const* d_in, const int* in_sizes, int n_in,
                              void* d_out, int out_size, void* d_ws, size_t ws_size,
                              hipStream_t stream)
{
    const float* x    = (const float*)d_in[0];
    const float* mask = (const float*)d_in[1];
    const float* w[8];
    const float* b[8];
    for (int i = 0; i < 8; ++i) {
        w[i] = (const float*)d_in[2 + 2 * i];
        b[i] = (const float*)d_in[3 + 2 * i];
    }
    char* ws = (char*)d_ws;
    dim3 blk(256);

    // byte offsets (liveness-audited; peak 188.4 MB < 206.8 proven)
    const size_t U_H1CL = 0;
    const size_t U_H2   = 37748736;
    const size_t U_H3   = 47185920;
    const size_t U_H4   = 66060288;
    const size_t U_H5   = 75497472;
    const size_t U_H6   = 84934656;     // ends 94,371,840
    const size_t U_X4   = 94371840;     // ends 99,090,432
    const size_t U_FGC  = 0;            // 2,359,296 [h1cl dead]
    const size_t U_BGC  = 2359296;      // -> 4,718,592
    const size_t B_BGC8 = 4718592;      // 1,179,648 -> 5,898,240
    const size_t B_G    = 15335424;     // 84,934,656 -> 100,270,080 [h2..x4 dead]
    const size_t B_P8   = 100270080;    // 84,934,656 -> 185,204,736
    const size_t B_W    = 15335424;     // over dead G
    const size_t F_R3S  = 100270080;    // 37,748,736 [P8 dead after wstencil2]
    const size_t U_UPCL = 138018816;    // 9,437,184 -> 147,456,000
    const size_t U_H7   = 147456000;    // -> 156,893,184
    const size_t F_H8   = 156893184;    // 18,874,368 -> 175,767,552
    const size_t U_WP1  = 185204736;
    const size_t U_WP2  = 185212928;
    const size_t U_WP3  = 185231360;
    const size_t U_WP4  = 185268224;
    const size_t U_WP5  = 185415680;
    const size_t U_WP6  = 185710592;
    const size_t U_WP7  = 186005504;
    const size_t U_WP8  = 186300416;
    const size_t D_RED  = 186595328;    // 331,776
    const size_t F_SCALE= 186927104;
    const size_t F_RS   = 186927360;
    const size_t F_INV  = 186964224;    // -> 187,001,088
    const size_t F_WT   = 187001088;    // 663,552 -> 187,664,640
    const size_t F_WQ   = 187664640;    // 663,552 -> 188,328,192
    const size_t F_RAT  = 188328192;    // 36,864 -> 188,365,056 (peak)

    u16* h1cl   = (u16*)(ws + U_H1CL);
    u16* h2     = (u16*)(ws + U_H2);
    u16* h3     = (u16*)(ws + U_H3);
    u16* h4     = (u16*)(ws + U_H4);
    u16* h5     = (u16*)(ws + U_H5);
    u16* h6     = (u16*)(ws + U_H6);
    u16* x4     = (u16*)(ws + U_X4);
    u16* fgC    = (u16*)(ws + U_FGC);
    u16* bgC    = (u16*)(ws + U_BGC);
    u8*  bgC8   = (u8*)(ws + B_BGC8);
    u8*  G      = (u8*)(ws + B_G);
    u8*  P8     = (u8*)(ws + B_P8);
    u8*  Wm     = (u8*)(ws + B_W);
    float* R3s  = (float*)(ws + F_R3S);
    u16* upCL   = (u16*)(ws + U_UPCL);
    u16* h7     = (u16*)(ws + U_H7);
    float* h8   = (float*)(ws + F_H8);
    u16* wp1    = (u16*)(ws + U_WP1);
    u16* wp2    = (u16*)(ws + U_WP2);
    u16* wp3    = (u16*)(ws + U_WP3);
    u16* wp4    = (u16*)(ws + U_WP4);
    u16* wp5    = (u16*)(ws + U_WP5);
    u16* wp6    = (u16*)(ws + U_WP6);
    u16* wp7    = (u16*)(ws + U_WP7);
    u16* wp8    = (u16*)(ws + U_WP8);
    double* red = (double*)(ws + D_RED);
    float* scale= (float*)(ws + F_SCALE);
    float* rs   = (float*)(ws + F_RS);
    float* inv  = (float*)(ws + F_INV);
    float* wt   = (float*)(ws + F_WT);
    float* wq   = (float*)(ws + F_WQ);
    float* ratio= (float*)(ws + F_RAT);

    // ---- prepack ----
    pack_w1_kernel<<<dim3(16), blk, 0, stream>>>(w[0], wp1);
    pack_w_kernel<<<dim3(36),  blk, 0, stream>>>(w[1], wp2, 32, 32);
    pack_w_kernel<<<dim3(72),  blk, 0, stream>>>(w[2], wp3, 64, 32);
    pack_w_kernel<<<dim3(288), blk, 0, stream>>>(w[3], wp4, 128, 64);
    pack_w_kernel<<<dim3(576), blk, 0, stream>>>(w[4], wp5, 128, 128);
    pack_w_kernel<<<dim3(576), blk, 0, stream>>>(w[5], wp6, 128, 128);
    pack_w_kernel<<<dim3(576), blk, 0, stream>>>(w[6], wp7, 128, 128);
    pack_w_kernel<<<dim3(576), blk, 0, stream>>>(w[7], wp8, 128, 128);
    x4cl_kernel<<<dim3(2304), blk, 0, stream>>>(x, x4);

    // ---- conv front-end ----
    conv1_mfma_kernel<<<dim3(48, 96), blk, 0, stream>>>(x4, wp1, b[0], h1cl);
    mfma_conv_kernel<4, 1, 2, 2, 2, 32, 32, 1, 0><<<dim3(24, 48), blk, 0, stream>>>(
        h1cl, wp2, b[1], h2, 768, 768, 384, 384, 32);
    mfma_conv_kernel<4, 2, 2, 2, 1, 32, 32, 1, 0><<<dim3(24, 48), blk, 0, stream>>>(
        h2, wp3, b[2], h3, 384, 384, 384, 384, 64);
    mfma_conv_kernel<4, 2, 2, 2, 2, 64, 32, 1, 0><<<dim3(12, 24, 2), blk, 0, stream>>>(
        h3, wp4, b[3], h4, 384, 384, 192, 192, 128);
    mfma_conv_kernel<4, 2, 2, 2, 1, 128, 128, 1, 0><<<dim3(12, 24, 2), blk, 0, stream>>>(
        h4, wp5, b[4], h5, 192, 192, 192, 192, 128);
    mfma_conv_kernel<4, 2, 2, 2, 1, 128, 128, 0, 0><<<dim3(12, 24, 2), blk, 0, stream>>>(
        h5, wp6, b[5], h6, 192, 192, 192, 192, 128);

    // ---- attention inputs ----
    build_fgbgc_kernel<<<dim3(576), blk, 0, stream>>>(h6, mask, fgC, bgC);
    build_bgc8_kernel<<<dim3(576), blk, 0, stream>>>(h6, bgC8);

    // ---- G (K=128 Gram, e5m2, x1/8) ----
    g_gemm_kernel<<<dim3(72, 72), blk, 0, stream>>>(fgC, bgC, G);

    // ---- stencil 1: S8 + Frobenius partials -> scale ----
    sstencil_kernel<<<dim3(18, 2304), blk, 0, stream>>>(G, P8, red);
    sumsq_stage2<<<dim3(1), blk, 0, stream>>>(red, 41472, scale);

    // ---- exp in-place (linear) + rowsums -> inv ----
    exp_rows_kernel<<<dim3(2304), blk, 0, stream>>>(P8, scale, rs);
    inv_kernel<<<dim3(36), blk, 0, stream>>>(rs, inv);

    // ---- stencil 2: W (e5m2, k-permuted) + quantization ratio ----
    wstencil2_kernel<<<dim3(18, 2304), blk, 0, stream>>>(P8, inv, Wm, wt, wq);
    ratio_kernel<<<dim3(36), blk, 0, stream>>>(wt, wq, ratio);

    // ---- out-GEMM (bf8 x fp8, split-K 8) -> partial R3s ----
    og_kernel<<<dim3(144, 8), blk, 0, stream>>>(Wm, bgC8, R3s);

    // ---- sum partials * ratio + mask + upsample -> channels-last bf16 ----
    up_sum_kernel<<<dim3(576), blk, 0, stream>>>(R3s, ratio, mask, upCL);

    // ---- back-end convs ----
    mfma_conv_kernel<4, 2, 2, 2, 1, 128, 128, 1, 0><<<dim3(12, 24, 2), blk, 0, stream>>>(
        upCL, wp7, b[6], h7, 192, 192, 192, 192, 128);
    mfma_conv_kernel<4, 2, 2, 2, 1, 128, 128, 1, 1><<<dim3(12, 24, 2), blk, 0, stream>>>(
        h7, wp8, b[7], h8, 192, 192, 192, 192, 128);
    cl2p_kernel<<<dim3(1152), blk, 0, stream>>>(h8, (float*)d_out);
}

// Round 17
// 651.773 us; speedup vs baseline: 1.8038x; 1.0471x over previous
//
#include <hip/hip_runtime.h>
#include <hip/hip_fp16.h>
#include <math.h>

// ---------------------------------------------------------------------------
// Round 16->17: v_perm_b32 unpack in both stencils (e5m2->fp16 = byte-to-
// high-byte, 1 perm per half2 word instead of ~5 bitops). Bit-identical math.
// Everything else identical to round 16 (682 us, absmax 0.0625).
// ---------------------------------------------------------------------------

typedef unsigned short u16;
typedef unsigned char u8;
typedef short short4v __attribute__((ext_vector_type(4)));
typedef short short8v __attribute__((ext_vector_type(8)));
typedef float f32x4 __attribute__((ext_vector_type(4)));
typedef long long2v __attribute__((ext_vector_type(2)));

__device__ __forceinline__ u16 f2bf(float f) {
    unsigned u = __float_as_uint(f);
    return (u16)((u + 0x7FFF + ((u >> 16) & 1)) >> 16);
}
__device__ __forceinline__ float bf2f(u16 h) {
    return __uint_as_float(((unsigned)h) << 16);
}
// f32 -> fp8 e5m2 (RNE via fp16 truncation; field-validated)
__device__ __forceinline__ u8 f2e5m2(float f) {
    unsigned short hb = __half_as_ushort(__float2half(f));
    unsigned rem = hb & 0xFF;
    unsigned b = hb >> 8;
    b += (rem > 0x80u) || (rem == 0x80u && (b & 1u));
    return (u8)b;
}
__device__ __forceinline__ float e5m2f(unsigned b) {
    return __half2float(__ushort_as_half((unsigned short)(b << 8)));
}
// f32 -> fp8 e4m3fn (OCP), RNE, saturate (field-validated)
__device__ __forceinline__ u8 f2e4m3(float f) {
    unsigned u = __float_as_uint(f);
    unsigned s = (u >> 24) & 0x80u;
    unsigned a = u & 0x7FFFFFFFu;
    if (a >= 0x43E00000u) return (u8)(s | 0x7Eu);
    int e = (int)(a >> 23) - 127;
    if (e >= -6) {
        unsigned keep = (a >> 20) & 7u;
        unsigned rem  = a & 0xFFFFFu;
        keep += (rem > 0x80000u) || (rem == 0x80000u && (keep & 1u));
        unsigned e4 = (unsigned)(e + 7);
        if (keep == 8u) { keep = 0u; ++e4; }
        if (e4 >= 15u && keep >= 7u) return (u8)(s | 0x7Eu);
        return (u8)(s | (e4 << 3) | keep);
    }
    float q = __uint_as_float(a) * 512.f;
    int m = (int)rintf(q);
    if (m >= 8) return (u8)(s | 0x08u);
    return (u8)(s | (unsigned)m);
}
// 8B-chunk permutation within a 128B k-block: (ks,lk) -> (lk,ks)
__device__ __forceinline__ int perm8(int o8) { return ((o8 & 3) << 2) | (o8 >> 2); }

#define GLOAD16(g, l) __builtin_amdgcn_global_load_lds(                      \
    (const __attribute__((address_space(1))) void*)(g),                      \
    (__attribute__((address_space(3))) void*)(l), 16, 0, 0)

// unpack 4 e5m2 bytes of a dword into two half2 words (byte -> high byte)
#define E5M2_UNPACK(dst, src32)                                              \
    dst[0] = __builtin_amdgcn_perm(0u, (src32), 0x010C000Cu);                \
    dst[1] = __builtin_amdgcn_perm(0u, (src32), 0x030C020Cu);

// ---------------- x -> channels-last bf16 ic4 (for conv1 MFMA) --------------
__global__ void x4cl_kernel(const float* __restrict__ x, u16* __restrict__ out)
{
    int i = blockIdx.x * 256 + threadIdx.x;
    if (i >= 589824) return;
    u16 v[4];
    v[0] = f2bf(x[i]);
    v[1] = f2bf(x[589824 + i]);
    v[2] = f2bf(x[1179648 + i]);
    v[3] = 0;
    *(short4v*)(out + (size_t)i * 4) = *(short4v*)v;
}

__global__ void pack_w1_kernel(const float* __restrict__ w, u16* __restrict__ wp)
{
    int i = blockIdx.x * 256 + threadIdx.x;
    if (i >= 4096) return;
    int oc = i >> 7, k = i & 127;
    int tap = k >> 2, ic = k & 3;
    u16 v = 0;
    if (tap < 25 && ic < 3) v = f2bf(w[oc * 75 + ic * 25 + tap]);
    wp[i] = v;
}

// ---------------- conv1 MFMA: 3->32, 5x5, s1, reflect pad2, ELU -------------
__global__ __launch_bounds__(256)
void conv1_mfma_kernel(const u16* __restrict__ x4, const u16* __restrict__ wp1,
                       const float* __restrict__ bias, u16* __restrict__ out)
{
    __shared__ __align__(16) u16 sIn[12 * 20 * 4];
    const int tid = threadIdx.x;
    const int lane = tid & 63;
    const int w = tid >> 6;
    const int lm = lane & 15;
    const int lk = lane >> 4;
    const int oy0 = blockIdx.y * 8, ox0 = blockIdx.x * 16;

    for (int u = tid; u < 240; u += 256) {
        int yt = u / 20, xt = u - yt * 20;
        int gy = oy0 - 2 + yt; gy = gy < 0 ? -gy : (gy >= 768 ? 1534 - gy : gy);
        int gx = ox0 - 2 + xt; gx = gx < 0 ? -gx : (gx >= 768 ? 1534 - gx : gx);
        *(short4v*)(sIn + u * 4) = *(const short4v*)(x4 + ((size_t)gy * 768 + gx) * 4);
    }
    int aoff[4][2];
#pragma unroll
    for (int ks = 0; ks < 4; ++ks) {
        int t0 = ks * 8 + lk * 2;
        int t1 = t0 + 1;
        if (t0 > 24) t0 = 24;
        if (t1 > 24) t1 = 24;
        int dy0 = t0 / 5, dx0 = t0 - 5 * dy0;
        int dy1 = t1 / 5, dx1 = t1 - 5 * dy1;
        aoff[ks][0] = (dy0 * 20 + dx0 + lm) * 4;
        aoff[ks][1] = (dy1 * 20 + dx1 + lm) * 4;
    }
    __syncthreads();

    f32x4 acc[2][2];
#pragma unroll
    for (int i = 0; i < 2; ++i)
#pragma unroll
        for (int j = 0; j < 2; ++j) acc[i][j] = (f32x4){0.f, 0.f, 0.f, 0.f};

#pragma unroll
    for (int ks = 0; ks < 4; ++ks) {
        short8v a[2], b[2];
#pragma unroll
        for (int fm = 0; fm < 2; ++fm) {
            int base = (w * 2 + fm) * 80;
            short4v lo = *(const short4v*)(sIn + base + aoff[ks][0]);
            short4v hi = *(const short4v*)(sIn + base + aoff[ks][1]);
            short8v av;
            av[0] = lo[0]; av[1] = lo[1]; av[2] = lo[2]; av[3] = lo[3];
            av[4] = hi[0]; av[5] = hi[1]; av[6] = hi[2]; av[7] = hi[3];
            a[fm] = av;
        }
#pragma unroll
        for (int fn = 0; fn < 2; ++fn)
            b[fn] = *(const short8v*)(wp1 + (size_t)(fn * 16 + lm) * 128 + ks * 32 + lk * 8);
#pragma unroll
        for (int fm = 0; fm < 2; ++fm)
#pragma unroll
            for (int fn = 0; fn < 2; ++fn)
                acc[fm][fn] = __builtin_amdgcn_mfma_f32_16x16x32_bf16(
                    a[fm], b[fn], acc[fm][fn], 0, 0, 0);
    }

#pragma unroll
    for (int fm = 0; fm < 2; ++fm) {
        int gy = oy0 + w * 2 + fm;
#pragma unroll
        for (int fn = 0; fn < 2; ++fn) {
            int oc = fn * 16 + lm;
            float bv = bias[oc];
#pragma unroll
            for (int i = 0; i < 4; ++i) {
                int xx = lk * 4 + i;
                float v = acc[fm][fn][i] + bv;
                v = v > 0.f ? v : expm1f(v);
                out[((size_t)gy * 768 + ox0 + xx) * 32 + oc] = f2bf(v);
            }
        }
    }
}

// ---------------- weight prepack ----------------
__global__ void pack_w_kernel(const float* __restrict__ w, u16* __restrict__ wp,
                              int OC, int IC)
{
    int idx = blockIdx.x * 256 + threadIdx.x;
    if (idx >= OC * 9 * IC) return;
    int oc = idx / (9 * IC);
    int r  = idx - oc * 9 * IC;
    int tap = r / IC;
    int ic  = r - tap * IC;
    wp[idx] = f2bf(w[((size_t)oc * IC + ic) * 9 + tap]);
}

// ---------------- MFMA implicit-GEMM conv (3x3, reflect pad 1) --------------
template<int FM, int FN, int NWM, int NWN, int S, int IC, int ICC, int ACT, int OUTF32>
__global__ __launch_bounds__(256)
void mfma_conv_kernel(const u16* __restrict__ in, const u16* __restrict__ wgtP,
                      const float* __restrict__ bias, void* __restrict__ out,
                      int H, int W, int Ho, int Wo, int OC)
{
    constexpr int TY = 7 * S + 3;
    constexpr int TX = 15 * S + 3;
    constexpr int NSLOT = ICC / 8;
    constexpr int SWMSK = NSLOT - 1;
    constexpr int KTOT = 9 * IC;
    __shared__ __align__(16) u16 sIn[TY * TX * ICC];

    const int tid  = threadIdx.x;
    const int lane = tid & 63;
    const int wid  = tid >> 6;
    const int wmi  = wid / NWN;
    const int wni  = wid % NWN;
    const int lm   = lane & 15;
    const int lk   = lane >> 4;
    const int noff = blockIdx.z * (NWN * FN * 16);

    f32x4 acc[FM][FN];
#pragma unroll
    for (int i = 0; i < FM; ++i)
#pragma unroll
        for (int j = 0; j < FN; ++j) acc[i][j] = (f32x4){0.f, 0.f, 0.f, 0.f};

    const int iy0 = blockIdx.y * 8 * S - 1;
    const int ix0 = blockIdx.x * 16 * S - 1;

    for (int c0 = 0; c0 < IC; c0 += ICC) {
        if (c0) __syncthreads();
        for (int u = tid; u < TY * TX * NSLOT; u += 256) {
            int yt = u / (TX * NSLOT);
            int r  = u - yt * (TX * NSLOT);
            int xt = r / NSLOT;
            int sl = r - xt * NSLOT;
            int gy = iy0 + yt; gy = gy < 0 ? -gy : (gy >= H ? 2 * H - 2 - gy : gy);
            int gx = ix0 + xt; gx = gx < 0 ? -gx : (gx >= W ? 2 * W - 2 - gx : gx);
            *(short8v*)((char*)sIn + (size_t)((yt * TX + xt) * NSLOT + (sl ^ (xt & SWMSK))) * 16) =
                *(const short8v*)(in + ((size_t)gy * W + gx) * IC + c0 + sl * 8);
        }
        __syncthreads();
#pragma unroll
        for (int tap = 0; tap < 9; ++tap) {
            const int dy = tap / 3, dx = tap % 3;
#pragma unroll
            for (int icw = 0; icw < ICC / 32; ++icw) {
                short8v a[FM], b[FN];
#pragma unroll
                for (int fm = 0; fm < FM; ++fm) {
                    int yt = (wmi * FM + fm) * S + dy;
                    int xt = lm * S + dx;
                    a[fm] = *(const short8v*)((const char*)sIn +
                        (size_t)((yt * TX + xt) * NSLOT + ((icw * 4 + lk) ^ (xt & SWMSK))) * 16);
                }
#pragma unroll
                for (int fn = 0; fn < FN; ++fn) {
                    int n = noff + wni * FN * 16 + fn * 16 + lm;
                    b[fn] = *(const short8v*)(wgtP + (size_t)n * KTOT + tap * IC + c0 + icw * 32 + lk * 8);
                }
#pragma unroll
                for (int fm = 0; fm < FM; ++fm)
#pragma unroll
                    for (int fn = 0; fn < FN; ++fn)
                        acc[fm][fn] = __builtin_amdgcn_mfma_f32_16x16x32_bf16(
                            a[fm], b[fn], acc[fm][fn], 0, 0, 0);
            }
        }
    }

#pragma unroll
    for (int fm = 0; fm < FM; ++fm) {
        int y = blockIdx.y * 8 + wmi * FM + fm;
#pragma unroll
        for (int fn = 0; fn < FN; ++fn) {
            int oc = noff + wni * FN * 16 + fn * 16 + lm;
            float bv = bias[oc];
#pragma unroll
            for (int i = 0; i < 4; ++i) {
                int x = blockIdx.x * 16 + lk * 4 + i;
                float v = acc[fm][fn][i] + bv;
                if (ACT == 0) v = v > 0.f ? v : 0.f;
                else          v = v > 0.f ? v : expm1f(v);
                size_t o = ((size_t)y * Wo + x) * OC + oc;
                if (OUTF32) ((float*)out)[o] = v;
                else        ((u16*)out)[o]   = f2bf(v);
            }
        }
    }
}

// channels-last f32 [36864][128] -> planar f32 [128][36864]
__global__ __launch_bounds__(256)
void cl2p_kernel(const float* __restrict__ in, float* __restrict__ out)
{
    __shared__ float t[32][130];
    const int tid = threadIdx.x;
    const int p0 = blockIdx.x * 32;
#pragma unroll
    for (int j = 0; j < 16; ++j) {
        int idx = j * 256 + tid;
        int px = idx >> 7, c = idx & 127;
        t[px][c] = in[(size_t)(p0 + px) * 128 + c];
    }
    __syncthreads();
#pragma unroll
    for (int j = 0; j < 16; ++j) {
        int c = j * 8 + (tid >> 5);
        int px = tid & 31;
        out[(size_t)c * 36864 + p0 + px] = t[px][c];
    }
}

// ---------------- half-res channel-last images: fgC (masked), bgC -----------
__global__ void build_fgbgc_kernel(const u16* __restrict__ h6, const float* __restrict__ mask,
                                   u16* __restrict__ fgC, u16* __restrict__ bgC)
{
    int idx = blockIdx.x * 256 + threadIdx.x;   // 9216*16
    if (idx >= 147456) return;
    int q = idx >> 4, cs = (idx & 15) * 8;
    int qy = q / 96, qx = q - qy * 96;
    const u16* src = h6 + ((size_t)(2 * qy) * 192 + 2 * qx) * 128 + cs;
    float m = mask[(size_t)(2 * qy) * 192 + 2 * qx];
    short8v v = *(const short8v*)src;
    u16 fo[8];
#pragma unroll
    for (int j = 0; j < 8; ++j) fo[j] = f2bf(bf2f((u16)v[j]) * m);
    *(short8v*)(bgC + (size_t)q * 128 + cs) = v;
    *(short8v*)(fgC + (size_t)q * 128 + cs) = *(short8v*)fo;
}

// ---------------- bgC8: e4m3 [128][9216] (unmasked bg, c-major), K-PERMUTED -
__global__ void build_bgc8_kernel(const u16* __restrict__ h6, u8* __restrict__ bgC8)
{
    int idx = blockIdx.x * 256 + threadIdx.x;   // 128 * 1152 chunks
    if (idx >= 128 * 1152) return;
    int c = idx / 1152, qc = idx - c * 1152;
    int q0 = qc << 3;
    int qy = q0 / 96, qx0 = q0 - qy * 96;
    const u16* row = h6 + (size_t)(2 * qy) * 192 * 128 + c;
    unsigned long long ow = 0;
#pragma unroll
    for (int j = 0; j < 8; ++j) {
        float v = bf2f(row[(size_t)(2 * (qx0 + j)) * 128]);
        ow |= (unsigned long long)f2e4m3(v) << (8 * j);
    }
    *(unsigned long long*)(bgC8 + (size_t)c * 9216 + (q0 & ~127) + perm8(qc & 15) * 8) = ow;
}

// ---------------- G-GEMM: G[a][b] = 1/8 * sum_c fgC[a][c]*bgC[b][c] ---------
__global__ __launch_bounds__(256)
void g_gemm_kernel(const u16* __restrict__ A, const u16* __restrict__ B,
                   u8* __restrict__ G)
{
    __shared__ __align__(16) u16 As[128 * 64];
    __shared__ __align__(16) u16 Bs[128 * 64];
    const int tid  = threadIdx.x;
    const int wid  = tid >> 6;
    const int lane = tid & 63;
    const int wm = (wid >> 1) * 64;
    const int wn = (wid & 1) * 64;
    const size_t bm = (size_t)blockIdx.y * 128;
    const size_t bn = (size_t)blockIdx.x * 128;

    f32x4 acc[4][4];
#pragma unroll
    for (int i = 0; i < 4; ++i)
#pragma unroll
        for (int j = 0; j < 4; ++j)
            acc[i][j] = (f32x4){0.f, 0.f, 0.f, 0.f};

    const int lrow = lane >> 3;
    const int lcb  = ((lane & 7) << 4) ^ ((lrow & 7) << 4);
    const char* gA = (const char*)A + ((bm + wid * 32 + lrow) * (size_t)128) * 2 + lcb;
    const char* gB = (const char*)B + ((bn + wid * 32 + lrow) * (size_t)128) * 2 + lcb;
    char* lA = (char*)As + (size_t)(wid * 32) * 128;
    char* lB = (char*)Bs + (size_t)(wid * 32) * 128;
    const size_t rs8 = (size_t)128 * 16;

    for (int k0 = 0; k0 < 128; k0 += 64) {
        __syncthreads();
#pragma unroll
        for (int j = 0; j < 4; ++j) {
            GLOAD16(gA + j * rs8 + (size_t)k0 * 2, lA + j * 1024);
            GLOAD16(gB + j * rs8 + (size_t)k0 * 2, lB + j * 1024);
        }
        __syncthreads();
#pragma unroll
        for (int ks = 0; ks < 2; ++ks) {
            short8v a[4], b[4];
#pragma unroll
            for (int f = 0; f < 4; ++f) {
                int ma = wm + f * 16 + (lane & 15);
                int kba = (ks * 64 + ((lane >> 4) * 16)) ^ ((ma & 7) << 4);
                a[f] = *(const short8v*)((const char*)As + ma * 128 + kba);
                int nb = wn + f * 16 + (lane & 15);
                int kbb = (ks * 64 + ((lane >> 4) * 16)) ^ ((nb & 7) << 4);
                b[f] = *(const short8v*)((const char*)Bs + nb * 128 + kbb);
            }
#pragma unroll
            for (int fm = 0; fm < 4; ++fm)
#pragma unroll
                for (int fn = 0; fn < 4; ++fn)
                    acc[fm][fn] = __builtin_amdgcn_mfma_f32_16x16x32_bf16(
                        a[fm], b[fn], acc[fm][fn], 0, 0, 0);
        }
    }

#pragma unroll
    for (int fm = 0; fm < 4; ++fm)
#pragma unroll
        for (int fn = 0; fn < 4; ++fn)
#pragma unroll
            for (int i = 0; i < 4; ++i) {
                int r = wm + fm * 16 + ((lane >> 4) * 4) + i;
                int c = wn + fn * 16 + (lane & 15);
                G[(bm + r) * (size_t)9216 + bn + c] = f2e5m2(0.125f * acc[fm][fn][i]);
            }
}

// ---------------- stencil 1: S8 = stencil(G), partial = sum S^2 (fp16) ------
__global__ __launch_bounds__(256)
void sstencil_kernel(const u8* __restrict__ G, u8* __restrict__ S8,
                     double* __restrict__ partial)
{
    const int wid  = threadIdx.x >> 6;
    const int lane = threadIdx.x & 63;
    const int p = blockIdx.y * 4 + wid;
    const int py = p / 96, px = p - py * 96;
    const int q0 = blockIdx.x * 512 + lane * 8;
    const int qy = q0 / 96, qx0 = q0 - qy * 96;

    __half2 hz = __floats2half2_rn(0.f, 0.f);
    __half2 hacc[4] = {hz, hz, hz, hz};

#pragma unroll
    for (int ey = -1; ey <= 1; ++ey) {
#pragma unroll
        for (int ex = -1; ex <= 1; ++ex) {
            if ((unsigned)(py + ey) >= 96u || (unsigned)(px + ex) >= 96u) continue;
            if ((unsigned)(qy + ey) >= 96u) continue;
            const int e = ey * 96 + ex;
            const u8* rp = G + (size_t)(p + e) * 9216;
            const int cc = q0 + e;
            unsigned long long v8;
            if (ex == 0) {
                v8 = *(const unsigned long long*)(rp + cc);
            } else {
                int base = cc & ~7;
                int sh = (cc & 7) * 8;
                unsigned long long lo = *(const unsigned long long*)(rp + base);
                unsigned long long hi = *(const unsigned long long*)(rp + base + 8);
                v8 = (lo >> sh) | (hi << (64 - sh));
            }
            if (ex == 1 && qx0 == 88) v8 &= 0x00FFFFFFFFFFFFFFull;
            if (ex == -1 && qx0 == 0) v8 &= 0xFFFFFFFFFFFFFF00ull;

            unsigned lo32 = (unsigned)v8, hi32 = (unsigned)(v8 >> 32);
            unsigned pk[4];
            E5M2_UNPACK(pk, lo32);
            E5M2_UNPACK((pk + 2), hi32);
#pragma unroll
            for (int i = 0; i < 4; ++i)
                hacc[i] = __hadd2(hacc[i], *(__half2*)&pk[i]);
        }
    }

    unsigned long long ow = 0;
    double s2 = 0.0;
#pragma unroll
    for (int i = 0; i < 4; ++i) {
        float2 f2 = __half22float2(hacc[i]);
        ow |= (unsigned long long)f2e5m2(f2.x) << (16 * i);
        ow |= (unsigned long long)f2e5m2(f2.y) << (16 * i + 8);
        s2 += (double)f2.x * f2.x + (double)f2.y * f2.y;
    }
    *(unsigned long long*)(S8 + (size_t)p * 9216 + q0) = ow;

    for (int off = 32; off; off >>= 1) s2 += __shfl_down(s2, off, 64);
    __shared__ double wsum[4];
    if (lane == 0) wsum[wid] = s2;
    __syncthreads();
    if (threadIdx.x == 0)
        partial[(size_t)blockIdx.y * 18 + blockIdx.x] = wsum[0] + wsum[1] + wsum[2] + wsum[3];
}

__global__ void sumsq_stage2(const double* __restrict__ partial, int nblocks, float* __restrict__ scale)
{
    double s = 0.0;
    for (int i = threadIdx.x; i < nblocks; i += 256) s += partial[i];
    for (int off = 32; off; off >>= 1) s += __shfl_down(s, off, 64);
    __shared__ double wsum[4];
    int lane = threadIdx.x & 63, wid = threadIdx.x >> 6;
    if (lane == 0) wsum[wid] = s;
    __syncthreads();
    if (threadIdx.x == 0) {
        double nrm = sqrt(wsum[0] + wsum[1] + wsum[2] + wsum[3]);
        if (nrm < 1e-12) nrm = 1e-12;
        *scale = (float)(10.0 / nrm);
    }
}

// ---------------- exp pass: P8 = e5m2(exp(scale*S8)) in-place (linear) ------
__global__ __launch_bounds__(256)
void exp_rows_kernel(u8* __restrict__ P8, const float* __restrict__ scale_p,
                     float* __restrict__ rs)
{
    const int wid = threadIdx.x >> 6, lane = threadIdx.x & 63;
    const int p = blockIdx.x * 4 + wid;   // grid 2304
    u8* rp = P8 + (size_t)p * 9216;
    const float scale = *scale_p;
    float s = 0.f;
#pragma unroll
    for (int it = 0; it < 18; ++it) {
        unsigned long long v8 = *(unsigned long long*)(rp + it * 512 + lane * 8);
        unsigned long long ow = 0;
#pragma unroll
        for (int j = 0; j < 8; ++j) {
            float sv = e5m2f((unsigned)(v8 >> (8 * j)) & 0xFFu);
            u8 e8 = f2e5m2(__expf(scale * sv));
            ow |= (unsigned long long)e8 << (8 * j);
            s += e5m2f(e8);
        }
        *(unsigned long long*)(rp + it * 512 + lane * 8) = ow;
    }
    for (int off = 32; off; off >>= 1) s += __shfl_down(s, off, 64);
    if (lane == 0) rs[p] = s;
}

__global__ void inv_kernel(const float* __restrict__ rs, float* __restrict__ inv)
{
    int i = blockIdx.x * 256 + threadIdx.x;
    if (i < 9216) inv[i] = 1.f / rs[i];
}

// ---------------- stencil 2: W = sum_t inv[p+e]*P[p+e][q+e], e5m2 K-PERM ----
__global__ __launch_bounds__(256)
void wstencil2_kernel(const u8* __restrict__ P8, const float* __restrict__ inv,
                      u8* __restrict__ W, float* __restrict__ wt,
                      float* __restrict__ wq)
{
    const int wid  = threadIdx.x >> 6;
    const int lane = threadIdx.x & 63;
    const int p = blockIdx.y * 4 + wid;
    const int py = p / 96, px = p - py * 96;
    const int q0 = blockIdx.x * 512 + lane * 8;
    const int qy = q0 / 96, qx0 = q0 - qy * 96;

    __half2 hz = __floats2half2_rn(0.f, 0.f);
    __half2 hacc[4] = {hz, hz, hz, hz};

#pragma unroll
    for (int ey = -1; ey <= 1; ++ey) {
#pragma unroll
        for (int ex = -1; ex <= 1; ++ex) {
            if ((unsigned)(py + ey) >= 96u || (unsigned)(px + ex) >= 96u) continue;
            if ((unsigned)(qy + ey) >= 96u) continue;
            const int e = ey * 96 + ex;
            const u8* rp = P8 + (size_t)(p + e) * 9216;
            const int cc = q0 + e;
            unsigned long long v8;
            if (ex == 0) {
                v8 = *(const unsigned long long*)(rp + cc);
            } else {
                int base = cc & ~7;
                int sh = (cc & 7) * 8;
                unsigned long long lo = *(const unsigned long long*)(rp + base);
                unsigned long long hi = *(const unsigned long long*)(rp + base + 8);
                v8 = (lo >> sh) | (hi << (64 - sh));
            }
            if (ex == 1 && qx0 == 88) v8 &= 0x00FFFFFFFFFFFFFFull;
            if (ex == -1 && qx0 == 0) v8 &= 0xFFFFFFFFFFFFFF00ull;

            float iv = inv[p + e];
            __half2 iv2 = __floats2half2_rn(iv, iv);
            unsigned lo32 = (unsigned)v8, hi32 = (unsigned)(v8 >> 32);
            unsigned pk[4];
            E5M2_UNPACK(pk, lo32);
            E5M2_UNPACK((pk + 2), hi32);
#pragma unroll
            for (int i = 0; i < 4; ++i)
                hacc[i] = __hfma2(*(__half2*)&pk[i], iv2, hacc[i]);
        }
    }

    unsigned long long ow = 0;
    float st = 0.f, sq = 0.f;
#pragma unroll
    for (int i = 0; i < 4; ++i) {
        float fx = __half2float(__low2half(hacc[i]));
        float fy = __half2float(__high2half(hacc[i]));
        u8 bx = f2e5m2(fx), by = f2e5m2(fy);
        ow |= (unsigned long long)bx << (16 * i);
        ow |= (unsigned long long)by << (16 * i + 8);
        st += fx + fy;
        sq += e5m2f(bx) + e5m2f(by);
    }
    *(unsigned long long*)(W + (size_t)p * 9216 + (q0 & ~127) + perm8(lane & 15) * 8) = ow;

    for (int off = 32; off; off >>= 1) {
        st += __shfl_down(st, off, 64);
        sq += __shfl_down(sq, off, 64);
    }
    if (lane == 0) {
        wt[(size_t)p * 18 + blockIdx.x] = st;
        wq[(size_t)p * 18 + blockIdx.x] = sq;
    }
}

// ratio[p] = sum(wt) / sum(wq), fixed order
__global__ void ratio_kernel(const float* __restrict__ wt, const float* __restrict__ wq,
                             float* __restrict__ ratio)
{
    int i = blockIdx.x * 256 + threadIdx.x;
    if (i >= 9216) return;
    float st = 0.f, sq = 0.f;
#pragma unroll
    for (int j = 0; j < 18; ++j) {
        st += wt[(size_t)i * 18 + j];
        sq += wq[(size_t)i * 18 + j];
    }
    ratio[i] = (sq > 0.f) ? st / sq : 0.f;
}

// ---------------- out-GEMM: R3s[z][p][c] = sum_{q chunk} W[p][q]*bg[c][q] ---
__global__ __launch_bounds__(256)
void og_kernel(const u8* __restrict__ Wm, const u8* __restrict__ Bc,
               float* __restrict__ R3s)
{
    __shared__ __align__(16) u8 As[64 * 128];
    __shared__ __align__(16) u8 Bs[128 * 128];
    const int tid  = threadIdx.x;
    const int wid  = tid >> 6;
    const int lane = tid & 63;
    const int wm = (wid >> 1) * 32;
    const int wn = (wid & 1) * 64;
    const size_t bm = (size_t)blockIdx.x * 64;
    const int kbeg = blockIdx.y * 1152;

    f32x4 acc[2][4];
#pragma unroll
    for (int i = 0; i < 2; ++i)
#pragma unroll
        for (int j = 0; j < 4; ++j)
            acc[i][j] = (f32x4){0.f, 0.f, 0.f, 0.f};

    const int lrow = lane >> 3;
    const int lcb  = ((lane & 7) << 4) ^ ((lrow & 7) << 4);
    const u8* gA = Wm + (bm + wid * 16 + lrow) * (size_t)9216 + lcb;
    const u8* gB = Bc + (wid * 32 + lrow) * (size_t)9216 + lcb;
    u8* lA = As + (size_t)(wid * 16) * 128;
    u8* lB = Bs + (size_t)(wid * 32) * 128;
    const size_t rstep = (size_t)9216 * 8;
    const int lm = lane & 15, lk = lane >> 4;

    for (int k0 = kbeg; k0 < kbeg + 1152; k0 += 128) {
        __syncthreads();
#pragma unroll
        for (int j = 0; j < 2; ++j)
            GLOAD16(gA + j * rstep + k0, lA + j * 1024);
#pragma unroll
        for (int j = 0; j < 4; ++j)
            GLOAD16(gB + j * rstep + k0, lB + j * 1024);
        __syncthreads();

        long2v aop[2][2], bop[4][2];
#pragma unroll
        for (int f = 0; f < 2; ++f) {
            int ma = wm + f * 16 + lm;
            int sw = (ma & 7) << 4;
            const u8* pr = As + ma * 128;
            aop[f][0] = *(const long2v*)(pr + ((lk * 32) ^ sw));
            aop[f][1] = *(const long2v*)(pr + ((lk * 32 + 16) ^ sw));
        }
#pragma unroll
        for (int f = 0; f < 4; ++f) {
            int nb = wn + f * 16 + lm;
            int sw = (nb & 7) << 4;
            const u8* pr = Bs + nb * 128;
            bop[f][0] = *(const long2v*)(pr + ((lk * 32) ^ sw));
            bop[f][1] = *(const long2v*)(pr + ((lk * 32 + 16) ^ sw));
        }
#pragma unroll
        for (int ks = 0; ks < 4; ++ks)
#pragma unroll
            for (int fm = 0; fm < 2; ++fm)
#pragma unroll
                for (int fn = 0; fn < 4; ++fn)
                    acc[fm][fn] = __builtin_amdgcn_mfma_f32_16x16x32_bf8_fp8(
                        aop[fm][ks >> 1][ks & 1], bop[fn][ks >> 1][ks & 1],
                        acc[fm][fn], 0, 0, 0);
    }

    float* out = R3s + (size_t)blockIdx.y * 9216 * 128;
#pragma unroll
    for (int fm = 0; fm < 2; ++fm)
#pragma unroll
        for (int fn = 0; fn < 4; ++fn)
#pragma unroll
            for (int i = 0; i < 4; ++i) {
                int r = wm + fm * 16 + ((lane >> 4) * 4) + i;
                int c = wn + fn * 16 + (lane & 15);
                out[(bm + r) * (size_t)128 + c] = acc[fm][fn][i];
            }
}

// ---------------- sum partials * ratio + mask + 2x upsample -> cl bf16 ------
__global__ void up_sum_kernel(const float* __restrict__ R3s, const float* __restrict__ ratio,
                              const float* __restrict__ mask, u16* __restrict__ upCL)
{
    int idx = blockIdx.x * 256 + threadIdx.x;   // 9216 * 16
    if (idx >= 147456) return;
    int p = idx >> 4, cs = (idx & 15) * 8;
    int y = p / 96, x = p - y * 96;
    float m = mask[(size_t)(2 * y) * 192 + 2 * x] * ratio[p];
    float acc[8];
#pragma unroll
    for (int j = 0; j < 8; ++j) acc[j] = 0.f;
#pragma unroll
    for (int z = 0; z < 8; ++z) {
        const float* rp = R3s + (size_t)z * 9216 * 128 + (size_t)p * 128 + cs;
        float4 a = *(const float4*)rp;
        float4 b = *(const float4*)(rp + 4);
        acc[0] += a.x; acc[1] += a.y; acc[2] += a.z; acc[3] += a.w;
        acc[4] += b.x; acc[5] += b.y; acc[6] += b.z; acc[7] += b.w;
    }
    u16 ov[8];
#pragma unroll
    for (int j = 0; j < 8; ++j) ov[j] = f2bf(acc[j] * m);
    short8v v = *(short8v*)ov;
    size_t r0 = ((size_t)(2 * y) * 192 + 2 * x) * 128 + cs;
    size_t r1 = ((size_t)(2 * y + 1) * 192 + 2 * x) * 128 + cs;
    *(short8v*)(upCL + r0)        = v;
    *(short8v*)(upCL + r0 + 128)  = v;
    *(short8v*)(upCL + r1)        = v;
    *(short8v*)(upCL + r1 + 128)  = v;
}

// ---------------------------------------------------------------------------
extern "C" void kernel_launch(void* const* d_in, const int* in_sizes, int n_in,
                              void* d_out, int out_size, void* d_ws, size_t ws_size,
                              hipStream_t stream)
{
    const float* x    = (const float*)d_in[0];
    const float* mask = (const float*)d_in[1];
    const float* w[8];
    const float* b[8];
    for (int i = 0; i < 8; ++i) {
        w[i] = (const float*)d_in[2 + 2 * i];
        b[i] = (const float*)d_in[3 + 2 * i];
    }
    char* ws = (char*)d_ws;
    dim3 blk(256);

    // byte offsets (identical to round 16; peak 188.4 MB, proven safe)
    const size_t U_H1CL = 0;
    const size_t U_H2   = 37748736;
    const size_t U_H3   = 47185920;
    const size_t U_H4   = 66060288;
    const size_t U_H5   = 75497472;
    const size_t U_H6   = 84934656;
    const size_t U_X4   = 94371840;
    const size_t U_FGC  = 0;
    const size_t U_BGC  = 2359296;
    const size_t B_BGC8 = 4718592;
    const size_t B_G    = 15335424;
    const size_t B_P8   = 100270080;
    const size_t B_W    = 15335424;
    const size_t F_R3S  = 100270080;
    const size_t U_UPCL = 138018816;
    const size_t U_H7   = 147456000;
    const size_t F_H8   = 156893184;
    const size_t U_WP1  = 185204736;
    const size_t U_WP2  = 185212928;
    const size_t U_WP3  = 185231360;
    const size_t U_WP4  = 185268224;
    const size_t U_WP5  = 185415680;
    const size_t U_WP6  = 185710592;
    const size_t U_WP7  = 186005504;
    const size_t U_WP8  = 186300416;
    const size_t D_RED  = 186595328;
    const size_t F_SCALE= 186927104;
    const size_t F_RS   = 186927360;
    const size_t F_INV  = 186964224;
    const size_t F_WT   = 187001088;
    const size_t F_WQ   = 187664640;
    const size_t F_RAT  = 188328192;

    u16* h1cl   = (u16*)(ws + U_H1CL);
    u16* h2     = (u16*)(ws + U_H2);
    u16* h3     = (u16*)(ws + U_H3);
    u16* h4     = (u16*)(ws + U_H4);
    u16* h5     = (u16*)(ws + U_H5);
    u16* h6     = (u16*)(ws + U_H6);
    u16* x4     = (u16*)(ws + U_X4);
    u16* fgC    = (u16*)(ws + U_FGC);
    u16* bgC    = (u16*)(ws + U_BGC);
    u8*  bgC8   = (u8*)(ws + B_BGC8);
    u8*  G      = (u8*)(ws + B_G);
    u8*  P8     = (u8*)(ws + B_P8);
    u8*  Wm     = (u8*)(ws + B_W);
    float* R3s  = (float*)(ws + F_R3S);
    u16* upCL   = (u16*)(ws + U_UPCL);
    u16* h7     = (u16*)(ws + U_H7);
    float* h8   = (float*)(ws + F_H8);
    u16* wp1    = (u16*)(ws + U_WP1);
    u16* wp2    = (u16*)(ws + U_WP2);
    u16* wp3    = (u16*)(ws + U_WP3);
    u16* wp4    = (u16*)(ws + U_WP4);
    u16* wp5    = (u16*)(ws + U_WP5);
    u16* wp6    = (u16*)(ws + U_WP6);
    u16* wp7    = (u16*)(ws + U_WP7);
    u16* wp8    = (u16*)(ws + U_WP8);
    double* red = (double*)(ws + D_RED);
    float* scale= (float*)(ws + F_SCALE);
    float* rs   = (float*)(ws + F_RS);
    float* inv  = (float*)(ws + F_INV);
    float* wt   = (float*)(ws + F_WT);
    float* wq   = (float*)(ws + F_WQ);
    float* ratio= (float*)(ws + F_RAT);

    // ---- prepack ----
    pack_w1_kernel<<<dim3(16), blk, 0, stream>>>(w[0], wp1);
    pack_w_kernel<<<dim3(36),  blk, 0, stream>>>(w[1], wp2, 32, 32);
    pack_w_kernel<<<dim3(72),  blk, 0, stream>>>(w[2], wp3, 64, 32);
    pack_w_kernel<<<dim3(288), blk, 0, stream>>>(w[3], wp4, 128, 64);
    pack_w_kernel<<<dim3(576), blk, 0, stream>>>(w[4], wp5, 128, 128);
    pack_w_kernel<<<dim3(576), blk, 0, stream>>>(w[5], wp6, 128, 128);
    pack_w_kernel<<<dim3(576), blk, 0, stream>>>(w[6], wp7, 128, 128);
    pack_w_kernel<<<dim3(576), blk, 0, stream>>>(w[7], wp8, 128, 128);
    x4cl_kernel<<<dim3(2304), blk, 0, stream>>>(x, x4);

    // ---- conv front-end ----
    conv1_mfma_kernel<<<dim3(48, 96), blk, 0, stream>>>(x4, wp1, b[0], h1cl);
    mfma_conv_kernel<4, 1, 2, 2, 2, 32, 32, 1, 0><<<dim3(24, 48), blk, 0, stream>>>(
        h1cl, wp2, b[1], h2, 768, 768, 384, 384, 32);
    mfma_conv_kernel<4, 2, 2, 2, 1, 32, 32, 1, 0><<<dim3(24, 48), blk, 0, stream>>>(
        h2, wp3, b[2], h3, 384, 384, 384, 384, 64);
    mfma_conv_kernel<4, 2, 2, 2, 2, 64, 32, 1, 0><<<dim3(12, 24, 2), blk, 0, stream>>>(
        h3, wp4, b[3], h4, 384, 384, 192, 192, 128);
    mfma_conv_kernel<4, 2, 2, 2, 1, 128, 128, 1, 0><<<dim3(12, 24, 2), blk, 0, stream>>>(
        h4, wp5, b[4], h5, 192, 192, 192, 192, 128);
    mfma_conv_kernel<4, 2, 2, 2, 1, 128, 128, 0, 0><<<dim3(12, 24, 2), blk, 0, stream>>>(
        h5, wp6, b[5], h6, 192, 192, 192, 192, 128);

    // ---- attention inputs ----
    build_fgbgc_kernel<<<dim3(576), blk, 0, stream>>>(h6, mask, fgC, bgC);
    build_bgc8_kernel<<<dim3(576), blk, 0, stream>>>(h6, bgC8);

    // ---- G (K=128 Gram, e5m2, x1/8) ----
    g_gemm_kernel<<<dim3(72, 72), blk, 0, stream>>>(fgC, bgC, G);

    // ---- stencil 1: S8 + Frobenius partials -> scale ----
    sstencil_kernel<<<dim3(18, 2304), blk, 0, stream>>>(G, P8, red);
    sumsq_stage2<<<dim3(1), blk, 0, stream>>>(red, 41472, scale);

    // ---- exp in-place (linear) + rowsums -> inv ----
    exp_rows_kernel<<<dim3(2304), blk, 0, stream>>>(P8, scale, rs);
    inv_kernel<<<dim3(36), blk, 0, stream>>>(rs, inv);

    // ---- stencil 2: W (e5m2, k-permuted) + quantization ratio ----
    wstencil2_kernel<<<dim3(18, 2304), blk, 0, stream>>>(P8, inv, Wm, wt, wq);
    ratio_kernel<<<dim3(36), blk, 0, stream>>>(wt, wq, ratio);

    // ---- out-GEMM (bf8 x fp8, split-K 8) -> partial R3s ----
    og_kernel<<<dim3(144, 8), blk, 0, stream>>>(Wm, bgC8, R3s);

    // ---- sum partials * ratio + mask + upsample -> channels-last bf16 ----
    up_sum_kernel<<<dim3(576), blk, 0, stream>>>(R3s, ratio, mask, upCL);

    // ---- back-end convs ----
    mfma_conv_kernel<4, 2, 2, 2, 1, 128, 128, 1, 0><<<dim3(12, 24, 2), blk, 0, stream>>>(
        upCL, wp7, b[6], h7, 192, 192, 192, 192, 128);
    mfma_conv_kernel<4, 2, 2, 2, 1, 128, 128, 1, 1><<<dim3(12, 24, 2), blk, 0, stream>>>(
        h7, wp8, b[7], h8, 192, 192, 192, 192, 128);
    cl2p_kernel<<<dim3(1152), blk, 0, stream>>>(h8, (float*)d_out);
}

// Round 18
// 620.182 us; speedup vs baseline: 1.8957x; 1.0509x over previous
//
#include <hip/hip_runtime.h>
#include <hip/hip_fp16.h>
#include <math.h>

// ---------------------------------------------------------------------------
// Round 17->18: packed e5m2 encode in stencil/exp epilogues.
// RNE-to-top-byte vectorized over half2: t = h + 0x007F007F + ((h>>8)&0x10001)
// (carry cannot cross 16-bit lanes for |x| < 57344); bytes gathered with
// v_perm; quantized fp16 = t & 0xFF00FF00 (bit-consistent with stored bytes).
// Everything else identical to round 17 (652 us, absmax 0.0625).
// ---------------------------------------------------------------------------

typedef unsigned short u16;
typedef unsigned char u8;
typedef short short4v __attribute__((ext_vector_type(4)));
typedef short short8v __attribute__((ext_vector_type(8)));
typedef float f32x4 __attribute__((ext_vector_type(4)));
typedef long long2v __attribute__((ext_vector_type(2)));

__device__ __forceinline__ u16 f2bf(float f) {
    unsigned u = __float_as_uint(f);
    return (u16)((u + 0x7FFF + ((u >> 16) & 1)) >> 16);
}
__device__ __forceinline__ float bf2f(u16 h) {
    return __uint_as_float(((unsigned)h) << 16);
}
// f32 -> fp8 e5m2 (RNE via fp16 truncation; field-validated)
__device__ __forceinline__ u8 f2e5m2(float f) {
    unsigned short hb = __half_as_ushort(__float2half(f));
    unsigned rem = hb & 0xFF;
    unsigned b = hb >> 8;
    b += (rem > 0x80u) || (rem == 0x80u && (b & 1u));
    return (u8)b;
}
__device__ __forceinline__ float e5m2f(unsigned b) {
    return __half2float(__ushort_as_half((unsigned short)(b << 8)));
}
// f32 -> fp8 e4m3fn (OCP), RNE, saturate (field-validated)
__device__ __forceinline__ u8 f2e4m3(float f) {
    unsigned u = __float_as_uint(f);
    unsigned s = (u >> 24) & 0x80u;
    unsigned a = u & 0x7FFFFFFFu;
    if (a >= 0x43E00000u) return (u8)(s | 0x7Eu);
    int e = (int)(a >> 23) - 127;
    if (e >= -6) {
        unsigned keep = (a >> 20) & 7u;
        unsigned rem  = a & 0xFFFFFu;
        keep += (rem > 0x80000u) || (rem == 0x80000u && (keep & 1u));
        unsigned e4 = (unsigned)(e + 7);
        if (keep == 8u) { keep = 0u; ++e4; }
        if (e4 >= 15u && keep >= 7u) return (u8)(s | 0x7Eu);
        return (u8)(s | (e4 << 3) | keep);
    }
    float q = __uint_as_float(a) * 512.f;
    int m = (int)rintf(q);
    if (m >= 8) return (u8)(s | 0x08u);
    return (u8)(s | (unsigned)m);
}
// 8B-chunk permutation within a 128B k-block: (ks,lk) -> (lk,ks)
__device__ __forceinline__ int perm8(int o8) { return ((o8 & 3) << 2) | (o8 >> 2); }

#define GLOAD16(g, l) __builtin_amdgcn_global_load_lds(                      \
    (const __attribute__((address_space(1))) void*)(g),                      \
    (__attribute__((address_space(3))) void*)(l), 16, 0, 0)

// unpack 4 e5m2 bytes of a dword into two half2 words (byte -> high byte)
#define E5M2_UNPACK(dst, src32)                                              \
    dst[0] = __builtin_amdgcn_perm(0u, (src32), 0x010C000Cu);                \
    dst[1] = __builtin_amdgcn_perm(0u, (src32), 0x030C020Cu);

// packed RNE fp16->e5m2 round: per-lane t = h + 0x7F + lsb (no cross-lane carry
// for |x| < 57344); rounded byte = t lane's high byte; quantized fp16 = t&0xFF00
__device__ __forceinline__ unsigned e5m2_round2(unsigned h) {
    return h + 0x007F007Fu + ((h >> 8) & 0x00010001u);
}

// ---------------- x -> channels-last bf16 ic4 (for conv1 MFMA) --------------
__global__ void x4cl_kernel(const float* __restrict__ x, u16* __restrict__ out)
{
    int i = blockIdx.x * 256 + threadIdx.x;
    if (i >= 589824) return;
    u16 v[4];
    v[0] = f2bf(x[i]);
    v[1] = f2bf(x[589824 + i]);
    v[2] = f2bf(x[1179648 + i]);
    v[3] = 0;
    *(short4v*)(out + (size_t)i * 4) = *(short4v*)v;
}

__global__ void pack_w1_kernel(const float* __restrict__ w, u16* __restrict__ wp)
{
    int i = blockIdx.x * 256 + threadIdx.x;
    if (i >= 4096) return;
    int oc = i >> 7, k = i & 127;
    int tap = k >> 2, ic = k & 3;
    u16 v = 0;
    if (tap < 25 && ic < 3) v = f2bf(w[oc * 75 + ic * 25 + tap]);
    wp[i] = v;
}

// ---------------- conv1 MFMA: 3->32, 5x5, s1, reflect pad2, ELU -------------
__global__ __launch_bounds__(256)
void conv1_mfma_kernel(const u16* __restrict__ x4, const u16* __restrict__ wp1,
                       const float* __restrict__ bias, u16* __restrict__ out)
{
    __shared__ __align__(16) u16 sIn[12 * 20 * 4];
    const int tid = threadIdx.x;
    const int lane = tid & 63;
    const int w = tid >> 6;
    const int lm = lane & 15;
    const int lk = lane >> 4;
    const int oy0 = blockIdx.y * 8, ox0 = blockIdx.x * 16;

    for (int u = tid; u < 240; u += 256) {
        int yt = u / 20, xt = u - yt * 20;
        int gy = oy0 - 2 + yt; gy = gy < 0 ? -gy : (gy >= 768 ? 1534 - gy : gy);
        int gx = ox0 - 2 + xt; gx = gx < 0 ? -gx : (gx >= 768 ? 1534 - gx : gx);
        *(short4v*)(sIn + u * 4) = *(const short4v*)(x4 + ((size_t)gy * 768 + gx) * 4);
    }
    int aoff[4][2];
#pragma unroll
    for (int ks = 0; ks < 4; ++ks) {
        int t0 = ks * 8 + lk * 2;
        int t1 = t0 + 1;
        if (t0 > 24) t0 = 24;
        if (t1 > 24) t1 = 24;
        int dy0 = t0 / 5, dx0 = t0 - 5 * dy0;
        int dy1 = t1 / 5, dx1 = t1 - 5 * dy1;
        aoff[ks][0] = (dy0 * 20 + dx0 + lm) * 4;
        aoff[ks][1] = (dy1 * 20 + dx1 + lm) * 4;
    }
    __syncthreads();

    f32x4 acc[2][2];
#pragma unroll
    for (int i = 0; i < 2; ++i)
#pragma unroll
        for (int j = 0; j < 2; ++j) acc[i][j] = (f32x4){0.f, 0.f, 0.f, 0.f};

#pragma unroll
    for (int ks = 0; ks < 4; ++ks) {
        short8v a[2], b[2];
#pragma unroll
        for (int fm = 0; fm < 2; ++fm) {
            int base = (w * 2 + fm) * 80;
            short4v lo = *(const short4v*)(sIn + base + aoff[ks][0]);
            short4v hi = *(const short4v*)(sIn + base + aoff[ks][1]);
            short8v av;
            av[0] = lo[0]; av[1] = lo[1]; av[2] = lo[2]; av[3] = lo[3];
            av[4] = hi[0]; av[5] = hi[1]; av[6] = hi[2]; av[7] = hi[3];
            a[fm] = av;
        }
#pragma unroll
        for (int fn = 0; fn < 2; ++fn)
            b[fn] = *(const short8v*)(wp1 + (size_t)(fn * 16 + lm) * 128 + ks * 32 + lk * 8);
#pragma unroll
        for (int fm = 0; fm < 2; ++fm)
#pragma unroll
            for (int fn = 0; fn < 2; ++fn)
                acc[fm][fn] = __builtin_amdgcn_mfma_f32_16x16x32_bf16(
                    a[fm], b[fn], acc[fm][fn], 0, 0, 0);
    }

#pragma unroll
    for (int fm = 0; fm < 2; ++fm) {
        int gy = oy0 + w * 2 + fm;
#pragma unroll
        for (int fn = 0; fn < 2; ++fn) {
            int oc = fn * 16 + lm;
            float bv = bias[oc];
#pragma unroll
            for (int i = 0; i < 4; ++i) {
                int xx = lk * 4 + i;
                float v = acc[fm][fn][i] + bv;
                v = v > 0.f ? v : expm1f(v);
                out[((size_t)gy * 768 + ox0 + xx) * 32 + oc] = f2bf(v);
            }
        }
    }
}

// ---------------- weight prepack ----------------
__global__ void pack_w_kernel(const float* __restrict__ w, u16* __restrict__ wp,
                              int OC, int IC)
{
    int idx = blockIdx.x * 256 + threadIdx.x;
    if (idx >= OC * 9 * IC) return;
    int oc = idx / (9 * IC);
    int r  = idx - oc * 9 * IC;
    int tap = r / IC;
    int ic  = r - tap * IC;
    wp[idx] = f2bf(w[((size_t)oc * IC + ic) * 9 + tap]);
}

// ---------------- MFMA implicit-GEMM conv (3x3, reflect pad 1) --------------
template<int FM, int FN, int NWM, int NWN, int S, int IC, int ICC, int ACT, int OUTF32>
__global__ __launch_bounds__(256)
void mfma_conv_kernel(const u16* __restrict__ in, const u16* __restrict__ wgtP,
                      const float* __restrict__ bias, void* __restrict__ out,
                      int H, int W, int Ho, int Wo, int OC)
{
    constexpr int TY = 7 * S + 3;
    constexpr int TX = 15 * S + 3;
    constexpr int NSLOT = ICC / 8;
    constexpr int SWMSK = NSLOT - 1;
    constexpr int KTOT = 9 * IC;
    __shared__ __align__(16) u16 sIn[TY * TX * ICC];

    const int tid  = threadIdx.x;
    const int lane = tid & 63;
    const int wid  = tid >> 6;
    const int wmi  = wid / NWN;
    const int wni  = wid % NWN;
    const int lm   = lane & 15;
    const int lk   = lane >> 4;
    const int noff = blockIdx.z * (NWN * FN * 16);

    f32x4 acc[FM][FN];
#pragma unroll
    for (int i = 0; i < FM; ++i)
#pragma unroll
        for (int j = 0; j < FN; ++j) acc[i][j] = (f32x4){0.f, 0.f, 0.f, 0.f};

    const int iy0 = blockIdx.y * 8 * S - 1;
    const int ix0 = blockIdx.x * 16 * S - 1;

    for (int c0 = 0; c0 < IC; c0 += ICC) {
        if (c0) __syncthreads();
        for (int u = tid; u < TY * TX * NSLOT; u += 256) {
            int yt = u / (TX * NSLOT);
            int r  = u - yt * (TX * NSLOT);
            int xt = r / NSLOT;
            int sl = r - xt * NSLOT;
            int gy = iy0 + yt; gy = gy < 0 ? -gy : (gy >= H ? 2 * H - 2 - gy : gy);
            int gx = ix0 + xt; gx = gx < 0 ? -gx : (gx >= W ? 2 * W - 2 - gx : gx);
            *(short8v*)((char*)sIn + (size_t)((yt * TX + xt) * NSLOT + (sl ^ (xt & SWMSK))) * 16) =
                *(const short8v*)(in + ((size_t)gy * W + gx) * IC + c0 + sl * 8);
        }
        __syncthreads();
#pragma unroll
        for (int tap = 0; tap < 9; ++tap) {
            const int dy = tap / 3, dx = tap % 3;
#pragma unroll
            for (int icw = 0; icw < ICC / 32; ++icw) {
                short8v a[FM], b[FN];
#pragma unroll
                for (int fm = 0; fm < FM; ++fm) {
                    int yt = (wmi * FM + fm) * S + dy;
                    int xt = lm * S + dx;
                    a[fm] = *(const short8v*)((const char*)sIn +
                        (size_t)((yt * TX + xt) * NSLOT + ((icw * 4 + lk) ^ (xt & SWMSK))) * 16);
                }
#pragma unroll
                for (int fn = 0; fn < FN; ++fn) {
                    int n = noff + wni * FN * 16 + fn * 16 + lm;
                    b[fn] = *(const short8v*)(wgtP + (size_t)n * KTOT + tap * IC + c0 + icw * 32 + lk * 8);
                }
#pragma unroll
                for (int fm = 0; fm < FM; ++fm)
#pragma unroll
                    for (int fn = 0; fn < FN; ++fn)
                        acc[fm][fn] = __builtin_amdgcn_mfma_f32_16x16x32_bf16(
                            a[fm], b[fn], acc[fm][fn], 0, 0, 0);
            }
        }
    }

#pragma unroll
    for (int fm = 0; fm < FM; ++fm) {
        int y = blockIdx.y * 8 + wmi * FM + fm;
#pragma unroll
        for (int fn = 0; fn < FN; ++fn) {
            int oc = noff + wni * FN * 16 + fn * 16 + lm;
            float bv = bias[oc];
#pragma unroll
            for (int i = 0; i < 4; ++i) {
                int x = blockIdx.x * 16 + lk * 4 + i;
                float v = acc[fm][fn][i] + bv;
                if (ACT == 0) v = v > 0.f ? v : 0.f;
                else          v = v > 0.f ? v : expm1f(v);
                size_t o = ((size_t)y * Wo + x) * OC + oc;
                if (OUTF32) ((float*)out)[o] = v;
                else        ((u16*)out)[o]   = f2bf(v);
            }
        }
    }
}

// channels-last f32 [36864][128] -> planar f32 [128][36864]
__global__ __launch_bounds__(256)
void cl2p_kernel(const float* __restrict__ in, float* __restrict__ out)
{
    __shared__ float t[32][130];
    const int tid = threadIdx.x;
    const int p0 = blockIdx.x * 32;
#pragma unroll
    for (int j = 0; j < 16; ++j) {
        int idx = j * 256 + tid;
        int px = idx >> 7, c = idx & 127;
        t[px][c] = in[(size_t)(p0 + px) * 128 + c];
    }
    __syncthreads();
#pragma unroll
    for (int j = 0; j < 16; ++j) {
        int c = j * 8 + (tid >> 5);
        int px = tid & 31;
        out[(size_t)c * 36864 + p0 + px] = t[px][c];
    }
}

// ---------------- half-res channel-last images: fgC (masked), bgC -----------
__global__ void build_fgbgc_kernel(const u16* __restrict__ h6, const float* __restrict__ mask,
                                   u16* __restrict__ fgC, u16* __restrict__ bgC)
{
    int idx = blockIdx.x * 256 + threadIdx.x;   // 9216*16
    if (idx >= 147456) return;
    int q = idx >> 4, cs = (idx & 15) * 8;
    int qy = q / 96, qx = q - qy * 96;
    const u16* src = h6 + ((size_t)(2 * qy) * 192 + 2 * qx) * 128 + cs;
    float m = mask[(size_t)(2 * qy) * 192 + 2 * qx];
    short8v v = *(const short8v*)src;
    u16 fo[8];
#pragma unroll
    for (int j = 0; j < 8; ++j) fo[j] = f2bf(bf2f((u16)v[j]) * m);
    *(short8v*)(bgC + (size_t)q * 128 + cs) = v;
    *(short8v*)(fgC + (size_t)q * 128 + cs) = *(short8v*)fo;
}

// ---------------- bgC8: e4m3 [128][9216] (unmasked bg, c-major), K-PERMUTED -
__global__ void build_bgc8_kernel(const u16* __restrict__ h6, u8* __restrict__ bgC8)
{
    int idx = blockIdx.x * 256 + threadIdx.x;   // 128 * 1152 chunks
    if (idx >= 128 * 1152) return;
    int c = idx / 1152, qc = idx - c * 1152;
    int q0 = qc << 3;
    int qy = q0 / 96, qx0 = q0 - qy * 96;
    const u16* row = h6 + (size_t)(2 * qy) * 192 * 128 + c;
    unsigned long long ow = 0;
#pragma unroll
    for (int j = 0; j < 8; ++j) {
        float v = bf2f(row[(size_t)(2 * (qx0 + j)) * 128]);
        ow |= (unsigned long long)f2e4m3(v) << (8 * j);
    }
    *(unsigned long long*)(bgC8 + (size_t)c * 9216 + (q0 & ~127) + perm8(qc & 15) * 8) = ow;
}

// ---------------- G-GEMM: G[a][b] = 1/8 * sum_c fgC[a][c]*bgC[b][c] ---------
__global__ __launch_bounds__(256)
void g_gemm_kernel(const u16* __restrict__ A, const u16* __restrict__ B,
                   u8* __restrict__ G)
{
    __shared__ __align__(16) u16 As[128 * 64];
    __shared__ __align__(16) u16 Bs[128 * 64];
    const int tid  = threadIdx.x;
    const int wid  = tid >> 6;
    const int lane = tid & 63;
    const int wm = (wid >> 1) * 64;
    const int wn = (wid & 1) * 64;
    const size_t bm = (size_t)blockIdx.y * 128;
    const size_t bn = (size_t)blockIdx.x * 128;

    f32x4 acc[4][4];
#pragma unroll
    for (int i = 0; i < 4; ++i)
#pragma unroll
        for (int j = 0; j < 4; ++j)
            acc[i][j] = (f32x4){0.f, 0.f, 0.f, 0.f};

    const int lrow = lane >> 3;
    const int lcb  = ((lane & 7) << 4) ^ ((lrow & 7) << 4);
    const char* gA = (const char*)A + ((bm + wid * 32 + lrow) * (size_t)128) * 2 + lcb;
    const char* gB = (const char*)B + ((bn + wid * 32 + lrow) * (size_t)128) * 2 + lcb;
    char* lA = (char*)As + (size_t)(wid * 32) * 128;
    char* lB = (char*)Bs + (size_t)(wid * 32) * 128;
    const size_t rs8 = (size_t)128 * 16;

    for (int k0 = 0; k0 < 128; k0 += 64) {
        __syncthreads();
#pragma unroll
        for (int j = 0; j < 4; ++j) {
            GLOAD16(gA + j * rs8 + (size_t)k0 * 2, lA + j * 1024);
            GLOAD16(gB + j * rs8 + (size_t)k0 * 2, lB + j * 1024);
        }
        __syncthreads();
#pragma unroll
        for (int ks = 0; ks < 2; ++ks) {
            short8v a[4], b[4];
#pragma unroll
            for (int f = 0; f < 4; ++f) {
                int ma = wm + f * 16 + (lane & 15);
                int kba = (ks * 64 + ((lane >> 4) * 16)) ^ ((ma & 7) << 4);
                a[f] = *(const short8v*)((const char*)As + ma * 128 + kba);
                int nb = wn + f * 16 + (lane & 15);
                int kbb = (ks * 64 + ((lane >> 4) * 16)) ^ ((nb & 7) << 4);
                b[f] = *(const short8v*)((const char*)Bs + nb * 128 + kbb);
            }
#pragma unroll
            for (int fm = 0; fm < 4; ++fm)
#pragma unroll
                for (int fn = 0; fn < 4; ++fn)
                    acc[fm][fn] = __builtin_amdgcn_mfma_f32_16x16x32_bf16(
                        a[fm], b[fn], acc[fm][fn], 0, 0, 0);
        }
    }

#pragma unroll
    for (int fm = 0; fm < 4; ++fm)
#pragma unroll
        for (int fn = 0; fn < 4; ++fn)
#pragma unroll
            for (int i = 0; i < 4; ++i) {
                int r = wm + fm * 16 + ((lane >> 4) * 4) + i;
                int c = wn + fn * 16 + (lane & 15);
                G[(bm + r) * (size_t)9216 + bn + c] = f2e5m2(0.125f * acc[fm][fn][i]);
            }
}

// ---------------- stencil 1: S8 = stencil(G), partial = sum S^2 (fp16) ------
__global__ __launch_bounds__(256)
void sstencil_kernel(const u8* __restrict__ G, u8* __restrict__ S8,
                     double* __restrict__ partial)
{
    const int wid  = threadIdx.x >> 6;
    const int lane = threadIdx.x & 63;
    const int p = blockIdx.y * 4 + wid;
    const int py = p / 96, px = p - py * 96;
    const int q0 = blockIdx.x * 512 + lane * 8;
    const int qy = q0 / 96, qx0 = q0 - qy * 96;

    __half2 hz = __floats2half2_rn(0.f, 0.f);
    __half2 hacc[4] = {hz, hz, hz, hz};

#pragma unroll
    for (int ey = -1; ey <= 1; ++ey) {
#pragma unroll
        for (int ex = -1; ex <= 1; ++ex) {
            if ((unsigned)(py + ey) >= 96u || (unsigned)(px + ex) >= 96u) continue;
            if ((unsigned)(qy + ey) >= 96u) continue;
            const int e = ey * 96 + ex;
            const u8* rp = G + (size_t)(p + e) * 9216;
            const int cc = q0 + e;
            unsigned long long v8;
            if (ex == 0) {
                v8 = *(const unsigned long long*)(rp + cc);
            } else {
                int base = cc & ~7;
                int sh = (cc & 7) * 8;
                unsigned long long lo = *(const unsigned long long*)(rp + base);
                unsigned long long hi = *(const unsigned long long*)(rp + base + 8);
                v8 = (lo >> sh) | (hi << (64 - sh));
            }
            if (ex == 1 && qx0 == 88) v8 &= 0x00FFFFFFFFFFFFFFull;
            if (ex == -1 && qx0 == 0) v8 &= 0xFFFFFFFFFFFFFF00ull;

            unsigned lo32 = (unsigned)v8, hi32 = (unsigned)(v8 >> 32);
            unsigned pk[4];
            E5M2_UNPACK(pk, lo32);
            E5M2_UNPACK((pk + 2), hi32);
#pragma unroll
            for (int i = 0; i < 4; ++i)
                hacc[i] = __hadd2(hacc[i], *(__half2*)&pk[i]);
        }
    }

    // packed RNE encode + fp32 sum of squares
    unsigned t[4];
    double s2 = 0.0;
#pragma unroll
    for (int i = 0; i < 4; ++i) {
        unsigned h = *(unsigned*)&hacc[i];
        t[i] = e5m2_round2(h);
        float2 f2 = __half22float2(hacc[i]);
        s2 += (double)f2.x * f2.x + (double)f2.y * f2.y;
    }
    unsigned lo = __builtin_amdgcn_perm(t[1], t[0], 0x07050301u);
    unsigned hi = __builtin_amdgcn_perm(t[3], t[2], 0x07050301u);
    unsigned long long ow = (unsigned long long)lo | ((unsigned long long)hi << 32);
    *(unsigned long long*)(S8 + (size_t)p * 9216 + q0) = ow;

    for (int off = 32; off; off >>= 1) s2 += __shfl_down(s2, off, 64);
    __shared__ double wsum[4];
    if (lane == 0) wsum[wid] = s2;
    __syncthreads();
    if (threadIdx.x == 0)
        partial[(size_t)blockIdx.y * 18 + blockIdx.x] = wsum[0] + wsum[1] + wsum[2] + wsum[3];
}

__global__ void sumsq_stage2(const double* __restrict__ partial, int nblocks, float* __restrict__ scale)
{
    double s = 0.0;
    for (int i = threadIdx.x; i < nblocks; i += 256) s += partial[i];
    for (int off = 32; off; off >>= 1) s += __shfl_down(s, off, 64);
    __shared__ double wsum[4];
    int lane = threadIdx.x & 63, wid = threadIdx.x >> 6;
    if (lane == 0) wsum[wid] = s;
    __syncthreads();
    if (threadIdx.x == 0) {
        double nrm = sqrt(wsum[0] + wsum[1] + wsum[2] + wsum[3]);
        if (nrm < 1e-12) nrm = 1e-12;
        *scale = (float)(10.0 / nrm);
    }
}

// ---------------- exp pass: P8 = e5m2(exp(scale*S8)) in-place (linear) ------
__global__ __launch_bounds__(256)
void exp_rows_kernel(u8* __restrict__ P8, const float* __restrict__ scale_p,
                     float* __restrict__ rs)
{
    const int wid = threadIdx.x >> 6, lane = threadIdx.x & 63;
    const int p = blockIdx.x * 4 + wid;   // grid 2304
    u8* rp = P8 + (size_t)p * 9216;
    const float scale = *scale_p;
    float s = 0.f;
#pragma unroll
    for (int it = 0; it < 18; ++it) {
        unsigned long long v8 = *(unsigned long long*)(rp + it * 512 + lane * 8);
        unsigned lo32 = (unsigned)v8, hi32 = (unsigned)(v8 >> 32);
        unsigned pkv[4];
        E5M2_UNPACK(pkv, lo32);
        E5M2_UNPACK((pkv + 2), hi32);
        unsigned t[4];
        __half2 sacc = __floats2half2_rn(0.f, 0.f);
#pragma unroll
        for (int j = 0; j < 4; ++j) {
            float2 f = __half22float2(*(__half2*)&pkv[j]);
            __half2 eh = __floats2half2_rn(__expf(scale * f.x), __expf(scale * f.y));
            t[j] = e5m2_round2(*(unsigned*)&eh);
            unsigned q = t[j] & 0xFF00FF00u;
            sacc = __hadd2(sacc, *(__half2*)&q);
        }
        unsigned lo = __builtin_amdgcn_perm(t[1], t[0], 0x07050301u);
        unsigned hi = __builtin_amdgcn_perm(t[3], t[2], 0x07050301u);
        *(unsigned long long*)(rp + it * 512 + lane * 8) =
            (unsigned long long)lo | ((unsigned long long)hi << 32);
        float2 sf = __half22float2(sacc);
        s += sf.x + sf.y;
    }
    for (int off = 32; off; off >>= 1) s += __shfl_down(s, off, 64);
    if (lane == 0) rs[p] = s;
}

__global__ void inv_kernel(const float* __restrict__ rs, float* __restrict__ inv)
{
    int i = blockIdx.x * 256 + threadIdx.x;
    if (i < 9216) inv[i] = 1.f / rs[i];
}

// ---------------- stencil 2: W = sum_t inv[p+e]*P[p+e][q+e], e5m2 K-PERM ----
__global__ __launch_bounds__(256)
void wstencil2_kernel(const u8* __restrict__ P8, const float* __restrict__ inv,
                      u8* __restrict__ W, float* __restrict__ wt,
                      float* __restrict__ wq)
{
    const int wid  = threadIdx.x >> 6;
    const int lane = threadIdx.x & 63;
    const int p = blockIdx.y * 4 + wid;
    const int py = p / 96, px = p - py * 96;
    const int q0 = blockIdx.x * 512 + lane * 8;
    const int qy = q0 / 96, qx0 = q0 - qy * 96;

    __half2 hz = __floats2half2_rn(0.f, 0.f);
    __half2 hacc[4] = {hz, hz, hz, hz};

#pragma unroll
    for (int ey = -1; ey <= 1; ++ey) {
#pragma unroll
        for (int ex = -1; ex <= 1; ++ex) {
            if ((unsigned)(py + ey) >= 96u || (unsigned)(px + ex) >= 96u) continue;
            if ((unsigned)(qy + ey) >= 96u) continue;
            const int e = ey * 96 + ex;
            const u8* rp = P8 + (size_t)(p + e) * 9216;
            const int cc = q0 + e;
            unsigned long long v8;
            if (ex == 0) {
                v8 = *(const unsigned long long*)(rp + cc);
            } else {
                int base = cc & ~7;
                int sh = (cc & 7) * 8;
                unsigned long long lo = *(const unsigned long long*)(rp + base);
                unsigned long long hi = *(const unsigned long long*)(rp + base + 8);
                v8 = (lo >> sh) | (hi << (64 - sh));
            }
            if (ex == 1 && qx0 == 88) v8 &= 0x00FFFFFFFFFFFFFFull;
            if (ex == -1 && qx0 == 0) v8 &= 0xFFFFFFFFFFFFFF00ull;

            float iv = inv[p + e];
            __half2 iv2 = __floats2half2_rn(iv, iv);
            unsigned lo32 = (unsigned)v8, hi32 = (unsigned)(v8 >> 32);
            unsigned pk[4];
            E5M2_UNPACK(pk, lo32);
            E5M2_UNPACK((pk + 2), hi32);
#pragma unroll
            for (int i = 0; i < 4; ++i)
                hacc[i] = __hfma2(*(__half2*)&pk[i], iv2, hacc[i]);
        }
    }

    // packed encode + fp16 pair sums (bit-consistent quantized sum via t&0xFF00)
    unsigned t[4];
    __half2 stacc = hz, sqacc = hz;
#pragma unroll
    for (int i = 0; i < 4; ++i) {
        unsigned h = *(unsigned*)&hacc[i];
        t[i] = e5m2_round2(h);
        stacc = __hadd2(stacc, hacc[i]);
        unsigned q = t[i] & 0xFF00FF00u;
        sqacc = __hadd2(sqacc, *(__half2*)&q);
    }
    unsigned lo = __builtin_amdgcn_perm(t[1], t[0], 0x07050301u);
    unsigned hi = __builtin_amdgcn_perm(t[3], t[2], 0x07050301u);
    *(unsigned long long*)(W + (size_t)p * 9216 + (q0 & ~127) + perm8(lane & 15) * 8) =
        (unsigned long long)lo | ((unsigned long long)hi << 32);

    float2 stf = __half22float2(stacc);
    float2 sqf = __half22float2(sqacc);
    float st = stf.x + stf.y, sq = sqf.x + sqf.y;
    for (int off = 32; off; off >>= 1) {
        st += __shfl_down(st, off, 64);
        sq += __shfl_down(sq, off, 64);
    }
    if (lane == 0) {
        wt[(size_t)p * 18 + blockIdx.x] = st;
        wq[(size_t)p * 18 + blockIdx.x] = sq;
    }
}

// ratio[p] = sum(wt) / sum(wq), fixed order
__global__ void ratio_kernel(const float* __restrict__ wt, const float* __restrict__ wq,
                             float* __restrict__ ratio)
{
    int i = blockIdx.x * 256 + threadIdx.x;
    if (i >= 9216) return;
    float st = 0.f, sq = 0.f;
#pragma unroll
    for (int j = 0; j < 18; ++j) {
        st += wt[(size_t)i * 18 + j];
        sq += wq[(size_t)i * 18 + j];
    }
    ratio[i] = (sq > 0.f) ? st / sq : 0.f;
}

// ---------------- out-GEMM: R3s[z][p][c] = sum_{q chunk} W[p][q]*bg[c][q] ---
__global__ __launch_bounds__(256)
void og_kernel(const u8* __restrict__ Wm, const u8* __restrict__ Bc,
               float* __restrict__ R3s)
{
    __shared__ __align__(16) u8 As[64 * 128];
    __shared__ __align__(16) u8 Bs[128 * 128];
    const int tid  = threadIdx.x;
    const int wid  = tid >> 6;
    const int lane = tid & 63;
    const int wm = (wid >> 1) * 32;
    const int wn = (wid & 1) * 64;
    const size_t bm = (size_t)blockIdx.x * 64;
    const int kbeg = blockIdx.y * 1152;

    f32x4 acc[2][4];
#pragma unroll
    for (int i = 0; i < 2; ++i)
#pragma unroll
        for (int j = 0; j < 4; ++j)
            acc[i][j] = (f32x4){0.f, 0.f, 0.f, 0.f};

    const int lrow = lane >> 3;
    const int lcb  = ((lane & 7) << 4) ^ ((lrow & 7) << 4);
    const u8* gA = Wm + (bm + wid * 16 + lrow) * (size_t)9216 + lcb;
    const u8* gB = Bc + (wid * 32 + lrow) * (size_t)9216 + lcb;
    u8* lA = As + (size_t)(wid * 16) * 128;
    u8* lB = Bs + (size_t)(wid * 32) * 128;
    const size_t rstep = (size_t)9216 * 8;
    const int lm = lane & 15, lk = lane >> 4;

    for (int k0 = kbeg; k0 < kbeg + 1152; k0 += 128) {
        __syncthreads();
#pragma unroll
        for (int j = 0; j < 2; ++j)
            GLOAD16(gA + j * rstep + k0, lA + j * 1024);
#pragma unroll
        for (int j = 0; j < 4; ++j)
            GLOAD16(gB + j * rstep + k0, lB + j * 1024);
        __syncthreads();

        long2v aop[2][2], bop[4][2];
#pragma unroll
        for (int f = 0; f < 2; ++f) {
            int ma = wm + f * 16 + lm;
            int sw = (ma & 7) << 4;
            const u8* pr = As + ma * 128;
            aop[f][0] = *(const long2v*)(pr + ((lk * 32) ^ sw));
            aop[f][1] = *(const long2v*)(pr + ((lk * 32 + 16) ^ sw));
        }
#pragma unroll
        for (int f = 0; f < 4; ++f) {
            int nb = wn + f * 16 + lm;
            int sw = (nb & 7) << 4;
            const u8* pr = Bs + nb * 128;
            bop[f][0] = *(const long2v*)(pr + ((lk * 32) ^ sw));
            bop[f][1] = *(const long2v*)(pr + ((lk * 32 + 16) ^ sw));
        }
#pragma unroll
        for (int ks = 0; ks < 4; ++ks)
#pragma unroll
            for (int fm = 0; fm < 2; ++fm)
#pragma unroll
                for (int fn = 0; fn < 4; ++fn)
                    acc[fm][fn] = __builtin_amdgcn_mfma_f32_16x16x32_bf8_fp8(
                        aop[fm][ks >> 1][ks & 1], bop[fn][ks >> 1][ks & 1],
                        acc[fm][fn], 0, 0, 0);
    }

    float* out = R3s + (size_t)blockIdx.y * 9216 * 128;
#pragma unroll
    for (int fm = 0; fm < 2; ++fm)
#pragma unroll
        for (int fn = 0; fn < 4; ++fn)
#pragma unroll
            for (int i = 0; i < 4; ++i) {
                int r = wm + fm * 16 + ((lane >> 4) * 4) + i;
                int c = wn + fn * 16 + (lane & 15);
                out[(bm + r) * (size_t)128 + c] = acc[fm][fn][i];
            }
}

// ---------------- sum partials * ratio + mask + 2x upsample -> cl bf16 ------
__global__ void up_sum_kernel(const float* __restrict__ R3s, const float* __restrict__ ratio,
                              const float* __restrict__ mask, u16* __restrict__ upCL)
{
    int idx = blockIdx.x * 256 + threadIdx.x;   // 9216 * 16
    if (idx >= 147456) return;
    int p = idx >> 4, cs = (idx & 15) * 8;
    int y = p / 96, x = p - y * 96;
    float m = mask[(size_t)(2 * y) * 192 + 2 * x] * ratio[p];
    float acc[8];
#pragma unroll
    for (int j = 0; j < 8; ++j) acc[j] = 0.f;
#pragma unroll
    for (int z = 0; z < 8; ++z) {
        const float* rp = R3s + (size_t)z * 9216 * 128 + (size_t)p * 128 + cs;
        float4 a = *(const float4*)rp;
        float4 b = *(const float4*)(rp + 4);
        acc[0] += a.x; acc[1] += a.y; acc[2] += a.z; acc[3] += a.w;
        acc[4] += b.x; acc[5] += b.y; acc[6] += b.z; acc[7] += b.w;
    }
    u16 ov[8];
#pragma unroll
    for (int j = 0; j < 8; ++j) ov[j] = f2bf(acc[j] * m);
    short8v v = *(short8v*)ov;
    size_t r0 = ((size_t)(2 * y) * 192 + 2 * x) * 128 + cs;
    size_t r1 = ((size_t)(2 * y + 1) * 192 + 2 * x) * 128 + cs;
    *(short8v*)(upCL + r0)        = v;
    *(short8v*)(upCL + r0 + 128)  = v;
    *(short8v*)(upCL + r1)        = v;
    *(short8v*)(upCL + r1 + 128)  = v;
}

// ---------------------------------------------------------------------------
extern "C" void kernel_launch(void* const* d_in, const int* in_sizes, int n_in,
                              void* d_out, int out_size, void* d_ws, size_t ws_size,
                              hipStream_t stream)
{
    const float* x    = (const float*)d_in[0];
    const float* mask = (const float*)d_in[1];
    const float* w[8];
    const float* b[8];
    for (int i = 0; i < 8; ++i) {
        w[i] = (const float*)d_in[2 + 2 * i];
        b[i] = (const float*)d_in[3 + 2 * i];
    }
    char* ws = (char*)d_ws;
    dim3 blk(256);

    // byte offsets (identical to round 16/17; peak 188.4 MB, proven safe)
    const size_t U_H1CL = 0;
    const size_t U_H2   = 37748736;
    const size_t U_H3   = 47185920;
    const size_t U_H4   = 66060288;
    const size_t U_H5   = 75497472;
    const size_t U_H6   = 84934656;
    const size_t U_X4   = 94371840;
    const size_t U_FGC  = 0;
    const size_t U_BGC  = 2359296;
    const size_t B_BGC8 = 4718592;
    const size_t B_G    = 15335424;
    const size_t B_P8   = 100270080;
    const size_t B_W    = 15335424;
    const size_t F_R3S  = 100270080;
    const size_t U_UPCL = 138018816;
    const size_t U_H7   = 147456000;
    const size_t F_H8   = 156893184;
    const size_t U_WP1  = 185204736;
    const size_t U_WP2  = 185212928;
    const size_t U_WP3  = 185231360;
    const size_t U_WP4  = 185268224;
    const size_t U_WP5  = 185415680;
    const size_t U_WP6  = 185710592;
    const size_t U_WP7  = 186005504;
    const size_t U_WP8  = 186300416;
    const size_t D_RED  = 186595328;
    const size_t F_SCALE= 186927104;
    const size_t F_RS   = 186927360;
    const size_t F_INV  = 186964224;
    const size_t F_WT   = 187001088;
    const size_t F_WQ   = 187664640;
    const size_t F_RAT  = 188328192;

    u16* h1cl   = (u16*)(ws + U_H1CL);
    u16* h2     = (u16*)(ws + U_H2);
    u16* h3     = (u16*)(ws + U_H3);
    u16* h4     = (u16*)(ws + U_H4);
    u16* h5     = (u16*)(ws + U_H5);
    u16* h6     = (u16*)(ws + U_H6);
    u16* x4     = (u16*)(ws + U_X4);
    u16* fgC    = (u16*)(ws + U_FGC);
    u16* bgC    = (u16*)(ws + U_BGC);
    u8*  bgC8   = (u8*)(ws + B_BGC8);
    u8*  G      = (u8*)(ws + B_G);
    u8*  P8     = (u8*)(ws + B_P8);
    u8*  Wm     = (u8*)(ws + B_W);
    float* R3s  = (float*)(ws + F_R3S);
    u16* upCL   = (u16*)(ws + U_UPCL);
    u16* h7     = (u16*)(ws + U_H7);
    float* h8   = (float*)(ws + F_H8);
    u16* wp1    = (u16*)(ws + U_WP1);
    u16* wp2    = (u16*)(ws + U_WP2);
    u16* wp3    = (u16*)(ws + U_WP3);
    u16* wp4    = (u16*)(ws + U_WP4);
    u16* wp5    = (u16*)(ws + U_WP5);
    u16* wp6    = (u16*)(ws + U_WP6);
    u16* wp7    = (u16*)(ws + U_WP7);
    u16* wp8    = (u16*)(ws + U_WP8);
    double* red = (double*)(ws + D_RED);
    float* scale= (float*)(ws + F_SCALE);
    float* rs   = (float*)(ws + F_RS);
    float* inv  = (float*)(ws + F_INV);
    float* wt   = (float*)(ws + F_WT);
    float* wq   = (float*)(ws + F_WQ);
    float* ratio= (float*)(ws + F_RAT);

    // ---- prepack ----
    pack_w1_kernel<<<dim3(16), blk, 0, stream>>>(w[0], wp1);
    pack_w_kernel<<<dim3(36),  blk, 0, stream>>>(w[1], wp2, 32, 32);
    pack_w_kernel<<<dim3(72),  blk, 0, stream>>>(w[2], wp3, 64, 32);
    pack_w_kernel<<<dim3(288), blk, 0, stream>>>(w[3], wp4, 128, 64);
    pack_w_kernel<<<dim3(576), blk, 0, stream>>>(w[4], wp5, 128, 128);
    pack_w_kernel<<<dim3(576), blk, 0, stream>>>(w[5], wp6, 128, 128);
    pack_w_kernel<<<dim3(576), blk, 0, stream>>>(w[6], wp7, 128, 128);
    pack_w_kernel<<<dim3(576), blk, 0, stream>>>(w[7], wp8, 128, 128);
    x4cl_kernel<<<dim3(2304), blk, 0, stream>>>(x, x4);

    // ---- conv front-end ----
    conv1_mfma_kernel<<<dim3(48, 96), blk, 0, stream>>>(x4, wp1, b[0], h1cl);
    mfma_conv_kernel<4, 1, 2, 2, 2, 32, 32, 1, 0><<<dim3(24, 48), blk, 0, stream>>>(
        h1cl, wp2, b[1], h2, 768, 768, 384, 384, 32);
    mfma_conv_kernel<4, 2, 2, 2, 1, 32, 32, 1, 0><<<dim3(24, 48), blk, 0, stream>>>(
        h2, wp3, b[2], h3, 384, 384, 384, 384, 64);
    mfma_conv_kernel<4, 2, 2, 2, 2, 64, 32, 1, 0><<<dim3(12, 24, 2), blk, 0, stream>>>(
        h3, wp4, b[3], h4, 384, 384, 192, 192, 128);
    mfma_conv_kernel<4, 2, 2, 2, 1, 128, 128, 1, 0><<<dim3(12, 24, 2), blk, 0, stream>>>(
        h4, wp5, b[4], h5, 192, 192, 192, 192, 128);
    mfma_conv_kernel<4, 2, 2, 2, 1, 128, 128, 0, 0><<<dim3(12, 24, 2), blk, 0, stream>>>(
        h5, wp6, b[5], h6, 192, 192, 192, 192, 128);

    // ---- attention inputs ----
    build_fgbgc_kernel<<<dim3(576), blk, 0, stream>>>(h6, mask, fgC, bgC);
    build_bgc8_kernel<<<dim3(576), blk, 0, stream>>>(h6, bgC8);

    // ---- G (K=128 Gram, e5m2, x1/8) ----
    g_gemm_kernel<<<dim3(72, 72), blk, 0, stream>>>(fgC, bgC, G);

    // ---- stencil 1: S8 + Frobenius partials -> scale ----
    sstencil_kernel<<<dim3(18, 2304), blk, 0, stream>>>(G, P8, red);
    sumsq_stage2<<<dim3(1), blk, 0, stream>>>(red, 41472, scale);

    // ---- exp in-place (linear) + rowsums -> inv ----
    exp_rows_kernel<<<dim3(2304), blk, 0, stream>>>(P8, scale, rs);
    inv_kernel<<<dim3(36), blk, 0, stream>>>(rs, inv);

    // ---- stencil 2: W (e5m2, k-permuted) + quantization ratio ----
    wstencil2_kernel<<<dim3(18, 2304), blk, 0, stream>>>(P8, inv, Wm, wt, wq);
    ratio_kernel<<<dim3(36), blk, 0, stream>>>(wt, wq, ratio);

    // ---- out-GEMM (bf8 x fp8, split-K 8) -> partial R3s ----
    og_kernel<<<dim3(144, 8), blk, 0, stream>>>(Wm, bgC8, R3s);

    // ---- sum partials * ratio + mask + upsample -> channels-last bf16 ----
    up_sum_kernel<<<dim3(576), blk, 0, stream>>>(R3s, ratio, mask, upCL);

    // ---- back-end convs ----
    mfma_conv_kernel<4, 2, 2, 2, 1, 128, 128, 1, 0><<<dim3(12, 24, 2), blk, 0, stream>>>(
        upCL, wp7, b[6], h7, 192, 192, 192, 192, 128);
    mfma_conv_kernel<4, 2, 2, 2, 1, 128, 128, 1, 1><<<dim3(12, 24, 2), blk, 0, stream>>>(
        h7, wp8, b[7], h8, 192, 192, 192, 192, 128);
    cl2p_kernel<<<dim3(1152), blk, 0, stream>>>(h8, (float*)d_out);
}

// Round 19
// 543.616 us; speedup vs baseline: 2.1627x; 1.1408x over previous
//
#include <hip/hip_runtime.h>
#include <hip/hip_fp16.h>
#include <math.h>

// ---------------------------------------------------------------------------
// Round 18->19: 16-q-per-thread stencils/exp (halved per-tap overhead;
// aligned b128 + compile-time byte-aligns replace unaligned b64 pairs).
// Tap arithmetic bit-identical to round 18 (620 us, absmax 0.0625).
// ---------------------------------------------------------------------------

typedef unsigned short u16;
typedef unsigned char u8;
typedef short short4v __attribute__((ext_vector_type(4)));
typedef short short8v __attribute__((ext_vector_type(8)));
typedef float f32x4 __attribute__((ext_vector_type(4)));
typedef long long2v __attribute__((ext_vector_type(2)));

__device__ __forceinline__ u16 f2bf(float f) {
    unsigned u = __float_as_uint(f);
    return (u16)((u + 0x7FFF + ((u >> 16) & 1)) >> 16);
}
__device__ __forceinline__ float bf2f(u16 h) {
    return __uint_as_float(((unsigned)h) << 16);
}
__device__ __forceinline__ u8 f2e5m2(float f) {
    unsigned short hb = __half_as_ushort(__float2half(f));
    unsigned rem = hb & 0xFF;
    unsigned b = hb >> 8;
    b += (rem > 0x80u) || (rem == 0x80u && (b & 1u));
    return (u8)b;
}
__device__ __forceinline__ float e5m2f(unsigned b) {
    return __half2float(__ushort_as_half((unsigned short)(b << 8)));
}
__device__ __forceinline__ u8 f2e4m3(float f) {
    unsigned u = __float_as_uint(f);
    unsigned s = (u >> 24) & 0x80u;
    unsigned a = u & 0x7FFFFFFFu;
    if (a >= 0x43E00000u) return (u8)(s | 0x7Eu);
    int e = (int)(a >> 23) - 127;
    if (e >= -6) {
        unsigned keep = (a >> 20) & 7u;
        unsigned rem  = a & 0xFFFFFu;
        keep += (rem > 0x80000u) || (rem == 0x80000u && (keep & 1u));
        unsigned e4 = (unsigned)(e + 7);
        if (keep == 8u) { keep = 0u; ++e4; }
        if (e4 >= 15u && keep >= 7u) return (u8)(s | 0x7Eu);
        return (u8)(s | (e4 << 3) | keep);
    }
    float q = __uint_as_float(a) * 512.f;
    int m = (int)rintf(q);
    if (m >= 8) return (u8)(s | 0x08u);
    return (u8)(s | (unsigned)m);
}
__device__ __forceinline__ int perm8(int o8) { return ((o8 & 3) << 2) | (o8 >> 2); }

#define GLOAD16(g, l) __builtin_amdgcn_global_load_lds(                      \
    (const __attribute__((address_space(1))) void*)(g),                      \
    (__attribute__((address_space(3))) void*)(l), 16, 0, 0)

#define E5M2_UNPACK(dst, src32)                                              \
    dst[0] = __builtin_amdgcn_perm(0u, (src32), 0x010C000Cu);                \
    dst[1] = __builtin_amdgcn_perm(0u, (src32), 0x030C020Cu);

__device__ __forceinline__ unsigned e5m2_round2(unsigned h) {
    return h + 0x007F007Fu + ((h >> 8) & 0x00010001u);
}

// shifted 16B load: bytes [base16+ex, base16+16+ex), ex in {-1,0,1} (folded)
__device__ __forceinline__ void load16_sh(const u8* base16, int ex, unsigned d[4]) {
    uint4 v = *(const uint4*)base16;
    if (ex == 0) {
        d[0] = v.x; d[1] = v.y; d[2] = v.z; d[3] = v.w;
    } else if (ex == 1) {
        unsigned b = *(const unsigned*)(base16 + 16);
        d[0] = (v.x >> 8) | (v.y << 24);
        d[1] = (v.y >> 8) | (v.z << 24);
        d[2] = (v.z >> 8) | (v.w << 24);
        d[3] = (v.w >> 8) | (b << 24);
    } else {
        unsigned b = *(const unsigned*)(base16 - 4);
        d[0] = (b >> 24) | (v.x << 8);
        d[1] = (v.x >> 24) | (v.y << 8);
        d[2] = (v.y >> 24) | (v.z << 8);
        d[3] = (v.z >> 24) | (v.w << 8);
    }
}

// ---------------- x -> channels-last bf16 ic4 (for conv1 MFMA) --------------
__global__ void x4cl_kernel(const float* __restrict__ x, u16* __restrict__ out)
{
    int i = blockIdx.x * 256 + threadIdx.x;
    if (i >= 589824) return;
    u16 v[4];
    v[0] = f2bf(x[i]);
    v[1] = f2bf(x[589824 + i]);
    v[2] = f2bf(x[1179648 + i]);
    v[3] = 0;
    *(short4v*)(out + (size_t)i * 4) = *(short4v*)v;
}

__global__ void pack_w1_kernel(const float* __restrict__ w, u16* __restrict__ wp)
{
    int i = blockIdx.x * 256 + threadIdx.x;
    if (i >= 4096) return;
    int oc = i >> 7, k = i & 127;
    int tap = k >> 2, ic = k & 3;
    u16 v = 0;
    if (tap < 25 && ic < 3) v = f2bf(w[oc * 75 + ic * 25 + tap]);
    wp[i] = v;
}

// ---------------- conv1 MFMA: 3->32, 5x5, s1, reflect pad2, ELU -------------
__global__ __launch_bounds__(256)
void conv1_mfma_kernel(const u16* __restrict__ x4, const u16* __restrict__ wp1,
                       const float* __restrict__ bias, u16* __restrict__ out)
{
    __shared__ __align__(16) u16 sIn[12 * 20 * 4];
    const int tid = threadIdx.x;
    const int lane = tid & 63;
    const int w = tid >> 6;
    const int lm = lane & 15;
    const int lk = lane >> 4;
    const int oy0 = blockIdx.y * 8, ox0 = blockIdx.x * 16;

    for (int u = tid; u < 240; u += 256) {
        int yt = u / 20, xt = u - yt * 20;
        int gy = oy0 - 2 + yt; gy = gy < 0 ? -gy : (gy >= 768 ? 1534 - gy : gy);
        int gx = ox0 - 2 + xt; gx = gx < 0 ? -gx : (gx >= 768 ? 1534 - gx : gx);
        *(short4v*)(sIn + u * 4) = *(const short4v*)(x4 + ((size_t)gy * 768 + gx) * 4);
    }
    int aoff[4][2];
#pragma unroll
    for (int ks = 0; ks < 4; ++ks) {
        int t0 = ks * 8 + lk * 2;
        int t1 = t0 + 1;
        if (t0 > 24) t0 = 24;
        if (t1 > 24) t1 = 24;
        int dy0 = t0 / 5, dx0 = t0 - 5 * dy0;
        int dy1 = t1 / 5, dx1 = t1 - 5 * dy1;
        aoff[ks][0] = (dy0 * 20 + dx0 + lm) * 4;
        aoff[ks][1] = (dy1 * 20 + dx1 + lm) * 4;
    }
    __syncthreads();

    f32x4 acc[2][2];
#pragma unroll
    for (int i = 0; i < 2; ++i)
#pragma unroll
        for (int j = 0; j < 2; ++j) acc[i][j] = (f32x4){0.f, 0.f, 0.f, 0.f};

#pragma unroll
    for (int ks = 0; ks < 4; ++ks) {
        short8v a[2], b[2];
#pragma unroll
        for (int fm = 0; fm < 2; ++fm) {
            int base = (w * 2 + fm) * 80;
            short4v lo = *(const short4v*)(sIn + base + aoff[ks][0]);
            short4v hi = *(const short4v*)(sIn + base + aoff[ks][1]);
            short8v av;
            av[0] = lo[0]; av[1] = lo[1]; av[2] = lo[2]; av[3] = lo[3];
            av[4] = hi[0]; av[5] = hi[1]; av[6] = hi[2]; av[7] = hi[3];
            a[fm] = av;
        }
#pragma unroll
        for (int fn = 0; fn < 2; ++fn)
            b[fn] = *(const short8v*)(wp1 + (size_t)(fn * 16 + lm) * 128 + ks * 32 + lk * 8);
#pragma unroll
        for (int fm = 0; fm < 2; ++fm)
#pragma unroll
            for (int fn = 0; fn < 2; ++fn)
                acc[fm][fn] = __builtin_amdgcn_mfma_f32_16x16x32_bf16(
                    a[fm], b[fn], acc[fm][fn], 0, 0, 0);
    }

#pragma unroll
    for (int fm = 0; fm < 2; ++fm) {
        int gy = oy0 + w * 2 + fm;
#pragma unroll
        for (int fn = 0; fn < 2; ++fn) {
            int oc = fn * 16 + lm;
            float bv = bias[oc];
#pragma unroll
            for (int i = 0; i < 4; ++i) {
                int xx = lk * 4 + i;
                float v = acc[fm][fn][i] + bv;
                v = v > 0.f ? v : expm1f(v);
                out[((size_t)gy * 768 + ox0 + xx) * 32 + oc] = f2bf(v);
            }
        }
    }
}

// ---------------- weight prepack ----------------
__global__ void pack_w_kernel(const float* __restrict__ w, u16* __restrict__ wp,
                              int OC, int IC)
{
    int idx = blockIdx.x * 256 + threadIdx.x;
    if (idx >= OC * 9 * IC) return;
    int oc = idx / (9 * IC);
    int r  = idx - oc * 9 * IC;
    int tap = r / IC;
    int ic  = r - tap * IC;
    wp[idx] = f2bf(w[((size_t)oc * IC + ic) * 9 + tap]);
}

// ---------------- MFMA implicit-GEMM conv (3x3, reflect pad 1) --------------
template<int FM, int FN, int NWM, int NWN, int S, int IC, int ICC, int ACT, int OUTF32>
__global__ __launch_bounds__(256)
void mfma_conv_kernel(const u16* __restrict__ in, const u16* __restrict__ wgtP,
                      const float* __restrict__ bias, void* __restrict__ out,
                      int H, int W, int Ho, int Wo, int OC)
{
    constexpr int TY = 7 * S + 3;
    constexpr int TX = 15 * S + 3;
    constexpr int NSLOT = ICC / 8;
    constexpr int SWMSK = NSLOT - 1;
    constexpr int KTOT = 9 * IC;
    __shared__ __align__(16) u16 sIn[TY * TX * ICC];

    const int tid  = threadIdx.x;
    const int lane = tid & 63;
    const int wid  = tid >> 6;
    const int wmi  = wid / NWN;
    const int wni  = wid % NWN;
    const int lm   = lane & 15;
    const int lk   = lane >> 4;
    const int noff = blockIdx.z * (NWN * FN * 16);

    f32x4 acc[FM][FN];
#pragma unroll
    for (int i = 0; i < FM; ++i)
#pragma unroll
        for (int j = 0; j < FN; ++j) acc[i][j] = (f32x4){0.f, 0.f, 0.f, 0.f};

    const int iy0 = blockIdx.y * 8 * S - 1;
    const int ix0 = blockIdx.x * 16 * S - 1;

    for (int c0 = 0; c0 < IC; c0 += ICC) {
        if (c0) __syncthreads();
        for (int u = tid; u < TY * TX * NSLOT; u += 256) {
            int yt = u / (TX * NSLOT);
            int r  = u - yt * (TX * NSLOT);
            int xt = r / NSLOT;
            int sl = r - xt * NSLOT;
            int gy = iy0 + yt; gy = gy < 0 ? -gy : (gy >= H ? 2 * H - 2 - gy : gy);
            int gx = ix0 + xt; gx = gx < 0 ? -gx : (gx >= W ? 2 * W - 2 - gx : gx);
            *(short8v*)((char*)sIn + (size_t)((yt * TX + xt) * NSLOT + (sl ^ (xt & SWMSK))) * 16) =
                *(const short8v*)(in + ((size_t)gy * W + gx) * IC + c0 + sl * 8);
        }
        __syncthreads();
#pragma unroll
        for (int tap = 0; tap < 9; ++tap) {
            const int dy = tap / 3, dx = tap % 3;
#pragma unroll
            for (int icw = 0; icw < ICC / 32; ++icw) {
                short8v a[FM], b[FN];
#pragma unroll
                for (int fm = 0; fm < FM; ++fm) {
                    int yt = (wmi * FM + fm) * S + dy;
                    int xt = lm * S + dx;
                    a[fm] = *(const short8v*)((const char*)sIn +
                        (size_t)((yt * TX + xt) * NSLOT + ((icw * 4 + lk) ^ (xt & SWMSK))) * 16);
                }
#pragma unroll
                for (int fn = 0; fn < FN; ++fn) {
                    int n = noff + wni * FN * 16 + fn * 16 + lm;
                    b[fn] = *(const short8v*)(wgtP + (size_t)n * KTOT + tap * IC + c0 + icw * 32 + lk * 8);
                }
#pragma unroll
                for (int fm = 0; fm < FM; ++fm)
#pragma unroll
                    for (int fn = 0; fn < FN; ++fn)
                        acc[fm][fn] = __builtin_amdgcn_mfma_f32_16x16x32_bf16(
                            a[fm], b[fn], acc[fm][fn], 0, 0, 0);
            }
        }
    }

#pragma unroll
    for (int fm = 0; fm < FM; ++fm) {
        int y = blockIdx.y * 8 + wmi * FM + fm;
#pragma unroll
        for (int fn = 0; fn < FN; ++fn) {
            int oc = noff + wni * FN * 16 + fn * 16 + lm;
            float bv = bias[oc];
#pragma unroll
            for (int i = 0; i < 4; ++i) {
                int x = blockIdx.x * 16 + lk * 4 + i;
                float v = acc[fm][fn][i] + bv;
                if (ACT == 0) v = v > 0.f ? v : 0.f;
                else          v = v > 0.f ? v : expm1f(v);
                size_t o = ((size_t)y * Wo + x) * OC + oc;
                if (OUTF32) ((float*)out)[o] = v;
                else        ((u16*)out)[o]   = f2bf(v);
            }
        }
    }
}

// channels-last f32 [36864][128] -> planar f32 [128][36864]
__global__ __launch_bounds__(256)
void cl2p_kernel(const float* __restrict__ in, float* __restrict__ out)
{
    __shared__ float t[32][130];
    const int tid = threadIdx.x;
    const int p0 = blockIdx.x * 32;
#pragma unroll
    for (int j = 0; j < 16; ++j) {
        int idx = j * 256 + tid;
        int px = idx >> 7, c = idx & 127;
        t[px][c] = in[(size_t)(p0 + px) * 128 + c];
    }
    __syncthreads();
#pragma unroll
    for (int j = 0; j < 16; ++j) {
        int c = j * 8 + (tid >> 5);
        int px = tid & 31;
        out[(size_t)c * 36864 + p0 + px] = t[px][c];
    }
}

// ---------------- half-res channel-last images: fgC (masked), bgC -----------
__global__ void build_fgbgc_kernel(const u16* __restrict__ h6, const float* __restrict__ mask,
                                   u16* __restrict__ fgC, u16* __restrict__ bgC)
{
    int idx = blockIdx.x * 256 + threadIdx.x;   // 9216*16
    if (idx >= 147456) return;
    int q = idx >> 4, cs = (idx & 15) * 8;
    int qy = q / 96, qx = q - qy * 96;
    const u16* src = h6 + ((size_t)(2 * qy) * 192 + 2 * qx) * 128 + cs;
    float m = mask[(size_t)(2 * qy) * 192 + 2 * qx];
    short8v v = *(const short8v*)src;
    u16 fo[8];
#pragma unroll
    for (int j = 0; j < 8; ++j) fo[j] = f2bf(bf2f((u16)v[j]) * m);
    *(short8v*)(bgC + (size_t)q * 128 + cs) = v;
    *(short8v*)(fgC + (size_t)q * 128 + cs) = *(short8v*)fo;
}

// ---------------- bgC8: e4m3 [128][9216] (unmasked bg, c-major), K-PERMUTED -
__global__ void build_bgc8_kernel(const u16* __restrict__ h6, u8* __restrict__ bgC8)
{
    int idx = blockIdx.x * 256 + threadIdx.x;   // 128 * 1152 chunks
    if (idx >= 128 * 1152) return;
    int c = idx / 1152, qc = idx - c * 1152;
    int q0 = qc << 3;
    int qy = q0 / 96, qx0 = q0 - qy * 96;
    const u16* row = h6 + (size_t)(2 * qy) * 192 * 128 + c;
    unsigned long long ow = 0;
#pragma unroll
    for (int j = 0; j < 8; ++j) {
        float v = bf2f(row[(size_t)(2 * (qx0 + j)) * 128]);
        ow |= (unsigned long long)f2e4m3(v) << (8 * j);
    }
    *(unsigned long long*)(bgC8 + (size_t)c * 9216 + (q0 & ~127) + perm8(qc & 15) * 8) = ow;
}

// ---------------- G-GEMM: G[a][b] = 1/8 * sum_c fgC[a][c]*bgC[b][c] ---------
__global__ __launch_bounds__(256)
void g_gemm_kernel(const u16* __restrict__ A, const u16* __restrict__ B,
                   u8* __restrict__ G)
{
    __shared__ __align__(16) u16 As[128 * 64];
    __shared__ __align__(16) u16 Bs[128 * 64];
    const int tid  = threadIdx.x;
    const int wid  = tid >> 6;
    const int lane = tid & 63;
    const int wm = (wid >> 1) * 64;
    const int wn = (wid & 1) * 64;
    const size_t bm = (size_t)blockIdx.y * 128;
    const size_t bn = (size_t)blockIdx.x * 128;

    f32x4 acc[4][4];
#pragma unroll
    for (int i = 0; i < 4; ++i)
#pragma unroll
        for (int j = 0; j < 4; ++j)
            acc[i][j] = (f32x4){0.f, 0.f, 0.f, 0.f};

    const int lrow = lane >> 3;
    const int lcb  = ((lane & 7) << 4) ^ ((lrow & 7) << 4);
    const char* gA = (const char*)A + ((bm + wid * 32 + lrow) * (size_t)128) * 2 + lcb;
    const char* gB = (const char*)B + ((bn + wid * 32 + lrow) * (size_t)128) * 2 + lcb;
    char* lA = (char*)As + (size_t)(wid * 32) * 128;
    char* lB = (char*)Bs + (size_t)(wid * 32) * 128;
    const size_t rs8 = (size_t)128 * 16;

    for (int k0 = 0; k0 < 128; k0 += 64) {
        __syncthreads();
#pragma unroll
        for (int j = 0; j < 4; ++j) {
            GLOAD16(gA + j * rs8 + (size_t)k0 * 2, lA + j * 1024);
            GLOAD16(gB + j * rs8 + (size_t)k0 * 2, lB + j * 1024);
        }
        __syncthreads();
#pragma unroll
        for (int ks = 0; ks < 2; ++ks) {
            short8v a[4], b[4];
#pragma unroll
            for (int f = 0; f < 4; ++f) {
                int ma = wm + f * 16 + (lane & 15);
                int kba = (ks * 64 + ((lane >> 4) * 16)) ^ ((ma & 7) << 4);
                a[f] = *(const short8v*)((const char*)As + ma * 128 + kba);
                int nb = wn + f * 16 + (lane & 15);
                int kbb = (ks * 64 + ((lane >> 4) * 16)) ^ ((nb & 7) << 4);
                b[f] = *(const short8v*)((const char*)Bs + nb * 128 + kbb);
            }
#pragma unroll
            for (int fm = 0; fm < 4; ++fm)
#pragma unroll
                for (int fn = 0; fn < 4; ++fn)
                    acc[fm][fn] = __builtin_amdgcn_mfma_f32_16x16x32_bf16(
                        a[fm], b[fn], acc[fm][fn], 0, 0, 0);
        }
    }

#pragma unroll
    for (int fm = 0; fm < 4; ++fm)
#pragma unroll
        for (int fn = 0; fn < 4; ++fn)
#pragma unroll
            for (int i = 0; i < 4; ++i) {
                int r = wm + fm * 16 + ((lane >> 4) * 4) + i;
                int c = wn + fn * 16 + (lane & 15);
                G[(bm + r) * (size_t)9216 + bn + c] = f2e5m2(0.125f * acc[fm][fn][i]);
            }
}

// ---------------- stencil 1: S8 = stencil(G) + sum S^2; 16 q/thread ---------
__global__ __launch_bounds__(256)
void sstencil_kernel(const u8* __restrict__ G, u8* __restrict__ S8,
                     double* __restrict__ partial)
{
    const int wid  = threadIdx.x >> 6;
    const int lane = threadIdx.x & 63;
    const int p = blockIdx.y * 4 + wid;
    const int py = p / 96, px = p - py * 96;
    const int q0 = blockIdx.x * 1024 + lane * 16;
    const int qy = q0 / 96, qx0 = q0 - qy * 96;

    __half2 hz = __floats2half2_rn(0.f, 0.f);
    __half2 hacc[8] = {hz, hz, hz, hz, hz, hz, hz, hz};

#pragma unroll
    for (int ey = -1; ey <= 1; ++ey) {
#pragma unroll
        for (int ex = -1; ex <= 1; ++ex) {
            if ((unsigned)(py + ey) >= 96u || (unsigned)(px + ex) >= 96u) continue;
            if ((unsigned)(qy + ey) >= 96u) continue;
            const int e = ey * 96 + ex;
            const u8* base16 = G + (size_t)(p + e) * 9216 + q0 + (e - ex);
            unsigned d[4];
            load16_sh(base16, ex, d);
            if (ex == 1 && qx0 == 80) d[3] &= 0x00FFFFFFu;
            if (ex == -1 && qx0 == 0) d[0] &= 0xFFFFFF00u;
#pragma unroll
            for (int i = 0; i < 4; ++i) {
                unsigned pk[2];
                E5M2_UNPACK(pk, d[i]);
                hacc[2 * i]     = __hadd2(hacc[2 * i],     *(__half2*)&pk[0]);
                hacc[2 * i + 1] = __hadd2(hacc[2 * i + 1], *(__half2*)&pk[1]);
            }
        }
    }

    unsigned t[8];
    double s2 = 0.0;
#pragma unroll
    for (int i = 0; i < 8; ++i) {
        unsigned h = *(unsigned*)&hacc[i];
        t[i] = e5m2_round2(h);
        float2 f2 = __half22float2(hacc[i]);
        s2 += (double)f2.x * f2.x + (double)f2.y * f2.y;
    }
    uint4 ow;
    ow.x = __builtin_amdgcn_perm(t[1], t[0], 0x07050301u);
    ow.y = __builtin_amdgcn_perm(t[3], t[2], 0x07050301u);
    ow.z = __builtin_amdgcn_perm(t[5], t[4], 0x07050301u);
    ow.w = __builtin_amdgcn_perm(t[7], t[6], 0x07050301u);
    *(uint4*)(S8 + (size_t)p * 9216 + q0) = ow;

    for (int off = 32; off; off >>= 1) s2 += __shfl_down(s2, off, 64);
    __shared__ double wsum[4];
    if (lane == 0) wsum[wid] = s2;
    __syncthreads();
    if (threadIdx.x == 0)
        partial[(size_t)blockIdx.y * 9 + blockIdx.x] = wsum[0] + wsum[1] + wsum[2] + wsum[3];
}

__global__ void sumsq_stage2(const double* __restrict__ partial, int nblocks, float* __restrict__ scale)
{
    double s = 0.0;
    for (int i = threadIdx.x; i < nblocks; i += 256) s += partial[i];
    for (int off = 32; off; off >>= 1) s += __shfl_down(s, off, 64);
    __shared__ double wsum[4];
    int lane = threadIdx.x & 63, wid = threadIdx.x >> 6;
    if (lane == 0) wsum[wid] = s;
    __syncthreads();
    if (threadIdx.x == 0) {
        double nrm = sqrt(wsum[0] + wsum[1] + wsum[2] + wsum[3]);
        if (nrm < 1e-12) nrm = 1e-12;
        *scale = (float)(10.0 / nrm);
    }
}

// ---------------- exp pass: P8 = e5m2(exp(scale*S8)) in-place; 16 B/iter ----
__global__ __launch_bounds__(256)
void exp_rows_kernel(u8* __restrict__ P8, const float* __restrict__ scale_p,
                     float* __restrict__ rs)
{
    const int wid = threadIdx.x >> 6, lane = threadIdx.x & 63;
    const int p = blockIdx.x * 4 + wid;   // grid 2304
    u8* rp = P8 + (size_t)p * 9216;
    const float scale = *scale_p;
    float s = 0.f;
#pragma unroll
    for (int it = 0; it < 9; ++it) {
        uint4 v = *(uint4*)(rp + it * 1024 + lane * 16);
        unsigned dv[4] = {v.x, v.y, v.z, v.w};
        unsigned t[8];
        __half2 sacc = __floats2half2_rn(0.f, 0.f);
#pragma unroll
        for (int i = 0; i < 4; ++i) {
            unsigned pk[2];
            E5M2_UNPACK(pk, dv[i]);
#pragma unroll
            for (int j = 0; j < 2; ++j) {
                float2 f = __half22float2(*(__half2*)&pk[j]);
                __half2 eh = __floats2half2_rn(__expf(scale * f.x), __expf(scale * f.y));
                t[2 * i + j] = e5m2_round2(*(unsigned*)&eh);
                unsigned q = t[2 * i + j] & 0xFF00FF00u;
                sacc = __hadd2(sacc, *(__half2*)&q);
            }
        }
        uint4 ow;
        ow.x = __builtin_amdgcn_perm(t[1], t[0], 0x07050301u);
        ow.y = __builtin_amdgcn_perm(t[3], t[2], 0x07050301u);
        ow.z = __builtin_amdgcn_perm(t[5], t[4], 0x07050301u);
        ow.w = __builtin_amdgcn_perm(t[7], t[6], 0x07050301u);
        *(uint4*)(rp + it * 1024 + lane * 16) = ow;
        float2 sf = __half22float2(sacc);
        s += sf.x + sf.y;
    }
    for (int off = 32; off; off >>= 1) s += __shfl_down(s, off, 64);
    if (lane == 0) rs[p] = s;
}

__global__ void inv_kernel(const float* __restrict__ rs, float* __restrict__ inv)
{
    int i = blockIdx.x * 256 + threadIdx.x;
    if (i < 9216) inv[i] = 1.f / rs[i];
}

// ---------------- stencil 2: W = sum_t inv*P taps; 16 q/thread, K-PERM ------
__global__ __launch_bounds__(256)
void wstencil2_kernel(const u8* __restrict__ P8, const float* __restrict__ inv,
                      u8* __restrict__ W, float* __restrict__ wt,
                      float* __restrict__ wq)
{
    const int wid  = threadIdx.x >> 6;
    const int lane = threadIdx.x & 63;
    const int p = blockIdx.y * 4 + wid;
    const int py = p / 96, px = p - py * 96;
    const int q0 = blockIdx.x * 1024 + lane * 16;
    const int qy = q0 / 96, qx0 = q0 - qy * 96;

    __half2 hz = __floats2half2_rn(0.f, 0.f);
    __half2 hacc[8] = {hz, hz, hz, hz, hz, hz, hz, hz};

#pragma unroll
    for (int ey = -1; ey <= 1; ++ey) {
#pragma unroll
        for (int ex = -1; ex <= 1; ++ex) {
            if ((unsigned)(py + ey) >= 96u || (unsigned)(px + ex) >= 96u) continue;
            if ((unsigned)(qy + ey) >= 96u) continue;
            const int e = ey * 96 + ex;
            const u8* base16 = P8 + (size_t)(p + e) * 9216 + q0 + (e - ex);
            unsigned d[4];
            load16_sh(base16, ex, d);
            if (ex == 1 && qx0 == 80) d[3] &= 0x00FFFFFFu;
            if (ex == -1 && qx0 == 0) d[0] &= 0xFFFFFF00u;

            float iv = inv[p + e];
            __half2 iv2 = __floats2half2_rn(iv, iv);
#pragma unroll
            for (int i = 0; i < 4; ++i) {
                unsigned pk[2];
                E5M2_UNPACK(pk, d[i]);
                hacc[2 * i]     = __hfma2(*(__half2*)&pk[0], iv2, hacc[2 * i]);
                hacc[2 * i + 1] = __hfma2(*(__half2*)&pk[1], iv2, hacc[2 * i + 1]);
            }
        }
    }

    unsigned t[8];
    __half2 stacc = hz, sqacc = hz;
#pragma unroll
    for (int i = 0; i < 8; ++i) {
        unsigned h = *(unsigned*)&hacc[i];
        t[i] = e5m2_round2(h);
        stacc = __hadd2(stacc, hacc[i]);
        unsigned q = t[i] & 0xFF00FF00u;
        sqacc = __hadd2(sqacc, *(__half2*)&q);
    }
    unsigned g0 = __builtin_amdgcn_perm(t[1], t[0], 0x07050301u);
    unsigned g1 = __builtin_amdgcn_perm(t[3], t[2], 0x07050301u);
    unsigned g2 = __builtin_amdgcn_perm(t[5], t[4], 0x07050301u);
    unsigned g3 = __builtin_amdgcn_perm(t[7], t[6], 0x07050301u);
    // two K-permuted 8B stores (chunks o8 and o8+1)
    int o8 = (q0 & 127) >> 3;
    u8* wrow = W + (size_t)p * 9216 + (q0 & ~127);
    *(unsigned long long*)(wrow + perm8(o8) * 8)     =
        (unsigned long long)g0 | ((unsigned long long)g1 << 32);
    *(unsigned long long*)(wrow + perm8(o8 + 1) * 8) =
        (unsigned long long)g2 | ((unsigned long long)g3 << 32);

    float2 stf = __half22float2(stacc);
    float2 sqf = __half22float2(sqacc);
    float st = stf.x + stf.y, sq = sqf.x + sqf.y;
    for (int off = 32; off; off >>= 1) {
        st += __shfl_down(st, off, 64);
        sq += __shfl_down(sq, off, 64);
    }
    if (lane == 0) {
        wt[(size_t)p * 9 + blockIdx.x] = st;
        wq[(size_t)p * 9 + blockIdx.x] = sq;
    }
}

// ratio[p] = sum(wt) / sum(wq), fixed order
__global__ void ratio_kernel(const float* __restrict__ wt, const float* __restrict__ wq,
                             float* __restrict__ ratio)
{
    int i = blockIdx.x * 256 + threadIdx.x;
    if (i >= 9216) return;
    float st = 0.f, sq = 0.f;
#pragma unroll
    for (int j = 0; j < 9; ++j) {
        st += wt[(size_t)i * 9 + j];
        sq += wq[(size_t)i * 9 + j];
    }
    ratio[i] = (sq > 0.f) ? st / sq : 0.f;
}

// ---------------- out-GEMM: R3s[z][p][c] = sum_{q chunk} W[p][q]*bg[c][q] ---
__global__ __launch_bounds__(256)
void og_kernel(const u8* __restrict__ Wm, const u8* __restrict__ Bc,
               float* __restrict__ R3s)
{
    __shared__ __align__(16) u8 As[64 * 128];
    __shared__ __align__(16) u8 Bs[128 * 128];
    const int tid  = threadIdx.x;
    const int wid  = tid >> 6;
    const int lane = tid & 63;
    const int wm = (wid >> 1) * 32;
    const int wn = (wid & 1) * 64;
    const size_t bm = (size_t)blockIdx.x * 64;
    const int kbeg = blockIdx.y * 1152;

    f32x4 acc[2][4];
#pragma unroll
    for (int i = 0; i < 2; ++i)
#pragma unroll
        for (int j = 0; j < 4; ++j)
            acc[i][j] = (f32x4){0.f, 0.f, 0.f, 0.f};

    const int lrow = lane >> 3;
    const int lcb  = ((lane & 7) << 4) ^ ((lrow & 7) << 4);
    const u8* gA = Wm + (bm + wid * 16 + lrow) * (size_t)9216 + lcb;
    const u8* gB = Bc + (wid * 32 + lrow) * (size_t)9216 + lcb;
    u8* lA = As + (size_t)(wid * 16) * 128;
    u8* lB = Bs + (size_t)(wid * 32) * 128;
    const size_t rstep = (size_t)9216 * 8;
    const int lm = lane & 15, lk = lane >> 4;

    for (int k0 = kbeg; k0 < kbeg + 1152; k0 += 128) {
        __syncthreads();
#pragma unroll
        for (int j = 0; j < 2; ++j)
            GLOAD16(gA + j * rstep + k0, lA + j * 1024);
#pragma unroll
        for (int j = 0; j < 4; ++j)
            GLOAD16(gB + j * rstep + k0, lB + j * 1024);
        __syncthreads();

        long2v aop[2][2], bop[4][2];
#pragma unroll
        for (int f = 0; f < 2; ++f) {
            int ma = wm + f * 16 + lm;
            int sw = (ma & 7) << 4;
            const u8* pr = As + ma * 128;
            aop[f][0] = *(const long2v*)(pr + ((lk * 32) ^ sw));
            aop[f][1] = *(const long2v*)(pr + ((lk * 32 + 16) ^ sw));
        }
#pragma unroll
        for (int f = 0; f < 4; ++f) {
            int nb = wn + f * 16 + lm;
            int sw = (nb & 7) << 4;
            const u8* pr = Bs + nb * 128;
            bop[f][0] = *(const long2v*)(pr + ((lk * 32) ^ sw));
            bop[f][1] = *(const long2v*)(pr + ((lk * 32 + 16) ^ sw));
        }
#pragma unroll
        for (int ks = 0; ks < 4; ++ks)
#pragma unroll
            for (int fm = 0; fm < 2; ++fm)
#pragma unroll
                for (int fn = 0; fn < 4; ++fn)
                    acc[fm][fn] = __builtin_amdgcn_mfma_f32_16x16x32_bf8_fp8(
                        aop[fm][ks >> 1][ks & 1], bop[fn][ks >> 1][ks & 1],
                        acc[fm][fn], 0, 0, 0);
    }

    float* out = R3s + (size_t)blockIdx.y * 9216 * 128;
#pragma unroll
    for (int fm = 0; fm < 2; ++fm)
#pragma unroll
        for (int fn = 0; fn < 4; ++fn)
#pragma unroll
            for (int i = 0; i < 4; ++i) {
                int r = wm + fm * 16 + ((lane >> 4) * 4) + i;
                int c = wn + fn * 16 + (lane & 15);
                out[(bm + r) * (size_t)128 + c] = acc[fm][fn][i];
            }
}

// ---------------- sum partials * ratio + mask + 2x upsample -> cl bf16 ------
__global__ void up_sum_kernel(const float* __restrict__ R3s, const float* __restrict__ ratio,
                              const float* __restrict__ mask, u16* __restrict__ upCL)
{
    int idx = blockIdx.x * 256 + threadIdx.x;   // 9216 * 16
    if (idx >= 147456) return;
    int p = idx >> 4, cs = (idx & 15) * 8;
    int y = p / 96, x = p - y * 96;
    float m = mask[(size_t)(2 * y) * 192 + 2 * x] * ratio[p];
    float acc[8];
#pragma unroll
    for (int j = 0; j < 8; ++j) acc[j] = 0.f;
#pragma unroll
    for (int z = 0; z < 8; ++z) {
        const float* rp = R3s + (size_t)z * 9216 * 128 + (size_t)p * 128 + cs;
        float4 a = *(const float4*)rp;
        float4 b = *(const float4*)(rp + 4);
        acc[0] += a.x; acc[1] += a.y; acc[2] += a.z; acc[3] += a.w;
        acc[4] += b.x; acc[5] += b.y; acc[6] += b.z; acc[7] += b.w;
    }
    u16 ov[8];
#pragma unroll
    for (int j = 0; j < 8; ++j) ov[j] = f2bf(acc[j] * m);
    short8v v = *(short8v*)ov;
    size_t r0 = ((size_t)(2 * y) * 192 + 2 * x) * 128 + cs;
    size_t r1 = ((size_t)(2 * y + 1) * 192 + 2 * x) * 128 + cs;
    *(short8v*)(upCL + r0)        = v;
    *(short8v*)(upCL + r0 + 128)  = v;
    *(short8v*)(upCL + r1)        = v;
    *(short8v*)(upCL + r1 + 128)  = v;
}

// ---------------------------------------------------------------------------
extern "C" void kernel_launch(void* const* d_in, const int* in_sizes, int n_in,
                              void* d_out, int out_size, void* d_ws, size_t ws_size,
                              hipStream_t stream)
{
    const float* x    = (const float*)d_in[0];
    const float* mask = (const float*)d_in[1];
    const float* w[8];
    const float* b[8];
    for (int i = 0; i < 8; ++i) {
        w[i] = (const float*)d_in[2 + 2 * i];
        b[i] = (const float*)d_in[3 + 2 * i];
    }
    char* ws = (char*)d_ws;
    dim3 blk(256);

    // byte offsets (identical to round 16-18; peak 188.4 MB, proven safe)
    const size_t U_H1CL = 0;
    const size_t U_H2   = 37748736;
    const size_t U_H3   = 47185920;
    const size_t U_H4   = 66060288;
    const size_t U_H5   = 75497472;
    const size_t U_H6   = 84934656;
    const size_t U_X4   = 94371840;
    const size_t U_FGC  = 0;
    const size_t U_BGC  = 2359296;
    const size_t B_BGC8 = 4718592;
    const size_t B_G    = 15335424;
    const size_t B_P8   = 100270080;
    const size_t B_W    = 15335424;
    const size_t F_R3S  = 100270080;
    const size_t U_UPCL = 138018816;
    const size_t U_H7   = 147456000;
    const size_t F_H8   = 156893184;
    const size_t U_WP1  = 185204736;
    const size_t U_WP2  = 185212928;
    const size_t U_WP3  = 185231360;
    const size_t U_WP4  = 185268224;
    const size_t U_WP5  = 185415680;
    const size_t U_WP6  = 185710592;
    const size_t U_WP7  = 186005504;
    const size_t U_WP8  = 186300416;
    const size_t D_RED  = 186595328;
    const size_t F_SCALE= 186927104;
    const size_t F_RS   = 186927360;
    const size_t F_INV  = 186964224;
    const size_t F_WT   = 187001088;
    const size_t F_WQ   = 187664640;
    const size_t F_RAT  = 188328192;

    u16* h1cl   = (u16*)(ws + U_H1CL);
    u16* h2     = (u16*)(ws + U_H2);
    u16* h3     = (u16*)(ws + U_H3);
    u16* h4     = (u16*)(ws + U_H4);
    u16* h5     = (u16*)(ws + U_H5);
    u16* h6     = (u16*)(ws + U_H6);
    u16* x4     = (u16*)(ws + U_X4);
    u16* fgC    = (u16*)(ws + U_FGC);
    u16* bgC    = (u16*)(ws + U_BGC);
    u8*  bgC8   = (u8*)(ws + B_BGC8);
    u8*  G      = (u8*)(ws + B_G);
    u8*  P8     = (u8*)(ws + B_P8);
    u8*  Wm     = (u8*)(ws + B_W);
    float* R3s  = (float*)(ws + F_R3S);
    u16* upCL   = (u16*)(ws + U_UPCL);
    u16* h7     = (u16*)(ws + U_H7);
    float* h8   = (float*)(ws + F_H8);
    u16* wp1    = (u16*)(ws + U_WP1);
    u16* wp2    = (u16*)(ws + U_WP2);
    u16* wp3    = (u16*)(ws + U_WP3);
    u16* wp4    = (u16*)(ws + U_WP4);
    u16* wp5    = (u16*)(ws + U_WP5);
    u16* wp6    = (u16*)(ws + U_WP6);
    u16* wp7    = (u16*)(ws + U_WP7);
    u16* wp8    = (u16*)(ws + U_WP8);
    double* red = (double*)(ws + D_RED);
    float* scale= (float*)(ws + F_SCALE);
    float* rs   = (float*)(ws + F_RS);
    float* inv  = (float*)(ws + F_INV);
    float* wt   = (float*)(ws + F_WT);
    float* wq   = (float*)(ws + F_WQ);
    float* ratio= (float*)(ws + F_RAT);

    // ---- prepack ----
    pack_w1_kernel<<<dim3(16), blk, 0, stream>>>(w[0], wp1);
    pack_w_kernel<<<dim3(36),  blk, 0, stream>>>(w[1], wp2, 32, 32);
    pack_w_kernel<<<dim3(72),  blk, 0, stream>>>(w[2], wp3, 64, 32);
    pack_w_kernel<<<dim3(288), blk, 0, stream>>>(w[3], wp4, 128, 64);
    pack_w_kernel<<<dim3(576), blk, 0, stream>>>(w[4], wp5, 128, 128);
    pack_w_kernel<<<dim3(576), blk, 0, stream>>>(w[5], wp6, 128, 128);
    pack_w_kernel<<<dim3(576), blk, 0, stream>>>(w[6], wp7, 128, 128);
    pack_w_kernel<<<dim3(576), blk, 0, stream>>>(w[7], wp8, 128, 128);
    x4cl_kernel<<<dim3(2304), blk, 0, stream>>>(x, x4);

    // ---- conv front-end ----
    conv1_mfma_kernel<<<dim3(48, 96), blk, 0, stream>>>(x4, wp1, b[0], h1cl);
    mfma_conv_kernel<4, 1, 2, 2, 2, 32, 32, 1, 0><<<dim3(24, 48), blk, 0, stream>>>(
        h1cl, wp2, b[1], h2, 768, 768, 384, 384, 32);
    mfma_conv_kernel<4, 2, 2, 2, 1, 32, 32, 1, 0><<<dim3(24, 48), blk, 0, stream>>>(
        h2, wp3, b[2], h3, 384, 384, 384, 384, 64);
    mfma_conv_kernel<4, 2, 2, 2, 2, 64, 32, 1, 0><<<dim3(12, 24, 2), blk, 0, stream>>>(
        h3, wp4, b[3], h4, 384, 384, 192, 192, 128);
    mfma_conv_kernel<4, 2, 2, 2, 1, 128, 128, 1, 0><<<dim3(12, 24, 2), blk, 0, stream>>>(
        h4, wp5, b[4], h5, 192, 192, 192, 192, 128);
    mfma_conv_kernel<4, 2, 2, 2, 1, 128, 128, 0, 0><<<dim3(12, 24, 2), blk, 0, stream>>>(
        h5, wp6, b[5], h6, 192, 192, 192, 192, 128);

    // ---- attention inputs ----
    build_fgbgc_kernel<<<dim3(576), blk, 0, stream>>>(h6, mask, fgC, bgC);
    build_bgc8_kernel<<<dim3(576), blk, 0, stream>>>(h6, bgC8);

    // ---- G (K=128 Gram, e5m2, x1/8) ----
    g_gemm_kernel<<<dim3(72, 72), blk, 0, stream>>>(fgC, bgC, G);

    // ---- stencil 1: S8 + Frobenius partials -> scale ----
    sstencil_kernel<<<dim3(9, 2304), blk, 0, stream>>>(G, P8, red);
    sumsq_stage2<<<dim3(1), blk, 0, stream>>>(red, 20736, scale);

    // ---- exp in-place (linear) + rowsums -> inv ----
    exp_rows_kernel<<<dim3(2304), blk, 0, stream>>>(P8, scale, rs);
    inv_kernel<<<dim3(36), blk, 0, stream>>>(rs, inv);

    // ---- stencil 2: W (e5m2, k-permuted) + quantization ratio ----
    wstencil2_kernel<<<dim3(9, 2304), blk, 0, stream>>>(P8, inv, Wm, wt, wq);
    ratio_kernel<<<dim3(36), blk, 0, stream>>>(wt, wq, ratio);

    // ---- out-GEMM (bf8 x fp8, split-K 8) -> partial R3s ----
    og_kernel<<<dim3(144, 8), blk, 0, stream>>>(Wm, bgC8, R3s);

    // ---- sum partials * ratio + mask + upsample -> channels-last bf16 ----
    up_sum_kernel<<<dim3(576), blk, 0, stream>>>(R3s, ratio, mask, upCL);

    // ---- back-end convs ----
    mfma_conv_kernel<4, 2, 2, 2, 1, 128, 128, 1, 0><<<dim3(12, 24, 2), blk, 0, stream>>>(
        upCL, wp7, b[6], h7, 192, 192, 192, 192, 128);
    mfma_conv_kernel<4, 2, 2, 2, 1, 128, 128, 1, 1><<<dim3(12, 24, 2), blk, 0, stream>>>(
        h7, wp8, b[7], h8, 192, 192, 192, 192, 128);
    cl2p_kernel<<<dim3(1152), blk, 0, stream>>>(h8, (float*)d_out);
}

// Round 20
// 541.742 us; speedup vs baseline: 2.1702x; 1.0035x over previous
//
#include <hip/hip_runtime.h>
#include <hip/hip_fp16.h>
#include <math.h>

// ---------------------------------------------------------------------------
// Round 19->20: z-split 4 on the 128-OC MFMA convs (conv4..conv8): FN=1,
// grid z=4 -> 1152 blocks (4.5/CU issued vs 2.25 before; LDS allows 3/CU).
// Everything else identical to round 19 (543 us, absmax 0.0625).
// ---------------------------------------------------------------------------

typedef unsigned short u16;
typedef unsigned char u8;
typedef short short4v __attribute__((ext_vector_type(4)));
typedef short short8v __attribute__((ext_vector_type(8)));
typedef float f32x4 __attribute__((ext_vector_type(4)));
typedef long long2v __attribute__((ext_vector_type(2)));

__device__ __forceinline__ u16 f2bf(float f) {
    unsigned u = __float_as_uint(f);
    return (u16)((u + 0x7FFF + ((u >> 16) & 1)) >> 16);
}
__device__ __forceinline__ float bf2f(u16 h) {
    return __uint_as_float(((unsigned)h) << 16);
}
__device__ __forceinline__ u8 f2e5m2(float f) {
    unsigned short hb = __half_as_ushort(__float2half(f));
    unsigned rem = hb & 0xFF;
    unsigned b = hb >> 8;
    b += (rem > 0x80u) || (rem == 0x80u && (b & 1u));
    return (u8)b;
}
__device__ __forceinline__ float e5m2f(unsigned b) {
    return __half2float(__ushort_as_half((unsigned short)(b << 8)));
}
__device__ __forceinline__ u8 f2e4m3(float f) {
    unsigned u = __float_as_uint(f);
    unsigned s = (u >> 24) & 0x80u;
    unsigned a = u & 0x7FFFFFFFu;
    if (a >= 0x43E00000u) return (u8)(s | 0x7Eu);
    int e = (int)(a >> 23) - 127;
    if (e >= -6) {
        unsigned keep = (a >> 20) & 7u;
        unsigned rem  = a & 0xFFFFFu;
        keep += (rem > 0x80000u) || (rem == 0x80000u && (keep & 1u));
        unsigned e4 = (unsigned)(e + 7);
        if (keep == 8u) { keep = 0u; ++e4; }
        if (e4 >= 15u && keep >= 7u) return (u8)(s | 0x7Eu);
        return (u8)(s | (e4 << 3) | keep);
    }
    float q = __uint_as_float(a) * 512.f;
    int m = (int)rintf(q);
    if (m >= 8) return (u8)(s | 0x08u);
    return (u8)(s | (unsigned)m);
}
__device__ __forceinline__ int perm8(int o8) { return ((o8 & 3) << 2) | (o8 >> 2); }

#define GLOAD16(g, l) __builtin_amdgcn_global_load_lds(                      \
    (const __attribute__((address_space(1))) void*)(g),                      \
    (__attribute__((address_space(3))) void*)(l), 16, 0, 0)

#define E5M2_UNPACK(dst, src32)                                              \
    dst[0] = __builtin_amdgcn_perm(0u, (src32), 0x010C000Cu);                \
    dst[1] = __builtin_amdgcn_perm(0u, (src32), 0x030C020Cu);

__device__ __forceinline__ unsigned e5m2_round2(unsigned h) {
    return h + 0x007F007Fu + ((h >> 8) & 0x00010001u);
}

// shifted 16B load: bytes [base16+ex, base16+16+ex), ex in {-1,0,1} (folded)
__device__ __forceinline__ void load16_sh(const u8* base16, int ex, unsigned d[4]) {
    uint4 v = *(const uint4*)base16;
    if (ex == 0) {
        d[0] = v.x; d[1] = v.y; d[2] = v.z; d[3] = v.w;
    } else if (ex == 1) {
        unsigned b = *(const unsigned*)(base16 + 16);
        d[0] = (v.x >> 8) | (v.y << 24);
        d[1] = (v.y >> 8) | (v.z << 24);
        d[2] = (v.z >> 8) | (v.w << 24);
        d[3] = (v.w >> 8) | (b << 24);
    } else {
        unsigned b = *(const unsigned*)(base16 - 4);
        d[0] = (b >> 24) | (v.x << 8);
        d[1] = (v.x >> 24) | (v.y << 8);
        d[2] = (v.y >> 24) | (v.z << 8);
        d[3] = (v.z >> 24) | (v.w << 8);
    }
}

// ---------------- x -> channels-last bf16 ic4 (for conv1 MFMA) --------------
__global__ void x4cl_kernel(const float* __restrict__ x, u16* __restrict__ out)
{
    int i = blockIdx.x * 256 + threadIdx.x;
    if (i >= 589824) return;
    u16 v[4];
    v[0] = f2bf(x[i]);
    v[1] = f2bf(x[589824 + i]);
    v[2] = f2bf(x[1179648 + i]);
    v[3] = 0;
    *(short4v*)(out + (size_t)i * 4) = *(short4v*)v;
}

__global__ void pack_w1_kernel(const float* __restrict__ w, u16* __restrict__ wp)
{
    int i = blockIdx.x * 256 + threadIdx.x;
    if (i >= 4096) return;
    int oc = i >> 7, k = i & 127;
    int tap = k >> 2, ic = k & 3;
    u16 v = 0;
    if (tap < 25 && ic < 3) v = f2bf(w[oc * 75 + ic * 25 + tap]);
    wp[i] = v;
}

// ---------------- conv1 MFMA: 3->32, 5x5, s1, reflect pad2, ELU -------------
__global__ __launch_bounds__(256)
void conv1_mfma_kernel(const u16* __restrict__ x4, const u16* __restrict__ wp1,
                       const float* __restrict__ bias, u16* __restrict__ out)
{
    __shared__ __align__(16) u16 sIn[12 * 20 * 4];
    const int tid = threadIdx.x;
    const int lane = tid & 63;
    const int w = tid >> 6;
    const int lm = lane & 15;
    const int lk = lane >> 4;
    const int oy0 = blockIdx.y * 8, ox0 = blockIdx.x * 16;

    for (int u = tid; u < 240; u += 256) {
        int yt = u / 20, xt = u - yt * 20;
        int gy = oy0 - 2 + yt; gy = gy < 0 ? -gy : (gy >= 768 ? 1534 - gy : gy);
        int gx = ox0 - 2 + xt; gx = gx < 0 ? -gx : (gx >= 768 ? 1534 - gx : gx);
        *(short4v*)(sIn + u * 4) = *(const short4v*)(x4 + ((size_t)gy * 768 + gx) * 4);
    }
    int aoff[4][2];
#pragma unroll
    for (int ks = 0; ks < 4; ++ks) {
        int t0 = ks * 8 + lk * 2;
        int t1 = t0 + 1;
        if (t0 > 24) t0 = 24;
        if (t1 > 24) t1 = 24;
        int dy0 = t0 / 5, dx0 = t0 - 5 * dy0;
        int dy1 = t1 / 5, dx1 = t1 - 5 * dy1;
        aoff[ks][0] = (dy0 * 20 + dx0 + lm) * 4;
        aoff[ks][1] = (dy1 * 20 + dx1 + lm) * 4;
    }
    __syncthreads();

    f32x4 acc[2][2];
#pragma unroll
    for (int i = 0; i < 2; ++i)
#pragma unroll
        for (int j = 0; j < 2; ++j) acc[i][j] = (f32x4){0.f, 0.f, 0.f, 0.f};

#pragma unroll
    for (int ks = 0; ks < 4; ++ks) {
        short8v a[2], b[2];
#pragma unroll
        for (int fm = 0; fm < 2; ++fm) {
            int base = (w * 2 + fm) * 80;
            short4v lo = *(const short4v*)(sIn + base + aoff[ks][0]);
            short4v hi = *(const short4v*)(sIn + base + aoff[ks][1]);
            short8v av;
            av[0] = lo[0]; av[1] = lo[1]; av[2] = lo[2]; av[3] = lo[3];
            av[4] = hi[0]; av[5] = hi[1]; av[6] = hi[2]; av[7] = hi[3];
            a[fm] = av;
        }
#pragma unroll
        for (int fn = 0; fn < 2; ++fn)
            b[fn] = *(const short8v*)(wp1 + (size_t)(fn * 16 + lm) * 128 + ks * 32 + lk * 8);
#pragma unroll
        for (int fm = 0; fm < 2; ++fm)
#pragma unroll
            for (int fn = 0; fn < 2; ++fn)
                acc[fm][fn] = __builtin_amdgcn_mfma_f32_16x16x32_bf16(
                    a[fm], b[fn], acc[fm][fn], 0, 0, 0);
    }

#pragma unroll
    for (int fm = 0; fm < 2; ++fm) {
        int gy = oy0 + w * 2 + fm;
#pragma unroll
        for (int fn = 0; fn < 2; ++fn) {
            int oc = fn * 16 + lm;
            float bv = bias[oc];
#pragma unroll
            for (int i = 0; i < 4; ++i) {
                int xx = lk * 4 + i;
                float v = acc[fm][fn][i] + bv;
                v = v > 0.f ? v : expm1f(v);
                out[((size_t)gy * 768 + ox0 + xx) * 32 + oc] = f2bf(v);
            }
        }
    }
}

// ---------------- weight prepack ----------------
__global__ void pack_w_kernel(const float* __restrict__ w, u16* __restrict__ wp,
                              int OC, int IC)
{
    int idx = blockIdx.x * 256 + threadIdx.x;
    if (idx >= OC * 9 * IC) return;
    int oc = idx / (9 * IC);
    int r  = idx - oc * 9 * IC;
    int tap = r / IC;
    int ic  = r - tap * IC;
    wp[idx] = f2bf(w[((size_t)oc * IC + ic) * 9 + tap]);
}

// ---------------- MFMA implicit-GEMM conv (3x3, reflect pad 1) --------------
template<int FM, int FN, int NWM, int NWN, int S, int IC, int ICC, int ACT, int OUTF32>
__global__ __launch_bounds__(256)
void mfma_conv_kernel(const u16* __restrict__ in, const u16* __restrict__ wgtP,
                      const float* __restrict__ bias, void* __restrict__ out,
                      int H, int W, int Ho, int Wo, int OC)
{
    constexpr int TY = 7 * S + 3;
    constexpr int TX = 15 * S + 3;
    constexpr int NSLOT = ICC / 8;
    constexpr int SWMSK = NSLOT - 1;
    constexpr int KTOT = 9 * IC;
    __shared__ __align__(16) u16 sIn[TY * TX * ICC];

    const int tid  = threadIdx.x;
    const int lane = tid & 63;
    const int wid  = tid >> 6;
    const int wmi  = wid / NWN;
    const int wni  = wid % NWN;
    const int lm   = lane & 15;
    const int lk   = lane >> 4;
    const int noff = blockIdx.z * (NWN * FN * 16);

    f32x4 acc[FM][FN];
#pragma unroll
    for (int i = 0; i < FM; ++i)
#pragma unroll
        for (int j = 0; j < FN; ++j) acc[i][j] = (f32x4){0.f, 0.f, 0.f, 0.f};

    const int iy0 = blockIdx.y * 8 * S - 1;
    const int ix0 = blockIdx.x * 16 * S - 1;

    for (int c0 = 0; c0 < IC; c0 += ICC) {
        if (c0) __syncthreads();
        for (int u = tid; u < TY * TX * NSLOT; u += 256) {
            int yt = u / (TX * NSLOT);
            int r  = u - yt * (TX * NSLOT);
            int xt = r / NSLOT;
            int sl = r - xt * NSLOT;
            int gy = iy0 + yt; gy = gy < 0 ? -gy : (gy >= H ? 2 * H - 2 - gy : gy);
            int gx = ix0 + xt; gx = gx < 0 ? -gx : (gx >= W ? 2 * W - 2 - gx : gx);
            *(short8v*)((char*)sIn + (size_t)((yt * TX + xt) * NSLOT + (sl ^ (xt & SWMSK))) * 16) =
                *(const short8v*)(in + ((size_t)gy * W + gx) * IC + c0 + sl * 8);
        }
        __syncthreads();
#pragma unroll
        for (int tap = 0; tap < 9; ++tap) {
            const int dy = tap / 3, dx = tap % 3;
#pragma unroll
            for (int icw = 0; icw < ICC / 32; ++icw) {
                short8v a[FM], b[FN];
#pragma unroll
                for (int fm = 0; fm < FM; ++fm) {
                    int yt = (wmi * FM + fm) * S + dy;
                    int xt = lm * S + dx;
                    a[fm] = *(const short8v*)((const char*)sIn +
                        (size_t)((yt * TX + xt) * NSLOT + ((icw * 4 + lk) ^ (xt & SWMSK))) * 16);
                }
#pragma unroll
                for (int fn = 0; fn < FN; ++fn) {
                    int n = noff + wni * FN * 16 + fn * 16 + lm;
                    b[fn] = *(const short8v*)(wgtP + (size_t)n * KTOT + tap * IC + c0 + icw * 32 + lk * 8);
                }
#pragma unroll
                for (int fm = 0; fm < FM; ++fm)
#pragma unroll
                    for (int fn = 0; fn < FN; ++fn)
                        acc[fm][fn] = __builtin_amdgcn_mfma_f32_16x16x32_bf16(
                            a[fm], b[fn], acc[fm][fn], 0, 0, 0);
            }
        }
    }

#pragma unroll
    for (int fm = 0; fm < FM; ++fm) {
        int y = blockIdx.y * 8 + wmi * FM + fm;
#pragma unroll
        for (int fn = 0; fn < FN; ++fn) {
            int oc = noff + wni * FN * 16 + fn * 16 + lm;
            float bv = bias[oc];
#pragma unroll
            for (int i = 0; i < 4; ++i) {
                int x = blockIdx.x * 16 + lk * 4 + i;
                float v = acc[fm][fn][i] + bv;
                if (ACT == 0) v = v > 0.f ? v : 0.f;
                else          v = v > 0.f ? v : expm1f(v);
                size_t o = ((size_t)y * Wo + x) * OC + oc;
                if (OUTF32) ((float*)out)[o] = v;
                else        ((u16*)out)[o]   = f2bf(v);
            }
        }
    }
}

// channels-last f32 [36864][128] -> planar f32 [128][36864]
__global__ __launch_bounds__(256)
void cl2p_kernel(const float* __restrict__ in, float* __restrict__ out)
{
    __shared__ float t[32][130];
    const int tid = threadIdx.x;
    const int p0 = blockIdx.x * 32;
#pragma unroll
    for (int j = 0; j < 16; ++j) {
        int idx = j * 256 + tid;
        int px = idx >> 7, c = idx & 127;
        t[px][c] = in[(size_t)(p0 + px) * 128 + c];
    }
    __syncthreads();
#pragma unroll
    for (int j = 0; j < 16; ++j) {
        int c = j * 8 + (tid >> 5);
        int px = tid & 31;
        out[(size_t)c * 36864 + p0 + px] = t[px][c];
    }
}

// ---------------- half-res channel-last images: fgC (masked), bgC -----------
__global__ void build_fgbgc_kernel(const u16* __restrict__ h6, const float* __restrict__ mask,
                                   u16* __restrict__ fgC, u16* __restrict__ bgC)
{
    int idx = blockIdx.x * 256 + threadIdx.x;   // 9216*16
    if (idx >= 147456) return;
    int q = idx >> 4, cs = (idx & 15) * 8;
    int qy = q / 96, qx = q - qy * 96;
    const u16* src = h6 + ((size_t)(2 * qy) * 192 + 2 * qx) * 128 + cs;
    float m = mask[(size_t)(2 * qy) * 192 + 2 * qx];
    short8v v = *(const short8v*)src;
    u16 fo[8];
#pragma unroll
    for (int j = 0; j < 8; ++j) fo[j] = f2bf(bf2f((u16)v[j]) * m);
    *(short8v*)(bgC + (size_t)q * 128 + cs) = v;
    *(short8v*)(fgC + (size_t)q * 128 + cs) = *(short8v*)fo;
}

// ---------------- bgC8: e4m3 [128][9216] (unmasked bg, c-major), K-PERMUTED -
__global__ void build_bgc8_kernel(const u16* __restrict__ h6, u8* __restrict__ bgC8)
{
    int idx = blockIdx.x * 256 + threadIdx.x;   // 128 * 1152 chunks
    if (idx >= 128 * 1152) return;
    int c = idx / 1152, qc = idx - c * 1152;
    int q0 = qc << 3;
    int qy = q0 / 96, qx0 = q0 - qy * 96;
    const u16* row = h6 + (size_t)(2 * qy) * 192 * 128 + c;
    unsigned long long ow = 0;
#pragma unroll
    for (int j = 0; j < 8; ++j) {
        float v = bf2f(row[(size_t)(2 * (qx0 + j)) * 128]);
        ow |= (unsigned long long)f2e4m3(v) << (8 * j);
    }
    *(unsigned long long*)(bgC8 + (size_t)c * 9216 + (q0 & ~127) + perm8(qc & 15) * 8) = ow;
}

// ---------------- G-GEMM: G[a][b] = 1/8 * sum_c fgC[a][c]*bgC[b][c] ---------
__global__ __launch_bounds__(256)
void g_gemm_kernel(const u16* __restrict__ A, const u16* __restrict__ B,
                   u8* __restrict__ G)
{
    __shared__ __align__(16) u16 As[128 * 64];
    __shared__ __align__(16) u16 Bs[128 * 64];
    const int tid  = threadIdx.x;
    const int wid  = tid >> 6;
    const int lane = tid & 63;
    const int wm = (wid >> 1) * 64;
    const int wn = (wid & 1) * 64;
    const size_t bm = (size_t)blockIdx.y * 128;
    const size_t bn = (size_t)blockIdx.x * 128;

    f32x4 acc[4][4];
#pragma unroll
    for (int i = 0; i < 4; ++i)
#pragma unroll
        for (int j = 0; j < 4; ++j)
            acc[i][j] = (f32x4){0.f, 0.f, 0.f, 0.f};

    const int lrow = lane >> 3;
    const int lcb  = ((lane & 7) << 4) ^ ((lrow & 7) << 4);
    const char* gA = (const char*)A + ((bm + wid * 32 + lrow) * (size_t)128) * 2 + lcb;
    const char* gB = (const char*)B + ((bn + wid * 32 + lrow) * (size_t)128) * 2 + lcb;
    char* lA = (char*)As + (size_t)(wid * 32) * 128;
    char* lB = (char*)Bs + (size_t)(wid * 32) * 128;
    const size_t rs8 = (size_t)128 * 16;

    for (int k0 = 0; k0 < 128; k0 += 64) {
        __syncthreads();
#pragma unroll
        for (int j = 0; j < 4; ++j) {
            GLOAD16(gA + j * rs8 + (size_t)k0 * 2, lA + j * 1024);
            GLOAD16(gB + j * rs8 + (size_t)k0 * 2, lB + j * 1024);
        }
        __syncthreads();
#pragma unroll
        for (int ks = 0; ks < 2; ++ks) {
            short8v a[4], b[4];
#pragma unroll
            for (int f = 0; f < 4; ++f) {
                int ma = wm + f * 16 + (lane & 15);
                int kba = (ks * 64 + ((lane >> 4) * 16)) ^ ((ma & 7) << 4);
                a[f] = *(const short8v*)((const char*)As + ma * 128 + kba);
                int nb = wn + f * 16 + (lane & 15);
                int kbb = (ks * 64 + ((lane >> 4) * 16)) ^ ((nb & 7) << 4);
                b[f] = *(const short8v*)((const char*)Bs + nb * 128 + kbb);
            }
#pragma unroll
            for (int fm = 0; fm < 4; ++fm)
#pragma unroll
                for (int fn = 0; fn < 4; ++fn)
                    acc[fm][fn] = __builtin_amdgcn_mfma_f32_16x16x32_bf16(
                        a[fm], b[fn], acc[fm][fn], 0, 0, 0);
        }
    }

#pragma unroll
    for (int fm = 0; fm < 4; ++fm)
#pragma unroll
        for (int fn = 0; fn < 4; ++fn)
#pragma unroll
            for (int i = 0; i < 4; ++i) {
                int r = wm + fm * 16 + ((lane >> 4) * 4) + i;
                int c = wn + fn * 16 + (lane & 15);
                G[(bm + r) * (size_t)9216 + bn + c] = f2e5m2(0.125f * acc[fm][fn][i]);
            }
}

// ---------------- stencil 1: S8 = stencil(G) + sum S^2; 16 q/thread ---------
__global__ __launch_bounds__(256)
void sstencil_kernel(const u8* __restrict__ G, u8* __restrict__ S8,
                     double* __restrict__ partial)
{
    const int wid  = threadIdx.x >> 6;
    const int lane = threadIdx.x & 63;
    const int p = blockIdx.y * 4 + wid;
    const int py = p / 96, px = p - py * 96;
    const int q0 = blockIdx.x * 1024 + lane * 16;
    const int qy = q0 / 96, qx0 = q0 - qy * 96;

    __half2 hz = __floats2half2_rn(0.f, 0.f);
    __half2 hacc[8] = {hz, hz, hz, hz, hz, hz, hz, hz};

#pragma unroll
    for (int ey = -1; ey <= 1; ++ey) {
#pragma unroll
        for (int ex = -1; ex <= 1; ++ex) {
            if ((unsigned)(py + ey) >= 96u || (unsigned)(px + ex) >= 96u) continue;
            if ((unsigned)(qy + ey) >= 96u) continue;
            const int e = ey * 96 + ex;
            const u8* base16 = G + (size_t)(p + e) * 9216 + q0 + (e - ex);
            unsigned d[4];
            load16_sh(base16, ex, d);
            if (ex == 1 && qx0 == 80) d[3] &= 0x00FFFFFFu;
            if (ex == -1 && qx0 == 0) d[0] &= 0xFFFFFF00u;
#pragma unroll
            for (int i = 0; i < 4; ++i) {
                unsigned pk[2];
                E5M2_UNPACK(pk, d[i]);
                hacc[2 * i]     = __hadd2(hacc[2 * i],     *(__half2*)&pk[0]);
                hacc[2 * i + 1] = __hadd2(hacc[2 * i + 1], *(__half2*)&pk[1]);
            }
        }
    }

    unsigned t[8];
    double s2 = 0.0;
#pragma unroll
    for (int i = 0; i < 8; ++i) {
        unsigned h = *(unsigned*)&hacc[i];
        t[i] = e5m2_round2(h);
        float2 f2 = __half22float2(hacc[i]);
        s2 += (double)f2.x * f2.x + (double)f2.y * f2.y;
    }
    uint4 ow;
    ow.x = __builtin_amdgcn_perm(t[1], t[0], 0x07050301u);
    ow.y = __builtin_amdgcn_perm(t[3], t[2], 0x07050301u);
    ow.z = __builtin_amdgcn_perm(t[5], t[4], 0x07050301u);
    ow.w = __builtin_amdgcn_perm(t[7], t[6], 0x07050301u);
    *(uint4*)(S8 + (size_t)p * 9216 + q0) = ow;

    for (int off = 32; off; off >>= 1) s2 += __shfl_down(s2, off, 64);
    __shared__ double wsum[4];
    if (lane == 0) wsum[wid] = s2;
    __syncthreads();
    if (threadIdx.x == 0)
        partial[(size_t)blockIdx.y * 9 + blockIdx.x] = wsum[0] + wsum[1] + wsum[2] + wsum[3];
}

__global__ void sumsq_stage2(const double* __restrict__ partial, int nblocks, float* __restrict__ scale)
{
    double s = 0.0;
    for (int i = threadIdx.x; i < nblocks; i += 256) s += partial[i];
    for (int off = 32; off; off >>= 1) s += __shfl_down(s, off, 64);
    __shared__ double wsum[4];
    int lane = threadIdx.x & 63, wid = threadIdx.x >> 6;
    if (lane == 0) wsum[wid] = s;
    __syncthreads();
    if (threadIdx.x == 0) {
        double nrm = sqrt(wsum[0] + wsum[1] + wsum[2] + wsum[3]);
        if (nrm < 1e-12) nrm = 1e-12;
        *scale = (float)(10.0 / nrm);
    }
}

// ---------------- exp pass: P8 = e5m2(exp(scale*S8)) in-place; 16 B/iter ----
__global__ __launch_bounds__(256)
void exp_rows_kernel(u8* __restrict__ P8, const float* __restrict__ scale_p,
                     float* __restrict__ rs)
{
    const int wid = threadIdx.x >> 6, lane = threadIdx.x & 63;
    const int p = blockIdx.x * 4 + wid;   // grid 2304
    u8* rp = P8 + (size_t)p * 9216;
    const float scale = *scale_p;
    float s = 0.f;
#pragma unroll
    for (int it = 0; it < 9; ++it) {
        uint4 v = *(uint4*)(rp + it * 1024 + lane * 16);
        unsigned dv[4] = {v.x, v.y, v.z, v.w};
        unsigned t[8];
        __half2 sacc = __floats2half2_rn(0.f, 0.f);
#pragma unroll
        for (int i = 0; i < 4; ++i) {
            unsigned pk[2];
            E5M2_UNPACK(pk, dv[i]);
#pragma unroll
            for (int j = 0; j < 2; ++j) {
                float2 f = __half22float2(*(__half2*)&pk[j]);
                __half2 eh = __floats2half2_rn(__expf(scale * f.x), __expf(scale * f.y));
                t[2 * i + j] = e5m2_round2(*(unsigned*)&eh);
                unsigned q = t[2 * i + j] & 0xFF00FF00u;
                sacc = __hadd2(sacc, *(__half2*)&q);
            }
        }
        uint4 ow;
        ow.x = __builtin_amdgcn_perm(t[1], t[0], 0x07050301u);
        ow.y = __builtin_amdgcn_perm(t[3], t[2], 0x07050301u);
        ow.z = __builtin_amdgcn_perm(t[5], t[4], 0x07050301u);
        ow.w = __builtin_amdgcn_perm(t[7], t[6], 0x07050301u);
        *(uint4*)(rp + it * 1024 + lane * 16) = ow;
        float2 sf = __half22float2(sacc);
        s += sf.x + sf.y;
    }
    for (int off = 32; off; off >>= 1) s += __shfl_down(s, off, 64);
    if (lane == 0) rs[p] = s;
}

__global__ void inv_kernel(const float* __restrict__ rs, float* __restrict__ inv)
{
    int i = blockIdx.x * 256 + threadIdx.x;
    if (i < 9216) inv[i] = 1.f / rs[i];
}

// ---------------- stencil 2: W = sum_t inv*P taps; 16 q/thread, K-PERM ------
__global__ __launch_bounds__(256)
void wstencil2_kernel(const u8* __restrict__ P8, const float* __restrict__ inv,
                      u8* __restrict__ W, float* __restrict__ wt,
                      float* __restrict__ wq)
{
    const int wid  = threadIdx.x >> 6;
    const int lane = threadIdx.x & 63;
    const int p = blockIdx.y * 4 + wid;
    const int py = p / 96, px = p - py * 96;
    const int q0 = blockIdx.x * 1024 + lane * 16;
    const int qy = q0 / 96, qx0 = q0 - qy * 96;

    __half2 hz = __floats2half2_rn(0.f, 0.f);
    __half2 hacc[8] = {hz, hz, hz, hz, hz, hz, hz, hz};

#pragma unroll
    for (int ey = -1; ey <= 1; ++ey) {
#pragma unroll
        for (int ex = -1; ex <= 1; ++ex) {
            if ((unsigned)(py + ey) >= 96u || (unsigned)(px + ex) >= 96u) continue;
            if ((unsigned)(qy + ey) >= 96u) continue;
            const int e = ey * 96 + ex;
            const u8* base16 = P8 + (size_t)(p + e) * 9216 + q0 + (e - ex);
            unsigned d[4];
            load16_sh(base16, ex, d);
            if (ex == 1 && qx0 == 80) d[3] &= 0x00FFFFFFu;
            if (ex == -1 && qx0 == 0) d[0] &= 0xFFFFFF00u;

            float iv = inv[p + e];
            __half2 iv2 = __floats2half2_rn(iv, iv);
#pragma unroll
            for (int i = 0; i < 4; ++i) {
                unsigned pk[2];
                E5M2_UNPACK(pk, d[i]);
                hacc[2 * i]     = __hfma2(*(__half2*)&pk[0], iv2, hacc[2 * i]);
                hacc[2 * i + 1] = __hfma2(*(__half2*)&pk[1], iv2, hacc[2 * i + 1]);
            }
        }
    }

    unsigned t[8];
    __half2 stacc = hz, sqacc = hz;
#pragma unroll
    for (int i = 0; i < 8; ++i) {
        unsigned h = *(unsigned*)&hacc[i];
        t[i] = e5m2_round2(h);
        stacc = __hadd2(stacc, hacc[i]);
        unsigned q = t[i] & 0xFF00FF00u;
        sqacc = __hadd2(sqacc, *(__half2*)&q);
    }
    unsigned g0 = __builtin_amdgcn_perm(t[1], t[0], 0x07050301u);
    unsigned g1 = __builtin_amdgcn_perm(t[3], t[2], 0x07050301u);
    unsigned g2 = __builtin_amdgcn_perm(t[5], t[4], 0x07050301u);
    unsigned g3 = __builtin_amdgcn_perm(t[7], t[6], 0x07050301u);
    int o8 = (q0 & 127) >> 3;
    u8* wrow = W + (size_t)p * 9216 + (q0 & ~127);
    *(unsigned long long*)(wrow + perm8(o8) * 8)     =
        (unsigned long long)g0 | ((unsigned long long)g1 << 32);
    *(unsigned long long*)(wrow + perm8(o8 + 1) * 8) =
        (unsigned long long)g2 | ((unsigned long long)g3 << 32);

    float2 stf = __half22float2(stacc);
    float2 sqf = __half22float2(sqacc);
    float st = stf.x + stf.y, sq = sqf.x + sqf.y;
    for (int off = 32; off; off >>= 1) {
        st += __shfl_down(st, off, 64);
        sq += __shfl_down(sq, off, 64);
    }
    if (lane == 0) {
        wt[(size_t)p * 9 + blockIdx.x] = st;
        wq[(size_t)p * 9 + blockIdx.x] = sq;
    }
}

// ratio[p] = sum(wt) / sum(wq), fixed order
__global__ void ratio_kernel(const float* __restrict__ wt, const float* __restrict__ wq,
                             float* __restrict__ ratio)
{
    int i = blockIdx.x * 256 + threadIdx.x;
    if (i >= 9216) return;
    float st = 0.f, sq = 0.f;
#pragma unroll
    for (int j = 0; j < 9; ++j) {
        st += wt[(size_t)i * 9 + j];
        sq += wq[(size_t)i * 9 + j];
    }
    ratio[i] = (sq > 0.f) ? st / sq : 0.f;
}

// ---------------- out-GEMM: R3s[z][p][c] = sum_{q chunk} W[p][q]*bg[c][q] ---
__global__ __launch_bounds__(256)
void og_kernel(const u8* __restrict__ Wm, const u8* __restrict__ Bc,
               float* __restrict__ R3s)
{
    __shared__ __align__(16) u8 As[64 * 128];
    __shared__ __align__(16) u8 Bs[128 * 128];
    const int tid  = threadIdx.x;
    const int wid  = tid >> 6;
    const int lane = tid & 63;
    const int wm = (wid >> 1) * 32;
    const int wn = (wid & 1) * 64;
    const size_t bm = (size_t)blockIdx.x * 64;
    const int kbeg = blockIdx.y * 1152;

    f32x4 acc[2][4];
#pragma unroll
    for (int i = 0; i < 2; ++i)
#pragma unroll
        for (int j = 0; j < 4; ++j)
            acc[i][j] = (f32x4){0.f, 0.f, 0.f, 0.f};

    const int lrow = lane >> 3;
    const int lcb  = ((lane & 7) << 4) ^ ((lrow & 7) << 4);
    const u8* gA = Wm + (bm + wid * 16 + lrow) * (size_t)9216 + lcb;
    const u8* gB = Bc + (wid * 32 + lrow) * (size_t)9216 + lcb;
    u8* lA = As + (size_t)(wid * 16) * 128;
    u8* lB = Bs + (size_t)(wid * 32) * 128;
    const size_t rstep = (size_t)9216 * 8;
    const int lm = lane & 15, lk = lane >> 4;

    for (int k0 = kbeg; k0 < kbeg + 1152; k0 += 128) {
        __syncthreads();
#pragma unroll
        for (int j = 0; j < 2; ++j)
            GLOAD16(gA + j * rstep + k0, lA + j * 1024);
#pragma unroll
        for (int j = 0; j < 4; ++j)
            GLOAD16(gB + j * rstep + k0, lB + j * 1024);
        __syncthreads();

        long2v aop[2][2], bop[4][2];
#pragma unroll
        for (int f = 0; f < 2; ++f) {
            int ma = wm + f * 16 + lm;
            int sw = (ma & 7) << 4;
            const u8* pr = As + ma * 128;
            aop[f][0] = *(const long2v*)(pr + ((lk * 32) ^ sw));
            aop[f][1] = *(const long2v*)(pr + ((lk * 32 + 16) ^ sw));
        }
#pragma unroll
        for (int f = 0; f < 4; ++f) {
            int nb = wn + f * 16 + lm;
            int sw = (nb & 7) << 4;
            const u8* pr = Bs + nb * 128;
            bop[f][0] = *(const long2v*)(pr + ((lk * 32) ^ sw));
            bop[f][1] = *(const long2v*)(pr + ((lk * 32 + 16) ^ sw));
        }
#pragma unroll
        for (int ks = 0; ks < 4; ++ks)
#pragma unroll
            for (int fm = 0; fm < 2; ++fm)
#pragma unroll
                for (int fn = 0; fn < 4; ++fn)
                    acc[fm][fn] = __builtin_amdgcn_mfma_f32_16x16x32_bf8_fp8(
                        aop[fm][ks >> 1][ks & 1], bop[fn][ks >> 1][ks & 1],
                        acc[fm][fn], 0, 0, 0);
    }

    float* out = R3s + (size_t)blockIdx.y * 9216 * 128;
#pragma unroll
    for (int fm = 0; fm < 2; ++fm)
#pragma unroll
        for (int fn = 0; fn < 4; ++fn)
#pragma unroll
            for (int i = 0; i < 4; ++i) {
                int r = wm + fm * 16 + ((lane >> 4) * 4) + i;
                int c = wn + fn * 16 + (lane & 15);
                out[(bm + r) * (size_t)128 + c] = acc[fm][fn][i];
            }
}

// ---------------- sum partials * ratio + mask + 2x upsample -> cl bf16 ------
__global__ void up_sum_kernel(const float* __restrict__ R3s, const float* __restrict__ ratio,
                              const float* __restrict__ mask, u16* __restrict__ upCL)
{
    int idx = blockIdx.x * 256 + threadIdx.x;   // 9216 * 16
    if (idx >= 147456) return;
    int p = idx >> 4, cs = (idx & 15) * 8;
    int y = p / 96, x = p - y * 96;
    float m = mask[(size_t)(2 * y) * 192 + 2 * x] * ratio[p];
    float acc[8];
#pragma unroll
    for (int j = 0; j < 8; ++j) acc[j] = 0.f;
#pragma unroll
    for (int z = 0; z < 8; ++z) {
        const float* rp = R3s + (size_t)z * 9216 * 128 + (size_t)p * 128 + cs;
        float4 a = *(const float4*)rp;
        float4 b = *(const float4*)(rp + 4);
        acc[0] += a.x; acc[1] += a.y; acc[2] += a.z; acc[3] += a.w;
        acc[4] += b.x; acc[5] += b.y; acc[6] += b.z; acc[7] += b.w;
    }
    u16 ov[8];
#pragma unroll
    for (int j = 0; j < 8; ++j) ov[j] = f2bf(acc[j] * m);
    short8v v = *(short8v*)ov;
    size_t r0 = ((size_t)(2 * y) * 192 + 2 * x) * 128 + cs;
    size_t r1 = ((size_t)(2 * y + 1) * 192 + 2 * x) * 128 + cs;
    *(short8v*)(upCL + r0)        = v;
    *(short8v*)(upCL + r0 + 128)  = v;
    *(short8v*)(upCL + r1)        = v;
    *(short8v*)(upCL + r1 + 128)  = v;
}

// ---------------------------------------------------------------------------
extern "C" void kernel_launch(void* const* d_in, const int* in_sizes, int n_in,
                              void* d_out, int out_size, void* d_ws, size_t ws_size,
                              hipStream_t stream)
{
    const float* x    = (const float*)d_in[0];
    const float* mask = (const float*)d_in[1];
    const float* w[8];
    const float* b[8];
    for (int i = 0; i < 8; ++i) {
        w[i] = (const float*)d_in[2 + 2 * i];
        b[i] = (const float*)d_in[3 + 2 * i];
    }
    char* ws = (char*)d_ws;
    dim3 blk(256);

    // byte offsets (identical to round 16-19; peak 188.4 MB, proven safe)
    const size_t U_H1CL = 0;
    const size_t U_H2   = 37748736;
    const size_t U_H3   = 47185920;
    const size_t U_H4   = 66060288;
    const size_t U_H5   = 75497472;
    const size_t U_H6   = 84934656;
    const size_t U_X4   = 94371840;
    const size_t U_FGC  = 0;
    const size_t U_BGC  = 2359296;
    const size_t B_BGC8 = 4718592;
    const size_t B_G    = 15335424;
    const size_t B_P8   = 100270080;
    const size_t B_W    = 15335424;
    const size_t F_R3S  = 100270080;
    const size_t U_UPCL = 138018816;
    const size_t U_H7   = 147456000;
    const size_t F_H8   = 156893184;
    const size_t U_WP1  = 185204736;
    const size_t U_WP2  = 185212928;
    const size_t U_WP3  = 185231360;
    const size_t U_WP4  = 185268224;
    const size_t U_WP5  = 185415680;
    const size_t U_WP6  = 185710592;
    const size_t U_WP7  = 186005504;
    const size_t U_WP8  = 186300416;
    const size_t D_RED  = 186595328;
    const size_t F_SCALE= 186927104;
    const size_t F_RS   = 186927360;
    const size_t F_INV  = 186964224;
    const size_t F_WT   = 187001088;
    const size_t F_WQ   = 187664640;
    const size_t F_RAT  = 188328192;

    u16* h1cl   = (u16*)(ws + U_H1CL);
    u16* h2     = (u16*)(ws + U_H2);
    u16* h3     = (u16*)(ws + U_H3);
    u16* h4     = (u16*)(ws + U_H4);
    u16* h5     = (u16*)(ws + U_H5);
    u16* h6     = (u16*)(ws + U_H6);
    u16* x4     = (u16*)(ws + U_X4);
    u16* fgC    = (u16*)(ws + U_FGC);
    u16* bgC    = (u16*)(ws + U_BGC);
    u8*  bgC8   = (u8*)(ws + B_BGC8);
    u8*  G      = (u8*)(ws + B_G);
    u8*  P8     = (u8*)(ws + B_P8);
    u8*  Wm     = (u8*)(ws + B_W);
    float* R3s  = (float*)(ws + F_R3S);
    u16* upCL   = (u16*)(ws + U_UPCL);
    u16* h7     = (u16*)(ws + U_H7);
    float* h8   = (float*)(ws + F_H8);
    u16* wp1    = (u16*)(ws + U_WP1);
    u16* wp2    = (u16*)(ws + U_WP2);
    u16* wp3    = (u16*)(ws + U_WP3);
    u16* wp4    = (u16*)(ws + U_WP4);
    u16* wp5    = (u16*)(ws + U_WP5);
    u16* wp6    = (u16*)(ws + U_WP6);
    u16* wp7    = (u16*)(ws + U_WP7);
    u16* wp8    = (u16*)(ws + U_WP8);
    double* red = (double*)(ws + D_RED);
    float* scale= (float*)(ws + F_SCALE);
    float* rs   = (float*)(ws + F_RS);
    float* inv  = (float*)(ws + F_INV);
    float* wt   = (float*)(ws + F_WT);
    float* wq   = (float*)(ws + F_WQ);
    float* ratio= (float*)(ws + F_RAT);

    // ---- prepack ----
    pack_w1_kernel<<<dim3(16), blk, 0, stream>>>(w[0], wp1);
    pack_w_kernel<<<dim3(36),  blk, 0, stream>>>(w[1], wp2, 32, 32);
    pack_w_kernel<<<dim3(72),  blk, 0, stream>>>(w[2], wp3, 64, 32);
    pack_w_kernel<<<dim3(288), blk, 0, stream>>>(w[3], wp4, 128, 64);
    pack_w_kernel<<<dim3(576), blk, 0, stream>>>(w[4], wp5, 128, 128);
    pack_w_kernel<<<dim3(576), blk, 0, stream>>>(w[5], wp6, 128, 128);
    pack_w_kernel<<<dim3(576), blk, 0, stream>>>(w[6], wp7, 128, 128);
    pack_w_kernel<<<dim3(576), blk, 0, stream>>>(w[7], wp8, 128, 128);
    x4cl_kernel<<<dim3(2304), blk, 0, stream>>>(x, x4);

    // ---- conv front-end ----
    conv1_mfma_kernel<<<dim3(48, 96), blk, 0, stream>>>(x4, wp1, b[0], h1cl);
    mfma_conv_kernel<4, 1, 2, 2, 2, 32, 32, 1, 0><<<dim3(24, 48), blk, 0, stream>>>(
        h1cl, wp2, b[1], h2, 768, 768, 384, 384, 32);
    mfma_conv_kernel<4, 2, 2, 2, 1, 32, 32, 1, 0><<<dim3(24, 48), blk, 0, stream>>>(
        h2, wp3, b[2], h3, 384, 384, 384, 384, 64);
    mfma_conv_kernel<4, 1, 2, 2, 2, 64, 32, 1, 0><<<dim3(12, 24, 4), blk, 0, stream>>>(
        h3, wp4, b[3], h4, 384, 384, 192, 192, 128);
    mfma_conv_kernel<4, 1, 2, 2, 1, 128, 128, 1, 0><<<dim3(12, 24, 4), blk, 0, stream>>>(
        h4, wp5, b[4], h5, 192, 192, 192, 192, 128);
    mfma_conv_kernel<4, 1, 2, 2, 1, 128, 128, 0, 0><<<dim3(12, 24, 4), blk, 0, stream>>>(
        h5, wp6, b[5], h6, 192, 192, 192, 192, 128);

    // ---- attention inputs ----
    build_fgbgc_kernel<<<dim3(576), blk, 0, stream>>>(h6, mask, fgC, bgC);
    build_bgc8_kernel<<<dim3(576), blk, 0, stream>>>(h6, bgC8);

    // ---- G (K=128 Gram, e5m2, x1/8) ----
    g_gemm_kernel<<<dim3(72, 72), blk, 0, stream>>>(fgC, bgC, G);

    // ---- stencil 1: S8 + Frobenius partials -> scale ----
    sstencil_kernel<<<dim3(9, 2304), blk, 0, stream>>>(G, P8, red);
    sumsq_stage2<<<dim3(1), blk, 0, stream>>>(red, 20736, scale);

    // ---- exp in-place (linear) + rowsums -> inv ----
    exp_rows_kernel<<<dim3(2304), blk, 0, stream>>>(P8, scale, rs);
    inv_kernel<<<dim3(36), blk, 0, stream>>>(rs, inv);

    // ---- stencil 2: W (e5m2, k-permuted) + quantization ratio ----
    wstencil2_kernel<<<dim3(9, 2304), blk, 0, stream>>>(P8, inv, Wm, wt, wq);
    ratio_kernel<<<dim3(36), blk, 0, stream>>>(wt, wq, ratio);

    // ---- out-GEMM (bf8 x fp8, split-K 8) -> partial R3s ----
    og_kernel<<<dim3(144, 8), blk, 0, stream>>>(Wm, bgC8, R3s);

    // ---- sum partials * ratio + mask + upsample -> channels-last bf16 ----
    up_sum_kernel<<<dim3(576), blk, 0, stream>>>(R3s, ratio, mask, upCL);

    // ---- back-end convs ----
    mfma_conv_kernel<4, 1, 2, 2, 1, 128, 128, 1, 0><<<dim3(12, 24, 4), blk, 0, stream>>>(
        upCL, wp7, b[6], h7, 192, 192, 192, 192, 128);
    mfma_conv_kernel<4, 1, 2, 2, 1, 128, 128, 1, 1><<<dim3(12, 24, 4), blk, 0, stream>>>(
        h7, wp8, b[7], h8, 192, 192, 192, 192, 128);
    cl2p_kernel<<<dim3(1152), blk, 0, stream>>>(h8, (float*)d_out);
}

// Round 21
// 517.804 us; speedup vs baseline: 2.2705x; 1.0462x over previous
//
#include <hip/hip_runtime.h>
#include <hip/hip_fp16.h>
#include <math.h>

// ---------------------------------------------------------------------------
// Round 20->21: launch-count reduction (29 -> 19 dispatches), bit-identical
// math: pack_all (9->1), x4cl folded into conv1 staging, merged attention
// builders, ratio folded into up_sum. Everything else identical to round 20
// (541 us, absmax 0.0625).
// ---------------------------------------------------------------------------

typedef unsigned short u16;
typedef unsigned char u8;
typedef short short4v __attribute__((ext_vector_type(4)));
typedef short short8v __attribute__((ext_vector_type(8)));
typedef float f32x4 __attribute__((ext_vector_type(4)));
typedef long long2v __attribute__((ext_vector_type(2)));

__device__ __forceinline__ u16 f2bf(float f) {
    unsigned u = __float_as_uint(f);
    return (u16)((u + 0x7FFF + ((u >> 16) & 1)) >> 16);
}
__device__ __forceinline__ float bf2f(u16 h) {
    return __uint_as_float(((unsigned)h) << 16);
}
__device__ __forceinline__ u8 f2e5m2(float f) {
    unsigned short hb = __half_as_ushort(__float2half(f));
    unsigned rem = hb & 0xFF;
    unsigned b = hb >> 8;
    b += (rem > 0x80u) || (rem == 0x80u && (b & 1u));
    return (u8)b;
}
__device__ __forceinline__ float e5m2f(unsigned b) {
    return __half2float(__ushort_as_half((unsigned short)(b << 8)));
}
__device__ __forceinline__ u8 f2e4m3(float f) {
    unsigned u = __float_as_uint(f);
    unsigned s = (u >> 24) & 0x80u;
    unsigned a = u & 0x7FFFFFFFu;
    if (a >= 0x43E00000u) return (u8)(s | 0x7Eu);
    int e = (int)(a >> 23) - 127;
    if (e >= -6) {
        unsigned keep = (a >> 20) & 7u;
        unsigned rem  = a & 0xFFFFFu;
        keep += (rem > 0x80000u) || (rem == 0x80000u && (keep & 1u));
        unsigned e4 = (unsigned)(e + 7);
        if (keep == 8u) { keep = 0u; ++e4; }
        if (e4 >= 15u && keep >= 7u) return (u8)(s | 0x7Eu);
        return (u8)(s | (e4 << 3) | keep);
    }
    float q = __uint_as_float(a) * 512.f;
    int m = (int)rintf(q);
    if (m >= 8) return (u8)(s | 0x08u);
    return (u8)(s | (unsigned)m);
}
__device__ __forceinline__ int perm8(int o8) { return ((o8 & 3) << 2) | (o8 >> 2); }

#define GLOAD16(g, l) __builtin_amdgcn_global_load_lds(                      \
    (const __attribute__((address_space(1))) void*)(g),                      \
    (__attribute__((address_space(3))) void*)(l), 16, 0, 0)

#define E5M2_UNPACK(dst, src32)                                              \
    dst[0] = __builtin_amdgcn_perm(0u, (src32), 0x010C000Cu);                \
    dst[1] = __builtin_amdgcn_perm(0u, (src32), 0x030C020Cu);

__device__ __forceinline__ unsigned e5m2_round2(unsigned h) {
    return h + 0x007F007Fu + ((h >> 8) & 0x00010001u);
}

// shifted 16B load: bytes [base16+ex, base16+16+ex), ex in {-1,0,1} (folded)
__device__ __forceinline__ void load16_sh(const u8* base16, int ex, unsigned d[4]) {
    uint4 v = *(const uint4*)base16;
    if (ex == 0) {
        d[0] = v.x; d[1] = v.y; d[2] = v.z; d[3] = v.w;
    } else if (ex == 1) {
        unsigned b = *(const unsigned*)(base16 + 16);
        d[0] = (v.x >> 8) | (v.y << 24);
        d[1] = (v.y >> 8) | (v.z << 24);
        d[2] = (v.z >> 8) | (v.w << 24);
        d[3] = (v.w >> 8) | (b << 24);
    } else {
        unsigned b = *(const unsigned*)(base16 - 4);
        d[0] = (b >> 24) | (v.x << 8);
        d[1] = (v.x >> 24) | (v.y << 8);
        d[2] = (v.y >> 24) | (v.z << 8);
        d[3] = (v.z >> 24) | (v.w << 8);
    }
}

// ---------------- unified weight prepack (all 8 layers, one launch) ---------
__device__ __forceinline__ void pack_generic(int l, const float* __restrict__ w,
                                             u16* __restrict__ wp, int IC)
{
    int oc = l / (9 * IC);
    int r  = l - oc * 9 * IC;
    int tap = r / IC;
    int ic  = r - tap * IC;
    wp[l] = f2bf(w[((size_t)oc * IC + ic) * 9 + tap]);
}

__global__ void pack_all_kernel(const float* __restrict__ w1, const float* __restrict__ w2,
                                const float* __restrict__ w3, const float* __restrict__ w4,
                                const float* __restrict__ w5, const float* __restrict__ w6,
                                const float* __restrict__ w7, const float* __restrict__ w8,
                                u16* __restrict__ wp1, u16* __restrict__ wp2,
                                u16* __restrict__ wp3, u16* __restrict__ wp4,
                                u16* __restrict__ wp5, u16* __restrict__ wp6,
                                u16* __restrict__ wp7, u16* __restrict__ wp8)
{
    int idx = blockIdx.x * 256 + threadIdx.x;
    if (idx < 4096) {
        int oc = idx >> 7, k = idx & 127;
        int tap = k >> 2, ic = k & 3;
        u16 v = 0;
        if (tap < 25 && ic < 3) v = f2bf(w1[oc * 75 + ic * 25 + tap]);
        wp1[idx] = v;
    } else if (idx < 13312)  pack_generic(idx - 4096,   w2, wp2, 32);
    else if (idx < 31744)    pack_generic(idx - 13312,  w3, wp3, 32);
    else if (idx < 105472)   pack_generic(idx - 31744,  w4, wp4, 64);
    else if (idx < 252928)   pack_generic(idx - 105472, w5, wp5, 128);
    else if (idx < 400384)   pack_generic(idx - 252928, w6, wp6, 128);
    else if (idx < 547840)   pack_generic(idx - 400384, w7, wp7, 128);
    else if (idx < 695296)   pack_generic(idx - 547840, w8, wp8, 128);
}

// ---------------- conv1 MFMA: 3->32, 5x5, s1, reflect pad2, ELU -------------
// Stages directly from planar fp32 x (x4cl folded in).
__global__ __launch_bounds__(256)
void conv1_mfma_kernel(const float* __restrict__ x, const u16* __restrict__ wp1,
                       const float* __restrict__ bias, u16* __restrict__ out)
{
    __shared__ __align__(16) u16 sIn[12 * 20 * 4];
    const int tid = threadIdx.x;
    const int lane = tid & 63;
    const int w = tid >> 6;
    const int lm = lane & 15;
    const int lk = lane >> 4;
    const int oy0 = blockIdx.y * 8, ox0 = blockIdx.x * 16;

    for (int u = tid; u < 240; u += 256) {
        int yt = u / 20, xt = u - yt * 20;
        int gy = oy0 - 2 + yt; gy = gy < 0 ? -gy : (gy >= 768 ? 1534 - gy : gy);
        int gx = ox0 - 2 + xt; gx = gx < 0 ? -gx : (gx >= 768 ? 1534 - gx : gx);
        const float* xp = x + (size_t)gy * 768 + gx;
        u16 v[4];
        v[0] = f2bf(xp[0]);
        v[1] = f2bf(xp[589824]);
        v[2] = f2bf(xp[1179648]);
        v[3] = 0;
        *(short4v*)(sIn + u * 4) = *(short4v*)v;
    }
    int aoff[4][2];
#pragma unroll
    for (int ks = 0; ks < 4; ++ks) {
        int t0 = ks * 8 + lk * 2;
        int t1 = t0 + 1;
        if (t0 > 24) t0 = 24;
        if (t1 > 24) t1 = 24;
        int dy0 = t0 / 5, dx0 = t0 - 5 * dy0;
        int dy1 = t1 / 5, dx1 = t1 - 5 * dy1;
        aoff[ks][0] = (dy0 * 20 + dx0 + lm) * 4;
        aoff[ks][1] = (dy1 * 20 + dx1 + lm) * 4;
    }
    __syncthreads();

    f32x4 acc[2][2];
#pragma unroll
    for (int i = 0; i < 2; ++i)
#pragma unroll
        for (int j = 0; j < 2; ++j) acc[i][j] = (f32x4){0.f, 0.f, 0.f, 0.f};

#pragma unroll
    for (int ks = 0; ks < 4; ++ks) {
        short8v a[2], b[2];
#pragma unroll
        for (int fm = 0; fm < 2; ++fm) {
            int base = (w * 2 + fm) * 80;
            short4v lo = *(const short4v*)(sIn + base + aoff[ks][0]);
            short4v hi = *(const short4v*)(sIn + base + aoff[ks][1]);
            short8v av;
            av[0] = lo[0]; av[1] = lo[1]; av[2] = lo[2]; av[3] = lo[3];
            av[4] = hi[0]; av[5] = hi[1]; av[6] = hi[2]; av[7] = hi[3];
            a[fm] = av;
        }
#pragma unroll
        for (int fn = 0; fn < 2; ++fn)
            b[fn] = *(const short8v*)(wp1 + (size_t)(fn * 16 + lm) * 128 + ks * 32 + lk * 8);
#pragma unroll
        for (int fm = 0; fm < 2; ++fm)
#pragma unroll
            for (int fn = 0; fn < 2; ++fn)
                acc[fm][fn] = __builtin_amdgcn_mfma_f32_16x16x32_bf16(
                    a[fm], b[fn], acc[fm][fn], 0, 0, 0);
    }

#pragma unroll
    for (int fm = 0; fm < 2; ++fm) {
        int gy = oy0 + w * 2 + fm;
#pragma unroll
        for (int fn = 0; fn < 2; ++fn) {
            int oc = fn * 16 + lm;
            float bv = bias[oc];
#pragma unroll
            for (int i = 0; i < 4; ++i) {
                int xx = lk * 4 + i;
                float v = acc[fm][fn][i] + bv;
                v = v > 0.f ? v : expm1f(v);
                out[((size_t)gy * 768 + ox0 + xx) * 32 + oc] = f2bf(v);
            }
        }
    }
}

// ---------------- MFMA implicit-GEMM conv (3x3, reflect pad 1) --------------
template<int FM, int FN, int NWM, int NWN, int S, int IC, int ICC, int ACT, int OUTF32>
__global__ __launch_bounds__(256)
void mfma_conv_kernel(const u16* __restrict__ in, const u16* __restrict__ wgtP,
                      const float* __restrict__ bias, void* __restrict__ out,
                      int H, int W, int Ho, int Wo, int OC)
{
    constexpr int TY = 7 * S + 3;
    constexpr int TX = 15 * S + 3;
    constexpr int NSLOT = ICC / 8;
    constexpr int SWMSK = NSLOT - 1;
    constexpr int KTOT = 9 * IC;
    __shared__ __align__(16) u16 sIn[TY * TX * ICC];

    const int tid  = threadIdx.x;
    const int lane = tid & 63;
    const int wid  = tid >> 6;
    const int wmi  = wid / NWN;
    const int wni  = wid % NWN;
    const int lm   = lane & 15;
    const int lk   = lane >> 4;
    const int noff = blockIdx.z * (NWN * FN * 16);

    f32x4 acc[FM][FN];
#pragma unroll
    for (int i = 0; i < FM; ++i)
#pragma unroll
        for (int j = 0; j < FN; ++j) acc[i][j] = (f32x4){0.f, 0.f, 0.f, 0.f};

    const int iy0 = blockIdx.y * 8 * S - 1;
    const int ix0 = blockIdx.x * 16 * S - 1;

    for (int c0 = 0; c0 < IC; c0 += ICC) {
        if (c0) __syncthreads();
        for (int u = tid; u < TY * TX * NSLOT; u += 256) {
            int yt = u / (TX * NSLOT);
            int r  = u - yt * (TX * NSLOT);
            int xt = r / NSLOT;
            int sl = r - xt * NSLOT;
            int gy = iy0 + yt; gy = gy < 0 ? -gy : (gy >= H ? 2 * H - 2 - gy : gy);
            int gx = ix0 + xt; gx = gx < 0 ? -gx : (gx >= W ? 2 * W - 2 - gx : gx);
            *(short8v*)((char*)sIn + (size_t)((yt * TX + xt) * NSLOT + (sl ^ (xt & SWMSK))) * 16) =
                *(const short8v*)(in + ((size_t)gy * W + gx) * IC + c0 + sl * 8);
        }
        __syncthreads();
#pragma unroll
        for (int tap = 0; tap < 9; ++tap) {
            const int dy = tap / 3, dx = tap % 3;
#pragma unroll
            for (int icw = 0; icw < ICC / 32; ++icw) {
                short8v a[FM], b[FN];
#pragma unroll
                for (int fm = 0; fm < FM; ++fm) {
                    int yt = (wmi * FM + fm) * S + dy;
                    int xt = lm * S + dx;
                    a[fm] = *(const short8v*)((const char*)sIn +
                        (size_t)((yt * TX + xt) * NSLOT + ((icw * 4 + lk) ^ (xt & SWMSK))) * 16);
                }
#pragma unroll
                for (int fn = 0; fn < FN; ++fn) {
                    int n = noff + wni * FN * 16 + fn * 16 + lm;
                    b[fn] = *(const short8v*)(wgtP + (size_t)n * KTOT + tap * IC + c0 + icw * 32 + lk * 8);
                }
#pragma unroll
                for (int fm = 0; fm < FM; ++fm)
#pragma unroll
                    for (int fn = 0; fn < FN; ++fn)
                        acc[fm][fn] = __builtin_amdgcn_mfma_f32_16x16x32_bf16(
                            a[fm], b[fn], acc[fm][fn], 0, 0, 0);
            }
        }
    }

#pragma unroll
    for (int fm = 0; fm < FM; ++fm) {
        int y = blockIdx.y * 8 + wmi * FM + fm;
#pragma unroll
        for (int fn = 0; fn < FN; ++fn) {
            int oc = noff + wni * FN * 16 + fn * 16 + lm;
            float bv = bias[oc];
#pragma unroll
            for (int i = 0; i < 4; ++i) {
                int x = blockIdx.x * 16 + lk * 4 + i;
                float v = acc[fm][fn][i] + bv;
                if (ACT == 0) v = v > 0.f ? v : 0.f;
                else          v = v > 0.f ? v : expm1f(v);
                size_t o = ((size_t)y * Wo + x) * OC + oc;
                if (OUTF32) ((float*)out)[o] = v;
                else        ((u16*)out)[o]   = f2bf(v);
            }
        }
    }
}

// channels-last f32 [36864][128] -> planar f32 [128][36864]
__global__ __launch_bounds__(256)
void cl2p_kernel(const float* __restrict__ in, float* __restrict__ out)
{
    __shared__ float t[32][130];
    const int tid = threadIdx.x;
    const int p0 = blockIdx.x * 32;
#pragma unroll
    for (int j = 0; j < 16; ++j) {
        int idx = j * 256 + tid;
        int px = idx >> 7, c = idx & 127;
        t[px][c] = in[(size_t)(p0 + px) * 128 + c];
    }
    __syncthreads();
#pragma unroll
    for (int j = 0; j < 16; ++j) {
        int c = j * 8 + (tid >> 5);
        int px = tid & 31;
        out[(size_t)c * 36864 + p0 + px] = t[px][c];
    }
}

// ---------------- merged attention-input builder ----------------------------
// blocks [0,576): fgC/bgC (channels-last bf16); blocks [576,1152): bgC8 e4m3.
__global__ void build_att_kernel(const u16* __restrict__ h6, const float* __restrict__ mask,
                                 u16* __restrict__ fgC, u16* __restrict__ bgC,
                                 u8* __restrict__ bgC8)
{
    if (blockIdx.x < 576) {
        int idx = blockIdx.x * 256 + threadIdx.x;   // 9216*16
        int q = idx >> 4, cs = (idx & 15) * 8;
        int qy = q / 96, qx = q - qy * 96;
        const u16* src = h6 + ((size_t)(2 * qy) * 192 + 2 * qx) * 128 + cs;
        float m = mask[(size_t)(2 * qy) * 192 + 2 * qx];
        short8v v = *(const short8v*)src;
        u16 fo[8];
#pragma unroll
        for (int j = 0; j < 8; ++j) fo[j] = f2bf(bf2f((u16)v[j]) * m);
        *(short8v*)(bgC + (size_t)q * 128 + cs) = v;
        *(short8v*)(fgC + (size_t)q * 128 + cs) = *(short8v*)fo;
    } else {
        int idx = (blockIdx.x - 576) * 256 + threadIdx.x;   // 128*1152 chunks
        int c = idx / 1152, qc = idx - c * 1152;
        int q0 = qc << 3;
        int qy = q0 / 96, qx0 = q0 - qy * 96;
        const u16* row = h6 + (size_t)(2 * qy) * 192 * 128 + c;
        unsigned long long ow = 0;
#pragma unroll
        for (int j = 0; j < 8; ++j) {
            float v = bf2f(row[(size_t)(2 * (qx0 + j)) * 128]);
            ow |= (unsigned long long)f2e4m3(v) << (8 * j);
        }
        *(unsigned long long*)(bgC8 + (size_t)c * 9216 + (q0 & ~127) + perm8(qc & 15) * 8) = ow;
    }
}

// ---------------- G-GEMM: G[a][b] = 1/8 * sum_c fgC[a][c]*bgC[b][c] ---------
__global__ __launch_bounds__(256)
void g_gemm_kernel(const u16* __restrict__ A, const u16* __restrict__ B,
                   u8* __restrict__ G)
{
    __shared__ __align__(16) u16 As[128 * 64];
    __shared__ __align__(16) u16 Bs[128 * 64];
    const int tid  = threadIdx.x;
    const int wid  = tid >> 6;
    const int lane = tid & 63;
    const int wm = (wid >> 1) * 64;
    const int wn = (wid & 1) * 64;
    const size_t bm = (size_t)blockIdx.y * 128;
    const size_t bn = (size_t)blockIdx.x * 128;

    f32x4 acc[4][4];
#pragma unroll
    for (int i = 0; i < 4; ++i)
#pragma unroll
        for (int j = 0; j < 4; ++j)
            acc[i][j] = (f32x4){0.f, 0.f, 0.f, 0.f};

    const int lrow = lane >> 3;
    const int lcb  = ((lane & 7) << 4) ^ ((lrow & 7) << 4);
    const char* gA = (const char*)A + ((bm + wid * 32 + lrow) * (size_t)128) * 2 + lcb;
    const char* gB = (const char*)B + ((bn + wid * 32 + lrow) * (size_t)128) * 2 + lcb;
    char* lA = (char*)As + (size_t)(wid * 32) * 128;
    char* lB = (char*)Bs + (size_t)(wid * 32) * 128;
    const size_t rs8 = (size_t)128 * 16;

    for (int k0 = 0; k0 < 128; k0 += 64) {
        __syncthreads();
#pragma unroll
        for (int j = 0; j < 4; ++j) {
            GLOAD16(gA + j * rs8 + (size_t)k0 * 2, lA + j * 1024);
            GLOAD16(gB + j * rs8 + (size_t)k0 * 2, lB + j * 1024);
        }
        __syncthreads();
#pragma unroll
        for (int ks = 0; ks < 2; ++ks) {
            short8v a[4], b[4];
#pragma unroll
            for (int f = 0; f < 4; ++f) {
                int ma = wm + f * 16 + (lane & 15);
                int kba = (ks * 64 + ((lane >> 4) * 16)) ^ ((ma & 7) << 4);
                a[f] = *(const short8v*)((const char*)As + ma * 128 + kba);
                int nb = wn + f * 16 + (lane & 15);
                int kbb = (ks * 64 + ((lane >> 4) * 16)) ^ ((nb & 7) << 4);
                b[f] = *(const short8v*)((const char*)Bs + nb * 128 + kbb);
            }
#pragma unroll
            for (int fm = 0; fm < 4; ++fm)
#pragma unroll
                for (int fn = 0; fn < 4; ++fn)
                    acc[fm][fn] = __builtin_amdgcn_mfma_f32_16x16x32_bf16(
                        a[fm], b[fn], acc[fm][fn], 0, 0, 0);
        }
    }

#pragma unroll
    for (int fm = 0; fm < 4; ++fm)
#pragma unroll
        for (int fn = 0; fn < 4; ++fn)
#pragma unroll
            for (int i = 0; i < 4; ++i) {
                int r = wm + fm * 16 + ((lane >> 4) * 4) + i;
                int c = wn + fn * 16 + (lane & 15);
                G[(bm + r) * (size_t)9216 + bn + c] = f2e5m2(0.125f * acc[fm][fn][i]);
            }
}

// ---------------- stencil 1: S8 = stencil(G) + sum S^2; 16 q/thread ---------
__global__ __launch_bounds__(256)
void sstencil_kernel(const u8* __restrict__ G, u8* __restrict__ S8,
                     double* __restrict__ partial)
{
    const int wid  = threadIdx.x >> 6;
    const int lane = threadIdx.x & 63;
    const int p = blockIdx.y * 4 + wid;
    const int py = p / 96, px = p - py * 96;
    const int q0 = blockIdx.x * 1024 + lane * 16;
    const int qy = q0 / 96, qx0 = q0 - qy * 96;

    __half2 hz = __floats2half2_rn(0.f, 0.f);
    __half2 hacc[8] = {hz, hz, hz, hz, hz, hz, hz, hz};

#pragma unroll
    for (int ey = -1; ey <= 1; ++ey) {
#pragma unroll
        for (int ex = -1; ex <= 1; ++ex) {
            if ((unsigned)(py + ey) >= 96u || (unsigned)(px + ex) >= 96u) continue;
            if ((unsigned)(qy + ey) >= 96u) continue;
            const int e = ey * 96 + ex;
            const u8* base16 = G + (size_t)(p + e) * 9216 + q0 + (e - ex);
            unsigned d[4];
            load16_sh(base16, ex, d);
            if (ex == 1 && qx0 == 80) d[3] &= 0x00FFFFFFu;
            if (ex == -1 && qx0 == 0) d[0] &= 0xFFFFFF00u;
#pragma unroll
            for (int i = 0; i < 4; ++i) {
                unsigned pk[2];
                E5M2_UNPACK(pk, d[i]);
                hacc[2 * i]     = __hadd2(hacc[2 * i],     *(__half2*)&pk[0]);
                hacc[2 * i + 1] = __hadd2(hacc[2 * i + 1], *(__half2*)&pk[1]);
            }
        }
    }

    unsigned t[8];
    double s2 = 0.0;
#pragma unroll
    for (int i = 0; i < 8; ++i) {
        unsigned h = *(unsigned*)&hacc[i];
        t[i] = e5m2_round2(h);
        float2 f2 = __half22float2(hacc[i]);
        s2 += (double)f2.x * f2.x + (double)f2.y * f2.y;
    }
    uint4 ow;
    ow.x = __builtin_amdgcn_perm(t[1], t[0], 0x07050301u);
    ow.y = __builtin_amdgcn_perm(t[3], t[2], 0x07050301u);
    ow.z = __builtin_amdgcn_perm(t[5], t[4], 0x07050301u);
    ow.w = __builtin_amdgcn_perm(t[7], t[6], 0x07050301u);
    *(uint4*)(S8 + (size_t)p * 9216 + q0) = ow;

    for (int off = 32; off; off >>= 1) s2 += __shfl_down(s2, off, 64);
    __shared__ double wsum[4];
    if (lane == 0) wsum[wid] = s2;
    __syncthreads();
    if (threadIdx.x == 0)
        partial[(size_t)blockIdx.y * 9 + blockIdx.x] = wsum[0] + wsum[1] + wsum[2] + wsum[3];
}

__global__ void sumsq_stage2(const double* __restrict__ partial, int nblocks, float* __restrict__ scale)
{
    double s = 0.0;
    for (int i = threadIdx.x; i < nblocks; i += 256) s += partial[i];
    for (int off = 32; off; off >>= 1) s += __shfl_down(s, off, 64);
    __shared__ double wsum[4];
    int lane = threadIdx.x & 63, wid = threadIdx.x >> 6;
    if (lane == 0) wsum[wid] = s;
    __syncthreads();
    if (threadIdx.x == 0) {
        double nrm = sqrt(wsum[0] + wsum[1] + wsum[2] + wsum[3]);
        if (nrm < 1e-12) nrm = 1e-12;
        *scale = (float)(10.0 / nrm);
    }
}

// ---------------- exp pass: P8 = e5m2(exp(scale*S8)) in-place; 16 B/iter ----
__global__ __launch_bounds__(256)
void exp_rows_kernel(u8* __restrict__ P8, const float* __restrict__ scale_p,
                     float* __restrict__ rs)
{
    const int wid = threadIdx.x >> 6, lane = threadIdx.x & 63;
    const int p = blockIdx.x * 4 + wid;   // grid 2304
    u8* rp = P8 + (size_t)p * 9216;
    const float scale = *scale_p;
    float s = 0.f;
#pragma unroll
    for (int it = 0; it < 9; ++it) {
        uint4 v = *(uint4*)(rp + it * 1024 + lane * 16);
        unsigned dv[4] = {v.x, v.y, v.z, v.w};
        unsigned t[8];
        __half2 sacc = __floats2half2_rn(0.f, 0.f);
#pragma unroll
        for (int i = 0; i < 4; ++i) {
            unsigned pk[2];
            E5M2_UNPACK(pk, dv[i]);
#pragma unroll
            for (int j = 0; j < 2; ++j) {
                float2 f = __half22float2(*(__half2*)&pk[j]);
                __half2 eh = __floats2half2_rn(__expf(scale * f.x), __expf(scale * f.y));
                t[2 * i + j] = e5m2_round2(*(unsigned*)&eh);
                unsigned q = t[2 * i + j] & 0xFF00FF00u;
                sacc = __hadd2(sacc, *(__half2*)&q);
            }
        }
        uint4 ow;
        ow.x = __builtin_amdgcn_perm(t[1], t[0], 0x07050301u);
        ow.y = __builtin_amdgcn_perm(t[3], t[2], 0x07050301u);
        ow.z = __builtin_amdgcn_perm(t[5], t[4], 0x07050301u);
        ow.w = __builtin_amdgcn_perm(t[7], t[6], 0x07050301u);
        *(uint4*)(rp + it * 1024 + lane * 16) = ow;
        float2 sf = __half22float2(sacc);
        s += sf.x + sf.y;
    }
    for (int off = 32; off; off >>= 1) s += __shfl_down(s, off, 64);
    if (lane == 0) rs[p] = s;
}

__global__ void inv_kernel(const float* __restrict__ rs, float* __restrict__ inv)
{
    int i = blockIdx.x * 256 + threadIdx.x;
    if (i < 9216) inv[i] = 1.f / rs[i];
}

// ---------------- stencil 2: W = sum_t inv*P taps; 16 q/thread, K-PERM ------
__global__ __launch_bounds__(256)
void wstencil2_kernel(const u8* __restrict__ P8, const float* __restrict__ inv,
                      u8* __restrict__ W, float* __restrict__ wt,
                      float* __restrict__ wq)
{
    const int wid  = threadIdx.x >> 6;
    const int lane = threadIdx.x & 63;
    const int p = blockIdx.y * 4 + wid;
    const int py = p / 96, px = p - py * 96;
    const int q0 = blockIdx.x * 1024 + lane * 16;
    const int qy = q0 / 96, qx0 = q0 - qy * 96;

    __half2 hz = __floats2half2_rn(0.f, 0.f);
    __half2 hacc[8] = {hz, hz, hz, hz, hz, hz, hz, hz};

#pragma unroll
    for (int ey = -1; ey <= 1; ++ey) {
#pragma unroll
        for (int ex = -1; ex <= 1; ++ex) {
            if ((unsigned)(py + ey) >= 96u || (unsigned)(px + ex) >= 96u) continue;
            if ((unsigned)(qy + ey) >= 96u) continue;
            const int e = ey * 96 + ex;
            const u8* base16 = P8 + (size_t)(p + e) * 9216 + q0 + (e - ex);
            unsigned d[4];
            load16_sh(base16, ex, d);
            if (ex == 1 && qx0 == 80) d[3] &= 0x00FFFFFFu;
            if (ex == -1 && qx0 == 0) d[0] &= 0xFFFFFF00u;

            float iv = inv[p + e];
            __half2 iv2 = __floats2half2_rn(iv, iv);
#pragma unroll
            for (int i = 0; i < 4; ++i) {
                unsigned pk[2];
                E5M2_UNPACK(pk, d[i]);
                hacc[2 * i]     = __hfma2(*(__half2*)&pk[0], iv2, hacc[2 * i]);
                hacc[2 * i + 1] = __hfma2(*(__half2*)&pk[1], iv2, hacc[2 * i + 1]);
            }
        }
    }

    unsigned t[8];
    __half2 stacc = hz, sqacc = hz;
#pragma unroll
    for (int i = 0; i < 8; ++i) {
        unsigned h = *(unsigned*)&hacc[i];
        t[i] = e5m2_round2(h);
        stacc = __hadd2(stacc, hacc[i]);
        unsigned q = t[i] & 0xFF00FF00u;
        sqacc = __hadd2(sqacc, *(__half2*)&q);
    }
    unsigned g0 = __builtin_amdgcn_perm(t[1], t[0], 0x07050301u);
    unsigned g1 = __builtin_amdgcn_perm(t[3], t[2], 0x07050301u);
    unsigned g2 = __builtin_amdgcn_perm(t[5], t[4], 0x07050301u);
    unsigned g3 = __builtin_amdgcn_perm(t[7], t[6], 0x07050301u);
    int o8 = (q0 & 127) >> 3;
    u8* wrow = W + (size_t)p * 9216 + (q0 & ~127);
    *(unsigned long long*)(wrow + perm8(o8) * 8)     =
        (unsigned long long)g0 | ((unsigned long long)g1 << 32);
    *(unsigned long long*)(wrow + perm8(o8 + 1) * 8) =
        (unsigned long long)g2 | ((unsigned long long)g3 << 32);

    float2 stf = __half22float2(stacc);
    float2 sqf = __half22float2(sqacc);
    float st = stf.x + stf.y, sq = sqf.x + sqf.y;
    for (int off = 32; off; off >>= 1) {
        st += __shfl_down(st, off, 64);
        sq += __shfl_down(sq, off, 64);
    }
    if (lane == 0) {
        wt[(size_t)p * 9 + blockIdx.x] = st;
        wq[(size_t)p * 9 + blockIdx.x] = sq;
    }
}

// ---------------- out-GEMM: R3s[z][p][c] = sum_{q chunk} W[p][q]*bg[c][q] ---
__global__ __launch_bounds__(256)
void og_kernel(const u8* __restrict__ Wm, const u8* __restrict__ Bc,
               float* __restrict__ R3s)
{
    __shared__ __align__(16) u8 As[64 * 128];
    __shared__ __align__(16) u8 Bs[128 * 128];
    const int tid  = threadIdx.x;
    const int wid  = tid >> 6;
    const int lane = tid & 63;
    const int wm = (wid >> 1) * 32;
    const int wn = (wid & 1) * 64;
    const size_t bm = (size_t)blockIdx.x * 64;
    const int kbeg = blockIdx.y * 1152;

    f32x4 acc[2][4];
#pragma unroll
    for (int i = 0; i < 2; ++i)
#pragma unroll
        for (int j = 0; j < 4; ++j)
            acc[i][j] = (f32x4){0.f, 0.f, 0.f, 0.f};

    const int lrow = lane >> 3;
    const int lcb  = ((lane & 7) << 4) ^ ((lrow & 7) << 4);
    const u8* gA = Wm + (bm + wid * 16 + lrow) * (size_t)9216 + lcb;
    const u8* gB = Bc + (wid * 32 + lrow) * (size_t)9216 + lcb;
    u8* lA = As + (size_t)(wid * 16) * 128;
    u8* lB = Bs + (size_t)(wid * 32) * 128;
    const size_t rstep = (size_t)9216 * 8;
    const int lm = lane & 15, lk = lane >> 4;

    for (int k0 = kbeg; k0 < kbeg + 1152; k0 += 128) {
        __syncthreads();
#pragma unroll
        for (int j = 0; j < 2; ++j)
            GLOAD16(gA + j * rstep + k0, lA + j * 1024);
#pragma unroll
        for (int j = 0; j < 4; ++j)
            GLOAD16(gB + j * rstep + k0, lB + j * 1024);
        __syncthreads();

        long2v aop[2][2], bop[4][2];
#pragma unroll
        for (int f = 0; f < 2; ++f) {
            int ma = wm + f * 16 + lm;
            int sw = (ma & 7) << 4;
            const u8* pr = As + ma * 128;
            aop[f][0] = *(const long2v*)(pr + ((lk * 32) ^ sw));
            aop[f][1] = *(const long2v*)(pr + ((lk * 32 + 16) ^ sw));
        }
#pragma unroll
        for (int f = 0; f < 4; ++f) {
            int nb = wn + f * 16 + lm;
            int sw = (nb & 7) << 4;
            const u8* pr = Bs + nb * 128;
            bop[f][0] = *(const long2v*)(pr + ((lk * 32) ^ sw));
            bop[f][1] = *(const long2v*)(pr + ((lk * 32 + 16) ^ sw));
        }
#pragma unroll
        for (int ks = 0; ks < 4; ++ks)
#pragma unroll
            for (int fm = 0; fm < 2; ++fm)
#pragma unroll
                for (int fn = 0; fn < 4; ++fn)
                    acc[fm][fn] = __builtin_amdgcn_mfma_f32_16x16x32_bf8_fp8(
                        aop[fm][ks >> 1][ks & 1], bop[fn][ks >> 1][ks & 1],
                        acc[fm][fn], 0, 0, 0);
    }

    float* out = R3s + (size_t)blockIdx.y * 9216 * 128;
#pragma unroll
    for (int fm = 0; fm < 2; ++fm)
#pragma unroll
        for (int fn = 0; fn < 4; ++fn)
#pragma unroll
            for (int i = 0; i < 4; ++i) {
                int r = wm + fm * 16 + ((lane >> 4) * 4) + i;
                int c = wn + fn * 16 + (lane & 15);
                out[(bm + r) * (size_t)128 + c] = acc[fm][fn][i];
            }
}

// ---------------- sum partials * ratio(inline) + mask + upsample -> cl bf16 -
__global__ void up_sum_kernel(const float* __restrict__ R3s,
                              const float* __restrict__ wt, const float* __restrict__ wq,
                              const float* __restrict__ mask, u16* __restrict__ upCL)
{
    int idx = blockIdx.x * 256 + threadIdx.x;   // 9216 * 16
    if (idx >= 147456) return;
    int p = idx >> 4, cs = (idx & 15) * 8;
    int y = p / 96, x = p - y * 96;
    float st = 0.f, sq = 0.f;
#pragma unroll
    for (int j = 0; j < 9; ++j) {
        st += wt[(size_t)p * 9 + j];
        sq += wq[(size_t)p * 9 + j];
    }
    float ratio = (sq > 0.f) ? st / sq : 0.f;
    float m = mask[(size_t)(2 * y) * 192 + 2 * x] * ratio;
    float acc[8];
#pragma unroll
    for (int j = 0; j < 8; ++j) acc[j] = 0.f;
#pragma unroll
    for (int z = 0; z < 8; ++z) {
        const float* rp = R3s + (size_t)z * 9216 * 128 + (size_t)p * 128 + cs;
        float4 a = *(const float4*)rp;
        float4 b = *(const float4*)(rp + 4);
        acc[0] += a.x; acc[1] += a.y; acc[2] += a.z; acc[3] += a.w;
        acc[4] += b.x; acc[5] += b.y; acc[6] += b.z; acc[7] += b.w;
    }
    u16 ov[8];
#pragma unroll
    for (int j = 0; j < 8; ++j) ov[j] = f2bf(acc[j] * m);
    short8v v = *(short8v*)ov;
    size_t r0 = ((size_t)(2 * y) * 192 + 2 * x) * 128 + cs;
    size_t r1 = ((size_t)(2 * y + 1) * 192 + 2 * x) * 128 + cs;
    *(short8v*)(upCL + r0)        = v;
    *(short8v*)(upCL + r0 + 128)  = v;
    *(short8v*)(upCL + r1)        = v;
    *(short8v*)(upCL + r1 + 128)  = v;
}

// ---------------------------------------------------------------------------
extern "C" void kernel_launch(void* const* d_in, const int* in_sizes, int n_in,
                              void* d_out, int out_size, void* d_ws, size_t ws_size,
                              hipStream_t stream)
{
    const float* x    = (const float*)d_in[0];
    const float* mask = (const float*)d_in[1];
    const float* w[8];
    const float* b[8];
    for (int i = 0; i < 8; ++i) {
        w[i] = (const float*)d_in[2 + 2 * i];
        b[i] = (const float*)d_in[3 + 2 * i];
    }
    char* ws = (char*)d_ws;
    dim3 blk(256);

    // byte offsets (identical to round 16-20; peak 188.4 MB, proven safe)
    const size_t U_H1CL = 0;
    const size_t U_H2   = 37748736;
    const size_t U_H3   = 47185920;
    const size_t U_H4   = 66060288;
    const size_t U_H5   = 75497472;
    const size_t U_H6   = 84934656;
    const size_t U_FGC  = 0;
    const size_t U_BGC  = 2359296;
    const size_t B_BGC8 = 4718592;
    const size_t B_G    = 15335424;
    const size_t B_P8   = 100270080;
    const size_t B_W    = 15335424;
    const size_t F_R3S  = 100270080;
    const size_t U_UPCL = 138018816;
    const size_t U_H7   = 147456000;
    const size_t F_H8   = 156893184;
    const size_t U_WP1  = 185204736;
    const size_t U_WP2  = 185212928;
    const size_t U_WP3  = 185231360;
    const size_t U_WP4  = 185268224;
    const size_t U_WP5  = 185415680;
    const size_t U_WP6  = 185710592;
    const size_t U_WP7  = 186005504;
    const size_t U_WP8  = 186300416;
    const size_t D_RED  = 186595328;
    const size_t F_SCALE= 186927104;
    const size_t F_RS   = 186927360;
    const size_t F_INV  = 186964224;
    const size_t F_WT   = 187001088;
    const size_t F_WQ   = 187664640;

    u16* h1cl   = (u16*)(ws + U_H1CL);
    u16* h2     = (u16*)(ws + U_H2);
    u16* h3     = (u16*)(ws + U_H3);
    u16* h4     = (u16*)(ws + U_H4);
    u16* h5     = (u16*)(ws + U_H5);
    u16* h6     = (u16*)(ws + U_H6);
    u16* fgC    = (u16*)(ws + U_FGC);
    u16* bgC    = (u16*)(ws + U_BGC);
    u8*  bgC8   = (u8*)(ws + B_BGC8);
    u8*  G      = (u8*)(ws + B_G);
    u8*  P8     = (u8*)(ws + B_P8);
    u8*  Wm     = (u8*)(ws + B_W);
    float* R3s  = (float*)(ws + F_R3S);
    u16* upCL   = (u16*)(ws + U_UPCL);
    u16* h7     = (u16*)(ws + U_H7);
    float* h8   = (float*)(ws + F_H8);
    u16* wp1    = (u16*)(ws + U_WP1);
    u16* wp2    = (u16*)(ws + U_WP2);
    u16* wp3    = (u16*)(ws + U_WP3);
    u16* wp4    = (u16*)(ws + U_WP4);
    u16* wp5    = (u16*)(ws + U_WP5);
    u16* wp6    = (u16*)(ws + U_WP6);
    u16* wp7    = (u16*)(ws + U_WP7);
    u16* wp8    = (u16*)(ws + U_WP8);
    double* red = (double*)(ws + D_RED);
    float* scale= (float*)(ws + F_SCALE);
    float* rs   = (float*)(ws + F_RS);
    float* inv  = (float*)(ws + F_INV);
    float* wt   = (float*)(ws + F_WT);
    float* wq   = (float*)(ws + F_WQ);

    // ---- prepack (one launch) ----
    pack_all_kernel<<<dim3(2716), blk, 0, stream>>>(
        w[0], w[1], w[2], w[3], w[4], w[5], w[6], w[7],
        wp1, wp2, wp3, wp4, wp5, wp6, wp7, wp8);

    // ---- conv front-end ----
    conv1_mfma_kernel<<<dim3(48, 96), blk, 0, stream>>>(x, wp1, b[0], h1cl);
    mfma_conv_kernel<4, 1, 2, 2, 2, 32, 32, 1, 0><<<dim3(24, 48), blk, 0, stream>>>(
        h1cl, wp2, b[1], h2, 768, 768, 384, 384, 32);
    mfma_conv_kernel<4, 2, 2, 2, 1, 32, 32, 1, 0><<<dim3(24, 48), blk, 0, stream>>>(
        h2, wp3, b[2], h3, 384, 384, 384, 384, 64);
    mfma_conv_kernel<4, 1, 2, 2, 2, 64, 32, 1, 0><<<dim3(12, 24, 4), blk, 0, stream>>>(
        h3, wp4, b[3], h4, 384, 384, 192, 192, 128);
    mfma_conv_kernel<4, 1, 2, 2, 1, 128, 128, 1, 0><<<dim3(12, 24, 4), blk, 0, stream>>>(
        h4, wp5, b[4], h5, 192, 192, 192, 192, 128);
    mfma_conv_kernel<4, 1, 2, 2, 1, 128, 128, 0, 0><<<dim3(12, 24, 4), blk, 0, stream>>>(
        h5, wp6, b[5], h6, 192, 192, 192, 192, 128);

    // ---- attention inputs (one launch) ----
    build_att_kernel<<<dim3(1152), blk, 0, stream>>>(h6, mask, fgC, bgC, bgC8);

    // ---- G (K=128 Gram, e5m2, x1/8) ----
    g_gemm_kernel<<<dim3(72, 72), blk, 0, stream>>>(fgC, bgC, G);

    // ---- stencil 1: S8 + Frobenius partials -> scale ----
    sstencil_kernel<<<dim3(9, 2304), blk, 0, stream>>>(G, P8, red);
    sumsq_stage2<<<dim3(1), blk, 0, stream>>>(red, 20736, scale);

    // ---- exp in-place (linear) + rowsums -> inv ----
    exp_rows_kernel<<<dim3(2304), blk, 0, stream>>>(P8, scale, rs);
    inv_kernel<<<dim3(36), blk, 0, stream>>>(rs, inv);

    // ---- stencil 2: W (e5m2, k-permuted) + quantization-ratio partials ----
    wstencil2_kernel<<<dim3(9, 2304), blk, 0, stream>>>(P8, inv, Wm, wt, wq);

    // ---- out-GEMM (bf8 x fp8, split-K 8) -> partial R3s ----
    og_kernel<<<dim3(144, 8), blk, 0, stream>>>(Wm, bgC8, R3s);

    // ---- sum partials * ratio + mask + upsample -> channels-last bf16 ----
    up_sum_kernel<<<dim3(576), blk, 0, stream>>>(R3s, wt, wq, mask, upCL);

    // ---- back-end convs ----
    mfma_conv_kernel<4, 1, 2, 2, 1, 128, 128, 1, 0><<<dim3(12, 24, 4), blk, 0, stream>>>(
        upCL, wp7, b[6], h7, 192, 192, 192, 192, 128);
    mfma_conv_kernel<4, 1, 2, 2, 1, 128, 128, 1, 1><<<dim3(12, 24, 4), blk, 0, stream>>>(
        h7, wp8, b[7], h8, 192, 192, 192, 192, 128);
    cl2p_kernel<<<dim3(1152), blk, 0, stream>>>(h8, (float*)d_out);
}

// Round 22
// 511.662 us; speedup vs baseline: 2.2978x; 1.0120x over previous
//
#include <hip/hip_runtime.h>
#include <hip/hip_fp16.h>
#include <math.h>

// ---------------------------------------------------------------------------
// Round 21->22: conv8 writes planar fp32 directly to d_out (OUTMODE=2),
// deleting the h8 buffer and the cl2p transpose dispatch. Everything else
// identical to round 21 (517.8 us, absmax 0.0625).
// ---------------------------------------------------------------------------

typedef unsigned short u16;
typedef unsigned char u8;
typedef short short4v __attribute__((ext_vector_type(4)));
typedef short short8v __attribute__((ext_vector_type(8)));
typedef float f32x4 __attribute__((ext_vector_type(4)));
typedef long long2v __attribute__((ext_vector_type(2)));

__device__ __forceinline__ u16 f2bf(float f) {
    unsigned u = __float_as_uint(f);
    return (u16)((u + 0x7FFF + ((u >> 16) & 1)) >> 16);
}
__device__ __forceinline__ float bf2f(u16 h) {
    return __uint_as_float(((unsigned)h) << 16);
}
__device__ __forceinline__ u8 f2e5m2(float f) {
    unsigned short hb = __half_as_ushort(__float2half(f));
    unsigned rem = hb & 0xFF;
    unsigned b = hb >> 8;
    b += (rem > 0x80u) || (rem == 0x80u && (b & 1u));
    return (u8)b;
}
__device__ __forceinline__ float e5m2f(unsigned b) {
    return __half2float(__ushort_as_half((unsigned short)(b << 8)));
}
__device__ __forceinline__ u8 f2e4m3(float f) {
    unsigned u = __float_as_uint(f);
    unsigned s = (u >> 24) & 0x80u;
    unsigned a = u & 0x7FFFFFFFu;
    if (a >= 0x43E00000u) return (u8)(s | 0x7Eu);
    int e = (int)(a >> 23) - 127;
    if (e >= -6) {
        unsigned keep = (a >> 20) & 7u;
        unsigned rem  = a & 0xFFFFFu;
        keep += (rem > 0x80000u) || (rem == 0x80000u && (keep & 1u));
        unsigned e4 = (unsigned)(e + 7);
        if (keep == 8u) { keep = 0u; ++e4; }
        if (e4 >= 15u && keep >= 7u) return (u8)(s | 0x7Eu);
        return (u8)(s | (e4 << 3) | keep);
    }
    float q = __uint_as_float(a) * 512.f;
    int m = (int)rintf(q);
    if (m >= 8) return (u8)(s | 0x08u);
    return (u8)(s | (unsigned)m);
}
__device__ __forceinline__ int perm8(int o8) { return ((o8 & 3) << 2) | (o8 >> 2); }

#define GLOAD16(g, l) __builtin_amdgcn_global_load_lds(                      \
    (const __attribute__((address_space(1))) void*)(g),                      \
    (__attribute__((address_space(3))) void*)(l), 16, 0, 0)

#define E5M2_UNPACK(dst, src32)                                              \
    dst[0] = __builtin_amdgcn_perm(0u, (src32), 0x010C000Cu);                \
    dst[1] = __builtin_amdgcn_perm(0u, (src32), 0x030C020Cu);

__device__ __forceinline__ unsigned e5m2_round2(unsigned h) {
    return h + 0x007F007Fu + ((h >> 8) & 0x00010001u);
}

// shifted 16B load: bytes [base16+ex, base16+16+ex), ex in {-1,0,1} (folded)
__device__ __forceinline__ void load16_sh(const u8* base16, int ex, unsigned d[4]) {
    uint4 v = *(const uint4*)base16;
    if (ex == 0) {
        d[0] = v.x; d[1] = v.y; d[2] = v.z; d[3] = v.w;
    } else if (ex == 1) {
        unsigned b = *(const unsigned*)(base16 + 16);
        d[0] = (v.x >> 8) | (v.y << 24);
        d[1] = (v.y >> 8) | (v.z << 24);
        d[2] = (v.z >> 8) | (v.w << 24);
        d[3] = (v.w >> 8) | (b << 24);
    } else {
        unsigned b = *(const unsigned*)(base16 - 4);
        d[0] = (b >> 24) | (v.x << 8);
        d[1] = (v.x >> 24) | (v.y << 8);
        d[2] = (v.y >> 24) | (v.z << 8);
        d[3] = (v.z >> 24) | (v.w << 8);
    }
}

// ---------------- unified weight prepack (all 8 layers, one launch) ---------
__device__ __forceinline__ void pack_generic(int l, const float* __restrict__ w,
                                             u16* __restrict__ wp, int IC)
{
    int oc = l / (9 * IC);
    int r  = l - oc * 9 * IC;
    int tap = r / IC;
    int ic  = r - tap * IC;
    wp[l] = f2bf(w[((size_t)oc * IC + ic) * 9 + tap]);
}

__global__ void pack_all_kernel(const float* __restrict__ w1, const float* __restrict__ w2,
                                const float* __restrict__ w3, const float* __restrict__ w4,
                                const float* __restrict__ w5, const float* __restrict__ w6,
                                const float* __restrict__ w7, const float* __restrict__ w8,
                                u16* __restrict__ wp1, u16* __restrict__ wp2,
                                u16* __restrict__ wp3, u16* __restrict__ wp4,
                                u16* __restrict__ wp5, u16* __restrict__ wp6,
                                u16* __restrict__ wp7, u16* __restrict__ wp8)
{
    int idx = blockIdx.x * 256 + threadIdx.x;
    if (idx < 4096) {
        int oc = idx >> 7, k = idx & 127;
        int tap = k >> 2, ic = k & 3;
        u16 v = 0;
        if (tap < 25 && ic < 3) v = f2bf(w1[oc * 75 + ic * 25 + tap]);
        wp1[idx] = v;
    } else if (idx < 13312)  pack_generic(idx - 4096,   w2, wp2, 32);
    else if (idx < 31744)    pack_generic(idx - 13312,  w3, wp3, 32);
    else if (idx < 105472)   pack_generic(idx - 31744,  w4, wp4, 64);
    else if (idx < 252928)   pack_generic(idx - 105472, w5, wp5, 128);
    else if (idx < 400384)   pack_generic(idx - 252928, w6, wp6, 128);
    else if (idx < 547840)   pack_generic(idx - 400384, w7, wp7, 128);
    else if (idx < 695296)   pack_generic(idx - 547840, w8, wp8, 128);
}

// ---------------- conv1 MFMA: 3->32, 5x5, s1, reflect pad2, ELU -------------
__global__ __launch_bounds__(256)
void conv1_mfma_kernel(const float* __restrict__ x, const u16* __restrict__ wp1,
                       const float* __restrict__ bias, u16* __restrict__ out)
{
    __shared__ __align__(16) u16 sIn[12 * 20 * 4];
    const int tid = threadIdx.x;
    const int lane = tid & 63;
    const int w = tid >> 6;
    const int lm = lane & 15;
    const int lk = lane >> 4;
    const int oy0 = blockIdx.y * 8, ox0 = blockIdx.x * 16;

    for (int u = tid; u < 240; u += 256) {
        int yt = u / 20, xt = u - yt * 20;
        int gy = oy0 - 2 + yt; gy = gy < 0 ? -gy : (gy >= 768 ? 1534 - gy : gy);
        int gx = ox0 - 2 + xt; gx = gx < 0 ? -gx : (gx >= 768 ? 1534 - gx : gx);
        const float* xp = x + (size_t)gy * 768 + gx;
        u16 v[4];
        v[0] = f2bf(xp[0]);
        v[1] = f2bf(xp[589824]);
        v[2] = f2bf(xp[1179648]);
        v[3] = 0;
        *(short4v*)(sIn + u * 4) = *(short4v*)v;
    }
    int aoff[4][2];
#pragma unroll
    for (int ks = 0; ks < 4; ++ks) {
        int t0 = ks * 8 + lk * 2;
        int t1 = t0 + 1;
        if (t0 > 24) t0 = 24;
        if (t1 > 24) t1 = 24;
        int dy0 = t0 / 5, dx0 = t0 - 5 * dy0;
        int dy1 = t1 / 5, dx1 = t1 - 5 * dy1;
        aoff[ks][0] = (dy0 * 20 + dx0 + lm) * 4;
        aoff[ks][1] = (dy1 * 20 + dx1 + lm) * 4;
    }
    __syncthreads();

    f32x4 acc[2][2];
#pragma unroll
    for (int i = 0; i < 2; ++i)
#pragma unroll
        for (int j = 0; j < 2; ++j) acc[i][j] = (f32x4){0.f, 0.f, 0.f, 0.f};

#pragma unroll
    for (int ks = 0; ks < 4; ++ks) {
        short8v a[2], b[2];
#pragma unroll
        for (int fm = 0; fm < 2; ++fm) {
            int base = (w * 2 + fm) * 80;
            short4v lo = *(const short4v*)(sIn + base + aoff[ks][0]);
            short4v hi = *(const short4v*)(sIn + base + aoff[ks][1]);
            short8v av;
            av[0] = lo[0]; av[1] = lo[1]; av[2] = lo[2]; av[3] = lo[3];
            av[4] = hi[0]; av[5] = hi[1]; av[6] = hi[2]; av[7] = hi[3];
            a[fm] = av;
        }
#pragma unroll
        for (int fn = 0; fn < 2; ++fn)
            b[fn] = *(const short8v*)(wp1 + (size_t)(fn * 16 + lm) * 128 + ks * 32 + lk * 8);
#pragma unroll
        for (int fm = 0; fm < 2; ++fm)
#pragma unroll
            for (int fn = 0; fn < 2; ++fn)
                acc[fm][fn] = __builtin_amdgcn_mfma_f32_16x16x32_bf16(
                    a[fm], b[fn], acc[fm][fn], 0, 0, 0);
    }

#pragma unroll
    for (int fm = 0; fm < 2; ++fm) {
        int gy = oy0 + w * 2 + fm;
#pragma unroll
        for (int fn = 0; fn < 2; ++fn) {
            int oc = fn * 16 + lm;
            float bv = bias[oc];
#pragma unroll
            for (int i = 0; i < 4; ++i) {
                int xx = lk * 4 + i;
                float v = acc[fm][fn][i] + bv;
                v = v > 0.f ? v : expm1f(v);
                out[((size_t)gy * 768 + ox0 + xx) * 32 + oc] = f2bf(v);
            }
        }
    }
}

// ---------------- MFMA implicit-GEMM conv (3x3, reflect pad 1) --------------
// OUTMODE: 0 = channels-last bf16, 1 = channels-last fp32, 2 = planar fp32
template<int FM, int FN, int NWM, int NWN, int S, int IC, int ICC, int ACT, int OUTMODE>
__global__ __launch_bounds__(256)
void mfma_conv_kernel(const u16* __restrict__ in, const u16* __restrict__ wgtP,
                      const float* __restrict__ bias, void* __restrict__ out,
                      int H, int W, int Ho, int Wo, int OC)
{
    constexpr int TY = 7 * S + 3;
    constexpr int TX = 15 * S + 3;
    constexpr int NSLOT = ICC / 8;
    constexpr int SWMSK = NSLOT - 1;
    constexpr int KTOT = 9 * IC;
    __shared__ __align__(16) u16 sIn[TY * TX * ICC];

    const int tid  = threadIdx.x;
    const int lane = tid & 63;
    const int wid  = tid >> 6;
    const int wmi  = wid / NWN;
    const int wni  = wid % NWN;
    const int lm   = lane & 15;
    const int lk   = lane >> 4;
    const int noff = blockIdx.z * (NWN * FN * 16);

    f32x4 acc[FM][FN];
#pragma unroll
    for (int i = 0; i < FM; ++i)
#pragma unroll
        for (int j = 0; j < FN; ++j) acc[i][j] = (f32x4){0.f, 0.f, 0.f, 0.f};

    const int iy0 = blockIdx.y * 8 * S - 1;
    const int ix0 = blockIdx.x * 16 * S - 1;

    for (int c0 = 0; c0 < IC; c0 += ICC) {
        if (c0) __syncthreads();
        for (int u = tid; u < TY * TX * NSLOT; u += 256) {
            int yt = u / (TX * NSLOT);
            int r  = u - yt * (TX * NSLOT);
            int xt = r / NSLOT;
            int sl = r - xt * NSLOT;
            int gy = iy0 + yt; gy = gy < 0 ? -gy : (gy >= H ? 2 * H - 2 - gy : gy);
            int gx = ix0 + xt; gx = gx < 0 ? -gx : (gx >= W ? 2 * W - 2 - gx : gx);
            *(short8v*)((char*)sIn + (size_t)((yt * TX + xt) * NSLOT + (sl ^ (xt & SWMSK))) * 16) =
                *(const short8v*)(in + ((size_t)gy * W + gx) * IC + c0 + sl * 8);
        }
        __syncthreads();
#pragma unroll
        for (int tap = 0; tap < 9; ++tap) {
            const int dy = tap / 3, dx = tap % 3;
#pragma unroll
            for (int icw = 0; icw < ICC / 32; ++icw) {
                short8v a[FM], b[FN];
#pragma unroll
                for (int fm = 0; fm < FM; ++fm) {
                    int yt = (wmi * FM + fm) * S + dy;
                    int xt = lm * S + dx;
                    a[fm] = *(const short8v*)((const char*)sIn +
                        (size_t)((yt * TX + xt) * NSLOT + ((icw * 4 + lk) ^ (xt & SWMSK))) * 16);
                }
#pragma unroll
                for (int fn = 0; fn < FN; ++fn) {
                    int n = noff + wni * FN * 16 + fn * 16 + lm;
                    b[fn] = *(const short8v*)(wgtP + (size_t)n * KTOT + tap * IC + c0 + icw * 32 + lk * 8);
                }
#pragma unroll
                for (int fm = 0; fm < FM; ++fm)
#pragma unroll
                    for (int fn = 0; fn < FN; ++fn)
                        acc[fm][fn] = __builtin_amdgcn_mfma_f32_16x16x32_bf16(
                            a[fm], b[fn], acc[fm][fn], 0, 0, 0);
            }
        }
    }

#pragma unroll
    for (int fm = 0; fm < FM; ++fm) {
        int y = blockIdx.y * 8 + wmi * FM + fm;
#pragma unroll
        for (int fn = 0; fn < FN; ++fn) {
            int oc = noff + wni * FN * 16 + fn * 16 + lm;
            float bv = bias[oc];
            float ov[4];
#pragma unroll
            for (int i = 0; i < 4; ++i) {
                float v = acc[fm][fn][i] + bv;
                if (ACT == 0) v = v > 0.f ? v : 0.f;
                else          v = v > 0.f ? v : expm1f(v);
                ov[i] = v;
            }
            int x = blockIdx.x * 16 + lk * 4;
            if (OUTMODE == 2) {
                // planar fp32: contiguous 16B per thread along x
                *(float4*)((float*)out + (size_t)oc * (Ho * Wo) + (size_t)y * Wo + x) =
                    *(float4*)ov;
            } else {
#pragma unroll
                for (int i = 0; i < 4; ++i) {
                    size_t o = ((size_t)y * Wo + x + i) * OC + oc;
                    if (OUTMODE == 1) ((float*)out)[o] = ov[i];
                    else              ((u16*)out)[o]   = f2bf(ov[i]);
                }
            }
        }
    }
}

// ---------------- merged attention-input builder ----------------------------
__global__ void build_att_kernel(const u16* __restrict__ h6, const float* __restrict__ mask,
                                 u16* __restrict__ fgC, u16* __restrict__ bgC,
                                 u8* __restrict__ bgC8)
{
    if (blockIdx.x < 576) {
        int idx = blockIdx.x * 256 + threadIdx.x;   // 9216*16
        int q = idx >> 4, cs = (idx & 15) * 8;
        int qy = q / 96, qx = q - qy * 96;
        const u16* src = h6 + ((size_t)(2 * qy) * 192 + 2 * qx) * 128 + cs;
        float m = mask[(size_t)(2 * qy) * 192 + 2 * qx];
        short8v v = *(const short8v*)src;
        u16 fo[8];
#pragma unroll
        for (int j = 0; j < 8; ++j) fo[j] = f2bf(bf2f((u16)v[j]) * m);
        *(short8v*)(bgC + (size_t)q * 128 + cs) = v;
        *(short8v*)(fgC + (size_t)q * 128 + cs) = *(short8v*)fo;
    } else {
        int idx = (blockIdx.x - 576) * 256 + threadIdx.x;   // 128*1152 chunks
        int c = idx / 1152, qc = idx - c * 1152;
        int q0 = qc << 3;
        int qy = q0 / 96, qx0 = q0 - qy * 96;
        const u16* row = h6 + (size_t)(2 * qy) * 192 * 128 + c;
        unsigned long long ow = 0;
#pragma unroll
        for (int j = 0; j < 8; ++j) {
            float v = bf2f(row[(size_t)(2 * (qx0 + j)) * 128]);
            ow |= (unsigned long long)f2e4m3(v) << (8 * j);
        }
        *(unsigned long long*)(bgC8 + (size_t)c * 9216 + (q0 & ~127) + perm8(qc & 15) * 8) = ow;
    }
}

// ---------------- G-GEMM: G[a][b] = 1/8 * sum_c fgC[a][c]*bgC[b][c] ---------
__global__ __launch_bounds__(256)
void g_gemm_kernel(const u16* __restrict__ A, const u16* __restrict__ B,
                   u8* __restrict__ G)
{
    __shared__ __align__(16) u16 As[128 * 64];
    __shared__ __align__(16) u16 Bs[128 * 64];
    const int tid  = threadIdx.x;
    const int wid  = tid >> 6;
    const int lane = tid & 63;
    const int wm = (wid >> 1) * 64;
    const int wn = (wid & 1) * 64;
    const size_t bm = (size_t)blockIdx.y * 128;
    const size_t bn = (size_t)blockIdx.x * 128;

    f32x4 acc[4][4];
#pragma unroll
    for (int i = 0; i < 4; ++i)
#pragma unroll
        for (int j = 0; j < 4; ++j)
            acc[i][j] = (f32x4){0.f, 0.f, 0.f, 0.f};

    const int lrow = lane >> 3;
    const int lcb  = ((lane & 7) << 4) ^ ((lrow & 7) << 4);
    const char* gA = (const char*)A + ((bm + wid * 32 + lrow) * (size_t)128) * 2 + lcb;
    const char* gB = (const char*)B + ((bn + wid * 32 + lrow) * (size_t)128) * 2 + lcb;
    char* lA = (char*)As + (size_t)(wid * 32) * 128;
    char* lB = (char*)Bs + (size_t)(wid * 32) * 128;
    const size_t rs8 = (size_t)128 * 16;

    for (int k0 = 0; k0 < 128; k0 += 64) {
        __syncthreads();
#pragma unroll
        for (int j = 0; j < 4; ++j) {
            GLOAD16(gA + j * rs8 + (size_t)k0 * 2, lA + j * 1024);
            GLOAD16(gB + j * rs8 + (size_t)k0 * 2, lB + j * 1024);
        }
        __syncthreads();
#pragma unroll
        for (int ks = 0; ks < 2; ++ks) {
            short8v a[4], b[4];
#pragma unroll
            for (int f = 0; f < 4; ++f) {
                int ma = wm + f * 16 + (lane & 15);
                int kba = (ks * 64 + ((lane >> 4) * 16)) ^ ((ma & 7) << 4);
                a[f] = *(const short8v*)((const char*)As + ma * 128 + kba);
                int nb = wn + f * 16 + (lane & 15);
                int kbb = (ks * 64 + ((lane >> 4) * 16)) ^ ((nb & 7) << 4);
                b[f] = *(const short8v*)((const char*)Bs + nb * 128 + kbb);
            }
#pragma unroll
            for (int fm = 0; fm < 4; ++fm)
#pragma unroll
                for (int fn = 0; fn < 4; ++fn)
                    acc[fm][fn] = __builtin_amdgcn_mfma_f32_16x16x32_bf16(
                        a[fm], b[fn], acc[fm][fn], 0, 0, 0);
        }
    }

#pragma unroll
    for (int fm = 0; fm < 4; ++fm)
#pragma unroll
        for (int fn = 0; fn < 4; ++fn)
#pragma unroll
            for (int i = 0; i < 4; ++i) {
                int r = wm + fm * 16 + ((lane >> 4) * 4) + i;
                int c = wn + fn * 16 + (lane & 15);
                G[(bm + r) * (size_t)9216 + bn + c] = f2e5m2(0.125f * acc[fm][fn][i]);
            }
}

// ---------------- stencil 1: S8 = stencil(G) + sum S^2; 16 q/thread ---------
__global__ __launch_bounds__(256)
void sstencil_kernel(const u8* __restrict__ G, u8* __restrict__ S8,
                     double* __restrict__ partial)
{
    const int wid  = threadIdx.x >> 6;
    const int lane = threadIdx.x & 63;
    const int p = blockIdx.y * 4 + wid;
    const int py = p / 96, px = p - py * 96;
    const int q0 = blockIdx.x * 1024 + lane * 16;
    const int qy = q0 / 96, qx0 = q0 - qy * 96;

    __half2 hz = __floats2half2_rn(0.f, 0.f);
    __half2 hacc[8] = {hz, hz, hz, hz, hz, hz, hz, hz};

#pragma unroll
    for (int ey = -1; ey <= 1; ++ey) {
#pragma unroll
        for (int ex = -1; ex <= 1; ++ex) {
            if ((unsigned)(py + ey) >= 96u || (unsigned)(px + ex) >= 96u) continue;
            if ((unsigned)(qy + ey) >= 96u) continue;
            const int e = ey * 96 + ex;
            const u8* base16 = G + (size_t)(p + e) * 9216 + q0 + (e - ex);
            unsigned d[4];
            load16_sh(base16, ex, d);
            if (ex == 1 && qx0 == 80) d[3] &= 0x00FFFFFFu;
            if (ex == -1 && qx0 == 0) d[0] &= 0xFFFFFF00u;
#pragma unroll
            for (int i = 0; i < 4; ++i) {
                unsigned pk[2];
                E5M2_UNPACK(pk, d[i]);
                hacc[2 * i]     = __hadd2(hacc[2 * i],     *(__half2*)&pk[0]);
                hacc[2 * i + 1] = __hadd2(hacc[2 * i + 1], *(__half2*)&pk[1]);
            }
        }
    }

    unsigned t[8];
    double s2 = 0.0;
#pragma unroll
    for (int i = 0; i < 8; ++i) {
        unsigned h = *(unsigned*)&hacc[i];
        t[i] = e5m2_round2(h);
        float2 f2 = __half22float2(hacc[i]);
        s2 += (double)f2.x * f2.x + (double)f2.y * f2.y;
    }
    uint4 ow;
    ow.x = __builtin_amdgcn_perm(t[1], t[0], 0x07050301u);
    ow.y = __builtin_amdgcn_perm(t[3], t[2], 0x07050301u);
    ow.z = __builtin_amdgcn_perm(t[5], t[4], 0x07050301u);
    ow.w = __builtin_amdgcn_perm(t[7], t[6], 0x07050301u);
    *(uint4*)(S8 + (size_t)p * 9216 + q0) = ow;

    for (int off = 32; off; off >>= 1) s2 += __shfl_down(s2, off, 64);
    __shared__ double wsum[4];
    if (lane == 0) wsum[wid] = s2;
    __syncthreads();
    if (threadIdx.x == 0)
        partial[(size_t)blockIdx.y * 9 + blockIdx.x] = wsum[0] + wsum[1] + wsum[2] + wsum[3];
}

__global__ void sumsq_stage2(const double* __restrict__ partial, int nblocks, float* __restrict__ scale)
{
    double s = 0.0;
    for (int i = threadIdx.x; i < nblocks; i += 256) s += partial[i];
    for (int off = 32; off; off >>= 1) s += __shfl_down(s, off, 64);
    __shared__ double wsum[4];
    int lane = threadIdx.x & 63, wid = threadIdx.x >> 6;
    if (lane == 0) wsum[wid] = s;
    __syncthreads();
    if (threadIdx.x == 0) {
        double nrm = sqrt(wsum[0] + wsum[1] + wsum[2] + wsum[3]);
        if (nrm < 1e-12) nrm = 1e-12;
        *scale = (float)(10.0 / nrm);
    }
}

// ---------------- exp pass: P8 = e5m2(exp(scale*S8)) in-place; 16 B/iter ----
__global__ __launch_bounds__(256)
void exp_rows_kernel(u8* __restrict__ P8, const float* __restrict__ scale_p,
                     float* __restrict__ rs)
{
    const int wid = threadIdx.x >> 6, lane = threadIdx.x & 63;
    const int p = blockIdx.x * 4 + wid;   // grid 2304
    u8* rp = P8 + (size_t)p * 9216;
    const float scale = *scale_p;
    float s = 0.f;
#pragma unroll
    for (int it = 0; it < 9; ++it) {
        uint4 v = *(uint4*)(rp + it * 1024 + lane * 16);
        unsigned dv[4] = {v.x, v.y, v.z, v.w};
        unsigned t[8];
        __half2 sacc = __floats2half2_rn(0.f, 0.f);
#pragma unroll
        for (int i = 0; i < 4; ++i) {
            unsigned pk[2];
            E5M2_UNPACK(pk, dv[i]);
#pragma unroll
            for (int j = 0; j < 2; ++j) {
                float2 f = __half22float2(*(__half2*)&pk[j]);
                __half2 eh = __floats2half2_rn(__expf(scale * f.x), __expf(scale * f.y));
                t[2 * i + j] = e5m2_round2(*(unsigned*)&eh);
                unsigned q = t[2 * i + j] & 0xFF00FF00u;
                sacc = __hadd2(sacc, *(__half2*)&q);
            }
        }
        uint4 ow;
        ow.x = __builtin_amdgcn_perm(t[1], t[0], 0x07050301u);
        ow.y = __builtin_amdgcn_perm(t[3], t[2], 0x07050301u);
        ow.z = __builtin_amdgcn_perm(t[5], t[4], 0x07050301u);
        ow.w = __builtin_amdgcn_perm(t[7], t[6], 0x07050301u);
        *(uint4*)(rp + it * 1024 + lane * 16) = ow;
        float2 sf = __half22float2(sacc);
        s += sf.x + sf.y;
    }
    for (int off = 32; off; off >>= 1) s += __shfl_down(s, off, 64);
    if (lane == 0) rs[p] = s;
}

__global__ void inv_kernel(const float* __restrict__ rs, float* __restrict__ inv)
{
    int i = blockIdx.x * 256 + threadIdx.x;
    if (i < 9216) inv[i] = 1.f / rs[i];
}

// ---------------- stencil 2: W = sum_t inv*P taps; 16 q/thread, K-PERM ------
__global__ __launch_bounds__(256)
void wstencil2_kernel(const u8* __restrict__ P8, const float* __restrict__ inv,
                      u8* __restrict__ W, float* __restrict__ wt,
                      float* __restrict__ wq)
{
    const int wid  = threadIdx.x >> 6;
    const int lane = threadIdx.x & 63;
    const int p = blockIdx.y * 4 + wid;
    const int py = p / 96, px = p - py * 96;
    const int q0 = blockIdx.x * 1024 + lane * 16;
    const int qy = q0 / 96, qx0 = q0 - qy * 96;

    __half2 hz = __floats2half2_rn(0.f, 0.f);
    __half2 hacc[8] = {hz, hz, hz, hz, hz, hz, hz, hz};

#pragma unroll
    for (int ey = -1; ey <= 1; ++ey) {
#pragma unroll
        for (int ex = -1; ex <= 1; ++ex) {
            if ((unsigned)(py + ey) >= 96u || (unsigned)(px + ex) >= 96u) continue;
            if ((unsigned)(qy + ey) >= 96u) continue;
            const int e = ey * 96 + ex;
            const u8* base16 = P8 + (size_t)(p + e) * 9216 + q0 + (e - ex);
            unsigned d[4];
            load16_sh(base16, ex, d);
            if (ex == 1 && qx0 == 80) d[3] &= 0x00FFFFFFu;
            if (ex == -1 && qx0 == 0) d[0] &= 0xFFFFFF00u;

            float iv = inv[p + e];
            __half2 iv2 = __floats2half2_rn(iv, iv);
#pragma unroll
            for (int i = 0; i < 4; ++i) {
                unsigned pk[2];
                E5M2_UNPACK(pk, d[i]);
                hacc[2 * i]     = __hfma2(*(__half2*)&pk[0], iv2, hacc[2 * i]);
                hacc[2 * i + 1] = __hfma2(*(__half2*)&pk[1], iv2, hacc[2 * i + 1]);
            }
        }
    }

    unsigned t[8];
    __half2 stacc = hz, sqacc = hz;
#pragma unroll
    for (int i = 0; i < 8; ++i) {
        unsigned h = *(unsigned*)&hacc[i];
        t[i] = e5m2_round2(h);
        stacc = __hadd2(stacc, hacc[i]);
        unsigned q = t[i] & 0xFF00FF00u;
        sqacc = __hadd2(sqacc, *(__half2*)&q);
    }
    unsigned g0 = __builtin_amdgcn_perm(t[1], t[0], 0x07050301u);
    unsigned g1 = __builtin_amdgcn_perm(t[3], t[2], 0x07050301u);
    unsigned g2 = __builtin_amdgcn_perm(t[5], t[4], 0x07050301u);
    unsigned g3 = __builtin_amdgcn_perm(t[7], t[6], 0x07050301u);
    int o8 = (q0 & 127) >> 3;
    u8* wrow = W + (size_t)p * 9216 + (q0 & ~127);
    *(unsigned long long*)(wrow + perm8(o8) * 8)     =
        (unsigned long long)g0 | ((unsigned long long)g1 << 32);
    *(unsigned long long*)(wrow + perm8(o8 + 1) * 8) =
        (unsigned long long)g2 | ((unsigned long long)g3 << 32);

    float2 stf = __half22float2(stacc);
    float2 sqf = __half22float2(sqacc);
    float st = stf.x + stf.y, sq = sqf.x + sqf.y;
    for (int off = 32; off; off >>= 1) {
        st += __shfl_down(st, off, 64);
        sq += __shfl_down(sq, off, 64);
    }
    if (lane == 0) {
        wt[(size_t)p * 9 + blockIdx.x] = st;
        wq[(size_t)p * 9 + blockIdx.x] = sq;
    }
}

// ---------------- out-GEMM: R3s[z][p][c] = sum_{q chunk} W[p][q]*bg[c][q] ---
__global__ __launch_bounds__(256)
void og_kernel(const u8* __restrict__ Wm, const u8* __restrict__ Bc,
               float* __restrict__ R3s)
{
    __shared__ __align__(16) u8 As[64 * 128];
    __shared__ __align__(16) u8 Bs[128 * 128];
    const int tid  = threadIdx.x;
    const int wid  = tid >> 6;
    const int lane = tid & 63;
    const int wm = (wid >> 1) * 32;
    const int wn = (wid & 1) * 64;
    const size_t bm = (size_t)blockIdx.x * 64;
    const int kbeg = blockIdx.y * 1152;

    f32x4 acc[2][4];
#pragma unroll
    for (int i = 0; i < 2; ++i)
#pragma unroll
        for (int j = 0; j < 4; ++j)
            acc[i][j] = (f32x4){0.f, 0.f, 0.f, 0.f};

    const int lrow = lane >> 3;
    const int lcb  = ((lane & 7) << 4) ^ ((lrow & 7) << 4);
    const u8* gA = Wm + (bm + wid * 16 + lrow) * (size_t)9216 + lcb;
    const u8* gB = Bc + (wid * 32 + lrow) * (size_t)9216 + lcb;
    u8* lA = As + (size_t)(wid * 16) * 128;
    u8* lB = Bs + (size_t)(wid * 32) * 128;
    const size_t rstep = (size_t)9216 * 8;
    const int lm = lane & 15, lk = lane >> 4;

    for (int k0 = kbeg; k0 < kbeg + 1152; k0 += 128) {
        __syncthreads();
#pragma unroll
        for (int j = 0; j < 2; ++j)
            GLOAD16(gA + j * rstep + k0, lA + j * 1024);
#pragma unroll
        for (int j = 0; j < 4; ++j)
            GLOAD16(gB + j * rstep + k0, lB + j * 1024);
        __syncthreads();

        long2v aop[2][2], bop[4][2];
#pragma unroll
        for (int f = 0; f < 2; ++f) {
            int ma = wm + f * 16 + lm;
            int sw = (ma & 7) << 4;
            const u8* pr = As + ma * 128;
            aop[f][0] = *(const long2v*)(pr + ((lk * 32) ^ sw));
            aop[f][1] = *(const long2v*)(pr + ((lk * 32 + 16) ^ sw));
        }
#pragma unroll
        for (int f = 0; f < 4; ++f) {
            int nb = wn + f * 16 + lm;
            int sw = (nb & 7) << 4;
            const u8* pr = Bs + nb * 128;
            bop[f][0] = *(const long2v*)(pr + ((lk * 32) ^ sw));
            bop[f][1] = *(const long2v*)(pr + ((lk * 32 + 16) ^ sw));
        }
#pragma unroll
        for (int ks = 0; ks < 4; ++ks)
#pragma unroll
            for (int fm = 0; fm < 2; ++fm)
#pragma unroll
                for (int fn = 0; fn < 4; ++fn)
                    acc[fm][fn] = __builtin_amdgcn_mfma_f32_16x16x32_bf8_fp8(
                        aop[fm][ks >> 1][ks & 1], bop[fn][ks >> 1][ks & 1],
                        acc[fm][fn], 0, 0, 0);
    }

    float* out = R3s + (size_t)blockIdx.y * 9216 * 128;
#pragma unroll
    for (int fm = 0; fm < 2; ++fm)
#pragma unroll
        for (int fn = 0; fn < 4; ++fn)
#pragma unroll
            for (int i = 0; i < 4; ++i) {
                int r = wm + fm * 16 + ((lane >> 4) * 4) + i;
                int c = wn + fn * 16 + (lane & 15);
                out[(bm + r) * (size_t)128 + c] = acc[fm][fn][i];
            }
}

// ---------------- sum partials * ratio(inline) + mask + upsample -> cl bf16 -
__global__ void up_sum_kernel(const float* __restrict__ R3s,
                              const float* __restrict__ wt, const float* __restrict__ wq,
                              const float* __restrict__ mask, u16* __restrict__ upCL)
{
    int idx = blockIdx.x * 256 + threadIdx.x;   // 9216 * 16
    if (idx >= 147456) return;
    int p = idx >> 4, cs = (idx & 15) * 8;
    int y = p / 96, x = p - y * 96;
    float st = 0.f, sq = 0.f;
#pragma unroll
    for (int j = 0; j < 9; ++j) {
        st += wt[(size_t)p * 9 + j];
        sq += wq[(size_t)p * 9 + j];
    }
    float ratio = (sq > 0.f) ? st / sq : 0.f;
    float m = mask[(size_t)(2 * y) * 192 + 2 * x] * ratio;
    float acc[8];
#pragma unroll
    for (int j = 0; j < 8; ++j) acc[j] = 0.f;
#pragma unroll
    for (int z = 0; z < 8; ++z) {
        const float* rp = R3s + (size_t)z * 9216 * 128 + (size_t)p * 128 + cs;
        float4 a = *(const float4*)rp;
        float4 b = *(const float4*)(rp + 4);
        acc[0] += a.x; acc[1] += a.y; acc[2] += a.z; acc[3] += a.w;
        acc[4] += b.x; acc[5] += b.y; acc[6] += b.z; acc[7] += b.w;
    }
    u16 ov[8];
#pragma unroll
    for (int j = 0; j < 8; ++j) ov[j] = f2bf(acc[j] * m);
    short8v v = *(short8v*)ov;
    size_t r0 = ((size_t)(2 * y) * 192 + 2 * x) * 128 + cs;
    size_t r1 = ((size_t)(2 * y + 1) * 192 + 2 * x) * 128 + cs;
    *(short8v*)(upCL + r0)        = v;
    *(short8v*)(upCL + r0 + 128)  = v;
    *(short8v*)(upCL + r1)        = v;
    *(short8v*)(upCL + r1 + 128)  = v;
}

// ---------------------------------------------------------------------------
extern "C" void kernel_launch(void* const* d_in, const int* in_sizes, int n_in,
                              void* d_out, int out_size, void* d_ws, size_t ws_size,
                              hipStream_t stream)
{
    const float* x    = (const float*)d_in[0];
    const float* mask = (const float*)d_in[1];
    const float* w[8];
    const float* b[8];
    for (int i = 0; i < 8; ++i) {
        w[i] = (const float*)d_in[2 + 2 * i];
        b[i] = (const float*)d_in[3 + 2 * i];
    }
    char* ws = (char*)d_ws;
    dim3 blk(256);

    // byte offsets (identical to round 16-21; peak 188.4 MB, proven safe)
    const size_t U_H1CL = 0;
    const size_t U_H2   = 37748736;
    const size_t U_H3   = 47185920;
    const size_t U_H4   = 66060288;
    const size_t U_H5   = 75497472;
    const size_t U_H6   = 84934656;
    const size_t U_FGC  = 0;
    const size_t U_BGC  = 2359296;
    const size_t B_BGC8 = 4718592;
    const size_t B_G    = 15335424;
    const size_t B_P8   = 100270080;
    const size_t B_W    = 15335424;
    const size_t F_R3S  = 100270080;
    const size_t U_UPCL = 138018816;
    const size_t U_H7   = 147456000;
    const size_t U_WP1  = 185204736;
    const size_t U_WP2  = 185212928;
    const size_t U_WP3  = 185231360;
    const size_t U_WP4  = 185268224;
    const size_t U_WP5  = 185415680;
    const size_t U_WP6  = 185710592;
    const size_t U_WP7  = 186005504;
    const size_t U_WP8  = 186300416;
    const size_t D_RED  = 186595328;
    const size_t F_SCALE= 186927104;
    const size_t F_RS   = 186927360;
    const size_t F_INV  = 186964224;
    const size_t F_WT   = 187001088;
    const size_t F_WQ   = 187664640;

    u16* h1cl   = (u16*)(ws + U_H1CL);
    u16* h2     = (u16*)(ws + U_H2);
    u16* h3     = (u16*)(ws + U_H3);
    u16* h4     = (u16*)(ws + U_H4);
    u16* h5     = (u16*)(ws + U_H5);
    u16* h6     = (u16*)(ws + U_H6);
    u16* fgC    = (u16*)(ws + U_FGC);
    u16* bgC    = (u16*)(ws + U_BGC);
    u8*  bgC8   = (u8*)(ws + B_BGC8);
    u8*  G      = (u8*)(ws + B_G);
    u8*  P8     = (u8*)(ws + B_P8);
    u8*  Wm     = (u8*)(ws + B_W);
    float* R3s  = (float*)(ws + F_R3S);
    u16* upCL   = (u16*)(ws + U_UPCL);
    u16* h7     = (u16*)(ws + U_H7);
    u16* wp1    = (u16*)(ws + U_WP1);
    u16* wp2    = (u16*)(ws + U_WP2);
    u16* wp3    = (u16*)(ws + U_WP3);
    u16* wp4    = (u16*)(ws + U_WP4);
    u16* wp5    = (u16*)(ws + U_WP5);
    u16* wp6    = (u16*)(ws + U_WP6);
    u16* wp7    = (u16*)(ws + U_WP7);
    u16* wp8    = (u16*)(ws + U_WP8);
    double* red = (double*)(ws + D_RED);
    float* scale= (float*)(ws + F_SCALE);
    float* rs   = (float*)(ws + F_RS);
    float* inv  = (float*)(ws + F_INV);
    float* wt   = (float*)(ws + F_WT);
    float* wq   = (float*)(ws + F_WQ);

    // ---- prepack (one launch) ----
    pack_all_kernel<<<dim3(2716), blk, 0, stream>>>(
        w[0], w[1], w[2], w[3], w[4], w[5], w[6], w[7],
        wp1, wp2, wp3, wp4, wp5, wp6, wp7, wp8);

    // ---- conv front-end ----
    conv1_mfma_kernel<<<dim3(48, 96), blk, 0, stream>>>(x, wp1, b[0], h1cl);
    mfma_conv_kernel<4, 1, 2, 2, 2, 32, 32, 1, 0><<<dim3(24, 48), blk, 0, stream>>>(
        h1cl, wp2, b[1], h2, 768, 768, 384, 384, 32);
    mfma_conv_kernel<4, 2, 2, 2, 1, 32, 32, 1, 0><<<dim3(24, 48), blk, 0, stream>>>(
        h2, wp3, b[2], h3, 384, 384, 384, 384, 64);
    mfma_conv_kernel<4, 1, 2, 2, 2, 64, 32, 1, 0><<<dim3(12, 24, 4), blk, 0, stream>>>(
        h3, wp4, b[3], h4, 384, 384, 192, 192, 128);
    mfma_conv_kernel<4, 1, 2, 2, 1, 128, 128, 1, 0><<<dim3(12, 24, 4), blk, 0, stream>>>(
        h4, wp5, b[4], h5, 192, 192, 192, 192, 128);
    mfma_conv_kernel<4, 1, 2, 2, 1, 128, 128, 0, 0><<<dim3(12, 24, 4), blk, 0, stream>>>(
        h5, wp6, b[5], h6, 192, 192, 192, 192, 128);

    // ---- attention inputs (one launch) ----
    build_att_kernel<<<dim3(1152), blk, 0, stream>>>(h6, mask, fgC, bgC, bgC8);

    // ---- G (K=128 Gram, e5m2, x1/8) ----
    g_gemm_kernel<<<dim3(72, 72), blk, 0, stream>>>(fgC, bgC, G);

    // ---- stencil 1: S8 + Frobenius partials -> scale ----
    sstencil_kernel<<<dim3(9, 2304), blk, 0, stream>>>(G, P8, red);
    sumsq_stage2<<<dim3(1), blk, 0, stream>>>(red, 20736, scale);

    // ---- exp in-place (linear) + rowsums -> inv ----
    exp_rows_kernel<<<dim3(2304), blk, 0, stream>>>(P8, scale, rs);
    inv_kernel<<<dim3(36), blk, 0, stream>>>(rs, inv);

    // ---- stencil 2: W (e5m2, k-permuted) + quantization-ratio partials ----
    wstencil2_kernel<<<dim3(9, 2304), blk, 0, stream>>>(P8, inv, Wm, wt, wq);

    // ---- out-GEMM (bf8 x fp8, split-K 8) -> partial R3s ----
    og_kernel<<<dim3(144, 8), blk, 0, stream>>>(Wm, bgC8, R3s);

    // ---- sum partials * ratio + mask + upsample -> channels-last bf16 ----
    up_sum_kernel<<<dim3(576), blk, 0, stream>>>(R3s, wt, wq, mask, upCL);

    // ---- back-end convs (conv8 writes planar fp32 directly to d_out) ----
    mfma_conv_kernel<4, 1, 2, 2, 1, 128, 128, 1, 0><<<dim3(12, 24, 4), blk, 0, stream>>>(
        upCL, wp7, b[6], h7, 192, 192, 192, 192, 128);
    mfma_conv_kernel<4, 1, 2, 2, 1, 128, 128, 1, 2><<<dim3(12, 24, 4), blk, 0, stream>>>(
        h7, wp8, b[7], (float*)d_out, 192, 192, 192, 192, 128);
}